// Round 3
// baseline (4028.957 us; speedup 1.0000x reference)
//
#include <hip/hip_runtime.h>

// ======================= types & helpers =======================
using u16 = unsigned short;

__device__ __forceinline__ float bf2f(u16 u) { return __uint_as_float(((unsigned)u) << 16); }
__device__ __forceinline__ u16 f2bf(float f) {  // round-to-nearest-even
  unsigned u = __float_as_uint(f);
  return (u16)((u + 0x7FFFu + ((u >> 16) & 1u)) >> 16);
}
__device__ __forceinline__ float ldv(const float* p) { return *p; }
__device__ __forceinline__ float ldv(const u16* p)   { return bf2f(*p); }
__device__ __forceinline__ void  stv(float* p, float v) { *p = v; }
__device__ __forceinline__ void  stv(u16* p, float v)   { *p = f2bf(v); }

// ======================= problem constants =======================
constexpr int cB = 4, cT = 12, cN = 2048, cF = 26;
constexpr int cHID = 128, cLF = 32, cFF = 256, cHOR = 12;
constexpr int cE = 16384;
constexpr int cR = cB * cT * cN;   // 98304
constexpr int cBT = cB * cT;       // 48
constexpr float cALPHA = 0.9f, cBETA = 0.8f, cEPS = 1e-5f;

#define FLAG_ACC  1
#define FLAG_BIAS 2
#define FLAG_RELU 4

// ======================= tiled GEMM (templated storage, f32 math) =======================
// C[m,n] = sum_k A[m,k]*B[k,n] (+bias) (+C) (relu). M%64==0, K%16==0, N guarded.
template <typename TA, typename TB, typename TC>
__global__ __launch_bounds__(256)
void gemm_tiled(const TA* __restrict__ A, const TB* __restrict__ Bm,
                TC* __restrict__ C, const float* __restrict__ bias,
                int M, int N, int K, int lda, int ldb, int ldc,
                long batchA, long batchB, long batchC, int flags)
{
  A  += (long)blockIdx.z * batchA;
  Bm += (long)blockIdx.z * batchB;
  C  += (long)blockIdx.z * batchC;
  __shared__ float As[16][64];   // [k][m]
  __shared__ float Bs[16][64];   // [k][n]
  const int tid = threadIdx.x;
  const int tx = tid & 15, ty = tid >> 4;
  const int m0 = blockIdx.x * 64, n0 = blockIdx.y * 64;
  const int ldm = tid >> 2, ldk = (tid & 3) * 4;
  const int bn = tid & 63, bk0 = tid >> 6;
  float acc[4][4] = {};

  for (int k0 = 0; k0 < K; k0 += 16) {
    {
      const TA* ap = A + (long)(m0 + ldm) * lda + k0 + ldk;
      As[ldk + 0][ldm] = ldv(ap + 0);
      As[ldk + 1][ldm] = ldv(ap + 1);
      As[ldk + 2][ldm] = ldv(ap + 2);
      As[ldk + 3][ldm] = ldv(ap + 3);
    }
    const int gn = n0 + bn;
#pragma unroll
    for (int q = 0; q < 4; ++q) {
      const int k = bk0 + q * 4;
      Bs[k][bn] = (gn < N) ? ldv(Bm + (long)(k0 + k) * ldb + gn) : 0.f;
    }
    __syncthreads();
#pragma unroll
    for (int kk = 0; kk < 16; ++kk) {
      const float4 a = *(const float4*)&As[kk][ty * 4];
      const float4 b = *(const float4*)&Bs[kk][tx * 4];
      const float av_[4] = {a.x, a.y, a.z, a.w};
      const float bv_[4] = {b.x, b.y, b.z, b.w};
#pragma unroll
      for (int i = 0; i < 4; ++i)
#pragma unroll
        for (int j = 0; j < 4; ++j)
          acc[i][j] = fmaf(av_[i], bv_[j], acc[i][j]);
    }
    __syncthreads();
  }

#pragma unroll
  for (int i = 0; i < 4; ++i) {
    const long gm = m0 + ty * 4 + i;
#pragma unroll
    for (int j = 0; j < 4; ++j) {
      const int gn = n0 + tx * 4 + j;
      if (gn < N) {
        float v = acc[i][j];
        if (flags & FLAG_BIAS) v += bias[gn];
        if (flags & FLAG_ACC)  v += ldv(&C[gm * ldc + gn]);
        if (flags & FLAG_RELU) v = fmaxf(v, 0.f);
        stv(&C[gm * ldc + gn], v);
      }
    }
  }
}

// ======================= graph preprocessing (CSR build) =======================
__global__ __launch_bounds__(256)
void edge_stats(const int* __restrict__ s, const int* __restrict__ d,
                const float* __restrict__ ew, float* degf, float* degb,
                int* cntf, int* cntb)
{
  const int e = blockIdx.x * 256 + threadIdx.x;
  atomicAdd(&degf[d[e]], ew[e]);
  atomicAdd(&degb[s[e]], ew[e]);
  atomicAdd(&cntf[d[e]], 1);
  atomicAdd(&cntb[s[e]], 1);
}

__global__ __launch_bounds__(256)
void scan2(const int* __restrict__ cf, const int* __restrict__ cb,
           int* __restrict__ rf, int* __restrict__ rb)
{
  const int* c = blockIdx.x ? cb : cf;
  int* r       = blockIdx.x ? rb : rf;
  __shared__ int part[256];
  const int t = threadIdx.x, base = t * 8;
  int loc[8]; int s = 0;
#pragma unroll
  for (int i = 0; i < 8; ++i) { loc[i] = c[base + i]; s += loc[i]; }
  part[t] = s; __syncthreads();
  if (t == 0) {
    int run = 0;
    for (int i = 0; i < 256; ++i) { const int v = part[i]; part[i] = run; run += v; }
    r[2048] = run;
  }
  __syncthreads();
  int run = part[t];
#pragma unroll
  for (int i = 0; i < 8; ++i) { r[base + i] = run; run += loc[i]; }
}

__global__ __launch_bounds__(256)
void fill_csr(const int* __restrict__ s, const int* __restrict__ d,
              const float* __restrict__ ew,
              const float* __restrict__ degf, const float* __restrict__ degb,
              const int* __restrict__ rowf, const int* __restrict__ rowb,
              int* curf, int* curb,
              int* __restrict__ colf, int* __restrict__ colb,
              float* __restrict__ wnf, float* __restrict__ wnb)
{
  const int e = blockIdx.x * 256 + threadIdx.x;
  const int si = s[e], di = d[e];
  const float w = ew[e];
  const int p = rowf[di] + atomicAdd(&curf[di], 1);
  colf[p] = si; wnf[p] = w / fmaxf(degf[di], 1e-6f);
  const int q = rowb[si] + atomicAdd(&curb[si], 1);
  colb[q] = di; wnb[q] = w / fmaxf(degb[si], 1e-6f);
}

// y[bt,n,:] = sum_j w[j]*x[bt,col[j],:]
__global__ __launch_bounds__(256)
void prop_gather(const u16* __restrict__ x, u16* __restrict__ y,
                 const int* __restrict__ rowptr, const int* __restrict__ col,
                 const float* __restrict__ w, int c)
{
  const int n = blockIdx.x, bt = blockIdx.y, ch = threadIdx.x;
  const int beg = rowptr[n], end = rowptr[n + 1];
  const u16* xb = x + (long)bt * cN * c;
  float acc = 0.f;
  for (int j = beg; j < end; ++j)
    acc = fmaf(w[j], bf2f(xb[(long)col[j] * c + ch]), acc);
  y[((long)bt * cN + n) * c + ch] = f2bf(acc);
}

// ======================= encoder: h[:, :128] = x@enc_w+enc_b+node_emb ; h[:,128:160]=lw0 ==========
__global__ __launch_bounds__(160)
void encoder(const float* __restrict__ x, const float* __restrict__ ew_,
             const float* __restrict__ eb, const float* __restrict__ ne,
             const float* __restrict__ lw, u16* __restrict__ h)
{
  __shared__ float xs[cF];
  const int tid = threadIdx.x;
  const long r0 = (long)blockIdx.x * 8;
  for (long row = r0; row < r0 + 8; ++row) {
    if (tid < cF) xs[tid] = x[row * cF + tid];
    __syncthreads();
    const int n = (int)(row % cN);
    float v;
    if (tid < cHID) {
      float acc = eb[tid] + ne[(long)n * cHID + tid];
#pragma unroll
      for (int f = 0; f < cF; ++f) acc = fmaf(xs[f], ew_[f * cHID + tid], acc);
      v = acc;
    } else {
      v = lw[(long)n * cLF + (tid - cHID)];
    }
    h[row * 160 + tid] = f2bf(v);
    __syncthreads();
  }
}

// ======================= adjacency: softmax_v(relu(src_emb @ tgt_emb^T)) =======================
__global__ __launch_bounds__(256)
void adj_softmax(const float* __restrict__ se, const float* __restrict__ te,
                 u16* __restrict__ adj)
{
  const int w = blockIdx.x, tid = threadIdx.x;
  __shared__ float sv[cHID];
  __shared__ float red[256];
  if (tid < cHID) sv[tid] = se[(long)w * cHID + tid];
  __syncthreads();
  float lg[8];
  float mx = 0.f;   // relu => >= 0
#pragma unroll
  for (int i = 0; i < 8; ++i) {
    const int v = tid + i * 256;
    float acc = 0.f;
#pragma unroll 8
    for (int k = 0; k < cHID; ++k) acc = fmaf(sv[k], te[(long)v * cHID + k], acc);
    acc = fmaxf(acc, 0.f);
    lg[i] = acc; mx = fmaxf(mx, acc);
  }
  red[tid] = mx; __syncthreads();
  for (int s = 128; s > 0; s >>= 1) { if (tid < s) red[tid] = fmaxf(red[tid], red[tid + s]); __syncthreads(); }
  const float m = red[0]; __syncthreads();
  float sum = 0.f;
#pragma unroll
  for (int i = 0; i < 8; ++i) { lg[i] = __expf(lg[i] - m); sum += lg[i]; }
  red[tid] = sum; __syncthreads();
  for (int s = 128; s > 0; s >>= 1) { if (tid < s) red[tid] += red[tid + s]; __syncthreads(); }
  const float inv = 1.f / red[0]; __syncthreads();
#pragma unroll
  for (int i = 0; i < 8; ++i) adj[(long)w * cN + tid + i * 256] = f2bf(lg[i] * inv);
}

// ======================= temporal 2nd-order LIF scan =======================
__global__ __launch_bounds__(256)
void scan_syn(const u16* __restrict__ in, u16* __restrict__ out, int c)
{
  const long total = (long)cB * cN * c;
  const long idx = (long)blockIdx.x * 256 + threadIdx.x;
  if (idx >= total) return;
  const long nc = (long)cN * c;
  const int b = (int)(idx / nc);
  const long rest = idx % nc;
  const u16* p = in  + (long)b * cT * nc + rest;
  u16*       q = out + (long)b * cT * nc + rest;
  float syn = 0.f, mem = 0.f;
#pragma unroll
  for (int t = 0; t < cT; ++t) {
    syn = fmaf(cALPHA, syn, bf2f(p[(long)t * nc]));
    mem = fmaf(cBETA, mem, syn);
    q[(long)t * nc] = f2bf(mem);
  }
}

// ======================= batch norm =======================
__global__ __launch_bounds__(256)
void bn_stats(const float* __restrict__ d, const u16* __restrict__ res,
              float* __restrict__ stat, int c)
{
  const int ch = threadIdx.x;
  const long r0 = (long)blockIdx.x * (cR / 512);
  float s = 0.f, s2 = 0.f;
  for (int i = 0; i < cR / 512; ++i) {
    const float v = d[(r0 + i) * c + ch] + bf2f(res[(r0 + i) * c + ch]);
    s += v; s2 = fmaf(v, v, s2);
  }
  atomicAdd(&stat[ch], s);
  atomicAdd(&stat[c + ch], s2);
}

__global__ __launch_bounds__(256)
void bn_finalize(const float* __restrict__ stat, const float* __restrict__ g,
                 const float* __restrict__ b, float* __restrict__ scsh, int c)
{
  const int ch = threadIdx.x;
  const float mu = stat[ch] / cR;
  const float var = stat[c + ch] / cR - mu * mu;
  const float sc = g[ch] * rsqrtf(var + cEPS);
  scsh[ch] = sc;
  scsh[c + ch] = fmaf(-mu, sc, b[ch]);
}

// BN(d+res) -> out (stride 192), cols [160,192) = lw1
__global__ __launch_bounds__(192)
void bn_apply_concat(const float* __restrict__ d, const u16* __restrict__ res,
                     const float* __restrict__ scsh, const float* __restrict__ lw,
                     u16* __restrict__ out)
{
  const int tid = threadIdx.x;
  const long r0 = (long)blockIdx.x * 8;
  for (long row = r0; row < r0 + 8; ++row) {
    const int n = (int)(row % cN);
    float v;
    if (tid < 160) v = fmaf(d[row * 160 + tid] + bf2f(res[row * 160 + tid]),
                            scsh[tid], scsh[160 + tid]);
    else           v = lw[(long)n * cLF + (tid - 160)];
    out[row * 192 + tid] = f2bf(v);
  }
}

// ======================= output transpose (f32 out) =======================
__global__ __launch_bounds__(256)
void final_transpose(const float* __restrict__ y, float* __restrict__ out)
{
  const long idx = (long)blockIdx.x * 256 + threadIdx.x;   // over B*HOR*N*F
  const int f = (int)(idx % cF);
  long t = idx / cF;
  const int n = (int)(t % cN); t /= cN;
  const int hor = (int)(t % cHOR);
  const int b = (int)(t / cHOR);
  out[idx] = y[((long)b * cN + n) * (cHOR * cF) + hor * cF + f];
}

__global__ __launch_bounds__(256)
void fill_f32(float* __restrict__ out, long n, float val)
{
  const long idx = (long)blockIdx.x * 256 + threadIdx.x;
  if (idx < n) out[idx] = val;
}

// ======================= stage diagnostics =======================
// Checks max|buf[0..255]| per stage, in pipeline order. First bad stage writes
// out[0] = 1000*(stage+1) + 111*reason (0=zero/poison, 1=nan/inf, 2=huge).
__global__ __launch_bounds__(256)
void diag_check(const u16* H0, const u16* T1, const float* Dd, const u16* G1,
                const float* outacc, const float* r1, const float* yb,
                float* out)
{
  __shared__ float rmax[256];
  __shared__ int rnan[256];
  __shared__ int decided;
  const int t = threadIdx.x;
  if (t == 0) decided = 0;
  __syncthreads();
  for (int s = 0; s < 7; ++s) {
    float v = 0.f;
    switch (s) {
      case 0: v = bf2f(H0[t]); break;
      case 1: v = bf2f(T1[t]); break;
      case 2: v = Dd[t]; break;
      case 3: v = bf2f(G1[t]); break;
      case 4: v = outacc[t]; break;
      case 5: v = r1[t]; break;
      case 6: v = yb[t]; break;
    }
    const int bad = !isfinite(v);
    rmax[t] = bad ? 0.f : fabsf(v);
    rnan[t] = bad;
    __syncthreads();
    for (int w = 128; w > 0; w >>= 1) {
      if (t < w) { rmax[t] = fmaxf(rmax[t], rmax[t + w]); rnan[t] |= rnan[t + w]; }
      __syncthreads();
    }
    if (t == 0 && !decided) {
      int reason = -1;
      if (rnan[0])              reason = 1;
      else if (rmax[0] <= 1e-9f) reason = 0;
      else if (rmax[0] >= 1e7f)  reason = 2;
      if (reason >= 0) { out[0] = 1000.f * (s + 1) + 111.f * reason; decided = 1; }
    }
    __syncthreads();
  }
}

// ======================= host orchestration =======================
extern "C" void kernel_launch(void* const* d_in, const int* in_sizes, int n_in,
                              void* d_out, int out_size, void* d_ws, size_t ws_size,
                              hipStream_t stream)
{
  float* outF = (float*)d_out;
  const long outN = out_size;
  // ---- sanity guards (decodable via absmax) ----
  if (n_in < 34) { fill_f32<<<(int)((outN + 255) / 256), 256, 0, stream>>>(outF, outN, 500.f); return; }
  if (in_sizes[0] != cB * cT * cN * cF || in_sizes[1] != 2 * cE || in_sizes[9] != 3 * 160 * 160) {
    fill_f32<<<(int)((outN + 255) / 256), 256, 0, stream>>>(outF, outN, 700.f); return;
  }

  const float* x        = (const float*)d_in[0];
  const int*   eidx     = (const int*)d_in[1];
  const float* ew       = (const float*)d_in[2];
  const float* enc_w    = (const float*)d_in[3];
  const float* enc_b    = (const float*)d_in[4];
  const float* node_emb = (const float*)d_in[5];
  const float* src_emb  = (const float*)d_in[6];
  const float* tgt_emb  = (const float*)d_in[7];
  const float* lw0  = (const float*)d_in[8];
  const float* tW0  = (const float*)d_in[9];
  const float* tb0  = (const float*)d_in[10];
  const float* dcw0 = (const float*)d_in[11];
  const float* dcb0 = (const float*)d_in[12];
  const float* dsw0 = (const float*)d_in[13];
  const float* dsb0 = (const float*)d_in[14];
  const float* skw0 = (const float*)d_in[15];
  const float* skb0 = (const float*)d_in[16];
  const float* ng0  = (const float*)d_in[17];
  const float* nb0  = (const float*)d_in[18];
  const float* lw1  = (const float*)d_in[19];
  const float* tW1  = (const float*)d_in[20];
  const float* tb1  = (const float*)d_in[21];
  // d_in[22..25, 28..29] feed only block-1's post-skip h (never read) -> dead.
  const float* skw1 = (const float*)d_in[26];
  const float* skb1 = (const float*)d_in[27];
  const float* rw1  = (const float*)d_in[30];
  const float* rb1  = (const float*)d_in[31];
  const float* rw2  = (const float*)d_in[32];
  const float* rb2  = (const float*)d_in[33];
  const int* srcI = eidx;
  const int* dstI = eidx + cE;

  // ---- workspace layout (bytes, 256-aligned) ----
  char* W = (char*)d_ws;
  size_t off = 0;
  auto A8 = [&](size_t bytes) { size_t r = off; off = (off + bytes + 255) & ~(size_t)255; return r; };
  const size_t oH0 = A8((size_t)cR * 160 * 2);   // res, bf16
  const size_t oHh = A8((size_t)cR * 160 * 2);   // chain h, bf16 (G1 [cR,192] aliases Hh..T1)
  const size_t oT1 = A8((size_t)cR * 160 * 2);   // scratch, bf16
  const size_t oS2 = A8((size_t)cR * 160 * 2);   // scratch2, bf16
  const size_t oDd = A8((size_t)cR * 160 * 4);   // accumulator, f32 (G2 aliases)
  const size_t oAdj = A8((size_t)cN * cN * 2);   // bf16
  const size_t oOut = A8((size_t)cB * cN * cFF * 4);      // skip acc, t=11 slice, f32
  const size_t oR1  = A8((size_t)cB * cN * 512 * 4);      // f32
  const size_t oY   = A8((size_t)cB * cN * cHOR * cF * 4);// f32
  const size_t oZero = A8(6 * 2048 * 4 + 2 * 192 * 4);
  const size_t oRowf = A8(2049 * 4), oRowb = A8(2049 * 4);
  const size_t oColf = A8((size_t)cE * 4), oColb = A8((size_t)cE * 4);
  const size_t oWnf  = A8((size_t)cE * 4), oWnb  = A8((size_t)cE * 4);
  const size_t oScSh = A8(2 * 192 * 4);
  if (off > ws_size) {
    fill_f32<<<(int)((outN + 255) / 256), 256, 0, stream>>>(outF, outN, 300.f);
    return;
  }

  u16 *H0 = (u16*)(W + oH0), *Hh = (u16*)(W + oHh), *T1 = (u16*)(W + oT1),
      *S2 = (u16*)(W + oS2), *adjb = (u16*)(W + oAdj);
  float* Dd = (float*)(W + oDd);
  u16 *G1 = (u16*)(W + oHh);   // alias: [cR,192] bf16 over Hh+start-of-T1 (used post-BN)
  u16 *G2 = (u16*)(W + oDd);   // alias: over Dd (used post-BN)
  float *outacc = (float*)(W + oOut), *r1 = (float*)(W + oR1), *yb = (float*)(W + oY);
  float* zero = (float*)(W + oZero);
  float *degf = zero, *degb = zero + 2048;
  int *cntf = (int*)(zero + 4096), *cntb = cntf + 2048,
      *curf = cntb + 2048, *curb = curf + 2048;
  float* stat = (float*)(curb + 2048);
  int *rowf = (int*)(W + oRowf), *rowb = (int*)(W + oRowb);
  int *colf = (int*)(W + oColf), *colb = (int*)(W + oColb);
  float *wnf = (float*)(W + oWnf), *wnb = (float*)(W + oWnb);
  float* scsh = (float*)(W + oScSh);

  // GEMM wrappers per type combo
  auto gUFU = [&](const u16* Aq, const float* Bq, u16* Cq, const float* bias,
                  int M, int N, int K, int lda, int ldb, int ldc,
                  long bA, long bB, long bC, int batch, int flags) {
    dim3 g(M / 64, (N + 63) / 64, batch);
    gemm_tiled<u16, float, u16><<<g, 256, 0, stream>>>(Aq, Bq, Cq, bias, M, N, K, lda, ldb, ldc, bA, bB, bC, flags);
  };
  auto gUFF = [&](const u16* Aq, const float* Bq, float* Cq, const float* bias,
                  int M, int N, int K, int lda, int ldb, int ldc,
                  long bA, long bB, long bC, int batch, int flags) {
    dim3 g(M / 64, (N + 63) / 64, batch);
    gemm_tiled<u16, float, float><<<g, 256, 0, stream>>>(Aq, Bq, Cq, bias, M, N, K, lda, ldb, ldc, bA, bB, bC, flags);
  };
  auto gUUU = [&](const u16* Aq, const u16* Bq, u16* Cq,
                  int M, int N, int K, int lda, int ldb, int ldc,
                  long bA, long bB, long bC, int batch) {
    dim3 g(M / 64, (N + 63) / 64, batch);
    gemm_tiled<u16, u16, u16><<<g, 256, 0, stream>>>(Aq, Bq, Cq, nullptr, M, N, K, lda, ldb, ldc, bA, bB, bC, 0);
  };
  auto gFFF = [&](const float* Aq, const float* Bq, float* Cq, const float* bias,
                  int M, int N, int K, int lda, int ldb, int ldc, int flags) {
    dim3 g(M / 64, (N + 63) / 64, 1);
    gemm_tiled<float, float, float><<<g, 256, 0, stream>>>(Aq, Bq, Cq, bias, M, N, K, lda, ldb, ldc, 0, 0, 0, flags);
  };

  // ---- phase 0: CSR build, encoder, learned adjacency ----
  hipMemsetAsync(zero, 0, 6 * 2048 * 4 + 2 * 192 * 4, stream);
  edge_stats<<<cE / 256, 256, 0, stream>>>(srcI, dstI, ew, degf, degb, cntf, cntb);
  scan2<<<2, 256, 0, stream>>>(cntf, cntb, rowf, rowb);
  fill_csr<<<cE / 256, 256, 0, stream>>>(srcI, dstI, ew, degf, degb, rowf, rowb,
                                         curf, curb, colf, colb, wnf, wnb);
  encoder<<<cR / 8, 160, 0, stream>>>(x, enc_w, enc_b, node_emb, lw0, H0);
  adj_softmax<<<cN, 256, 0, stream>>>(src_emb, tgt_emb, adjb);

  // ---- block 0 (c = 160) ----
  {
    const int c = 160;
    const long NC = (long)cN * c;
    const int scanGrid = (int)(((long)cB * cN * c + 255) / 256);
    // synaptic chain: H0 (res) -> Hh
    gUFU(H0, tW0 + 0L * c * c, T1, tb0 + 0 * c, cR, c, c, c, c, c, 0, 0, 0, 1, FLAG_BIAS);
    scan_syn<<<scanGrid, 256, 0, stream>>>(T1, Hh, c);
    for (int l = 1; l < 3; ++l) {
      gUFU(Hh, tW0 + (long)l * c * c, T1, tb0 + l * c, cR, c, c, c, c, c, 0, 0, 0, 1, FLAG_BIAS);
      scan_syn<<<scanGrid, 256, 0, stream>>>(T1, Hh, c);
    }
    // skip (t=11 only): outacc[b] = h[b,11]@skw0 + skb0
    gUFF(Hh + 11L * NC, skw0, outacc, skb0, cN, cFF, c, c, cFF, cFF,
         (long)cT * NC, 0, (long)cN * cFF, cB, FLAG_BIAS);
    // diffconv: Dd = P h @W0 + P^2 h @W1 + Pb h @W2 + Pb^2 h @W3 + b
    dim3 pg(cN, cBT);
    prop_gather<<<pg, c, 0, stream>>>(Hh, T1, rowf, colf, wnf, c);
    gUFF(T1, dcw0 + 0L * c * c, Dd, dcb0, cR, c, c, c, c, c, 0, 0, 0, 1, FLAG_BIAS);
    prop_gather<<<pg, c, 0, stream>>>(T1, S2, rowf, colf, wnf, c);
    gUFF(S2, dcw0 + 1L * c * c, Dd, nullptr, cR, c, c, c, c, c, 0, 0, 0, 1, FLAG_ACC);
    prop_gather<<<pg, c, 0, stream>>>(Hh, T1, rowb, colb, wnb, c);
    gUFF(T1, dcw0 + 2L * c * c, Dd, nullptr, cR, c, c, c, c, c, 0, 0, 0, 1, FLAG_ACC);
    prop_gather<<<pg, c, 0, stream>>>(T1, S2, rowb, colb, wnb, c);
    gUFF(S2, dcw0 + 3L * c * c, Dd, nullptr, cR, c, c, c, c, c, 0, 0, 0, 1, FLAG_ACC);
    // dense conv: x1 = adj@h -> T1 ; Dd += x1@dsw[:c] ; x2 = adj@x1 -> S2 ; Dd += x2@dsw[c:]
    gUUU(adjb, Hh, T1, cN, c, cN, cN, c, c, 0, NC, NC, cBT);
    gUFF(T1, dsw0, Dd, dsb0, cR, c, c, c, c, c, 0, 0, 0, 1, FLAG_BIAS | FLAG_ACC);
    gUUU(adjb, T1, S2, cN, c, cN, cN, c, c, 0, NC, NC, cBT);
    gUFF(S2, dsw0 + (long)c * c, Dd, nullptr, cR, c, c, c, c, c, 0, 0, 0, 1, FLAG_ACC);
    // BN(Dd + H0) -> G1 (stride 192) with lw1 appended
    bn_stats<<<512, c, 0, stream>>>(Dd, H0, stat, c);
    bn_finalize<<<1, c, 0, stream>>>(stat, ng0, nb0, scsh, c);
    bn_apply_concat<<<cR / 8, 192, 0, stream>>>(Dd, H0, scsh, lw1, G1);
  }

  // ---- block 1 (c = 192): only chain + skip live; G1/G2 alias freed regions ----
  {
    const int c = 192;
    const long NC = (long)cN * c;
    const int scanGrid = (int)(((long)cB * cN * c + 255) / 256);
    for (int l = 0; l < 3; ++l) {
      gUFU(G1, tW1 + (long)l * c * c, G2, tb1 + l * c, cR, c, c, c, c, c, 0, 0, 0, 1, FLAG_BIAS);
      scan_syn<<<scanGrid, 256, 0, stream>>>(G2, G1, c);
    }
    // outacc = relu(h1[:,11]@skw1 + skb1 + outacc)
    gUFF(G1 + 11L * NC, skw1, outacc, skb1, cN, cFF, c, c, cFF, cFF,
         (long)cT * NC, 0, (long)cN * cFF, cB, FLAG_BIAS | FLAG_ACC | FLAG_RELU);
  }

  // ---- readout ----
  gFFF(outacc, rw1, r1, rb1, cB * cN, 2 * cFF, cFF, cFF, 2 * cFF, 2 * cFF, FLAG_BIAS | FLAG_RELU);
  gFFF(r1, rw2, yb, rb2, cB * cN, cHOR * cF, 2 * cFF, 2 * cFF, cHOR * cF, cHOR * cF, FLAG_BIAS);
  final_transpose<<<(cB * cHOR * cN * cF) / 256, 256, 0, stream>>>(yb, outF);

  // ---- stage diagnostics (writes out[0] only if a stage failed) ----
  diag_check<<<1, 256, 0, stream>>>(H0, T1, Dd, G1, outacc, r1, yb, outF);
}

// Round 4
// 2528.866 us; speedup vs baseline: 1.5932x; 1.5932x over previous
//
#include <hip/hip_runtime.h>

// ======================= types & helpers =======================
using u16 = unsigned short;
typedef short bf16x8 __attribute__((ext_vector_type(8)));
typedef float f32x4  __attribute__((ext_vector_type(4)));

__device__ __forceinline__ float bf2f(u16 u) { return __uint_as_float(((unsigned)u) << 16); }
__device__ __forceinline__ u16 f2bf(float f) {  // round-to-nearest-even
  unsigned u = __float_as_uint(f);
  return (u16)((u + 0x7FFFu + ((u >> 16) & 1u)) >> 16);
}
__device__ __forceinline__ float ldv(const float* p) { return *p; }
__device__ __forceinline__ float ldv(const u16* p)   { return bf2f(*p); }
__device__ __forceinline__ void  stv(float* p, float v) { *p = v; }
__device__ __forceinline__ void  stv(u16* p, float v)   { *p = f2bf(v); }

// ======================= problem constants =======================
constexpr int cB = 4, cT = 12, cN = 2048, cF = 26;
constexpr int cHID = 128, cLF = 32, cFF = 256, cHOR = 12;
constexpr int cE = 16384;
constexpr int cR = cB * cT * cN;   // 98304
constexpr int cBT = cB * cT;       // 48
constexpr float cALPHA = 0.9f, cBETA = 0.8f, cEPS = 1e-5f;

#define FLAG_ACC  1
#define FLAG_BIAS 2
#define FLAG_RELU 4

// ======================= MFMA bf16 GEMM =======================
// C[m,n] = sum_k A[m,k] * BT[n,k]  (+bias) (+C) (relu)
// A: bf16 [M,K] lda ; BT: bf16 [N,K] ldbt (i.e. B transposed).
// M % 128 == 0, K % 32 == 0, lda/ldbt % 8 == 0; N guarded.
// Tile 128 x (NF*32); 4 waves in 2x2; per wave 4x NF frags of 16x16.
// LDS rows padded 32->40 bf16 (80B): frag ds_read_b128 is 2-way (free).
template <int NF, typename TC>
__global__ __launch_bounds__(256)
void gemm_mfma(const u16* __restrict__ A, const u16* __restrict__ BT,
               TC* __restrict__ C, const float* __restrict__ bias,
               int M, int N, int K, int lda, int ldbt, int ldc,
               long batchA, long batchB, long batchC, int flags)
{
  constexpr int TN = NF * 32;
  constexpr int BROWS = 128 + TN;
  __shared__ u16 S[BROWS * 40];    // A rows [0,128), BT rows [128,128+TN)
  A  += (long)blockIdx.z * batchA;
  BT += (long)blockIdx.z * batchB;
  C  += (long)blockIdx.z * batchC;
  const int tid = threadIdx.x;
  const int lane = tid & 63, wid = tid >> 6;
  const int wm = wid & 1, wn = wid >> 1;
  const int m0 = blockIdx.x * 128, n0 = blockIdx.y * TN;
  const int fr = lane & 15, kh = lane >> 4;   // frag row/col, k-half
  f32x4 acc[4][NF];
#pragma unroll
  for (int i = 0; i < 4; ++i)
#pragma unroll
    for (int j = 0; j < NF; ++j) acc[i][j] = f32x4{0.f, 0.f, 0.f, 0.f};

  for (int k0 = 0; k0 < K; k0 += 32) {
    __syncthreads();
    for (int idx = tid; idx < BROWS * 4; idx += 256) {
      const int row = idx >> 2, q = idx & 3;
      uint4 v = {0u, 0u, 0u, 0u};
      if (row < 128) {
        v = *(const uint4*)(A + (long)(m0 + row) * lda + k0 + q * 8);
      } else {
        const int n = n0 + row - 128;
        if (n < N) v = *(const uint4*)(BT + (long)n * ldbt + k0 + q * 8);
      }
      *(uint4*)&S[row * 40 + q * 8] = v;
    }
    __syncthreads();
    bf16x8 af[4];
#pragma unroll
    for (int mf = 0; mf < 4; ++mf)
      af[mf] = *(const bf16x8*)&S[(wm * 64 + mf * 16 + fr) * 40 + kh * 8];
#pragma unroll
    for (int nf = 0; nf < NF; ++nf) {
      const bf16x8 bfr = *(const bf16x8*)&S[(128 + wn * NF * 16 + nf * 16 + fr) * 40 + kh * 8];
#pragma unroll
      for (int mf = 0; mf < 4; ++mf)
        acc[mf][nf] = __builtin_amdgcn_mfma_f32_16x16x32_bf16(af[mf], bfr, acc[mf][nf], 0, 0, 0);
    }
  }

#pragma unroll
  for (int mf = 0; mf < 4; ++mf)
#pragma unroll
    for (int nf = 0; nf < NF; ++nf) {
      const int gn = n0 + wn * NF * 16 + nf * 16 + fr;
      if (gn < N) {
#pragma unroll
        for (int r = 0; r < 4; ++r) {
          const long gm = m0 + wm * 64 + mf * 16 + kh * 4 + r;   // C/D: row=(lane>>4)*4+r
          float v = acc[mf][nf][r];
          if (flags & FLAG_BIAS) v += bias[gn];
          if (flags & FLAG_ACC)  v += ldv(&C[gm * ldc + gn]);
          if (flags & FLAG_RELU) v = fmaxf(v, 0.f);
          stv(&C[gm * ldc + gn], v);
        }
      }
    }
}

// ======================= weight convert + transpose (f32 [K,N] -> bf16 [N,K]) ==========
__global__ __launch_bounds__(256)
void wconvT(const float* __restrict__ w, u16* __restrict__ wt, int K, int N)
{
  const long idx = (long)blockIdx.x * 256 + threadIdx.x;
  if (idx >= (long)K * N) return;
  const int n = (int)(idx / K), k = (int)(idx % K);
  wt[idx] = f2bf(w[(long)k * N + n]);
}

// ======================= tiled bf16 transpose: in [R,Cc] -> out [Cc,R], batched ==========
__global__ __launch_bounds__(256)
void transpose_bf16(const u16* __restrict__ in, u16* __restrict__ out,
                    int R, int Cc, long batchIn, long batchOut)
{
  __shared__ u16 t[64][65];
  in  += (long)blockIdx.z * batchIn;
  out += (long)blockIdx.z * batchOut;
  const int tid = threadIdx.x;
  const int r0 = blockIdx.x * 64, c0 = blockIdx.y * 64;
  for (int i = tid; i < 64 * 64; i += 256) {
    const int r = i >> 6, c = i & 63;
    t[r][c] = (r0 + r < R && c0 + c < Cc) ? in[(long)(r0 + r) * Cc + c0 + c] : (u16)0;
  }
  __syncthreads();
  for (int i = tid; i < 64 * 64; i += 256) {
    const int c = i >> 6, r = i & 63;
    if (c0 + c < Cc && r0 + r < R) out[(long)(c0 + c) * R + r0 + r] = t[r][c];
  }
}

__global__ __launch_bounds__(256)
void cvt_f2bf(const float* __restrict__ in, u16* __restrict__ out, long n)
{
  const long idx = (long)blockIdx.x * 256 + threadIdx.x;
  if (idx < n) out[idx] = f2bf(in[idx]);
}

// ======================= graph preprocessing (CSR build) =======================
__global__ __launch_bounds__(256)
void edge_stats(const int* __restrict__ s, const int* __restrict__ d,
                const float* __restrict__ ew, float* degf, float* degb,
                int* cntf, int* cntb)
{
  const int e = blockIdx.x * 256 + threadIdx.x;
  atomicAdd(&degf[d[e]], ew[e]);
  atomicAdd(&degb[s[e]], ew[e]);
  atomicAdd(&cntf[d[e]], 1);
  atomicAdd(&cntb[s[e]], 1);
}

__global__ __launch_bounds__(256)
void scan2(const int* __restrict__ cf, const int* __restrict__ cb,
           int* __restrict__ rf, int* __restrict__ rb)
{
  const int* c = blockIdx.x ? cb : cf;
  int* r       = blockIdx.x ? rb : rf;
  __shared__ int part[256];
  const int t = threadIdx.x, base = t * 8;
  int loc[8]; int s = 0;
#pragma unroll
  for (int i = 0; i < 8; ++i) { loc[i] = c[base + i]; s += loc[i]; }
  part[t] = s; __syncthreads();
  if (t == 0) {
    int run = 0;
    for (int i = 0; i < 256; ++i) { const int v = part[i]; part[i] = run; run += v; }
    r[2048] = run;
  }
  __syncthreads();
  int run = part[t];
#pragma unroll
  for (int i = 0; i < 8; ++i) { r[base + i] = run; run += loc[i]; }
}

__global__ __launch_bounds__(256)
void fill_csr(const int* __restrict__ s, const int* __restrict__ d,
              const float* __restrict__ ew,
              const float* __restrict__ degf, const float* __restrict__ degb,
              const int* __restrict__ rowf, const int* __restrict__ rowb,
              int* curf, int* curb,
              int* __restrict__ colf, int* __restrict__ colb,
              float* __restrict__ wnf, float* __restrict__ wnb)
{
  const int e = blockIdx.x * 256 + threadIdx.x;
  const int si = s[e], di = d[e];
  const float w = ew[e];
  const int p = rowf[di] + atomicAdd(&curf[di], 1);
  colf[p] = si; wnf[p] = w / fmaxf(degf[di], 1e-6f);
  const int q = rowb[si] + atomicAdd(&curb[si], 1);
  colb[q] = di; wnb[q] = w / fmaxf(degb[si], 1e-6f);
}

// y[bt,n,:] = sum_j w[j]*x[bt,col[j],:]
__global__ __launch_bounds__(256)
void prop_gather(const u16* __restrict__ x, u16* __restrict__ y,
                 const int* __restrict__ rowptr, const int* __restrict__ col,
                 const float* __restrict__ w, int c)
{
  const int n = blockIdx.x, bt = blockIdx.y, ch = threadIdx.x;
  const int beg = rowptr[n], end = rowptr[n + 1];
  const u16* xb = x + (long)bt * cN * c;
  float acc = 0.f;
  for (int j = beg; j < end; ++j)
    acc = fmaf(w[j], bf2f(xb[(long)col[j] * c + ch]), acc);
  y[((long)bt * cN + n) * c + ch] = f2bf(acc);
}

// ======================= encoder =======================
__global__ __launch_bounds__(160)
void encoder(const float* __restrict__ x, const float* __restrict__ ew_,
             const float* __restrict__ eb, const float* __restrict__ ne,
             const float* __restrict__ lw, u16* __restrict__ h)
{
  __shared__ float xs[cF];
  const int tid = threadIdx.x;
  const long r0 = (long)blockIdx.x * 8;
  for (long row = r0; row < r0 + 8; ++row) {
    if (tid < cF) xs[tid] = x[row * cF + tid];
    __syncthreads();
    const int n = (int)(row % cN);
    float v;
    if (tid < cHID) {
      float acc = eb[tid] + ne[(long)n * cHID + tid];
#pragma unroll
      for (int f = 0; f < cF; ++f) acc = fmaf(xs[f], ew_[f * cHID + tid], acc);
      v = acc;
    } else {
      v = lw[(long)n * cLF + (tid - cHID)];
    }
    h[row * 160 + tid] = f2bf(v);
    __syncthreads();
  }
}

// ======================= adjacency: softmax_v(relu(src_emb @ tgt_emb^T)) ==========
__global__ __launch_bounds__(256)
void adj_softmax(const float* __restrict__ se, const float* __restrict__ te,
                 u16* __restrict__ adj)
{
  const int w = blockIdx.x, tid = threadIdx.x;
  __shared__ float sv[cHID];
  __shared__ float red[256];
  if (tid < cHID) sv[tid] = se[(long)w * cHID + tid];
  __syncthreads();
  float lg[8];
  float mx = 0.f;
#pragma unroll
  for (int i = 0; i < 8; ++i) {
    const int v = tid + i * 256;
    float acc = 0.f;
#pragma unroll 8
    for (int k = 0; k < cHID; ++k) acc = fmaf(sv[k], te[(long)v * cHID + k], acc);
    acc = fmaxf(acc, 0.f);
    lg[i] = acc; mx = fmaxf(mx, acc);
  }
  red[tid] = mx; __syncthreads();
  for (int s = 128; s > 0; s >>= 1) { if (tid < s) red[tid] = fmaxf(red[tid], red[tid + s]); __syncthreads(); }
  const float m = red[0]; __syncthreads();
  float sum = 0.f;
#pragma unroll
  for (int i = 0; i < 8; ++i) { lg[i] = __expf(lg[i] - m); sum += lg[i]; }
  red[tid] = sum; __syncthreads();
  for (int s = 128; s > 0; s >>= 1) { if (tid < s) red[tid] += red[tid + s]; __syncthreads(); }
  const float inv = 1.f / red[0]; __syncthreads();
#pragma unroll
  for (int i = 0; i < 8; ++i) adj[(long)w * cN + tid + i * 256] = f2bf(lg[i] * inv);
}

// ======================= temporal 2nd-order LIF scan =======================
__global__ __launch_bounds__(256)
void scan_syn(const u16* __restrict__ in, u16* __restrict__ out, int c)
{
  const long total = (long)cB * cN * c;
  const long idx = (long)blockIdx.x * 256 + threadIdx.x;
  if (idx >= total) return;
  const long nc = (long)cN * c;
  const int b = (int)(idx / nc);
  const long rest = idx % nc;
  const u16* p = in  + (long)b * cT * nc + rest;
  u16*       q = out + (long)b * cT * nc + rest;
  float syn = 0.f, mem = 0.f;
#pragma unroll
  for (int t = 0; t < cT; ++t) {
    syn = fmaf(cALPHA, syn, bf2f(p[(long)t * nc]));
    mem = fmaf(cBETA, mem, syn);
    q[(long)t * nc] = f2bf(mem);
  }
}

// ======================= batch norm =======================
__global__ __launch_bounds__(256)
void bn_stats(const float* __restrict__ d, const u16* __restrict__ res,
              float* __restrict__ stat, int c)
{
  const int ch = threadIdx.x;
  const long r0 = (long)blockIdx.x * (cR / 512);
  float s = 0.f, s2 = 0.f;
  for (int i = 0; i < cR / 512; ++i) {
    const float v = d[(r0 + i) * c + ch] + bf2f(res[(r0 + i) * c + ch]);
    s += v; s2 = fmaf(v, v, s2);
  }
  atomicAdd(&stat[ch], s);
  atomicAdd(&stat[c + ch], s2);
}

__global__ __launch_bounds__(256)
void bn_finalize(const float* __restrict__ stat, const float* __restrict__ g,
                 const float* __restrict__ b, float* __restrict__ scsh, int c)
{
  const int ch = threadIdx.x;
  const float mu = stat[ch] / cR;
  const float var = stat[c + ch] / cR - mu * mu;
  const float sc = g[ch] * rsqrtf(var + cEPS);
  scsh[ch] = sc;
  scsh[c + ch] = fmaf(-mu, sc, b[ch]);
}

__global__ __launch_bounds__(192)
void bn_apply_concat(const float* __restrict__ d, const u16* __restrict__ res,
                     const float* __restrict__ scsh, const float* __restrict__ lw,
                     u16* __restrict__ out)
{
  const int tid = threadIdx.x;
  const long r0 = (long)blockIdx.x * 8;
  for (long row = r0; row < r0 + 8; ++row) {
    const int n = (int)(row % cN);
    float v;
    if (tid < 160) v = fmaf(d[row * 160 + tid] + bf2f(res[row * 160 + tid]),
                            scsh[tid], scsh[160 + tid]);
    else           v = lw[(long)n * cLF + (tid - 160)];
    out[row * 192 + tid] = f2bf(v);
  }
}

// ======================= output transpose (f32 out) =======================
__global__ __launch_bounds__(256)
void final_transpose(const float* __restrict__ y, float* __restrict__ out)
{
  const long idx = (long)blockIdx.x * 256 + threadIdx.x;
  const int f = (int)(idx % cF);
  long t = idx / cF;
  const int n = (int)(t % cN); t /= cN;
  const int hor = (int)(t % cHOR);
  const int b = (int)(t / cHOR);
  out[idx] = y[((long)b * cN + n) * (cHOR * cF) + hor * cF + f];
}

__global__ __launch_bounds__(256)
void fill_f32(float* __restrict__ out, long n, float val)
{
  const long idx = (long)blockIdx.x * 256 + threadIdx.x;
  if (idx < n) out[idx] = val;
}

// ======================= host orchestration =======================
extern "C" void kernel_launch(void* const* d_in, const int* in_sizes, int n_in,
                              void* d_out, int out_size, void* d_ws, size_t ws_size,
                              hipStream_t stream)
{
  float* outF = (float*)d_out;
  const long outN = out_size;
  if (n_in < 34) { fill_f32<<<(int)((outN + 255) / 256), 256, 0, stream>>>(outF, outN, 500.f); return; }
  if (in_sizes[0] != cB * cT * cN * cF || in_sizes[1] != 2 * cE || in_sizes[9] != 3 * 160 * 160) {
    fill_f32<<<(int)((outN + 255) / 256), 256, 0, stream>>>(outF, outN, 700.f); return;
  }

  const float* x        = (const float*)d_in[0];
  const int*   eidx     = (const int*)d_in[1];
  const float* ew       = (const float*)d_in[2];
  const float* enc_w    = (const float*)d_in[3];
  const float* enc_b    = (const float*)d_in[4];
  const float* node_emb = (const float*)d_in[5];
  const float* src_emb  = (const float*)d_in[6];
  const float* tgt_emb  = (const float*)d_in[7];
  const float* lw0  = (const float*)d_in[8];
  const float* tW0  = (const float*)d_in[9];
  const float* tb0  = (const float*)d_in[10];
  const float* dcw0 = (const float*)d_in[11];
  const float* dcb0 = (const float*)d_in[12];
  const float* dsw0 = (const float*)d_in[13];
  const float* dsb0 = (const float*)d_in[14];
  const float* skw0 = (const float*)d_in[15];
  const float* skb0 = (const float*)d_in[16];
  const float* ng0  = (const float*)d_in[17];
  const float* nb0  = (const float*)d_in[18];
  const float* lw1  = (const float*)d_in[19];
  const float* tW1  = (const float*)d_in[20];
  const float* tb1  = (const float*)d_in[21];
  // d_in[22..25, 28..29] feed only block-1's post-skip h (never read) -> dead.
  const float* skw1 = (const float*)d_in[26];
  const float* skb1 = (const float*)d_in[27];
  const float* rw1  = (const float*)d_in[30];
  const float* rb1  = (const float*)d_in[31];
  const float* rw2  = (const float*)d_in[32];
  const float* rb2  = (const float*)d_in[33];
  const int* srcI = eidx;
  const int* dstI = eidx + cE;

  // ---- workspace layout ----
  char* W = (char*)d_ws;
  size_t off = 0;
  auto A8 = [&](size_t bytes) { size_t r = off; off = (off + bytes + 255) & ~(size_t)255; return r; };
  const size_t oH0 = A8((size_t)cR * 160 * 2);   // res, bf16
  const size_t oHh = A8((size_t)cR * 160 * 2);   // chain h (G1 [cR,192] aliases Hh+T1-head)
  const size_t oT1 = A8((size_t)cR * 160 * 2);   // scratch
  const size_t oS2 = A8((size_t)cR * 160 * 2);   // scratch2 / hT / outaccB
  const size_t oDd = A8((size_t)cR * 160 * 4);   // f32 accumulator (G2 aliases)
  const size_t oAdj = A8((size_t)cN * cN * 2);
  const size_t oOut = A8((size_t)cB * cN * cFF * 4);       // f32 skip acc (t=11)
  const size_t oR1  = A8((size_t)cB * cN * 512 * 2);       // bf16 r1
  const size_t oY   = A8((size_t)cB * cN * cHOR * cF * 4); // f32
  const size_t oZero = A8(6 * 2048 * 4 + 2 * 192 * 4);
  const size_t oRowf = A8(2049 * 4), oRowb = A8(2049 * 4);
  const size_t oColf = A8((size_t)cE * 4), oColb = A8((size_t)cE * 4);
  const size_t oWnf  = A8((size_t)cE * 4), oWnb  = A8((size_t)cE * 4);
  const size_t oScSh = A8(2 * 192 * 4);
  const size_t oWT   = A8((size_t)721920 * 2);   // bf16 transposed weights
  if (off > ws_size) {
    fill_f32<<<(int)((outN + 255) / 256), 256, 0, stream>>>(outF, outN, 300.f);
    return;
  }

  u16 *H0 = (u16*)(W + oH0), *Hh = (u16*)(W + oHh), *T1 = (u16*)(W + oT1),
      *S2 = (u16*)(W + oS2), *adjb = (u16*)(W + oAdj);
  float* Dd = (float*)(W + oDd);
  u16 *G1 = (u16*)(W + oHh);   // [cR,192] bf16 over Hh(+T1 head), post-BN only
  u16 *G2 = (u16*)(W + oDd);   // over Dd, post-BN only
  float *outacc = (float*)(W + oOut), *yb = (float*)(W + oY);
  u16 *r1b = (u16*)(W + oR1);
  float* zero = (float*)(W + oZero);
  float *degf = zero, *degb = zero + 2048;
  int *cntf = (int*)(zero + 4096), *cntb = cntf + 2048,
      *curf = cntb + 2048, *curb = curf + 2048;
  float* stat = (float*)(curb + 2048);
  int *rowf = (int*)(W + oRowf), *rowb = (int*)(W + oRowb);
  int *colf = (int*)(W + oColf), *colb = (int*)(W + oColb);
  float *wnf = (float*)(W + oWnf), *wnb = (float*)(W + oWnb);
  float* scsh = (float*)(W + oScSh);
  u16* wt   = (u16*)(W + oWT);
  u16 *wt0 = wt,             *wt1 = wt0 + 3 * 25600,  *wdc = wt1 + 3 * 36864,
      *wds = wdc + 4 * 25600, *wsk0 = wds + 2 * 25600, *wsk1 = wsk0 + 40960,
      *wr1 = wsk1 + 49152,    *wr2 = wr1 + 131072;

  auto g5u = [&](const u16* Aq, const u16* Bq, u16* Cq, const float* bias,
                 int M, int N, int K, int lda, int ldbt, int ldc,
                 long bA, long bB, long bC, int batch, int flags) {
    dim3 g(M / 128, (N + 159) / 160, batch);
    gemm_mfma<5, u16><<<g, 256, 0, stream>>>(Aq, Bq, Cq, bias, M, N, K, lda, ldbt, ldc, bA, bB, bC, flags);
  };
  auto g5f = [&](const u16* Aq, const u16* Bq, float* Cq, const float* bias,
                 int M, int N, int K, int lda, int ldbt, int ldc, int flags) {
    dim3 g(M / 128, (N + 159) / 160, 1);
    gemm_mfma<5, float><<<g, 256, 0, stream>>>(Aq, Bq, Cq, bias, M, N, K, lda, ldbt, ldc, 0, 0, 0, flags);
  };
  auto g6u = [&](const u16* Aq, const u16* Bq, u16* Cq, const float* bias,
                 int M, int N, int K, int lda, int ldbt, int ldc, int flags) {
    dim3 g(M / 128, (N + 191) / 192, 1);
    gemm_mfma<6, u16><<<g, 256, 0, stream>>>(Aq, Bq, Cq, bias, M, N, K, lda, ldbt, ldc, 0, 0, 0, flags);
  };
  auto g4f = [&](const u16* Aq, const u16* Bq, float* Cq, const float* bias,
                 int M, int N, int K, int lda, int ldbt, int ldc,
                 long bA, long bB, long bC, int batch, int flags) {
    dim3 g(M / 128, (N + 127) / 128, batch);
    gemm_mfma<4, float><<<g, 256, 0, stream>>>(Aq, Bq, Cq, bias, M, N, K, lda, ldbt, ldc, bA, bB, bC, flags);
  };
  auto g4u = [&](const u16* Aq, const u16* Bq, u16* Cq, const float* bias,
                 int M, int N, int K, int lda, int ldbt, int ldc, int flags) {
    dim3 g(M / 128, (N + 127) / 128, 1);
    gemm_mfma<4, u16><<<g, 256, 0, stream>>>(Aq, Bq, Cq, bias, M, N, K, lda, ldbt, ldc, 0, 0, 0, flags);
  };
  auto wcv = [&](const float* src, u16* dst, int K, int N) {
    wconvT<<<(int)(((long)K * N + 255) / 256), 256, 0, stream>>>(src, dst, K, N);
  };

  // ---- phase 0: weight conversion, CSR, encoder, adjacency ----
  for (int l = 0; l < 3; ++l) wcv(tW0 + (long)l * 25600, wt0 + (long)l * 25600, 160, 160);
  for (int l = 0; l < 3; ++l) wcv(tW1 + (long)l * 36864, wt1 + (long)l * 36864, 192, 192);
  for (int i = 0; i < 4; ++i) wcv(dcw0 + (long)i * 25600, wdc + (long)i * 25600, 160, 160);
  for (int i = 0; i < 2; ++i) wcv(dsw0 + (long)i * 25600, wds + (long)i * 25600, 160, 160);
  wcv(skw0, wsk0, 160, 256);
  wcv(skw1, wsk1, 192, 256);
  wcv(rw1, wr1, 256, 512);
  wcv(rw2, wr2, 512, 312);

  hipMemsetAsync(zero, 0, 6 * 2048 * 4 + 2 * 192 * 4, stream);
  edge_stats<<<cE / 256, 256, 0, stream>>>(srcI, dstI, ew, degf, degb, cntf, cntb);
  scan2<<<2, 256, 0, stream>>>(cntf, cntb, rowf, rowb);
  fill_csr<<<cE / 256, 256, 0, stream>>>(srcI, dstI, ew, degf, degb, rowf, rowb,
                                         curf, curb, colf, colb, wnf, wnb);
  encoder<<<cR / 8, 160, 0, stream>>>(x, enc_w, enc_b, node_emb, lw0, H0);
  adj_softmax<<<cN, 256, 0, stream>>>(src_emb, tgt_emb, adjb);

  // ---- block 0 (c = 160) ----
  {
    const int c = 160;
    const long NC = (long)cN * c;
    const int scanGrid = (int)(((long)cB * cN * c + 255) / 256);
    // synaptic chain: H0 (res) -> Hh
    g5u(H0, wt0 + 0L * 25600, T1, tb0 + 0 * c, cR, c, c, c, c, c, 0, 0, 0, 1, FLAG_BIAS);
    scan_syn<<<scanGrid, 256, 0, stream>>>(T1, Hh, c);
    for (int l = 1; l < 3; ++l) {
      g5u(Hh, wt0 + (long)l * 25600, T1, tb0 + l * c, cR, c, c, c, c, c, 0, 0, 0, 1, FLAG_BIAS);
      scan_syn<<<scanGrid, 256, 0, stream>>>(T1, Hh, c);
    }
    // skip (t=11): outacc[b] = h[b,11]@skw0 + skb0
    g4f(Hh + 11L * NC, wsk0, outacc, skb0, cN, cFF, c, c, c, cFF,
        (long)cT * NC, 0, (long)cN * cFF, cB, FLAG_BIAS);
    // diffconv
    dim3 pg(cN, cBT);
    prop_gather<<<pg, c, 0, stream>>>(Hh, T1, rowf, colf, wnf, c);
    g5f(T1, wdc + 0L * 25600, Dd, dcb0, cR, c, c, c, c, c, FLAG_BIAS);
    prop_gather<<<pg, c, 0, stream>>>(T1, S2, rowf, colf, wnf, c);
    g5f(S2, wdc + 1L * 25600, Dd, nullptr, cR, c, c, c, c, c, FLAG_ACC);
    prop_gather<<<pg, c, 0, stream>>>(Hh, T1, rowb, colb, wnb, c);
    g5f(T1, wdc + 2L * 25600, Dd, nullptr, cR, c, c, c, c, c, FLAG_ACC);
    prop_gather<<<pg, c, 0, stream>>>(T1, S2, rowb, colb, wnb, c);
    g5f(S2, wdc + 3L * 25600, Dd, nullptr, cR, c, c, c, c, c, FLAG_ACC);
    // dense conv: hT -> S2 ; x1 = adj@h -> T1 ; Dd += x1@dsw0 ; x1T -> S2 ; x2 -> T1 ; Dd += x2@dsw1
    dim3 tg(cN / 64, (c + 63) / 64, cBT);
    transpose_bf16<<<tg, 256, 0, stream>>>(Hh, S2, cN, c, NC, NC);
    g5u(adjb, S2, T1, nullptr, cN, c, cN, cN, cN, c, 0, NC, NC, cBT, 0);
    g5f(T1, wds + 0L * 25600, Dd, dsb0, cR, c, c, c, c, c, FLAG_BIAS | FLAG_ACC);
    transpose_bf16<<<tg, 256, 0, stream>>>(T1, S2, cN, c, NC, NC);
    g5u(adjb, S2, T1, nullptr, cN, c, cN, cN, cN, c, 0, NC, NC, cBT, 0);
    g5f(T1, wds + 1L * 25600, Dd, nullptr, cR, c, c, c, c, c, FLAG_ACC);
    // BN(Dd + H0) -> G1 (stride 192) + lw1
    bn_stats<<<512, c, 0, stream>>>(Dd, H0, stat, c);
    bn_finalize<<<1, c, 0, stream>>>(stat, ng0, nb0, scsh, c);
    bn_apply_concat<<<cR / 8, 192, 0, stream>>>(Dd, H0, scsh, lw1, G1);
  }

  // ---- block 1 (c = 192): chain + skip only ----
  {
    const int c = 192;
    const long NC = (long)cN * c;
    const int scanGrid = (int)(((long)cB * cN * c + 255) / 256);
    for (int l = 0; l < 3; ++l) {
      g6u(G1, wt1 + (long)l * 36864, G2, tb1 + l * c, cR, c, c, c, c, c, FLAG_BIAS);
      scan_syn<<<scanGrid, 256, 0, stream>>>(G2, G1, c);
    }
    g4f(G1 + 11L * NC, wsk1, outacc, skb1, cN, cFF, c, c, c, cFF,
        (long)cT * NC, 0, (long)cN * cFF, cB, FLAG_BIAS | FLAG_ACC | FLAG_RELU);
  }

  // ---- readout (outacc f32 -> bf16 in S2, then two MFMA GEMMs) ----
  cvt_f2bf<<<(int)(((long)cB * cN * cFF + 255) / 256), 256, 0, stream>>>(outacc, S2, (long)cB * cN * cFF);
  g4u(S2, wr1, r1b, rb1, cB * cN, 2 * cFF, cFF, cFF, cFF, 2 * cFF, FLAG_BIAS | FLAG_RELU);
  g4f(r1b, wr2, yb, rb2, cB * cN, cHOR * cF, 2 * cFF, 2 * cFF, 2 * cFF, cHOR * cF,
      0, 0, 0, 1, FLAG_BIAS);
  final_transpose<<<(cB * cHOR * cN * cF) / 256, 256, 0, stream>>>(yb, outF);
}

// Round 5
// 2214.417 us; speedup vs baseline: 1.8194x; 1.1420x over previous
//
#include <hip/hip_runtime.h>

// ======================= types & helpers =======================
using u16 = unsigned short;
typedef short bf16x8 __attribute__((ext_vector_type(8)));
typedef float f32x4  __attribute__((ext_vector_type(4)));

__device__ __forceinline__ float bf2f(u16 u) { return __uint_as_float(((unsigned)u) << 16); }
__device__ __forceinline__ u16 f2bf(float f) {  // round-to-nearest-even
  unsigned u = __float_as_uint(f);
  return (u16)((u + 0x7FFFu + ((u >> 16) & 1u)) >> 16);
}
__device__ __forceinline__ float ldv(const float* p) { return *p; }
__device__ __forceinline__ float ldv(const u16* p)   { return bf2f(*p); }
__device__ __forceinline__ void  stv(float* p, float v) { *p = v; }
__device__ __forceinline__ void  stv(u16* p, float v)   { *p = f2bf(v); }

// ======================= problem constants =======================
constexpr int cB = 4, cT = 12, cN = 2048, cF = 26;
constexpr int cHID = 128, cLF = 32, cFF = 256, cHOR = 12;
constexpr int cE = 16384;
constexpr int cR = cB * cT * cN;   // 98304
constexpr int cBT = cB * cT;       // 48
constexpr float cALPHA = 0.9f, cBETA = 0.8f, cEPS = 1e-5f;

#define FLAG_ACC  1
#define FLAG_BIAS 2
#define FLAG_RELU 4

// ======================= MFMA bf16 GEMM =======================
// C[m,n] = sum_k A[m,k] * BT[n,k]  (+bias) (+C) (relu)
// A: bf16 [M,K] lda ; BT: bf16 [N,K] ldbt (i.e. B transposed).
// M % 128 == 0, K % 32 == 0, lda/ldbt % 8 == 0; N guarded.
// Tile 128 x (NF*32); 4 waves in 2x2; per wave 4x NF frags of 16x16.
// LDS rows padded 32->40 bf16 (80B): frag ds_read_b128 is 2-way (free).
template <int NF, typename TC>
__global__ __launch_bounds__(256)
void gemm_mfma(const u16* __restrict__ A, const u16* __restrict__ BT,
               TC* __restrict__ C, const float* __restrict__ bias,
               int M, int N, int K, int lda, int ldbt, int ldc,
               long batchA, long batchB, long batchC, int flags)
{
  constexpr int TN = NF * 32;
  constexpr int BROWS = 128 + TN;
  __shared__ u16 S[BROWS * 40];    // A rows [0,128), BT rows [128,128+TN)
  A  += (long)blockIdx.z * batchA;
  BT += (long)blockIdx.z * batchB;
  C  += (long)blockIdx.z * batchC;
  const int tid = threadIdx.x;
  const int lane = tid & 63, wid = tid >> 6;
  const int wm = wid & 1, wn = wid >> 1;
  const int m0 = blockIdx.x * 128, n0 = blockIdx.y * TN;
  const int fr = lane & 15, kh = lane >> 4;   // frag row/col, k-half
  f32x4 acc[4][NF];
#pragma unroll
  for (int i = 0; i < 4; ++i)
#pragma unroll
    for (int j = 0; j < NF; ++j) acc[i][j] = f32x4{0.f, 0.f, 0.f, 0.f};

  for (int k0 = 0; k0 < K; k0 += 32) {
    __syncthreads();
    for (int idx = tid; idx < BROWS * 4; idx += 256) {
      const int row = idx >> 2, q = idx & 3;
      uint4 v = {0u, 0u, 0u, 0u};
      if (row < 128) {
        v = *(const uint4*)(A + (long)(m0 + row) * lda + k0 + q * 8);
      } else {
        const int n = n0 + row - 128;
        if (n < N) v = *(const uint4*)(BT + (long)n * ldbt + k0 + q * 8);
      }
      *(uint4*)&S[row * 40 + q * 8] = v;
    }
    __syncthreads();
    bf16x8 af[4];
#pragma unroll
    for (int mf = 0; mf < 4; ++mf)
      af[mf] = *(const bf16x8*)&S[(wm * 64 + mf * 16 + fr) * 40 + kh * 8];
#pragma unroll
    for (int nf = 0; nf < NF; ++nf) {
      const bf16x8 bfr = *(const bf16x8*)&S[(128 + wn * NF * 16 + nf * 16 + fr) * 40 + kh * 8];
#pragma unroll
      for (int mf = 0; mf < 4; ++mf)
        acc[mf][nf] = __builtin_amdgcn_mfma_f32_16x16x32_bf16(af[mf], bfr, acc[mf][nf], 0, 0, 0);
    }
  }

#pragma unroll
  for (int mf = 0; mf < 4; ++mf)
#pragma unroll
    for (int nf = 0; nf < NF; ++nf) {
      const int gn = n0 + wn * NF * 16 + nf * 16 + fr;
      if (gn < N) {
#pragma unroll
        for (int r = 0; r < 4; ++r) {
          const long gm = m0 + wm * 64 + mf * 16 + kh * 4 + r;   // C/D: row=(lane>>4)*4+r
          float v = acc[mf][nf][r];
          if (flags & FLAG_BIAS) v += bias[gn];
          if (flags & FLAG_ACC)  v += ldv(&C[gm * ldc + gn]);
          if (flags & FLAG_RELU) v = fmaxf(v, 0.f);
          stv(&C[gm * ldc + gn], v);
        }
      }
    }
}

// ======================= weight convert + transpose (f32 [K,N] -> bf16 [N,K]) ==========
__global__ __launch_bounds__(256)
void wconvT(const float* __restrict__ w, u16* __restrict__ wt, int K, int N)
{
  const long idx = (long)blockIdx.x * 256 + threadIdx.x;
  if (idx >= (long)K * N) return;
  const int n = (int)(idx / K), k = (int)(idx % K);
  wt[idx] = f2bf(w[(long)k * N + n]);
}

// ======================= tiled bf16 transpose: in [R,Cc] -> out [Cc,R], batched ==========
__global__ __launch_bounds__(256)
void transpose_bf16(const u16* __restrict__ in, u16* __restrict__ out,
                    int R, int Cc, long batchIn, long batchOut)
{
  __shared__ u16 t[64][65];
  in  += (long)blockIdx.z * batchIn;
  out += (long)blockIdx.z * batchOut;
  const int tid = threadIdx.x;
  const int r0 = blockIdx.x * 64, c0 = blockIdx.y * 64;
  for (int i = tid; i < 64 * 64; i += 256) {
    const int r = i >> 6, c = i & 63;
    t[r][c] = (r0 + r < R && c0 + c < Cc) ? in[(long)(r0 + r) * Cc + c0 + c] : (u16)0;
  }
  __syncthreads();
  for (int i = tid; i < 64 * 64; i += 256) {
    const int c = i >> 6, r = i & 63;
    if (c0 + c < Cc && r0 + r < R) out[(long)(c0 + c) * R + r0 + r] = t[r][c];
  }
}

__global__ __launch_bounds__(256)
void cvt_f2bf(const float* __restrict__ in, u16* __restrict__ out, long n)
{
  const long idx = (long)blockIdx.x * 256 + threadIdx.x;
  if (idx < n) out[idx] = f2bf(in[idx]);
}

// ======================= graph preprocessing (CSR build) =======================
__global__ __launch_bounds__(256)
void edge_stats(const int* __restrict__ s, const int* __restrict__ d,
                const float* __restrict__ ew, float* degf, float* degb,
                int* cntf, int* cntb)
{
  const int e = blockIdx.x * 256 + threadIdx.x;
  atomicAdd(&degf[d[e]], ew[e]);
  atomicAdd(&degb[s[e]], ew[e]);
  atomicAdd(&cntf[d[e]], 1);
  atomicAdd(&cntb[s[e]], 1);
}

__global__ __launch_bounds__(256)
void scan2(const int* __restrict__ cf, const int* __restrict__ cb,
           int* __restrict__ rf, int* __restrict__ rb)
{
  const int* c = blockIdx.x ? cb : cf;
  int* r       = blockIdx.x ? rb : rf;
  __shared__ int part[256];
  const int t = threadIdx.x, base = t * 8;
  int loc[8]; int s = 0;
#pragma unroll
  for (int i = 0; i < 8; ++i) { loc[i] = c[base + i]; s += loc[i]; }
  part[t] = s; __syncthreads();
  if (t == 0) {
    int run = 0;
    for (int i = 0; i < 256; ++i) { const int v = part[i]; part[i] = run; run += v; }
    r[2048] = run;
  }
  __syncthreads();
  int run = part[t];
#pragma unroll
  for (int i = 0; i < 8; ++i) { r[base + i] = run; run += loc[i]; }
}

__global__ __launch_bounds__(256)
void fill_csr(const int* __restrict__ s, const int* __restrict__ d,
              const float* __restrict__ ew,
              const float* __restrict__ degf, const float* __restrict__ degb,
              const int* __restrict__ rowf, const int* __restrict__ rowb,
              int* curf, int* curb,
              int* __restrict__ colf, int* __restrict__ colb,
              float* __restrict__ wnf, float* __restrict__ wnb)
{
  const int e = blockIdx.x * 256 + threadIdx.x;
  const int si = s[e], di = d[e];
  const float w = ew[e];
  const int p = rowf[di] + atomicAdd(&curf[di], 1);
  colf[p] = si; wnf[p] = w / fmaxf(degf[di], 1e-6f);
  const int q = rowb[si] + atomicAdd(&curb[si], 1);
  colb[q] = di; wnb[q] = w / fmaxf(degb[si], 1e-6f);
}

// y[bt,n,:] = sum_j w[j]*x[bt,col[j],:]
__global__ __launch_bounds__(256)
void prop_gather(const u16* __restrict__ x, u16* __restrict__ y,
                 const int* __restrict__ rowptr, const int* __restrict__ col,
                 const float* __restrict__ w, int c)
{
  const int n = blockIdx.x, bt = blockIdx.y, ch = threadIdx.x;
  const int beg = rowptr[n], end = rowptr[n + 1];
  const u16* xb = x + (long)bt * cN * c;
  float acc = 0.f;
  for (int j = beg; j < end; ++j)
    acc = fmaf(w[j], bf2f(xb[(long)col[j] * c + ch]), acc);
  y[((long)bt * cN + n) * c + ch] = f2bf(acc);
}

// ======================= encoder =======================
__global__ __launch_bounds__(160)
void encoder(const float* __restrict__ x, const float* __restrict__ ew_,
             const float* __restrict__ eb, const float* __restrict__ ne,
             const float* __restrict__ lw, u16* __restrict__ h)
{
  __shared__ float xs[cF];
  const int tid = threadIdx.x;
  const long r0 = (long)blockIdx.x * 8;
  for (long row = r0; row < r0 + 8; ++row) {
    if (tid < cF) xs[tid] = x[row * cF + tid];
    __syncthreads();
    const int n = (int)(row % cN);
    float v;
    if (tid < cHID) {
      float acc = eb[tid] + ne[(long)n * cHID + tid];
#pragma unroll
      for (int f = 0; f < cF; ++f) acc = fmaf(xs[f], ew_[f * cHID + tid], acc);
      v = acc;
    } else {
      v = lw[(long)n * cLF + (tid - cHID)];
    }
    h[row * 160 + tid] = f2bf(v);
    __syncthreads();
  }
}

// ======================= adjacency: row softmax of relu(scores) ==========
// scores: f32 [cN, cN]; adj out: bf16 [cN, cN]
__global__ __launch_bounds__(256)
void relu_softmax_rows(const float* __restrict__ sc, u16* __restrict__ adj)
{
  const int row = blockIdx.x, tid = threadIdx.x;
  const float* p = sc + (long)row * cN;
  __shared__ float red[256];
  float lv[8];
  float mx = 0.f;   // relu => all >= 0
#pragma unroll
  for (int i = 0; i < 8; ++i) {
    const float v = fmaxf(p[tid + i * 256], 0.f);
    lv[i] = v; mx = fmaxf(mx, v);
  }
  red[tid] = mx; __syncthreads();
  for (int s = 128; s > 0; s >>= 1) { if (tid < s) red[tid] = fmaxf(red[tid], red[tid + s]); __syncthreads(); }
  const float m = red[0]; __syncthreads();
  float sum = 0.f;
#pragma unroll
  for (int i = 0; i < 8; ++i) { lv[i] = __expf(lv[i] - m); sum += lv[i]; }
  red[tid] = sum; __syncthreads();
  for (int s = 128; s > 0; s >>= 1) { if (tid < s) red[tid] += red[tid + s]; __syncthreads(); }
  const float inv = 1.f / red[0]; __syncthreads();
#pragma unroll
  for (int i = 0; i < 8; ++i) adj[(long)row * cN + tid + i * 256] = f2bf(lv[i] * inv);
}

// ======================= temporal 2nd-order LIF scan =======================
__global__ __launch_bounds__(256)
void scan_syn(const u16* __restrict__ in, u16* __restrict__ out, int c)
{
  const long total = (long)cB * cN * c;
  const long idx = (long)blockIdx.x * 256 + threadIdx.x;
  if (idx >= total) return;
  const long nc = (long)cN * c;
  const int b = (int)(idx / nc);
  const long rest = idx % nc;
  const u16* p = in  + (long)b * cT * nc + rest;
  u16*       q = out + (long)b * cT * nc + rest;
  float syn = 0.f, mem = 0.f;
#pragma unroll
  for (int t = 0; t < cT; ++t) {
    syn = fmaf(cALPHA, syn, bf2f(p[(long)t * nc]));
    mem = fmaf(cBETA, mem, syn);
    q[(long)t * nc] = f2bf(mem);
  }
}

// ======================= batch norm =======================
__global__ __launch_bounds__(256)
void bn_stats(const float* __restrict__ d, const u16* __restrict__ res,
              float* __restrict__ stat, int c)
{
  const int ch = threadIdx.x;
  const long r0 = (long)blockIdx.x * (cR / 512);
  float s = 0.f, s2 = 0.f;
  for (int i = 0; i < cR / 512; ++i) {
    const float v = d[(r0 + i) * c + ch] + bf2f(res[(r0 + i) * c + ch]);
    s += v; s2 = fmaf(v, v, s2);
  }
  atomicAdd(&stat[ch], s);
  atomicAdd(&stat[c + ch], s2);
}

__global__ __launch_bounds__(256)
void bn_finalize(const float* __restrict__ stat, const float* __restrict__ g,
                 const float* __restrict__ b, float* __restrict__ scsh, int c)
{
  const int ch = threadIdx.x;
  const float mu = stat[ch] / cR;
  const float var = stat[c + ch] / cR - mu * mu;
  const float sc = g[ch] * rsqrtf(var + cEPS);
  scsh[ch] = sc;
  scsh[c + ch] = fmaf(-mu, sc, b[ch]);
}

__global__ __launch_bounds__(192)
void bn_apply_concat(const float* __restrict__ d, const u16* __restrict__ res,
                     const float* __restrict__ scsh, const float* __restrict__ lw,
                     u16* __restrict__ out)
{
  const int tid = threadIdx.x;
  const long r0 = (long)blockIdx.x * 8;
  for (long row = r0; row < r0 + 8; ++row) {
    const int n = (int)(row % cN);
    float v;
    if (tid < 160) v = fmaf(d[row * 160 + tid] + bf2f(res[row * 160 + tid]),
                            scsh[tid], scsh[160 + tid]);
    else           v = lw[(long)n * cLF + (tid - 160)];
    out[row * 192 + tid] = f2bf(v);
  }
}

// ======================= output transpose (f32 out) =======================
__global__ __launch_bounds__(256)
void final_transpose(const float* __restrict__ y, float* __restrict__ out)
{
  const long idx = (long)blockIdx.x * 256 + threadIdx.x;
  const int f = (int)(idx % cF);
  long t = idx / cF;
  const int n = (int)(t % cN); t /= cN;
  const int hor = (int)(t % cHOR);
  const int b = (int)(t / cHOR);
  out[idx] = y[((long)b * cN + n) * (cHOR * cF) + hor * cF + f];
}

__global__ __launch_bounds__(256)
void fill_f32(float* __restrict__ out, long n, float val)
{
  const long idx = (long)blockIdx.x * 256 + threadIdx.x;
  if (idx < n) out[idx] = val;
}

// ======================= host orchestration =======================
extern "C" void kernel_launch(void* const* d_in, const int* in_sizes, int n_in,
                              void* d_out, int out_size, void* d_ws, size_t ws_size,
                              hipStream_t stream)
{
  float* outF = (float*)d_out;
  const long outN = out_size;
  if (n_in < 34) { fill_f32<<<(int)((outN + 255) / 256), 256, 0, stream>>>(outF, outN, 500.f); return; }
  if (in_sizes[0] != cB * cT * cN * cF || in_sizes[1] != 2 * cE || in_sizes[9] != 3 * 160 * 160) {
    fill_f32<<<(int)((outN + 255) / 256), 256, 0, stream>>>(outF, outN, 700.f); return;
  }

  const float* x        = (const float*)d_in[0];
  const int*   eidx     = (const int*)d_in[1];
  const float* ew       = (const float*)d_in[2];
  const float* enc_w    = (const float*)d_in[3];
  const float* enc_b    = (const float*)d_in[4];
  const float* node_emb = (const float*)d_in[5];
  const float* src_emb  = (const float*)d_in[6];
  const float* tgt_emb  = (const float*)d_in[7];
  const float* lw0  = (const float*)d_in[8];
  const float* tW0  = (const float*)d_in[9];
  const float* tb0  = (const float*)d_in[10];
  const float* dcw0 = (const float*)d_in[11];
  const float* dcb0 = (const float*)d_in[12];
  const float* dsw0 = (const float*)d_in[13];
  const float* dsb0 = (const float*)d_in[14];
  const float* skw0 = (const float*)d_in[15];
  const float* skb0 = (const float*)d_in[16];
  const float* ng0  = (const float*)d_in[17];
  const float* nb0  = (const float*)d_in[18];
  const float* lw1  = (const float*)d_in[19];
  const float* tW1  = (const float*)d_in[20];
  const float* tb1  = (const float*)d_in[21];
  // d_in[22..25, 28..29] feed only block-1's post-skip h (never read) -> dead.
  const float* skw1 = (const float*)d_in[26];
  const float* skb1 = (const float*)d_in[27];
  const float* rw1  = (const float*)d_in[30];
  const float* rb1  = (const float*)d_in[31];
  const float* rw2  = (const float*)d_in[32];
  const float* rb2  = (const float*)d_in[33];
  const int* srcI = eidx;
  const int* dstI = eidx + cE;

  // ---- workspace layout ----
  char* W = (char*)d_ws;
  size_t off = 0;
  auto A8 = [&](size_t bytes) { size_t r = off; off = (off + bytes + 255) & ~(size_t)255; return r; };
  const size_t oH0 = A8((size_t)cR * 160 * 2);   // res, bf16
  const size_t oHh = A8((size_t)cR * 160 * 2);   // chain h (G1 [cR,192] aliases Hh+T1-head)
  const size_t oT1 = A8((size_t)cR * 160 * 2);   // scratch
  const size_t oS2 = A8((size_t)cR * 160 * 2);   // scratch2 / hT / outaccB
  const size_t oDd = A8((size_t)cR * 160 * 4);   // f32 accumulator (G2, scores alias)
  const size_t oAdj = A8((size_t)cN * cN * 2);
  const size_t oOut = A8((size_t)cB * cN * cFF * 4);       // f32 skip acc (t=11)
  const size_t oR1  = A8((size_t)cB * cN * 512 * 2);       // bf16 r1
  const size_t oY   = A8((size_t)cB * cN * cHOR * cF * 4); // f32
  const size_t oZero = A8(6 * 2048 * 4 + 2 * 192 * 4);
  const size_t oRowf = A8(2049 * 4), oRowb = A8(2049 * 4);
  const size_t oColf = A8((size_t)cE * 4), oColb = A8((size_t)cE * 4);
  const size_t oWnf  = A8((size_t)cE * 4), oWnb  = A8((size_t)cE * 4);
  const size_t oScSh = A8(2 * 192 * 4);
  const size_t oWT   = A8((size_t)721920 * 2);   // bf16 transposed weights
  const size_t oSeb  = A8((size_t)cN * cHID * 2);
  const size_t oTeb  = A8((size_t)cN * cHID * 2);
  if (off > ws_size) {
    fill_f32<<<(int)((outN + 255) / 256), 256, 0, stream>>>(outF, outN, 300.f);
    return;
  }

  u16 *H0 = (u16*)(W + oH0), *Hh = (u16*)(W + oHh), *T1 = (u16*)(W + oT1),
      *S2 = (u16*)(W + oS2), *adjb = (u16*)(W + oAdj);
  float* Dd = (float*)(W + oDd);
  u16 *G1 = (u16*)(W + oHh);   // [cR,192] bf16 over Hh(+T1 head), post-BN only
  u16 *G2 = (u16*)(W + oDd);   // over Dd, post-BN only
  float* scores = (float*)(W + oDd);   // phase-0 scratch (16.8 MB <= 63 MB), dead before Dd use
  float *outacc = (float*)(W + oOut), *yb = (float*)(W + oY);
  u16 *r1b = (u16*)(W + oR1);
  float* zero = (float*)(W + oZero);
  float *degf = zero, *degb = zero + 2048;
  int *cntf = (int*)(zero + 4096), *cntb = cntf + 2048,
      *curf = cntb + 2048, *curb = curf + 2048;
  float* stat = (float*)(curb + 2048);
  int *rowf = (int*)(W + oRowf), *rowb = (int*)(W + oRowb);
  int *colf = (int*)(W + oColf), *colb = (int*)(W + oColb);
  float *wnf = (float*)(W + oWnf), *wnb = (float*)(W + oWnb);
  float* scsh = (float*)(W + oScSh);
  u16* wt   = (u16*)(W + oWT);
  u16 *wt0 = wt,             *wt1 = wt0 + 3 * 25600,  *wdc = wt1 + 3 * 36864,
      *wds = wdc + 4 * 25600, *wsk0 = wds + 2 * 25600, *wsk1 = wsk0 + 40960,
      *wr1 = wsk1 + 49152,    *wr2 = wr1 + 131072;
  u16 *seb = (u16*)(W + oSeb), *teb = (u16*)(W + oTeb);

  auto g5u = [&](const u16* Aq, const u16* Bq, u16* Cq, const float* bias,
                 int M, int N, int K, int lda, int ldbt, int ldc,
                 long bA, long bB, long bC, int batch, int flags) {
    dim3 g(M / 128, (N + 159) / 160, batch);
    gemm_mfma<5, u16><<<g, 256, 0, stream>>>(Aq, Bq, Cq, bias, M, N, K, lda, ldbt, ldc, bA, bB, bC, flags);
  };
  auto g5f = [&](const u16* Aq, const u16* Bq, float* Cq, const float* bias,
                 int M, int N, int K, int lda, int ldbt, int ldc, int flags) {
    dim3 g(M / 128, (N + 159) / 160, 1);
    gemm_mfma<5, float><<<g, 256, 0, stream>>>(Aq, Bq, Cq, bias, M, N, K, lda, ldbt, ldc, 0, 0, 0, flags);
  };
  auto g6u = [&](const u16* Aq, const u16* Bq, u16* Cq, const float* bias,
                 int M, int N, int K, int lda, int ldbt, int ldc, int flags) {
    dim3 g(M / 128, (N + 191) / 192, 1);
    gemm_mfma<6, u16><<<g, 256, 0, stream>>>(Aq, Bq, Cq, bias, M, N, K, lda, ldbt, ldc, 0, 0, 0, flags);
  };
  auto g4f = [&](const u16* Aq, const u16* Bq, float* Cq, const float* bias,
                 int M, int N, int K, int lda, int ldbt, int ldc,
                 long bA, long bB, long bC, int batch, int flags) {
    dim3 g(M / 128, (N + 127) / 128, batch);
    gemm_mfma<4, float><<<g, 256, 0, stream>>>(Aq, Bq, Cq, bias, M, N, K, lda, ldbt, ldc, bA, bB, bC, flags);
  };
  auto g4u = [&](const u16* Aq, const u16* Bq, u16* Cq, const float* bias,
                 int M, int N, int K, int lda, int ldbt, int ldc, int flags) {
    dim3 g(M / 128, (N + 127) / 128, 1);
    gemm_mfma<4, u16><<<g, 256, 0, stream>>>(Aq, Bq, Cq, bias, M, N, K, lda, ldbt, ldc, 0, 0, 0, flags);
  };
  auto wcv = [&](const float* src, u16* dst, int K, int N) {
    wconvT<<<(int)(((long)K * N + 255) / 256), 256, 0, stream>>>(src, dst, K, N);
  };

  // ---- phase 0: weight conversion, CSR, encoder, adjacency ----
  for (int l = 0; l < 3; ++l) wcv(tW0 + (long)l * 25600, wt0 + (long)l * 25600, 160, 160);
  for (int l = 0; l < 3; ++l) wcv(tW1 + (long)l * 36864, wt1 + (long)l * 36864, 192, 192);
  for (int i = 0; i < 4; ++i) wcv(dcw0 + (long)i * 25600, wdc + (long)i * 25600, 160, 160);
  for (int i = 0; i < 2; ++i) wcv(dsw0 + (long)i * 25600, wds + (long)i * 25600, 160, 160);
  wcv(skw0, wsk0, 160, 256);
  wcv(skw1, wsk1, 192, 256);
  wcv(rw1, wr1, 256, 512);
  wcv(rw2, wr2, 512, 312);

  hipMemsetAsync(zero, 0, 6 * 2048 * 4 + 2 * 192 * 4, stream);
  edge_stats<<<cE / 256, 256, 0, stream>>>(srcI, dstI, ew, degf, degb, cntf, cntb);
  scan2<<<2, 256, 0, stream>>>(cntf, cntb, rowf, rowb);
  fill_csr<<<cE / 256, 256, 0, stream>>>(srcI, dstI, ew, degf, degb, rowf, rowb,
                                         curf, curb, colf, colb, wnf, wnb);
  encoder<<<cR / 8, 160, 0, stream>>>(x, enc_w, enc_b, node_emb, lw0, H0);

  // learned adjacency: scores = se @ te^T via MFMA, then row relu-softmax
  cvt_f2bf<<<(cN * cHID + 255) / 256, 256, 0, stream>>>(src_emb, seb, (long)cN * cHID);
  cvt_f2bf<<<(cN * cHID + 255) / 256, 256, 0, stream>>>(tgt_emb, teb, (long)cN * cHID);
  g4f(seb, teb, scores, nullptr, cN, cN, cHID, cHID, cHID, cN, 0, 0, 0, 1, 0);
  relu_softmax_rows<<<cN, 256, 0, stream>>>(scores, adjb);

  // ---- block 0 (c = 160) ----
  {
    const int c = 160;
    const long NC = (long)cN * c;
    const int scanGrid = (int)(((long)cB * cN * c + 255) / 256);
    // synaptic chain: H0 (res) -> Hh
    g5u(H0, wt0 + 0L * 25600, T1, tb0 + 0 * c, cR, c, c, c, c, c, 0, 0, 0, 1, FLAG_BIAS);
    scan_syn<<<scanGrid, 256, 0, stream>>>(T1, Hh, c);
    for (int l = 1; l < 3; ++l) {
      g5u(Hh, wt0 + (long)l * 25600, T1, tb0 + l * c, cR, c, c, c, c, c, 0, 0, 0, 1, FLAG_BIAS);
      scan_syn<<<scanGrid, 256, 0, stream>>>(T1, Hh, c);
    }
    // skip (t=11): outacc[b] = h[b,11]@skw0 + skb0
    g4f(Hh + 11L * NC, wsk0, outacc, skb0, cN, cFF, c, c, c, cFF,
        (long)cT * NC, 0, (long)cN * cFF, cB, FLAG_BIAS);
    // diffconv
    dim3 pg(cN, cBT);
    prop_gather<<<pg, c, 0, stream>>>(Hh, T1, rowf, colf, wnf, c);
    g5f(T1, wdc + 0L * 25600, Dd, dcb0, cR, c, c, c, c, c, FLAG_BIAS);
    prop_gather<<<pg, c, 0, stream>>>(T1, S2, rowf, colf, wnf, c);
    g5f(S2, wdc + 1L * 25600, Dd, nullptr, cR, c, c, c, c, c, FLAG_ACC);
    prop_gather<<<pg, c, 0, stream>>>(Hh, T1, rowb, colb, wnb, c);
    g5f(T1, wdc + 2L * 25600, Dd, nullptr, cR, c, c, c, c, c, FLAG_ACC);
    prop_gather<<<pg, c, 0, stream>>>(T1, S2, rowb, colb, wnb, c);
    g5f(S2, wdc + 3L * 25600, Dd, nullptr, cR, c, c, c, c, c, FLAG_ACC);
    // dense conv: hT -> S2 ; x1 = adj@h -> T1 ; Dd += x1@dsw0 ; x1T -> S2 ; x2 -> T1 ; Dd += x2@dsw1
    dim3 tg(cN / 64, (c + 63) / 64, cBT);
    transpose_bf16<<<tg, 256, 0, stream>>>(Hh, S2, cN, c, NC, NC);
    g5u(adjb, S2, T1, nullptr, cN, c, cN, cN, cN, c, 0, NC, NC, cBT, 0);
    g5f(T1, wds + 0L * 25600, Dd, dsb0, cR, c, c, c, c, c, FLAG_BIAS | FLAG_ACC);
    transpose_bf16<<<tg, 256, 0, stream>>>(T1, S2, cN, c, NC, NC);
    g5u(adjb, S2, T1, nullptr, cN, c, cN, cN, cN, c, 0, NC, NC, cBT, 0);
    g5f(T1, wds + 1L * 25600, Dd, nullptr, cR, c, c, c, c, c, FLAG_ACC);
    // BN(Dd + H0) -> G1 (stride 192) + lw1
    bn_stats<<<512, c, 0, stream>>>(Dd, H0, stat, c);
    bn_finalize<<<1, c, 0, stream>>>(stat, ng0, nb0, scsh, c);
    bn_apply_concat<<<cR / 8, 192, 0, stream>>>(Dd, H0, scsh, lw1, G1);
  }

  // ---- block 1 (c = 192): chain + skip only ----
  {
    const int c = 192;
    const long NC = (long)cN * c;
    const int scanGrid = (int)(((long)cB * cN * c + 255) / 256);
    for (int l = 0; l < 3; ++l) {
      g6u(G1, wt1 + (long)l * 36864, G2, tb1 + l * c, cR, c, c, c, c, c, FLAG_BIAS);
      scan_syn<<<scanGrid, 256, 0, stream>>>(G2, G1, c);
    }
    g4f(G1 + 11L * NC, wsk1, outacc, skb1, cN, cFF, c, c, c, cFF,
        (long)cT * NC, 0, (long)cN * cFF, cB, FLAG_BIAS | FLAG_ACC | FLAG_RELU);
  }

  // ---- readout (outacc f32 -> bf16 in S2, then two MFMA GEMMs) ----
  cvt_f2bf<<<(int)(((long)cB * cN * cFF + 255) / 256), 256, 0, stream>>>(outacc, S2, (long)cB * cN * cFF);
  g4u(S2, wr1, r1b, rb1, cB * cN, 2 * cFF, cFF, cFF, cFF, 2 * cFF, FLAG_BIAS | FLAG_RELU);
  g4f(r1b, wr2, yb, rb2, cB * cN, cHOR * cF, 2 * cFF, 2 * cFF, 2 * cFF, cHOR * cF,
      0, 0, 0, 1, FLAG_BIAS);
  final_transpose<<<(cB * cHOR * cN * cF) / 256, 256, 0, stream>>>(yb, outF);
}

// Round 6
// 1750.330 us; speedup vs baseline: 2.3018x; 1.2651x over previous
//
#include <hip/hip_runtime.h>

// ======================= types & helpers =======================
using u16 = unsigned short;
typedef short bf16x8 __attribute__((ext_vector_type(8)));
typedef float f32x4  __attribute__((ext_vector_type(4)));

__device__ __forceinline__ float bf2f(u16 u) { return __uint_as_float(((unsigned)u) << 16); }
__device__ __forceinline__ u16 f2bf(float f) {  // round-to-nearest-even
  unsigned u = __float_as_uint(f);
  return (u16)((u + 0x7FFFu + ((u >> 16) & 1u)) >> 16);
}
__device__ __forceinline__ float ldv(const float* p) { return *p; }
__device__ __forceinline__ float ldv(const u16* p)   { return bf2f(*p); }
__device__ __forceinline__ void  stv(float* p, float v) { *p = v; }
__device__ __forceinline__ void  stv(u16* p, float v)   { *p = f2bf(v); }

// ======================= problem constants =======================
constexpr int cB = 4, cT = 12, cN = 2048, cF = 26;
constexpr int cHID = 128, cLF = 32, cFF = 256, cHOR = 12;
constexpr int cE = 16384;
constexpr int cR = cB * cT * cN;   // 98304
constexpr int cBT = cB * cT;       // 48
constexpr float cALPHA = 0.9f, cBETA = 0.8f, cEPS = 1e-5f;

#define FLAG_ACC  1
#define FLAG_BIAS 2
#define FLAG_RELU 4

// ======================= MFMA bf16 GEMM (global_load_lds staging) =======================
// C[m,n] = sum_k A[m,k] * BT[n,k]  (+bias) (+C) (relu)
// A: bf16 [M,K] lda ; BT: bf16 [N,K] ldbt. M%128==0, K%32==0, lda/ldbt%8==0; N guarded
// (OOB B rows clamp to N-1; their output columns are never stored).
// LDS: linear [128+TN][32] bf16 (64B rows). Staging via global_load_lds width 16:
// wave-instr s writes 64 contiguous 16B slots at S + s*1024B from per-lane global addrs.
template <int NF, typename TC>
__global__ __launch_bounds__(256)
void gemm_mfma(const u16* __restrict__ A, const u16* __restrict__ BT,
               TC* __restrict__ C, const float* __restrict__ bias,
               int M, int N, int K, int lda, int ldbt, int ldc,
               long batchA, long batchB, long batchC, int flags)
{
  constexpr int TN = NF * 32;
  constexpr int ROWS = 128 + TN;        // A rows then BT rows
  constexpr int NINST = ROWS / 16;      // wave-instrs per K-step (16 rows each)
  __shared__ __align__(16) u16 S[ROWS * 32];
  A  += (long)blockIdx.z * batchA;
  BT += (long)blockIdx.z * batchB;
  C  += (long)blockIdx.z * batchC;
  const int tid = threadIdx.x;
  const int lane = tid & 63, wid = tid >> 6;
  const int wm = wid & 1, wn = wid >> 1;
  const int m0 = blockIdx.x * 128, n0 = blockIdx.y * TN;
  const int fr = lane & 15, kh = lane >> 4;   // frag row / k-half
  f32x4 acc[4][NF];
#pragma unroll
  for (int i = 0; i < 4; ++i)
#pragma unroll
    for (int j = 0; j < NF; ++j) acc[i][j] = f32x4{0.f, 0.f, 0.f, 0.f};

  for (int k0 = 0; k0 < K; k0 += 32) {
    __syncthreads();                     // prior K-step's reads done
    for (int s = wid; s < NINST; s += 4) {
      const int slot = s * 64 + lane;    // 16B slot index
      const int row = slot >> 2, q = slot & 3;
      const u16* g;
      if (row < 128) {
        g = A + (long)(m0 + row) * lda + k0 + q * 8;
      } else {
        const int n = min(n0 + row - 128, N - 1);
        g = BT + (long)n * ldbt + k0 + q * 8;
      }
      __builtin_amdgcn_global_load_lds(
          (const __attribute__((address_space(1))) unsigned int*)g,
          (__attribute__((address_space(3))) unsigned int*)&S[s * 512],
          16, 0, 0);
    }
    __syncthreads();                     // drains vmcnt -> LDS tile ready
    bf16x8 af[4];
#pragma unroll
    for (int mf = 0; mf < 4; ++mf)
      af[mf] = *(const bf16x8*)&S[(wm * 64 + mf * 16 + fr) * 32 + kh * 8];
#pragma unroll
    for (int nf = 0; nf < NF; ++nf) {
      const bf16x8 bfr = *(const bf16x8*)&S[(128 + wn * NF * 16 + nf * 16 + fr) * 32 + kh * 8];
#pragma unroll
      for (int mf = 0; mf < 4; ++mf)
        acc[mf][nf] = __builtin_amdgcn_mfma_f32_16x16x32_bf16(af[mf], bfr, acc[mf][nf], 0, 0, 0);
    }
  }

#pragma unroll
  for (int mf = 0; mf < 4; ++mf)
#pragma unroll
    for (int nf = 0; nf < NF; ++nf) {
      const int gn = n0 + wn * NF * 16 + nf * 16 + fr;
      if (gn < N) {
#pragma unroll
        for (int r = 0; r < 4; ++r) {
          const long gm = m0 + wm * 64 + mf * 16 + kh * 4 + r;   // C/D: row=(lane>>4)*4+r
          float v = acc[mf][nf][r];
          if (flags & FLAG_BIAS) v += bias[gn];
          if (flags & FLAG_ACC)  v += ldv(&C[gm * ldc + gn]);
          if (flags & FLAG_RELU) v = fmaxf(v, 0.f);
          stv(&C[gm * ldc + gn], v);
        }
      }
    }
}

// ======================= weight convert + transpose (f32 [K,N] -> bf16 [N,K]) ==========
__global__ __launch_bounds__(256)
void wconvT(const float* __restrict__ w, u16* __restrict__ wt, int K, int N)
{
  const long idx = (long)blockIdx.x * 256 + threadIdx.x;
  if (idx >= (long)K * N) return;
  const int n = (int)(idx / K), k = (int)(idx % K);
  wt[idx] = f2bf(w[(long)k * N + n]);
}

// ======================= tiled bf16 transpose: in [R,Cc] -> out [Cc,R], batched ==========
__global__ __launch_bounds__(256)
void transpose_bf16(const u16* __restrict__ in, u16* __restrict__ out,
                    int R, int Cc, long batchIn, long batchOut)
{
  __shared__ u16 t[64][65];
  in  += (long)blockIdx.z * batchIn;
  out += (long)blockIdx.z * batchOut;
  const int tid = threadIdx.x;
  const int r0 = blockIdx.x * 64, c0 = blockIdx.y * 64;
  for (int i = tid; i < 64 * 64; i += 256) {
    const int r = i >> 6, c = i & 63;
    t[r][c] = (r0 + r < R && c0 + c < Cc) ? in[(long)(r0 + r) * Cc + c0 + c] : (u16)0;
  }
  __syncthreads();
  for (int i = tid; i < 64 * 64; i += 256) {
    const int c = i >> 6, r = i & 63;
    if (c0 + c < Cc && r0 + r < R) out[(long)(c0 + c) * R + r0 + r] = t[r][c];
  }
}

__global__ __launch_bounds__(256)
void cvt_f2bf(const float* __restrict__ in, u16* __restrict__ out, long n)
{
  const long idx = (long)blockIdx.x * 256 + threadIdx.x;
  if (idx < n) out[idx] = f2bf(in[idx]);
}

// ======================= graph preprocessing (CSR build) =======================
__global__ __launch_bounds__(256)
void edge_stats(const int* __restrict__ s, const int* __restrict__ d,
                const float* __restrict__ ew, float* degf, float* degb,
                int* cntf, int* cntb)
{
  const int e = blockIdx.x * 256 + threadIdx.x;
  atomicAdd(&degf[d[e]], ew[e]);
  atomicAdd(&degb[s[e]], ew[e]);
  atomicAdd(&cntf[d[e]], 1);
  atomicAdd(&cntb[s[e]], 1);
}

__global__ __launch_bounds__(256)
void scan2(const int* __restrict__ cf, const int* __restrict__ cb,
           int* __restrict__ rf, int* __restrict__ rb)
{
  const int* c = blockIdx.x ? cb : cf;
  int* r       = blockIdx.x ? rb : rf;
  __shared__ int part[256];
  const int t = threadIdx.x, base = t * 8;
  int loc[8]; int s = 0;
#pragma unroll
  for (int i = 0; i < 8; ++i) { loc[i] = c[base + i]; s += loc[i]; }
  part[t] = s; __syncthreads();
  if (t == 0) {
    int run = 0;
    for (int i = 0; i < 256; ++i) { const int v = part[i]; part[i] = run; run += v; }
    r[2048] = run;
  }
  __syncthreads();
  int run = part[t];
#pragma unroll
  for (int i = 0; i < 8; ++i) { r[base + i] = run; run += loc[i]; }
}

__global__ __launch_bounds__(256)
void fill_csr(const int* __restrict__ s, const int* __restrict__ d,
              const float* __restrict__ ew,
              const float* __restrict__ degf, const float* __restrict__ degb,
              const int* __restrict__ rowf, const int* __restrict__ rowb,
              int* curf, int* curb,
              int* __restrict__ colf, int* __restrict__ colb,
              float* __restrict__ wnf, float* __restrict__ wnb)
{
  const int e = blockIdx.x * 256 + threadIdx.x;
  const int si = s[e], di = d[e];
  const float w = ew[e];
  const int p = rowf[di] + atomicAdd(&curf[di], 1);
  colf[p] = si; wnf[p] = w / fmaxf(degf[di], 1e-6f);
  const int q = rowb[si] + atomicAdd(&curb[si], 1);
  colb[q] = di; wnb[q] = w / fmaxf(degb[si], 1e-6f);
}

// y[bt,n,:] = sum_j w[j]*x[bt,col[j],:]   (ldx/ldy allow column-block packing)
__global__ __launch_bounds__(256)
void prop_gather(const u16* __restrict__ x, int ldx, u16* __restrict__ y, int ldy,
                 const int* __restrict__ rowptr, const int* __restrict__ col,
                 const float* __restrict__ w)
{
  const int n = blockIdx.x, bt = blockIdx.y, ch = threadIdx.x;
  const int beg = rowptr[n], end = rowptr[n + 1];
  const u16* xb = x + (long)bt * cN * ldx;
  float acc = 0.f;
  for (int j = beg; j < end; ++j)
    acc = fmaf(w[j], bf2f(xb[(long)col[j] * ldx + ch]), acc);
  y[((long)bt * cN + n) * ldy + ch] = f2bf(acc);
}

// ======================= encoder =======================
__global__ __launch_bounds__(160)
void encoder(const float* __restrict__ x, const float* __restrict__ ew_,
             const float* __restrict__ eb, const float* __restrict__ ne,
             const float* __restrict__ lw, u16* __restrict__ h)
{
  __shared__ float xs[cF];
  const int tid = threadIdx.x;
  const long r0 = (long)blockIdx.x * 8;
  for (long row = r0; row < r0 + 8; ++row) {
    if (tid < cF) xs[tid] = x[row * cF + tid];
    __syncthreads();
    const int n = (int)(row % cN);
    float v;
    if (tid < cHID) {
      float acc = eb[tid] + ne[(long)n * cHID + tid];
#pragma unroll
      for (int f = 0; f < cF; ++f) acc = fmaf(xs[f], ew_[f * cHID + tid], acc);
      v = acc;
    } else {
      v = lw[(long)n * cLF + (tid - cHID)];
    }
    h[row * 160 + tid] = f2bf(v);
    __syncthreads();
  }
}

// ======================= adjacency: row softmax of relu(scores) ==========
__global__ __launch_bounds__(256)
void relu_softmax_rows(const float* __restrict__ sc, u16* __restrict__ adj)
{
  const int row = blockIdx.x, tid = threadIdx.x;
  const float* p = sc + (long)row * cN;
  __shared__ float red[256];
  float lv[8];
  float mx = 0.f;   // relu => all >= 0
#pragma unroll
  for (int i = 0; i < 8; ++i) {
    const float v = fmaxf(p[tid + i * 256], 0.f);
    lv[i] = v; mx = fmaxf(mx, v);
  }
  red[tid] = mx; __syncthreads();
  for (int s = 128; s > 0; s >>= 1) { if (tid < s) red[tid] = fmaxf(red[tid], red[tid + s]); __syncthreads(); }
  const float m = red[0]; __syncthreads();
  float sum = 0.f;
#pragma unroll
  for (int i = 0; i < 8; ++i) { lv[i] = __expf(lv[i] - m); sum += lv[i]; }
  red[tid] = sum; __syncthreads();
  for (int s = 128; s > 0; s >>= 1) { if (tid < s) red[tid] += red[tid + s]; __syncthreads(); }
  const float inv = 1.f / red[0]; __syncthreads();
#pragma unroll
  for (int i = 0; i < 8; ++i) adj[(long)row * cN + tid + i * 256] = f2bf(lv[i] * inv);
}

// ======================= temporal 2nd-order LIF scan =======================
__global__ __launch_bounds__(256)
void scan_syn(const u16* __restrict__ in, u16* __restrict__ out, int c)
{
  const long total = (long)cB * cN * c;
  const long idx = (long)blockIdx.x * 256 + threadIdx.x;
  if (idx >= total) return;
  const long nc = (long)cN * c;
  const int b = (int)(idx / nc);
  const long rest = idx % nc;
  const u16* p = in  + (long)b * cT * nc + rest;
  u16*       q = out + (long)b * cT * nc + rest;
  float syn = 0.f, mem = 0.f;
#pragma unroll
  for (int t = 0; t < cT; ++t) {
    syn = fmaf(cALPHA, syn, bf2f(p[(long)t * nc]));
    mem = fmaf(cBETA, mem, syn);
    q[(long)t * nc] = f2bf(mem);
  }
}

// ======================= batch norm =======================
__global__ __launch_bounds__(256)
void bn_stats(const float* __restrict__ d, const u16* __restrict__ res,
              float* __restrict__ stat, int c)
{
  const int ch = threadIdx.x;
  const long r0 = (long)blockIdx.x * (cR / 512);
  float s = 0.f, s2 = 0.f;
  for (int i = 0; i < cR / 512; ++i) {
    const float v = d[(r0 + i) * c + ch] + bf2f(res[(r0 + i) * c + ch]);
    s += v; s2 = fmaf(v, v, s2);
  }
  atomicAdd(&stat[ch], s);
  atomicAdd(&stat[c + ch], s2);
}

__global__ __launch_bounds__(256)
void bn_finalize(const float* __restrict__ stat, const float* __restrict__ g,
                 const float* __restrict__ b, float* __restrict__ scsh, int c)
{
  const int ch = threadIdx.x;
  const float mu = stat[ch] / cR;
  const float var = stat[c + ch] / cR - mu * mu;
  const float sc = g[ch] * rsqrtf(var + cEPS);
  scsh[ch] = sc;
  scsh[c + ch] = fmaf(-mu, sc, b[ch]);
}

__global__ __launch_bounds__(192)
void bn_apply_concat(const float* __restrict__ d, const u16* __restrict__ res,
                     const float* __restrict__ scsh, const float* __restrict__ lw,
                     u16* __restrict__ out)
{
  const int tid = threadIdx.x;
  const long r0 = (long)blockIdx.x * 8;
  for (long row = r0; row < r0 + 8; ++row) {
    const int n = (int)(row % cN);
    float v;
    if (tid < 160) v = fmaf(d[row * 160 + tid] + bf2f(res[row * 160 + tid]),
                            scsh[tid], scsh[160 + tid]);
    else           v = lw[(long)n * cLF + (tid - 160)];
    out[row * 192 + tid] = f2bf(v);
  }
}

// ======================= output transpose (f32 out) =======================
__global__ __launch_bounds__(256)
void final_transpose(const float* __restrict__ y, float* __restrict__ out)
{
  const long idx = (long)blockIdx.x * 256 + threadIdx.x;
  const int f = (int)(idx % cF);
  long t = idx / cF;
  const int n = (int)(t % cN); t /= cN;
  const int hor = (int)(t % cHOR);
  const int b = (int)(t / cHOR);
  out[idx] = y[((long)b * cN + n) * (cHOR * cF) + hor * cF + f];
}

__global__ __launch_bounds__(256)
void fill_f32(float* __restrict__ out, long n, float val)
{
  const long idx = (long)blockIdx.x * 256 + threadIdx.x;
  if (idx < n) out[idx] = val;
}

// ======================= host orchestration =======================
extern "C" void kernel_launch(void* const* d_in, const int* in_sizes, int n_in,
                              void* d_out, int out_size, void* d_ws, size_t ws_size,
                              hipStream_t stream)
{
  float* outF = (float*)d_out;
  const long outN = out_size;
  if (n_in < 34) { fill_f32<<<(int)((outN + 255) / 256), 256, 0, stream>>>(outF, outN, 500.f); return; }
  if (in_sizes[0] != cB * cT * cN * cF || in_sizes[1] != 2 * cE || in_sizes[9] != 3 * 160 * 160) {
    fill_f32<<<(int)((outN + 255) / 256), 256, 0, stream>>>(outF, outN, 700.f); return;
  }

  const float* x        = (const float*)d_in[0];
  const int*   eidx     = (const int*)d_in[1];
  const float* ew       = (const float*)d_in[2];
  const float* enc_w    = (const float*)d_in[3];
  const float* enc_b    = (const float*)d_in[4];
  const float* node_emb = (const float*)d_in[5];
  const float* src_emb  = (const float*)d_in[6];
  const float* tgt_emb  = (const float*)d_in[7];
  const float* lw0  = (const float*)d_in[8];
  const float* tW0  = (const float*)d_in[9];
  const float* tb0  = (const float*)d_in[10];
  const float* dcw0 = (const float*)d_in[11];
  const float* dcb0 = (const float*)d_in[12];
  const float* dsw0 = (const float*)d_in[13];
  const float* dsb0 = (const float*)d_in[14];
  const float* skw0 = (const float*)d_in[15];
  const float* skb0 = (const float*)d_in[16];
  const float* ng0  = (const float*)d_in[17];
  const float* nb0  = (const float*)d_in[18];
  const float* lw1  = (const float*)d_in[19];
  const float* tW1  = (const float*)d_in[20];
  const float* tb1  = (const float*)d_in[21];
  // d_in[22..25, 28..29] feed only block-1's post-skip h (never read) -> dead.
  const float* skw1 = (const float*)d_in[26];
  const float* skb1 = (const float*)d_in[27];
  const float* rw1  = (const float*)d_in[30];
  const float* rb1  = (const float*)d_in[31];
  const float* rw2  = (const float*)d_in[32];
  const float* rb2  = (const float*)d_in[33];
  const int* srcI = eidx;
  const int* dstI = eidx + cE;

  // ---- workspace layout ----
  char* W = (char*)d_ws;
  size_t off = 0;
  auto A8 = [&](size_t bytes) { size_t r = off; off = (off + bytes + 255) & ~(size_t)255; return r; };
  const size_t oH0 = A8((size_t)cR * 160 * 2);   // res, bf16
  const size_t oHh = A8((size_t)cR * 160 * 2);   // chain h (G1 [cR,192] aliases Hh+T1-head)
  const size_t oT1 = A8((size_t)cR * 160 * 2);   // scratch (Z12 [cR,320] aliases T1+S2)
  const size_t oS2 = A8((size_t)cR * 160 * 2);   // scratch2 / hT
  const size_t oDd = A8((size_t)cR * 160 * 4);   // f32 accumulator (G2, scores alias)
  const size_t oAdj = A8((size_t)cN * cN * 2);
  const size_t oOut = A8((size_t)cB * cN * cFF * 4);       // f32 skip acc (t=11)
  const size_t oR1  = A8((size_t)cB * cN * 512 * 2);       // bf16 r1
  const size_t oY   = A8((size_t)cB * cN * cHOR * cF * 4); // f32
  const size_t oZero = A8(6 * 2048 * 4 + 2 * 192 * 4);
  const size_t oRowf = A8(2049 * 4), oRowb = A8(2049 * 4);
  const size_t oColf = A8((size_t)cE * 4), oColb = A8((size_t)cE * 4);
  const size_t oWnf  = A8((size_t)cE * 4), oWnb  = A8((size_t)cE * 4);
  const size_t oScSh = A8(2 * 192 * 4);
  const size_t oWT   = A8((size_t)721920 * 2);   // bf16 transposed weights
  const size_t oSeb  = A8((size_t)cN * cHID * 2);
  const size_t oTeb  = A8((size_t)cN * cHID * 2);
  if (off > ws_size) {
    fill_f32<<<(int)((outN + 255) / 256), 256, 0, stream>>>(outF, outN, 300.f);
    return;
  }

  u16 *H0 = (u16*)(W + oH0), *Hh = (u16*)(W + oHh), *T1 = (u16*)(W + oT1),
      *S2 = (u16*)(W + oS2), *adjb = (u16*)(W + oAdj);
  float* Dd = (float*)(W + oDd);
  u16 *G1 = (u16*)(W + oHh);   // [cR,192] bf16 over Hh(+T1 head), post-BN only
  u16 *G2 = (u16*)(W + oDd);   // over Dd, post-BN only
  u16 *Z12 = T1;               // [cR,320] bf16 over T1+S2 (diffconv packing)
  float* scores = (float*)(W + oDd);   // phase-0 scratch, dead before Dd use
  float *outacc = (float*)(W + oOut), *yb = (float*)(W + oY);
  u16 *r1b = (u16*)(W + oR1);
  float* zero = (float*)(W + oZero);
  float *degf = zero, *degb = zero + 2048;
  int *cntf = (int*)(zero + 4096), *cntb = cntf + 2048,
      *curf = cntb + 2048, *curb = curf + 2048;
  float* stat = (float*)(curb + 2048);
  int *rowf = (int*)(W + oRowf), *rowb = (int*)(W + oRowb);
  int *colf = (int*)(W + oColf), *colb = (int*)(W + oColb);
  float *wnf = (float*)(W + oWnf), *wnb = (float*)(W + oWnb);
  float* scsh = (float*)(W + oScSh);
  u16* wt   = (u16*)(W + oWT);
  u16 *wt0 = wt,              *wt1 = wt0 + 3 * 25600, *wdc = wt1 + 3 * 36864,
      *wds = wdc + 102400,    *wsk0 = wds + 51200,    *wsk1 = wsk0 + 40960,
      *wr1 = wsk1 + 49152,    *wr2 = wr1 + 131072;
  u16 *seb = (u16*)(W + oSeb), *teb = (u16*)(W + oTeb);

  auto g5u = [&](const u16* Aq, const u16* Bq, u16* Cq, const float* bias,
                 int M, int N, int K, int lda, int ldbt, int ldc,
                 long bA, long bB, long bC, int batch, int flags) {
    dim3 g(M / 128, (N + 159) / 160, batch);
    gemm_mfma<5, u16><<<g, 256, 0, stream>>>(Aq, Bq, Cq, bias, M, N, K, lda, ldbt, ldc, bA, bB, bC, flags);
  };
  auto g5f = [&](const u16* Aq, const u16* Bq, float* Cq, const float* bias,
                 int M, int N, int K, int lda, int ldbt, int ldc, int flags) {
    dim3 g(M / 128, (N + 159) / 160, 1);
    gemm_mfma<5, float><<<g, 256, 0, stream>>>(Aq, Bq, Cq, bias, M, N, K, lda, ldbt, ldc, 0, 0, 0, flags);
  };
  auto g6u = [&](const u16* Aq, const u16* Bq, u16* Cq, const float* bias,
                 int M, int N, int K, int lda, int ldbt, int ldc, int flags) {
    dim3 g(M / 128, (N + 191) / 192, 1);
    gemm_mfma<6, u16><<<g, 256, 0, stream>>>(Aq, Bq, Cq, bias, M, N, K, lda, ldbt, ldc, 0, 0, 0, flags);
  };
  auto g4f = [&](const u16* Aq, const u16* Bq, float* Cq, const float* bias,
                 int M, int N, int K, int lda, int ldbt, int ldc,
                 long bA, long bB, long bC, int batch, int flags) {
    dim3 g(M / 128, (N + 127) / 128, batch);
    gemm_mfma<4, float><<<g, 256, 0, stream>>>(Aq, Bq, Cq, bias, M, N, K, lda, ldbt, ldc, bA, bB, bC, flags);
  };
  auto g4u = [&](const u16* Aq, const u16* Bq, u16* Cq, const float* bias,
                 int M, int N, int K, int lda, int ldbt, int ldc, int flags) {
    dim3 g(M / 128, (N + 127) / 128, 1);
    gemm_mfma<4, u16><<<g, 256, 0, stream>>>(Aq, Bq, Cq, bias, M, N, K, lda, ldbt, ldc, 0, 0, 0, flags);
  };
  auto wcv = [&](const float* src, u16* dst, int K, int N) {
    wconvT<<<(int)(((long)K * N + 255) / 256), 256, 0, stream>>>(src, dst, K, N);
  };

  // ---- phase 0: weight conversion, CSR, encoder, adjacency ----
  for (int l = 0; l < 3; ++l) wcv(tW0 + (long)l * 25600, wt0 + (long)l * 25600, 160, 160);
  for (int l = 0; l < 3; ++l) wcv(tW1 + (long)l * 36864, wt1 + (long)l * 36864, 192, 192);
  wcv(dcw0, wdc, 640, 160);   // [640,160] -> [160][640] (concat-K layout)
  wcv(dsw0, wds, 320, 160);   // [320,160] -> [160][320]
  wcv(skw0, wsk0, 160, 256);
  wcv(skw1, wsk1, 192, 256);
  wcv(rw1, wr1, 256, 512);
  wcv(rw2, wr2, 512, 312);

  hipMemsetAsync(zero, 0, 6 * 2048 * 4 + 2 * 192 * 4, stream);
  edge_stats<<<cE / 256, 256, 0, stream>>>(srcI, dstI, ew, degf, degb, cntf, cntb);
  scan2<<<2, 256, 0, stream>>>(cntf, cntb, rowf, rowb);
  fill_csr<<<cE / 256, 256, 0, stream>>>(srcI, dstI, ew, degf, degb, rowf, rowb,
                                         curf, curb, colf, colb, wnf, wnb);
  encoder<<<cR / 8, 160, 0, stream>>>(x, enc_w, enc_b, node_emb, lw0, H0);

  // learned adjacency: scores = se @ te^T via MFMA, then row relu-softmax
  cvt_f2bf<<<(cN * cHID + 255) / 256, 256, 0, stream>>>(src_emb, seb, (long)cN * cHID);
  cvt_f2bf<<<(cN * cHID + 255) / 256, 256, 0, stream>>>(tgt_emb, teb, (long)cN * cHID);
  g4f(seb, teb, scores, nullptr, cN, cN, cHID, cHID, cHID, cN, 0, 0, 0, 1, 0);
  relu_softmax_rows<<<cN, 256, 0, stream>>>(scores, adjb);

  // ---- block 0 (c = 160) ----
  {
    const int c = 160;
    const long NC = (long)cN * c;
    const int scanGrid = (int)(((long)cB * cN * c + 255) / 256);
    // synaptic chain: H0 (res) -> Hh
    g5u(H0, wt0 + 0L * 25600, T1, tb0 + 0 * c, cR, c, c, c, c, c, 0, 0, 0, 1, FLAG_BIAS);
    scan_syn<<<scanGrid, 256, 0, stream>>>(T1, Hh, c);
    for (int l = 1; l < 3; ++l) {
      g5u(Hh, wt0 + (long)l * 25600, T1, tb0 + l * c, cR, c, c, c, c, c, 0, 0, 0, 1, FLAG_BIAS);
      scan_syn<<<scanGrid, 256, 0, stream>>>(T1, Hh, c);
    }
    // skip (t=11): outacc[b] = h[b,11]@skw0 + skb0
    g4f(Hh + 11L * NC, wsk0, outacc, skb0, cN, cFF, c, c, c, cFF,
        (long)cT * NC, 0, (long)cN * cFF, cB, FLAG_BIAS);
    // diffconv: pack [z1|z2] then [z3|z4] into Z12 [cR,320]; two K=320 GEMMs
    dim3 pg(cN, cBT);
    prop_gather<<<pg, c, 0, stream>>>(Hh, 160, Z12, 320, rowf, colf, wnf);
    prop_gather<<<pg, c, 0, stream>>>(Z12, 320, Z12 + 160, 320, rowf, colf, wnf);
    g5f(Z12, wdc, Dd, dcb0, cR, c, 320, 320, 640, c, FLAG_BIAS);
    prop_gather<<<pg, c, 0, stream>>>(Hh, 160, Z12, 320, rowb, colb, wnb);
    prop_gather<<<pg, c, 0, stream>>>(Z12, 320, Z12 + 160, 320, rowb, colb, wnb);
    g5f(Z12, wdc + 320, Dd, nullptr, cR, c, 320, 320, 640, c, FLAG_ACC);
    // dense conv: hT -> S2 ; x1 = adj@hT -> T1 ; Dd += x1@dsw[:,0:160] ;
    //             x1T -> S2 ; x2 = adj@x1T -> T1 ; Dd += x2@dsw[:,160:320]
    dim3 tg(cN / 64, (c + 63) / 64, cBT);
    transpose_bf16<<<tg, 256, 0, stream>>>(Hh, S2, cN, c, NC, NC);
    g5u(adjb, S2, T1, nullptr, cN, c, cN, cN, cN, c, 0, NC, NC, cBT, 0);
    g5f(T1, wds, Dd, dsb0, cR, c, c, c, 320, c, FLAG_BIAS | FLAG_ACC);
    transpose_bf16<<<tg, 256, 0, stream>>>(T1, S2, cN, c, NC, NC);
    g5u(adjb, S2, T1, nullptr, cN, c, cN, cN, cN, c, 0, NC, NC, cBT, 0);
    g5f(T1, wds + 160, Dd, nullptr, cR, c, c, c, 320, c, FLAG_ACC);
    // BN(Dd + H0) -> G1 (stride 192) + lw1
    bn_stats<<<512, c, 0, stream>>>(Dd, H0, stat, c);
    bn_finalize<<<1, c, 0, stream>>>(stat, ng0, nb0, scsh, c);
    bn_apply_concat<<<cR / 8, 192, 0, stream>>>(Dd, H0, scsh, lw1, G1);
  }

  // ---- block 1 (c = 192): chain + skip only ----
  {
    const int c = 192;
    const long NC = (long)cN * c;
    const int scanGrid = (int)(((long)cB * cN * c + 255) / 256);
    for (int l = 0; l < 3; ++l) {
      g6u(G1, wt1 + (long)l * 36864, G2, tb1 + l * c, cR, c, c, c, c, c, FLAG_BIAS);
      scan_syn<<<scanGrid, 256, 0, stream>>>(G2, G1, c);
    }
    g4f(G1 + 11L * NC, wsk1, outacc, skb1, cN, cFF, c, c, c, cFF,
        (long)cT * NC, 0, (long)cN * cFF, cB, FLAG_BIAS | FLAG_ACC | FLAG_RELU);
  }

  // ---- readout (outacc f32 -> bf16 in S2, then two MFMA GEMMs) ----
  cvt_f2bf<<<(int)(((long)cB * cN * cFF + 255) / 256), 256, 0, stream>>>(outacc, S2, (long)cB * cN * cFF);
  g4u(S2, wr1, r1b, rb1, cB * cN, 2 * cFF, cFF, cFF, cFF, 2 * cFF, FLAG_BIAS | FLAG_RELU);
  g4f(r1b, wr2, yb, rb2, cB * cN, cHOR * cF, 2 * cFF, 2 * cFF, 2 * cFF, cHOR * cF,
      0, 0, 0, 1, FLAG_BIAS);
  final_transpose<<<(cB * cHOR * cN * cF) / 256, 256, 0, stream>>>(yb, outF);
}

// Round 7
// 1421.199 us; speedup vs baseline: 2.8349x; 1.2316x over previous
//
#include <hip/hip_runtime.h>

// ======================= types & helpers =======================
using u16 = unsigned short;
typedef short bf16x8 __attribute__((ext_vector_type(8)));
typedef float f32x4  __attribute__((ext_vector_type(4)));

__device__ __forceinline__ float bf2f(u16 u) { return __uint_as_float(((unsigned)u) << 16); }
__device__ __forceinline__ u16 f2bf(float f) {  // round-to-nearest-even
  unsigned u = __float_as_uint(f);
  return (u16)((u + 0x7FFFu + ((u >> 16) & 1u)) >> 16);
}
__device__ __forceinline__ float ldv(const float* p) { return *p; }
__device__ __forceinline__ float ldv(const u16* p)   { return bf2f(*p); }
__device__ __forceinline__ void  stv(float* p, float v) { *p = v; }
__device__ __forceinline__ void  stv(u16* p, float v)   { *p = f2bf(v); }

// ======================= problem constants =======================
constexpr int cB = 4, cT = 12, cN = 2048, cF = 26;
constexpr int cHID = 128, cLF = 32, cFF = 256, cHOR = 12;
constexpr int cE = 16384;
constexpr int cR = cB * cT * cN;   // 98304
constexpr int cBT = cB * cT;       // 48
constexpr float cALPHA = 0.9f, cBETA = 0.8f, cEPS = 1e-5f;

#define FLAG_ACC  1
#define FLAG_BIAS 2
#define FLAG_RELU 4

// ======================= MFMA bf16 GEMM (gload_lds + double-buffer prefetch) ==========
// C[m,n] = sum_k A[m,k] * BT[n,k]  (+bias) (+C) (relu)
// A: bf16 [M,K] lda ; BT: bf16 [N,K] ldbt. M%128==0, K%32==0, lda/ldbt%8==0; N guarded
// (OOB B rows clamp to N-1; their output columns are never stored).
// LDS: 2 x linear [128+TN][32] bf16. Stage step s+1 into buf^1 BEFORE computing buf,
// single barrier per step: the vmcnt(0) drain at the NEXT barrier lands after a full
// compute phase -> load latency hidden.
template <int NF, typename TC>
__global__ __launch_bounds__(256)
void gemm_mfma(const u16* __restrict__ A, const u16* __restrict__ BT,
               TC* __restrict__ C, const float* __restrict__ bias,
               int M, int N, int K, int lda, int ldbt, int ldc,
               long batchA, long batchB, long batchC, int flags)
{
  constexpr int TN = NF * 32;
  constexpr int ROWS = 128 + TN;        // A rows then BT rows
  constexpr int NINST = ROWS / 16;      // gload_lds wave-instrs per K-step
  __shared__ __align__(16) u16 S[2][ROWS * 32];
  A  += (long)blockIdx.z * batchA;
  BT += (long)blockIdx.z * batchB;
  C  += (long)blockIdx.z * batchC;
  const int tid = threadIdx.x;
  const int lane = tid & 63, wid = tid >> 6;
  const int wm = wid & 1, wn = wid >> 1;
  const int m0 = blockIdx.x * 128, n0 = blockIdx.y * TN;
  const int fr = lane & 15, kh = lane >> 4;   // frag row / k-half
  f32x4 acc[4][NF];
#pragma unroll
  for (int i = 0; i < 4; ++i)
#pragma unroll
    for (int j = 0; j < NF; ++j) acc[i][j] = f32x4{0.f, 0.f, 0.f, 0.f};

  auto STAGE = [&](int buf, int k0s) {
    for (int s = wid; s < NINST; s += 4) {
      const int slot = s * 64 + lane;    // 16B slot index
      const int row = slot >> 2, q = slot & 3;
      const u16* g;
      if (row < 128) {
        g = A + (long)(m0 + row) * lda + k0s + q * 8;
      } else {
        const int n = min(n0 + row - 128, N - 1);
        g = BT + (long)n * ldbt + k0s + q * 8;
      }
      __builtin_amdgcn_global_load_lds(
          (const __attribute__((address_space(1))) unsigned int*)g,
          (__attribute__((address_space(3))) unsigned int*)&S[buf][s * 512],
          16, 0, 0);
    }
  };

  STAGE(0, 0);
  int cur = 0;
  for (int k0 = 0; k0 < K; k0 += 32) {
    __syncthreads();                 // drains vmcnt -> S[cur] ready; prior reads of S[cur^1] done
    if (k0 + 32 < K) STAGE(cur ^ 1, k0 + 32);
    bf16x8 af[4];
#pragma unroll
    for (int mf = 0; mf < 4; ++mf)
      af[mf] = *(const bf16x8*)&S[cur][(wm * 64 + mf * 16 + fr) * 32 + kh * 8];
#pragma unroll
    for (int nf = 0; nf < NF; ++nf) {
      const bf16x8 bfr = *(const bf16x8*)&S[cur][(128 + wn * NF * 16 + nf * 16 + fr) * 32 + kh * 8];
#pragma unroll
      for (int mf = 0; mf < 4; ++mf)
        acc[mf][nf] = __builtin_amdgcn_mfma_f32_16x16x32_bf16(af[mf], bfr, acc[mf][nf], 0, 0, 0);
    }
    cur ^= 1;
  }

#pragma unroll
  for (int mf = 0; mf < 4; ++mf)
#pragma unroll
    for (int nf = 0; nf < NF; ++nf) {
      const int gn = n0 + wn * NF * 16 + nf * 16 + fr;
      if (gn < N) {
#pragma unroll
        for (int r = 0; r < 4; ++r) {
          const long gm = m0 + wm * 64 + mf * 16 + kh * 4 + r;   // C/D: row=(lane>>4)*4+r
          float v = acc[mf][nf][r];
          if (flags & FLAG_BIAS) v += bias[gn];
          if (flags & FLAG_ACC)  v += ldv(&C[gm * ldc + gn]);
          if (flags & FLAG_RELU) v = fmaxf(v, 0.f);
          stv(&C[gm * ldc + gn], v);
        }
      }
    }
}

// ======================= weight convert + transpose (f32 [K,N] -> bf16 [N,K]) ==========
__global__ __launch_bounds__(256)
void wconvT(const float* __restrict__ w, u16* __restrict__ wt, int K, int N)
{
  const long idx = (long)blockIdx.x * 256 + threadIdx.x;
  if (idx >= (long)K * N) return;
  const int n = (int)(idx / K), k = (int)(idx % K);
  wt[idx] = f2bf(w[(long)k * N + n]);
}

// ======================= tiled bf16 transpose: in [R,Cc] -> out [Cc,R], batched ==========
__global__ __launch_bounds__(256)
void transpose_bf16(const u16* __restrict__ in, u16* __restrict__ out,
                    int R, int Cc, long batchIn, long batchOut)
{
  __shared__ u16 t[64][65];
  in  += (long)blockIdx.z * batchIn;
  out += (long)blockIdx.z * batchOut;
  const int tid = threadIdx.x;
  const int r0 = blockIdx.x * 64, c0 = blockIdx.y * 64;
  for (int i = tid; i < 64 * 64; i += 256) {
    const int r = i >> 6, c = i & 63;
    t[r][c] = (r0 + r < R && c0 + c < Cc) ? in[(long)(r0 + r) * Cc + c0 + c] : (u16)0;
  }
  __syncthreads();
  for (int i = tid; i < 64 * 64; i += 256) {
    const int c = i >> 6, r = i & 63;
    if (c0 + c < Cc && r0 + r < R) out[(long)(c0 + c) * R + r0 + r] = t[r][c];
  }
}

__global__ __launch_bounds__(256)
void cvt_f2bf(const float* __restrict__ in, u16* __restrict__ out, long n)
{
  const long idx = (long)blockIdx.x * 256 + threadIdx.x;
  if (idx < n) out[idx] = f2bf(in[idx]);
}

// ======================= graph preprocessing (CSR build) =======================
__global__ __launch_bounds__(256)
void edge_stats(const int* __restrict__ s, const int* __restrict__ d,
                const float* __restrict__ ew, float* degf, float* degb,
                int* cntf, int* cntb)
{
  const int e = blockIdx.x * 256 + threadIdx.x;
  atomicAdd(&degf[d[e]], ew[e]);
  atomicAdd(&degb[s[e]], ew[e]);
  atomicAdd(&cntf[d[e]], 1);
  atomicAdd(&cntb[s[e]], 1);
}

__global__ __launch_bounds__(256)
void scan2(const int* __restrict__ cf, const int* __restrict__ cb,
           int* __restrict__ rf, int* __restrict__ rb)
{
  const int* c = blockIdx.x ? cb : cf;
  int* r       = blockIdx.x ? rb : rf;
  __shared__ int part[256];
  const int t = threadIdx.x, base = t * 8;
  int loc[8]; int s = 0;
#pragma unroll
  for (int i = 0; i < 8; ++i) { loc[i] = c[base + i]; s += loc[i]; }
  part[t] = s; __syncthreads();
  if (t == 0) {
    int run = 0;
    for (int i = 0; i < 256; ++i) { const int v = part[i]; part[i] = run; run += v; }
    r[2048] = run;
  }
  __syncthreads();
  int run = part[t];
#pragma unroll
  for (int i = 0; i < 8; ++i) { r[base + i] = run; run += loc[i]; }
}

__global__ __launch_bounds__(256)
void fill_csr(const int* __restrict__ s, const int* __restrict__ d,
              const float* __restrict__ ew,
              const float* __restrict__ degf, const float* __restrict__ degb,
              const int* __restrict__ rowf, const int* __restrict__ rowb,
              int* curf, int* curb,
              int* __restrict__ colf, int* __restrict__ colb,
              float* __restrict__ wnf, float* __restrict__ wnb)
{
  const int e = blockIdx.x * 256 + threadIdx.x;
  const int si = s[e], di = d[e];
  const float w = ew[e];
  const int p = rowf[di] + atomicAdd(&curf[di], 1);
  colf[p] = si; wnf[p] = w / fmaxf(degf[di], 1e-6f);
  const int q = rowb[si] + atomicAdd(&curb[si], 1);
  colb[q] = di; wnb[q] = w / fmaxf(degb[si], 1e-6f);
}

// ======================= diffusion step, all 48 bt per node ==========
// y[bt,n,ch] = sum_j w[j]*x[bt,col[j],ch]  — block per node; CSR read once (uniform);
// bf16x8 loads; 960 work items (bt,ch8) over 256 threads x 4.
__global__ __launch_bounds__(256)
void prop_gather_all(const u16* __restrict__ x, int ldx, u16* __restrict__ y, int ldy,
                     const int* __restrict__ rowptr, const int* __restrict__ col,
                     const float* __restrict__ w)
{
  const int n = blockIdx.x;
  const int beg = rowptr[n], end = rowptr[n + 1];
  const int tid = threadIdx.x;
  float acc[4][8];
#pragma unroll
  for (int r = 0; r < 4; ++r)
#pragma unroll
    for (int q = 0; q < 8; ++q) acc[r][q] = 0.f;
  int bt_[4], ch_[4];
#pragma unroll
  for (int r = 0; r < 4; ++r) {
    const int item = tid + r * 256;            // < 960 = 48 bt * 20 ch8
    bt_[r] = (item < 960) ? item / 20 : -1;
    ch_[r] = (item % 20) * 8;
  }
  for (int j = beg; j < end; ++j) {
    const int cj = col[j];
    const float wj = w[j];
#pragma unroll
    for (int r = 0; r < 4; ++r) {
      if (bt_[r] < 0) continue;
      const bf16x8 v = *(const bf16x8*)&x[((long)bt_[r] * cN + cj) * ldx + ch_[r]];
#pragma unroll
      for (int q = 0; q < 8; ++q) acc[r][q] = fmaf(wj, bf2f((u16)v[q]), acc[r][q]);
    }
  }
#pragma unroll
  for (int r = 0; r < 4; ++r) {
    if (bt_[r] < 0) continue;
    u16 o[8];
#pragma unroll
    for (int q = 0; q < 8; ++q) o[q] = f2bf(acc[r][q]);
    *(bf16x8*)&y[((long)bt_[r] * cN + n) * ldy + ch_[r]] = *(const bf16x8*)o;
  }
}

// ======================= encoder =======================
__global__ __launch_bounds__(160)
void encoder(const float* __restrict__ x, const float* __restrict__ ew_,
             const float* __restrict__ eb, const float* __restrict__ ne,
             const float* __restrict__ lw, u16* __restrict__ h)
{
  __shared__ float xs[cF];
  const int tid = threadIdx.x;
  const long r0 = (long)blockIdx.x * 8;
  for (long row = r0; row < r0 + 8; ++row) {
    if (tid < cF) xs[tid] = x[row * cF + tid];
    __syncthreads();
    const int n = (int)(row % cN);
    float v;
    if (tid < cHID) {
      float acc = eb[tid] + ne[(long)n * cHID + tid];
#pragma unroll
      for (int f = 0; f < cF; ++f) acc = fmaf(xs[f], ew_[f * cHID + tid], acc);
      v = acc;
    } else {
      v = lw[(long)n * cLF + (tid - cHID)];
    }
    h[row * 160 + tid] = f2bf(v);
    __syncthreads();
  }
}

// ======================= adjacency: row softmax of relu(scores) ==========
__global__ __launch_bounds__(256)
void relu_softmax_rows(const float* __restrict__ sc, u16* __restrict__ adj)
{
  const int row = blockIdx.x, tid = threadIdx.x;
  const float* p = sc + (long)row * cN;
  __shared__ float red[256];
  float lv[8];
  float mx = 0.f;   // relu => all >= 0
#pragma unroll
  for (int i = 0; i < 8; ++i) {
    const float v = fmaxf(p[tid + i * 256], 0.f);
    lv[i] = v; mx = fmaxf(mx, v);
  }
  red[tid] = mx; __syncthreads();
  for (int s = 128; s > 0; s >>= 1) { if (tid < s) red[tid] = fmaxf(red[tid], red[tid + s]); __syncthreads(); }
  const float m = red[0]; __syncthreads();
  float sum = 0.f;
#pragma unroll
  for (int i = 0; i < 8; ++i) { lv[i] = __expf(lv[i] - m); sum += lv[i]; }
  red[tid] = sum; __syncthreads();
  for (int s = 128; s > 0; s >>= 1) { if (tid < s) red[tid] += red[tid + s]; __syncthreads(); }
  const float inv = 1.f / red[0]; __syncthreads();
#pragma unroll
  for (int i = 0; i < 8; ++i) adj[(long)row * cN + tid + i * 256] = f2bf(lv[i] * inv);
}

// ======================= temporal 2nd-order LIF scan, bf16x8 ==========
__global__ __launch_bounds__(256)
void scan_syn8(const u16* __restrict__ in, u16* __restrict__ out, int c)
{
  const int c8 = c >> 3;
  const long total = (long)cB * cN * c8;
  const long idx = (long)blockIdx.x * 256 + threadIdx.x;
  if (idx >= total) return;
  const long nc = (long)cN * c;
  const int b = (int)(idx / ((long)cN * c8));
  const long rest = (idx % ((long)cN * c8)) * 8;
  const u16* p = in  + (long)b * cT * nc + rest;
  u16*       q = out + (long)b * cT * nc + rest;
  float syn[8], mem[8];
#pragma unroll
  for (int e = 0; e < 8; ++e) { syn[e] = 0.f; mem[e] = 0.f; }
#pragma unroll
  for (int t = 0; t < cT; ++t) {
    const bf16x8 v = *(const bf16x8*)&p[(long)t * nc];
    u16 o[8];
#pragma unroll
    for (int e = 0; e < 8; ++e) {
      syn[e] = fmaf(cALPHA, syn[e], bf2f((u16)v[e]));
      mem[e] = fmaf(cBETA, mem[e], syn[e]);
      o[e] = f2bf(mem[e]);
    }
    *(bf16x8*)&q[(long)t * nc] = *(const bf16x8*)o;
  }
}

// ======================= batch norm =======================
__global__ __launch_bounds__(256)
void bn_stats(const float* __restrict__ d, const u16* __restrict__ res,
              float* __restrict__ stat, int c)
{
  const int ch = threadIdx.x;
  const long r0 = (long)blockIdx.x * (cR / 512);
  float s = 0.f, s2 = 0.f;
  for (int i = 0; i < cR / 512; ++i) {
    const float v = d[(r0 + i) * c + ch] + bf2f(res[(r0 + i) * c + ch]);
    s += v; s2 = fmaf(v, v, s2);
  }
  atomicAdd(&stat[ch], s);
  atomicAdd(&stat[c + ch], s2);
}

__global__ __launch_bounds__(256)
void bn_finalize(const float* __restrict__ stat, const float* __restrict__ g,
                 const float* __restrict__ b, float* __restrict__ scsh, int c)
{
  const int ch = threadIdx.x;
  const float mu = stat[ch] / cR;
  const float var = stat[c + ch] / cR - mu * mu;
  const float sc = g[ch] * rsqrtf(var + cEPS);
  scsh[ch] = sc;
  scsh[c + ch] = fmaf(-mu, sc, b[ch]);
}

__global__ __launch_bounds__(192)
void bn_apply_concat(const float* __restrict__ d, const u16* __restrict__ res,
                     const float* __restrict__ scsh, const float* __restrict__ lw,
                     u16* __restrict__ out)
{
  const int tid = threadIdx.x;
  const long r0 = (long)blockIdx.x * 8;
  for (long row = r0; row < r0 + 8; ++row) {
    const int n = (int)(row % cN);
    float v;
    if (tid < 160) v = fmaf(d[row * 160 + tid] + bf2f(res[row * 160 + tid]),
                            scsh[tid], scsh[160 + tid]);
    else           v = lw[(long)n * cLF + (tid - 160)];
    out[row * 192 + tid] = f2bf(v);
  }
}

// ======================= output transpose (f32 out) =======================
__global__ __launch_bounds__(256)
void final_transpose(const float* __restrict__ y, float* __restrict__ out)
{
  const long idx = (long)blockIdx.x * 256 + threadIdx.x;
  const int f = (int)(idx % cF);
  long t = idx / cF;
  const int n = (int)(t % cN); t /= cN;
  const int hor = (int)(t % cHOR);
  const int b = (int)(t / cHOR);
  out[idx] = y[((long)b * cN + n) * (cHOR * cF) + hor * cF + f];
}

__global__ __launch_bounds__(256)
void fill_f32(float* __restrict__ out, long n, float val)
{
  const long idx = (long)blockIdx.x * 256 + threadIdx.x;
  if (idx < n) out[idx] = val;
}

// ======================= host orchestration =======================
extern "C" void kernel_launch(void* const* d_in, const int* in_sizes, int n_in,
                              void* d_out, int out_size, void* d_ws, size_t ws_size,
                              hipStream_t stream)
{
  float* outF = (float*)d_out;
  const long outN = out_size;
  if (n_in < 34) { fill_f32<<<(int)((outN + 255) / 256), 256, 0, stream>>>(outF, outN, 500.f); return; }
  if (in_sizes[0] != cB * cT * cN * cF || in_sizes[1] != 2 * cE || in_sizes[9] != 3 * 160 * 160) {
    fill_f32<<<(int)((outN + 255) / 256), 256, 0, stream>>>(outF, outN, 700.f); return;
  }

  const float* x        = (const float*)d_in[0];
  const int*   eidx     = (const int*)d_in[1];
  const float* ew       = (const float*)d_in[2];
  const float* enc_w    = (const float*)d_in[3];
  const float* enc_b    = (const float*)d_in[4];
  const float* node_emb = (const float*)d_in[5];
  const float* src_emb  = (const float*)d_in[6];
  const float* tgt_emb  = (const float*)d_in[7];
  const float* lw0  = (const float*)d_in[8];
  const float* tW0  = (const float*)d_in[9];
  const float* tb0  = (const float*)d_in[10];
  const float* dcw0 = (const float*)d_in[11];
  const float* dcb0 = (const float*)d_in[12];
  const float* dsw0 = (const float*)d_in[13];
  const float* dsb0 = (const float*)d_in[14];
  const float* skw0 = (const float*)d_in[15];
  const float* skb0 = (const float*)d_in[16];
  const float* ng0  = (const float*)d_in[17];
  const float* nb0  = (const float*)d_in[18];
  const float* lw1  = (const float*)d_in[19];
  const float* tW1  = (const float*)d_in[20];
  const float* tb1  = (const float*)d_in[21];
  // d_in[22..25, 28..29] feed only block-1's post-skip h (never read) -> dead.
  const float* skw1 = (const float*)d_in[26];
  const float* skb1 = (const float*)d_in[27];
  const float* rw1  = (const float*)d_in[30];
  const float* rb1  = (const float*)d_in[31];
  const float* rw2  = (const float*)d_in[32];
  const float* rb2  = (const float*)d_in[33];
  const int* srcI = eidx;
  const int* dstI = eidx + cE;

  // ---- workspace layout ----
  char* W = (char*)d_ws;
  size_t off = 0;
  auto A8 = [&](size_t bytes) { size_t r = off; off = (off + bytes + 255) & ~(size_t)255; return r; };
  const size_t oH0 = A8((size_t)cR * 160 * 2);   // res, bf16
  const size_t oHh = A8((size_t)cR * 160 * 2);   // chain h (G1 [cR,192] aliases Hh+T1-head)
  const size_t oT1 = A8((size_t)cR * 160 * 2);   // scratch (Z12 [cR,320] aliases T1+S2)
  const size_t oS2 = A8((size_t)cR * 160 * 2);   // scratch2 / hT
  const size_t oDd = A8((size_t)cR * 160 * 4);   // f32 accumulator (G2, scores alias)
  const size_t oAdj = A8((size_t)cN * cN * 2);
  const size_t oOut = A8((size_t)cB * cN * cFF * 4);       // f32 skip acc (t=11)
  const size_t oR1  = A8((size_t)cB * cN * 512 * 2);       // bf16 r1
  const size_t oY   = A8((size_t)cB * cN * cHOR * cF * 4); // f32
  const size_t oZero = A8(6 * 2048 * 4 + 2 * 192 * 4);
  const size_t oRowf = A8(2049 * 4), oRowb = A8(2049 * 4);
  const size_t oColf = A8((size_t)cE * 4), oColb = A8((size_t)cE * 4);
  const size_t oWnf  = A8((size_t)cE * 4), oWnb  = A8((size_t)cE * 4);
  const size_t oScSh = A8(2 * 192 * 4);
  const size_t oWT   = A8((size_t)721920 * 2);   // bf16 transposed weights
  const size_t oSeb  = A8((size_t)cN * cHID * 2);
  const size_t oTeb  = A8((size_t)cN * cHID * 2);
  if (off > ws_size) {
    fill_f32<<<(int)((outN + 255) / 256), 256, 0, stream>>>(outF, outN, 300.f);
    return;
  }

  u16 *H0 = (u16*)(W + oH0), *Hh = (u16*)(W + oHh), *T1 = (u16*)(W + oT1),
      *S2 = (u16*)(W + oS2), *adjb = (u16*)(W + oAdj);
  float* Dd = (float*)(W + oDd);
  u16 *G1 = (u16*)(W + oHh);   // [cR,192] bf16 over Hh(+T1 head), post-BN only
  u16 *G2 = (u16*)(W + oDd);   // over Dd, post-BN only
  u16 *Z12 = T1;               // [cR,320] bf16 over T1+S2 (diffconv packing)
  float* scores = (float*)(W + oDd);   // phase-0 scratch, dead before Dd use
  float *outacc = (float*)(W + oOut), *yb = (float*)(W + oY);
  u16 *r1b = (u16*)(W + oR1);
  float* zero = (float*)(W + oZero);
  float *degf = zero, *degb = zero + 2048;
  int *cntf = (int*)(zero + 4096), *cntb = cntf + 2048,
      *curf = cntb + 2048, *curb = curf + 2048;
  float* stat = (float*)(curb + 2048);
  int *rowf = (int*)(W + oRowf), *rowb = (int*)(W + oRowb);
  int *colf = (int*)(W + oColf), *colb = (int*)(W + oColb);
  float *wnf = (float*)(W + oWnf), *wnb = (float*)(W + oWnb);
  float* scsh = (float*)(W + oScSh);
  u16* wt   = (u16*)(W + oWT);
  u16 *wt0 = wt,              *wt1 = wt0 + 3 * 25600, *wdc = wt1 + 3 * 36864,
      *wds = wdc + 102400,    *wsk0 = wds + 51200,    *wsk1 = wsk0 + 40960,
      *wr1 = wsk1 + 49152,    *wr2 = wr1 + 131072;
  u16 *seb = (u16*)(W + oSeb), *teb = (u16*)(W + oTeb);

  auto g5u = [&](const u16* Aq, const u16* Bq, u16* Cq, const float* bias,
                 int M, int N, int K, int lda, int ldbt, int ldc,
                 long bA, long bB, long bC, int batch, int flags) {
    dim3 g(M / 128, (N + 159) / 160, batch);
    gemm_mfma<5, u16><<<g, 256, 0, stream>>>(Aq, Bq, Cq, bias, M, N, K, lda, ldbt, ldc, bA, bB, bC, flags);
  };
  auto g5f = [&](const u16* Aq, const u16* Bq, float* Cq, const float* bias,
                 int M, int N, int K, int lda, int ldbt, int ldc, int flags) {
    dim3 g(M / 128, (N + 159) / 160, 1);
    gemm_mfma<5, float><<<g, 256, 0, stream>>>(Aq, Bq, Cq, bias, M, N, K, lda, ldbt, ldc, 0, 0, 0, flags);
  };
  auto g6u = [&](const u16* Aq, const u16* Bq, u16* Cq, const float* bias,
                 int M, int N, int K, int lda, int ldbt, int ldc, int flags) {
    dim3 g(M / 128, (N + 191) / 192, 1);
    gemm_mfma<6, u16><<<g, 256, 0, stream>>>(Aq, Bq, Cq, bias, M, N, K, lda, ldbt, ldc, 0, 0, 0, flags);
  };
  auto g4f = [&](const u16* Aq, const u16* Bq, float* Cq, const float* bias,
                 int M, int N, int K, int lda, int ldbt, int ldc,
                 long bA, long bB, long bC, int batch, int flags) {
    dim3 g(M / 128, (N + 127) / 128, batch);
    gemm_mfma<4, float><<<g, 256, 0, stream>>>(Aq, Bq, Cq, bias, M, N, K, lda, ldbt, ldc, bA, bB, bC, flags);
  };
  auto g4u = [&](const u16* Aq, const u16* Bq, u16* Cq, const float* bias,
                 int M, int N, int K, int lda, int ldbt, int ldc, int flags) {
    dim3 g(M / 128, (N + 127) / 128, 1);
    gemm_mfma<4, u16><<<g, 256, 0, stream>>>(Aq, Bq, Cq, bias, M, N, K, lda, ldbt, ldc, 0, 0, 0, flags);
  };
  auto wcv = [&](const float* src, u16* dst, int K, int N) {
    wconvT<<<(int)(((long)K * N + 255) / 256), 256, 0, stream>>>(src, dst, K, N);
  };

  // ---- phase 0: weight conversion, CSR, encoder, adjacency ----
  for (int l = 0; l < 3; ++l) wcv(tW0 + (long)l * 25600, wt0 + (long)l * 25600, 160, 160);
  for (int l = 0; l < 3; ++l) wcv(tW1 + (long)l * 36864, wt1 + (long)l * 36864, 192, 192);
  wcv(dcw0, wdc, 640, 160);   // [640,160] -> [160][640] (concat-K layout)
  wcv(dsw0, wds, 320, 160);   // [320,160] -> [160][320]
  wcv(skw0, wsk0, 160, 256);
  wcv(skw1, wsk1, 192, 256);
  wcv(rw1, wr1, 256, 512);
  wcv(rw2, wr2, 512, 312);

  hipMemsetAsync(zero, 0, 6 * 2048 * 4 + 2 * 192 * 4, stream);
  edge_stats<<<cE / 256, 256, 0, stream>>>(srcI, dstI, ew, degf, degb, cntf, cntb);
  scan2<<<2, 256, 0, stream>>>(cntf, cntb, rowf, rowb);
  fill_csr<<<cE / 256, 256, 0, stream>>>(srcI, dstI, ew, degf, degb, rowf, rowb,
                                         curf, curb, colf, colb, wnf, wnb);
  encoder<<<cR / 8, 160, 0, stream>>>(x, enc_w, enc_b, node_emb, lw0, H0);

  // learned adjacency: scores = se @ te^T via MFMA, then row relu-softmax
  cvt_f2bf<<<(cN * cHID + 255) / 256, 256, 0, stream>>>(src_emb, seb, (long)cN * cHID);
  cvt_f2bf<<<(cN * cHID + 255) / 256, 256, 0, stream>>>(tgt_emb, teb, (long)cN * cHID);
  g4f(seb, teb, scores, nullptr, cN, cN, cHID, cHID, cHID, cN, 0, 0, 0, 1, 0);
  relu_softmax_rows<<<cN, 256, 0, stream>>>(scores, adjb);

  // ---- block 0 (c = 160) ----
  {
    const int c = 160;
    const long NC = (long)cN * c;
    const int scanGrid = (int)(((long)cB * cN * (c / 8) + 255) / 256);
    // synaptic chain: H0 (res) -> Hh
    g5u(H0, wt0 + 0L * 25600, T1, tb0 + 0 * c, cR, c, c, c, c, c, 0, 0, 0, 1, FLAG_BIAS);
    scan_syn8<<<scanGrid, 256, 0, stream>>>(T1, Hh, c);
    for (int l = 1; l < 3; ++l) {
      g5u(Hh, wt0 + (long)l * 25600, T1, tb0 + l * c, cR, c, c, c, c, c, 0, 0, 0, 1, FLAG_BIAS);
      scan_syn8<<<scanGrid, 256, 0, stream>>>(T1, Hh, c);
    }
    // skip (t=11): outacc[b] = h[b,11]@skw0 + skb0
    g4f(Hh + 11L * NC, wsk0, outacc, skb0, cN, cFF, c, c, c, cFF,
        (long)cT * NC, 0, (long)cN * cFF, cB, FLAG_BIAS);
    // diffconv: pack [z1|z2] then [z3|z4] into Z12 [cR,320]; two K=320 GEMMs
    prop_gather_all<<<cN, 256, 0, stream>>>(Hh, 160, Z12, 320, rowf, colf, wnf);
    prop_gather_all<<<cN, 256, 0, stream>>>(Z12, 320, Z12 + 160, 320, rowf, colf, wnf);
    g5f(Z12, wdc, Dd, dcb0, cR, c, 320, 320, 640, c, FLAG_BIAS);
    prop_gather_all<<<cN, 256, 0, stream>>>(Hh, 160, Z12, 320, rowb, colb, wnb);
    prop_gather_all<<<cN, 256, 0, stream>>>(Z12, 320, Z12 + 160, 320, rowb, colb, wnb);
    g5f(Z12, wdc + 320, Dd, nullptr, cR, c, 320, 320, 640, c, FLAG_ACC);
    // dense conv: hT -> S2 ; x1 = adj@hT -> T1 ; Dd += x1@dsw[:,0:160] ;
    //             x1T -> S2 ; x2 = adj@x1T -> T1 ; Dd += x2@dsw[:,160:320]
    dim3 tg(cN / 64, (c + 63) / 64, cBT);
    transpose_bf16<<<tg, 256, 0, stream>>>(Hh, S2, cN, c, NC, NC);
    g5u(adjb, S2, T1, nullptr, cN, c, cN, cN, cN, c, 0, NC, NC, cBT, 0);
    g5f(T1, wds, Dd, dsb0, cR, c, c, c, 320, c, FLAG_BIAS | FLAG_ACC);
    transpose_bf16<<<tg, 256, 0, stream>>>(T1, S2, cN, c, NC, NC);
    g5u(adjb, S2, T1, nullptr, cN, c, cN, cN, cN, c, 0, NC, NC, cBT, 0);
    g5f(T1, wds + 160, Dd, nullptr, cR, c, c, c, 320, c, FLAG_ACC);
    // BN(Dd + H0) -> G1 (stride 192) + lw1
    bn_stats<<<512, c, 0, stream>>>(Dd, H0, stat, c);
    bn_finalize<<<1, c, 0, stream>>>(stat, ng0, nb0, scsh, c);
    bn_apply_concat<<<cR / 8, 192, 0, stream>>>(Dd, H0, scsh, lw1, G1);
  }

  // ---- block 1 (c = 192): chain + skip only ----
  {
    const int c = 192;
    const long NC = (long)cN * c;
    const int scanGrid = (int)(((long)cB * cN * (c / 8) + 255) / 256);
    for (int l = 0; l < 3; ++l) {
      g6u(G1, wt1 + (long)l * 36864, G2, tb1 + l * c, cR, c, c, c, c, c, FLAG_BIAS);
      scan_syn8<<<scanGrid, 256, 0, stream>>>(G2, G1, c);
    }
    g4f(G1 + 11L * NC, wsk1, outacc, skb1, cN, cFF, c, c, c, cFF,
        (long)cT * NC, 0, (long)cN * cFF, cB, FLAG_BIAS | FLAG_ACC | FLAG_RELU);
  }

  // ---- readout (outacc f32 -> bf16 in S2, then two MFMA GEMMs) ----
  cvt_f2bf<<<(int)(((long)cB * cN * cFF + 255) / 256), 256, 0, stream>>>(outacc, S2, (long)cB * cN * cFF);
  g4u(S2, wr1, r1b, rb1, cB * cN, 2 * cFF, cFF, cFF, cFF, 2 * cFF, FLAG_BIAS | FLAG_RELU);
  g4f(r1b, wr2, yb, rb2, cB * cN, cHOR * cF, 2 * cFF, 2 * cFF, 2 * cFF, cHOR * cF,
      0, 0, 0, 1, FLAG_BIAS);
  final_transpose<<<(cB * cHOR * cN * cF) / 256, 256, 0, stream>>>(yb, outF);
}

// Round 8
// 1404.610 us; speedup vs baseline: 2.8684x; 1.0118x over previous
//
#include <hip/hip_runtime.h>

// ======================= types & helpers =======================
using u16 = unsigned short;
typedef short bf16x8 __attribute__((ext_vector_type(8)));
typedef float f32x4  __attribute__((ext_vector_type(4)));

__device__ __forceinline__ float bf2f(u16 u) { return __uint_as_float(((unsigned)u) << 16); }
__device__ __forceinline__ u16 f2bf(float f) {  // round-to-nearest-even
  unsigned u = __float_as_uint(f);
  return (u16)((u + 0x7FFFu + ((u >> 16) & 1u)) >> 16);
}
__device__ __forceinline__ float ldv(const float* p) { return *p; }
__device__ __forceinline__ float ldv(const u16* p)   { return bf2f(*p); }
__device__ __forceinline__ void  stv(float* p, float v) { *p = v; }
__device__ __forceinline__ void  stv(u16* p, float v)   { *p = f2bf(v); }

// ======================= problem constants =======================
constexpr int cB = 4, cT = 12, cN = 2048, cF = 26;
constexpr int cHID = 128, cLF = 32, cFF = 256, cHOR = 12;
constexpr int cE = 16384;
constexpr int cR = cB * cT * cN;   // 98304
constexpr int cBT = cB * cT;       // 48
constexpr float cALPHA = 0.9f, cBETA = 0.8f, cEPS = 1e-5f;

#define FLAG_ACC  1
#define FLAG_BIAS 2
#define FLAG_RELU 4

// ======================= MFMA bf16 GEMM (gload_lds + dbuf + XOR swizzle) ==========
// C[m,n] = sum_k A[m,k] * BT[n,k]  (+bias) (+C) (relu)
// A: bf16 [M,K] lda ; BT: bf16 [N,K] ldbt. M%128==0, K%32==0, lda/ldbt%8==0; N guarded
// (OOB B rows clamp to N-1; their output columns are never stored).
// LDS: 2 x linear [128+TN][32] bf16 rows (64B). Bank-conflict fix (rule #21,
// both-sides-or-neither): LDS slot (row,q) holds global 16B-chunk q^(row&3);
// fragment reads use slot kh^(fr&3) (row&3==fr&3 for all fragment rows since
// every row base is a multiple of 16). ds_read_b128 becomes throughput-conflict-free.
template <int NF, typename TC>
__global__ __launch_bounds__(256)
void gemm_mfma(const u16* __restrict__ A, const u16* __restrict__ BT,
               TC* __restrict__ C, const float* __restrict__ bias,
               int M, int N, int K, int lda, int ldbt, int ldc,
               long batchA, long batchB, long batchC, int flags)
{
  constexpr int TN = NF * 32;
  constexpr int ROWS = 128 + TN;        // A rows then BT rows
  constexpr int NINST = ROWS / 16;      // gload_lds wave-instrs per K-step
  __shared__ __align__(16) u16 S[2][ROWS * 32];
  A  += (long)blockIdx.z * batchA;
  BT += (long)blockIdx.z * batchB;
  C  += (long)blockIdx.z * batchC;
  const int tid = threadIdx.x;
  const int lane = tid & 63, wid = tid >> 6;
  const int wm = wid & 1, wn = wid >> 1;
  const int m0 = blockIdx.x * 128, n0 = blockIdx.y * TN;
  const int fr = lane & 15, kh = lane >> 4;   // frag row / k-half
  const int q3 = fr & 3;                      // = row&3 of every fragment row
  f32x4 acc[4][NF];
#pragma unroll
  for (int i = 0; i < 4; ++i)
#pragma unroll
    for (int j = 0; j < NF; ++j) acc[i][j] = f32x4{0.f, 0.f, 0.f, 0.f};

  auto STAGE = [&](int buf, int k0s) {
    for (int s = wid; s < NINST; s += 4) {
      const int slot = s * 64 + lane;    // linear 16B LDS slot
      const int row = slot >> 2, q = slot & 3;
      const int qg = q ^ (row & 3);      // inverse-swizzled global chunk
      const u16* g;
      if (row < 128) {
        g = A + (long)(m0 + row) * lda + k0s + qg * 8;
      } else {
        const int n = min(n0 + row - 128, N - 1);
        g = BT + (long)n * ldbt + k0s + qg * 8;
      }
      __builtin_amdgcn_global_load_lds(
          (const __attribute__((address_space(1))) unsigned int*)g,
          (__attribute__((address_space(3))) unsigned int*)&S[buf][s * 512],
          16, 0, 0);
    }
  };

  STAGE(0, 0);
  int cur = 0;
  for (int k0 = 0; k0 < K; k0 += 32) {
    __syncthreads();                 // drains vmcnt -> S[cur] ready; prior reads of S[cur^1] done
    if (k0 + 32 < K) STAGE(cur ^ 1, k0 + 32);
    bf16x8 af[4];
#pragma unroll
    for (int mf = 0; mf < 4; ++mf)
      af[mf] = *(const bf16x8*)&S[cur][(wm * 64 + mf * 16 + fr) * 32 + (kh ^ q3) * 8];
#pragma unroll
    for (int nf = 0; nf < NF; ++nf) {
      const bf16x8 bfr =
          *(const bf16x8*)&S[cur][(128 + wn * NF * 16 + nf * 16 + fr) * 32 + (kh ^ q3) * 8];
#pragma unroll
      for (int mf = 0; mf < 4; ++mf)
        acc[mf][nf] = __builtin_amdgcn_mfma_f32_16x16x32_bf16(af[mf], bfr, acc[mf][nf], 0, 0, 0);
    }
    cur ^= 1;
  }

#pragma unroll
  for (int mf = 0; mf < 4; ++mf)
#pragma unroll
    for (int nf = 0; nf < NF; ++nf) {
      const int gn = n0 + wn * NF * 16 + nf * 16 + fr;
      if (gn < N) {
#pragma unroll
        for (int r = 0; r < 4; ++r) {
          const long gm = m0 + wm * 64 + mf * 16 + kh * 4 + r;   // C/D: row=(lane>>4)*4+r
          float v = acc[mf][nf][r];
          if (flags & FLAG_BIAS) v += bias[gn];
          if (flags & FLAG_ACC)  v += ldv(&C[gm * ldc + gn]);
          if (flags & FLAG_RELU) v = fmaxf(v, 0.f);
          stv(&C[gm * ldc + gn], v);
        }
      }
    }
}

// ======================= weight convert + transpose (f32 [K,N] -> bf16 [N,K]) ==========
__global__ __launch_bounds__(256)
void wconvT(const float* __restrict__ w, u16* __restrict__ wt, int K, int N)
{
  const long idx = (long)blockIdx.x * 256 + threadIdx.x;
  if (idx >= (long)K * N) return;
  const int n = (int)(idx / K), k = (int)(idx % K);
  wt[idx] = f2bf(w[(long)k * N + n]);
}

// ======================= tiled bf16 transpose: in [R,Cc] -> out [Cc,R], batched ==========
__global__ __launch_bounds__(256)
void transpose_bf16(const u16* __restrict__ in, u16* __restrict__ out,
                    int R, int Cc, long batchIn, long batchOut)
{
  __shared__ u16 t[64][65];
  in  += (long)blockIdx.z * batchIn;
  out += (long)blockIdx.z * batchOut;
  const int tid = threadIdx.x;
  const int r0 = blockIdx.x * 64, c0 = blockIdx.y * 64;
  for (int i = tid; i < 64 * 64; i += 256) {
    const int r = i >> 6, c = i & 63;
    t[r][c] = (r0 + r < R && c0 + c < Cc) ? in[(long)(r0 + r) * Cc + c0 + c] : (u16)0;
  }
  __syncthreads();
  for (int i = tid; i < 64 * 64; i += 256) {
    const int c = i >> 6, r = i & 63;
    if (c0 + c < Cc && r0 + r < R) out[(long)(c0 + c) * R + r0 + r] = t[r][c];
  }
}

__global__ __launch_bounds__(256)
void cvt_f2bf(const float* __restrict__ in, u16* __restrict__ out, long n)
{
  const long idx = (long)blockIdx.x * 256 + threadIdx.x;
  if (idx < n) out[idx] = f2bf(in[idx]);
}

// ======================= graph preprocessing (CSR build) =======================
__global__ __launch_bounds__(256)
void edge_stats(const int* __restrict__ s, const int* __restrict__ d,
                const float* __restrict__ ew, float* degf, float* degb,
                int* cntf, int* cntb)
{
  const int e = blockIdx.x * 256 + threadIdx.x;
  atomicAdd(&degf[d[e]], ew[e]);
  atomicAdd(&degb[s[e]], ew[e]);
  atomicAdd(&cntf[d[e]], 1);
  atomicAdd(&cntb[s[e]], 1);
}

__global__ __launch_bounds__(256)
void scan2(const int* __restrict__ cf, const int* __restrict__ cb,
           int* __restrict__ rf, int* __restrict__ rb)
{
  const int* c = blockIdx.x ? cb : cf;
  int* r       = blockIdx.x ? rb : rf;
  __shared__ int part[256];
  const int t = threadIdx.x, base = t * 8;
  int loc[8]; int s = 0;
#pragma unroll
  for (int i = 0; i < 8; ++i) { loc[i] = c[base + i]; s += loc[i]; }
  part[t] = s; __syncthreads();
  if (t == 0) {
    int run = 0;
    for (int i = 0; i < 256; ++i) { const int v = part[i]; part[i] = run; run += v; }
    r[2048] = run;
  }
  __syncthreads();
  int run = part[t];
#pragma unroll
  for (int i = 0; i < 8; ++i) { r[base + i] = run; run += loc[i]; }
}

__global__ __launch_bounds__(256)
void fill_csr(const int* __restrict__ s, const int* __restrict__ d,
              const float* __restrict__ ew,
              const float* __restrict__ degf, const float* __restrict__ degb,
              const int* __restrict__ rowf, const int* __restrict__ rowb,
              int* curf, int* curb,
              int* __restrict__ colf, int* __restrict__ colb,
              float* __restrict__ wnf, float* __restrict__ wnb)
{
  const int e = blockIdx.x * 256 + threadIdx.x;
  const int si = s[e], di = d[e];
  const float w = ew[e];
  const int p = rowf[di] + atomicAdd(&curf[di], 1);
  colf[p] = si; wnf[p] = w / fmaxf(degf[di], 1e-6f);
  const int q = rowb[si] + atomicAdd(&curb[si], 1);
  colb[q] = di; wnb[q] = w / fmaxf(degb[si], 1e-6f);
}

// ======================= diffusion step, all 48 bt per node ==========
// y[bt,n,ch] = sum_j w[j]*x[bt,col[j],ch] — block per node; CSR read once (uniform);
// bf16x8 loads; edge loop unrolled x2 for load-latency overlap.
__global__ __launch_bounds__(256)
void prop_gather_all(const u16* __restrict__ x, int ldx, u16* __restrict__ y, int ldy,
                     const int* __restrict__ rowptr, const int* __restrict__ col,
                     const float* __restrict__ w)
{
  const int n = blockIdx.x;
  const int beg = rowptr[n], end = rowptr[n + 1];
  const int tid = threadIdx.x;
  float acc[4][8];
#pragma unroll
  for (int r = 0; r < 4; ++r)
#pragma unroll
    for (int q = 0; q < 8; ++q) acc[r][q] = 0.f;
  int bt_[4], ch_[4];
#pragma unroll
  for (int r = 0; r < 4; ++r) {
    const int item = tid + r * 256;            // < 960 = 48 bt * 20 ch8
    bt_[r] = (item < 960) ? item / 20 : -1;
    ch_[r] = (item % 20) * 8;
  }
  int j = beg;
  for (; j + 1 < end; j += 2) {
    const int c0 = col[j], c1 = col[j + 1];
    const float w0 = w[j], w1 = w[j + 1];
#pragma unroll
    for (int r = 0; r < 4; ++r) {
      if (bt_[r] < 0) continue;
      const bf16x8 v0 = *(const bf16x8*)&x[((long)bt_[r] * cN + c0) * ldx + ch_[r]];
      const bf16x8 v1 = *(const bf16x8*)&x[((long)bt_[r] * cN + c1) * ldx + ch_[r]];
#pragma unroll
      for (int q = 0; q < 8; ++q) {
        acc[r][q] = fmaf(w0, bf2f((u16)v0[q]), acc[r][q]);
        acc[r][q] = fmaf(w1, bf2f((u16)v1[q]), acc[r][q]);
      }
    }
  }
  if (j < end) {
    const int c0 = col[j];
    const float w0 = w[j];
#pragma unroll
    for (int r = 0; r < 4; ++r) {
      if (bt_[r] < 0) continue;
      const bf16x8 v0 = *(const bf16x8*)&x[((long)bt_[r] * cN + c0) * ldx + ch_[r]];
#pragma unroll
      for (int q = 0; q < 8; ++q) acc[r][q] = fmaf(w0, bf2f((u16)v0[q]), acc[r][q]);
    }
  }
#pragma unroll
  for (int r = 0; r < 4; ++r) {
    if (bt_[r] < 0) continue;
    u16 o[8];
#pragma unroll
    for (int q = 0; q < 8; ++q) o[q] = f2bf(acc[r][q]);
    *(bf16x8*)&y[((long)bt_[r] * cN + n) * ldy + ch_[r]] = *(const bf16x8*)o;
  }
}

// ======================= encoder =======================
__global__ __launch_bounds__(160)
void encoder(const float* __restrict__ x, const float* __restrict__ ew_,
             const float* __restrict__ eb, const float* __restrict__ ne,
             const float* __restrict__ lw, u16* __restrict__ h)
{
  __shared__ float xs[cF];
  const int tid = threadIdx.x;
  const long r0 = (long)blockIdx.x * 8;
  for (long row = r0; row < r0 + 8; ++row) {
    if (tid < cF) xs[tid] = x[row * cF + tid];
    __syncthreads();
    const int n = (int)(row % cN);
    float v;
    if (tid < cHID) {
      float acc = eb[tid] + ne[(long)n * cHID + tid];
#pragma unroll
      for (int f = 0; f < cF; ++f) acc = fmaf(xs[f], ew_[f * cHID + tid], acc);
      v = acc;
    } else {
      v = lw[(long)n * cLF + (tid - cHID)];
    }
    h[row * 160 + tid] = f2bf(v);
    __syncthreads();
  }
}

// ======================= adjacency: row softmax of relu(scores) ==========
__global__ __launch_bounds__(256)
void relu_softmax_rows(const float* __restrict__ sc, u16* __restrict__ adj)
{
  const int row = blockIdx.x, tid = threadIdx.x;
  const float* p = sc + (long)row * cN;
  __shared__ float red[256];
  float lv[8];
  float mx = 0.f;   // relu => all >= 0
#pragma unroll
  for (int i = 0; i < 8; ++i) {
    const float v = fmaxf(p[tid + i * 256], 0.f);
    lv[i] = v; mx = fmaxf(mx, v);
  }
  red[tid] = mx; __syncthreads();
  for (int s = 128; s > 0; s >>= 1) { if (tid < s) red[tid] = fmaxf(red[tid], red[tid + s]); __syncthreads(); }
  const float m = red[0]; __syncthreads();
  float sum = 0.f;
#pragma unroll
  for (int i = 0; i < 8; ++i) { lv[i] = __expf(lv[i] - m); sum += lv[i]; }
  red[tid] = sum; __syncthreads();
  for (int s = 128; s > 0; s >>= 1) { if (tid < s) red[tid] += red[tid + s]; __syncthreads(); }
  const float inv = 1.f / red[0]; __syncthreads();
#pragma unroll
  for (int i = 0; i < 8; ++i) adj[(long)row * cN + tid + i * 256] = f2bf(lv[i] * inv);
}

// ======================= temporal 2nd-order LIF scan, bf16x8 ==========
__global__ __launch_bounds__(256)
void scan_syn8(const u16* __restrict__ in, u16* __restrict__ out, int c)
{
  const int c8 = c >> 3;
  const long total = (long)cB * cN * c8;
  const long idx = (long)blockIdx.x * 256 + threadIdx.x;
  if (idx >= total) return;
  const long nc = (long)cN * c;
  const int b = (int)(idx / ((long)cN * c8));
  const long rest = (idx % ((long)cN * c8)) * 8;
  const u16* p = in  + (long)b * cT * nc + rest;
  u16*       q = out + (long)b * cT * nc + rest;
  float syn[8], mem[8];
#pragma unroll
  for (int e = 0; e < 8; ++e) { syn[e] = 0.f; mem[e] = 0.f; }
#pragma unroll
  for (int t = 0; t < cT; ++t) {
    const bf16x8 v = *(const bf16x8*)&p[(long)t * nc];
    u16 o[8];
#pragma unroll
    for (int e = 0; e < 8; ++e) {
      syn[e] = fmaf(cALPHA, syn[e], bf2f((u16)v[e]));
      mem[e] = fmaf(cBETA, mem[e], syn[e]);
      o[e] = f2bf(mem[e]);
    }
    *(bf16x8*)&q[(long)t * nc] = *(const bf16x8*)o;
  }
}

// ======================= batch norm =======================
__global__ __launch_bounds__(256)
void bn_stats(const float* __restrict__ d, const u16* __restrict__ res,
              float* __restrict__ stat, int c)
{
  const int ch = threadIdx.x;
  const long r0 = (long)blockIdx.x * (cR / 512);
  float s = 0.f, s2 = 0.f;
  for (int i = 0; i < cR / 512; ++i) {
    const float v = d[(r0 + i) * c + ch] + bf2f(res[(r0 + i) * c + ch]);
    s += v; s2 = fmaf(v, v, s2);
  }
  atomicAdd(&stat[ch], s);
  atomicAdd(&stat[c + ch], s2);
}

__global__ __launch_bounds__(256)
void bn_finalize(const float* __restrict__ stat, const float* __restrict__ g,
                 const float* __restrict__ b, float* __restrict__ scsh, int c)
{
  const int ch = threadIdx.x;
  const float mu = stat[ch] / cR;
  const float var = stat[c + ch] / cR - mu * mu;
  const float sc = g[ch] * rsqrtf(var + cEPS);
  scsh[ch] = sc;
  scsh[c + ch] = fmaf(-mu, sc, b[ch]);
}

__global__ __launch_bounds__(192)
void bn_apply_concat(const float* __restrict__ d, const u16* __restrict__ res,
                     const float* __restrict__ scsh, const float* __restrict__ lw,
                     u16* __restrict__ out)
{
  const int tid = threadIdx.x;
  const long r0 = (long)blockIdx.x * 8;
  for (long row = r0; row < r0 + 8; ++row) {
    const int n = (int)(row % cN);
    float v;
    if (tid < 160) v = fmaf(d[row * 160 + tid] + bf2f(res[row * 160 + tid]),
                            scsh[tid], scsh[160 + tid]);
    else           v = lw[(long)n * cLF + (tid - 160)];
    out[row * 192 + tid] = f2bf(v);
  }
}

// ======================= output transpose (f32 out) =======================
__global__ __launch_bounds__(256)
void final_transpose(const float* __restrict__ y, float* __restrict__ out)
{
  const long idx = (long)blockIdx.x * 256 + threadIdx.x;
  const int f = (int)(idx % cF);
  long t = idx / cF;
  const int n = (int)(t % cN); t /= cN;
  const int hor = (int)(t % cHOR);
  const int b = (int)(t / cHOR);
  out[idx] = y[((long)b * cN + n) * (cHOR * cF) + hor * cF + f];
}

__global__ __launch_bounds__(256)
void fill_f32(float* __restrict__ out, long n, float val)
{
  const long idx = (long)blockIdx.x * 256 + threadIdx.x;
  if (idx < n) out[idx] = val;
}

// ======================= host orchestration =======================
extern "C" void kernel_launch(void* const* d_in, const int* in_sizes, int n_in,
                              void* d_out, int out_size, void* d_ws, size_t ws_size,
                              hipStream_t stream)
{
  float* outF = (float*)d_out;
  const long outN = out_size;
  if (n_in < 34) { fill_f32<<<(int)((outN + 255) / 256), 256, 0, stream>>>(outF, outN, 500.f); return; }
  if (in_sizes[0] != cB * cT * cN * cF || in_sizes[1] != 2 * cE || in_sizes[9] != 3 * 160 * 160) {
    fill_f32<<<(int)((outN + 255) / 256), 256, 0, stream>>>(outF, outN, 700.f); return;
  }

  const float* x        = (const float*)d_in[0];
  const int*   eidx     = (const int*)d_in[1];
  const float* ew       = (const float*)d_in[2];
  const float* enc_w    = (const float*)d_in[3];
  const float* enc_b    = (const float*)d_in[4];
  const float* node_emb = (const float*)d_in[5];
  const float* src_emb  = (const float*)d_in[6];
  const float* tgt_emb  = (const float*)d_in[7];
  const float* lw0  = (const float*)d_in[8];
  const float* tW0  = (const float*)d_in[9];
  const float* tb0  = (const float*)d_in[10];
  const float* dcw0 = (const float*)d_in[11];
  const float* dcb0 = (const float*)d_in[12];
  const float* dsw0 = (const float*)d_in[13];
  const float* dsb0 = (const float*)d_in[14];
  const float* skw0 = (const float*)d_in[15];
  const float* skb0 = (const float*)d_in[16];
  const float* ng0  = (const float*)d_in[17];
  const float* nb0  = (const float*)d_in[18];
  const float* lw1  = (const float*)d_in[19];
  const float* tW1  = (const float*)d_in[20];
  const float* tb1  = (const float*)d_in[21];
  // d_in[22..25, 28..29] feed only block-1's post-skip h (never read) -> dead.
  const float* skw1 = (const float*)d_in[26];
  const float* skb1 = (const float*)d_in[27];
  const float* rw1  = (const float*)d_in[30];
  const float* rb1  = (const float*)d_in[31];
  const float* rw2  = (const float*)d_in[32];
  const float* rb2  = (const float*)d_in[33];
  const int* srcI = eidx;
  const int* dstI = eidx + cE;

  // ---- workspace layout ----
  char* W = (char*)d_ws;
  size_t off = 0;
  auto A8 = [&](size_t bytes) { size_t r = off; off = (off + bytes + 255) & ~(size_t)255; return r; };
  const size_t oH0 = A8((size_t)cR * 160 * 2);   // res, bf16
  const size_t oHh = A8((size_t)cR * 160 * 2);   // chain h (G1 [cR,192] aliases Hh+T1-head)
  const size_t oT1 = A8((size_t)cR * 160 * 2);   // scratch (Z12 [cR,320] aliases T1+S2)
  const size_t oS2 = A8((size_t)cR * 160 * 2);   // scratch2 / hT
  const size_t oDd = A8((size_t)cR * 160 * 4);   // f32 accumulator (G2, scores alias)
  const size_t oAdj = A8((size_t)cN * cN * 2);
  const size_t oOut = A8((size_t)cB * cN * cFF * 4);       // f32 skip acc (t=11)
  const size_t oR1  = A8((size_t)cB * cN * 512 * 2);       // bf16 r1
  const size_t oY   = A8((size_t)cB * cN * cHOR * cF * 4); // f32
  const size_t oZero = A8(6 * 2048 * 4 + 2 * 192 * 4);
  const size_t oRowf = A8(2049 * 4), oRowb = A8(2049 * 4);
  const size_t oColf = A8((size_t)cE * 4), oColb = A8((size_t)cE * 4);
  const size_t oWnf  = A8((size_t)cE * 4), oWnb  = A8((size_t)cE * 4);
  const size_t oScSh = A8(2 * 192 * 4);
  const size_t oWT   = A8((size_t)721920 * 2);   // bf16 transposed weights
  const size_t oSeb  = A8((size_t)cN * cHID * 2);
  const size_t oTeb  = A8((size_t)cN * cHID * 2);
  if (off > ws_size) {
    fill_f32<<<(int)((outN + 255) / 256), 256, 0, stream>>>(outF, outN, 300.f);
    return;
  }

  u16 *H0 = (u16*)(W + oH0), *Hh = (u16*)(W + oHh), *T1 = (u16*)(W + oT1),
      *S2 = (u16*)(W + oS2), *adjb = (u16*)(W + oAdj);
  float* Dd = (float*)(W + oDd);
  u16 *G1 = (u16*)(W + oHh);   // [cR,192] bf16 over Hh(+T1 head), post-BN only
  u16 *G2 = (u16*)(W + oDd);   // over Dd, post-BN only
  u16 *Z12 = T1;               // [cR,320] bf16 over T1+S2 (diffconv packing)
  float* scores = (float*)(W + oDd);   // phase-0 scratch, dead before Dd use
  float *outacc = (float*)(W + oOut), *yb = (float*)(W + oY);
  u16 *r1b = (u16*)(W + oR1);
  float* zero = (float*)(W + oZero);
  float *degf = zero, *degb = zero + 2048;
  int *cntf = (int*)(zero + 4096), *cntb = cntf + 2048,
      *curf = cntb + 2048, *curb = curf + 2048;
  float* stat = (float*)(curb + 2048);
  int *rowf = (int*)(W + oRowf), *rowb = (int*)(W + oRowb);
  int *colf = (int*)(W + oColf), *colb = (int*)(W + oColb);
  float *wnf = (float*)(W + oWnf), *wnb = (float*)(W + oWnb);
  float* scsh = (float*)(W + oScSh);
  u16* wt   = (u16*)(W + oWT);
  u16 *wt0 = wt,              *wt1 = wt0 + 3 * 25600, *wdc = wt1 + 3 * 36864,
      *wds = wdc + 102400,    *wsk0 = wds + 51200,    *wsk1 = wsk0 + 40960,
      *wr1 = wsk1 + 49152,    *wr2 = wr1 + 131072;
  u16 *seb = (u16*)(W + oSeb), *teb = (u16*)(W + oTeb);

  auto g5u = [&](const u16* Aq, const u16* Bq, u16* Cq, const float* bias,
                 int M, int N, int K, int lda, int ldbt, int ldc,
                 long bA, long bB, long bC, int batch, int flags) {
    dim3 g(M / 128, (N + 159) / 160, batch);
    gemm_mfma<5, u16><<<g, 256, 0, stream>>>(Aq, Bq, Cq, bias, M, N, K, lda, ldbt, ldc, bA, bB, bC, flags);
  };
  auto g5f = [&](const u16* Aq, const u16* Bq, float* Cq, const float* bias,
                 int M, int N, int K, int lda, int ldbt, int ldc, int flags) {
    dim3 g(M / 128, (N + 159) / 160, 1);
    gemm_mfma<5, float><<<g, 256, 0, stream>>>(Aq, Bq, Cq, bias, M, N, K, lda, ldbt, ldc, 0, 0, 0, flags);
  };
  auto g6u = [&](const u16* Aq, const u16* Bq, u16* Cq, const float* bias,
                 int M, int N, int K, int lda, int ldbt, int ldc, int flags) {
    dim3 g(M / 128, (N + 191) / 192, 1);
    gemm_mfma<6, u16><<<g, 256, 0, stream>>>(Aq, Bq, Cq, bias, M, N, K, lda, ldbt, ldc, 0, 0, 0, flags);
  };
  auto g4f = [&](const u16* Aq, const u16* Bq, float* Cq, const float* bias,
                 int M, int N, int K, int lda, int ldbt, int ldc,
                 long bA, long bB, long bC, int batch, int flags) {
    dim3 g(M / 128, (N + 127) / 128, batch);
    gemm_mfma<4, float><<<g, 256, 0, stream>>>(Aq, Bq, Cq, bias, M, N, K, lda, ldbt, ldc, bA, bB, bC, flags);
  };
  auto g4u = [&](const u16* Aq, const u16* Bq, u16* Cq, const float* bias,
                 int M, int N, int K, int lda, int ldbt, int ldc, int flags) {
    dim3 g(M / 128, (N + 127) / 128, 1);
    gemm_mfma<4, u16><<<g, 256, 0, stream>>>(Aq, Bq, Cq, bias, M, N, K, lda, ldbt, ldc, 0, 0, 0, flags);
  };
  auto wcv = [&](const float* src, u16* dst, int K, int N) {
    wconvT<<<(int)(((long)K * N + 255) / 256), 256, 0, stream>>>(src, dst, K, N);
  };

  // ---- phase 0: weight conversion, CSR, encoder, adjacency ----
  for (int l = 0; l < 3; ++l) wcv(tW0 + (long)l * 25600, wt0 + (long)l * 25600, 160, 160);
  for (int l = 0; l < 3; ++l) wcv(tW1 + (long)l * 36864, wt1 + (long)l * 36864, 192, 192);
  wcv(dcw0, wdc, 640, 160);   // [640,160] -> [160][640] (concat-K layout)
  wcv(dsw0, wds, 320, 160);   // [320,160] -> [160][320]
  wcv(skw0, wsk0, 160, 256);
  wcv(skw1, wsk1, 192, 256);
  wcv(rw1, wr1, 256, 512);
  wcv(rw2, wr2, 512, 312);

  hipMemsetAsync(zero, 0, 6 * 2048 * 4 + 2 * 192 * 4, stream);
  edge_stats<<<cE / 256, 256, 0, stream>>>(srcI, dstI, ew, degf, degb, cntf, cntb);
  scan2<<<2, 256, 0, stream>>>(cntf, cntb, rowf, rowb);
  fill_csr<<<cE / 256, 256, 0, stream>>>(srcI, dstI, ew, degf, degb, rowf, rowb,
                                         curf, curb, colf, colb, wnf, wnb);
  encoder<<<cR / 8, 160, 0, stream>>>(x, enc_w, enc_b, node_emb, lw0, H0);

  // learned adjacency: scores = se @ te^T via MFMA, then row relu-softmax
  cvt_f2bf<<<(cN * cHID + 255) / 256, 256, 0, stream>>>(src_emb, seb, (long)cN * cHID);
  cvt_f2bf<<<(cN * cHID + 255) / 256, 256, 0, stream>>>(tgt_emb, teb, (long)cN * cHID);
  g4f(seb, teb, scores, nullptr, cN, cN, cHID, cHID, cHID, cN, 0, 0, 0, 1, 0);
  relu_softmax_rows<<<cN, 256, 0, stream>>>(scores, adjb);

  // ---- block 0 (c = 160) ----
  {
    const int c = 160;
    const long NC = (long)cN * c;
    const int scanGrid = (int)(((long)cB * cN * (c / 8) + 255) / 256);
    // synaptic chain: H0 (res) -> Hh
    g5u(H0, wt0 + 0L * 25600, T1, tb0 + 0 * c, cR, c, c, c, c, c, 0, 0, 0, 1, FLAG_BIAS);
    scan_syn8<<<scanGrid, 256, 0, stream>>>(T1, Hh, c);
    for (int l = 1; l < 3; ++l) {
      g5u(Hh, wt0 + (long)l * 25600, T1, tb0 + l * c, cR, c, c, c, c, c, 0, 0, 0, 1, FLAG_BIAS);
      scan_syn8<<<scanGrid, 256, 0, stream>>>(T1, Hh, c);
    }
    // skip (t=11): outacc[b] = h[b,11]@skw0 + skb0
    g4f(Hh + 11L * NC, wsk0, outacc, skb0, cN, cFF, c, c, c, cFF,
        (long)cT * NC, 0, (long)cN * cFF, cB, FLAG_BIAS);
    // diffconv: pack [z1|z2] then [z3|z4] into Z12 [cR,320]; two K=320 GEMMs
    prop_gather_all<<<cN, 256, 0, stream>>>(Hh, 160, Z12, 320, rowf, colf, wnf);
    prop_gather_all<<<cN, 256, 0, stream>>>(Z12, 320, Z12 + 160, 320, rowf, colf, wnf);
    g5f(Z12, wdc, Dd, dcb0, cR, c, 320, 320, 640, c, FLAG_BIAS);
    prop_gather_all<<<cN, 256, 0, stream>>>(Hh, 160, Z12, 320, rowb, colb, wnb);
    prop_gather_all<<<cN, 256, 0, stream>>>(Z12, 320, Z12 + 160, 320, rowb, colb, wnb);
    g5f(Z12, wdc + 320, Dd, nullptr, cR, c, 320, 320, 640, c, FLAG_ACC);
    // dense conv: hT -> S2 ; x1 = adj@hT -> T1 ; Dd += x1@dsw[:,0:160] ;
    //             x1T -> S2 ; x2 = adj@x1T -> T1 ; Dd += x2@dsw[:,160:320]
    dim3 tg(cN / 64, (c + 63) / 64, cBT);
    transpose_bf16<<<tg, 256, 0, stream>>>(Hh, S2, cN, c, NC, NC);
    g5u(adjb, S2, T1, nullptr, cN, c, cN, cN, cN, c, 0, NC, NC, cBT, 0);
    g5f(T1, wds, Dd, dsb0, cR, c, c, c, 320, c, FLAG_BIAS | FLAG_ACC);
    transpose_bf16<<<tg, 256, 0, stream>>>(T1, S2, cN, c, NC, NC);
    g5u(adjb, S2, T1, nullptr, cN, c, cN, cN, cN, c, 0, NC, NC, cBT, 0);
    g5f(T1, wds + 160, Dd, nullptr, cR, c, c, c, 320, c, FLAG_ACC);
    // BN(Dd + H0) -> G1 (stride 192) + lw1
    bn_stats<<<512, c, 0, stream>>>(Dd, H0, stat, c);
    bn_finalize<<<1, c, 0, stream>>>(stat, ng0, nb0, scsh, c);
    bn_apply_concat<<<cR / 8, 192, 0, stream>>>(Dd, H0, scsh, lw1, G1);
  }

  // ---- block 1 (c = 192): chain + skip only ----
  {
    const int c = 192;
    const long NC = (long)cN * c;
    const int scanGrid = (int)(((long)cB * cN * (c / 8) + 255) / 256);
    for (int l = 0; l < 3; ++l) {
      g6u(G1, wt1 + (long)l * 36864, G2, tb1 + l * c, cR, c, c, c, c, c, FLAG_BIAS);
      scan_syn8<<<scanGrid, 256, 0, stream>>>(G2, G1, c);
    }
    g4f(G1 + 11L * NC, wsk1, outacc, skb1, cN, cFF, c, c, c, cFF,
        (long)cT * NC, 0, (long)cN * cFF, cB, FLAG_BIAS | FLAG_ACC | FLAG_RELU);
  }

  // ---- readout (outacc f32 -> bf16 in S2, then two MFMA GEMMs) ----
  cvt_f2bf<<<(int)(((long)cB * cN * cFF + 255) / 256), 256, 0, stream>>>(outacc, S2, (long)cB * cN * cFF);
  g4u(S2, wr1, r1b, rb1, cB * cN, 2 * cFF, cFF, cFF, cFF, 2 * cFF, FLAG_BIAS | FLAG_RELU);
  g4f(r1b, wr2, yb, rb2, cB * cN, cHOR * cF, 2 * cFF, 2 * cFF, 2 * cFF, cHOR * cF,
      0, 0, 0, 1, FLAG_BIAS);
  final_transpose<<<(cB * cHOR * cN * cF) / 256, 256, 0, stream>>>(yb, outF);
}

// Round 9
// 1342.878 us; speedup vs baseline: 3.0002x; 1.0460x over previous
//
#include <hip/hip_runtime.h>

// ======================= types & helpers =======================
using u16 = unsigned short;
typedef short bf16x8 __attribute__((ext_vector_type(8)));
typedef float f32x4  __attribute__((ext_vector_type(4)));

__device__ __forceinline__ float bf2f(u16 u) { return __uint_as_float(((unsigned)u) << 16); }
__device__ __forceinline__ u16 f2bf(float f) {  // round-to-nearest-even
  unsigned u = __float_as_uint(f);
  return (u16)((u + 0x7FFFu + ((u >> 16) & 1u)) >> 16);
}
__device__ __forceinline__ float ldv(const float* p) { return *p; }
__device__ __forceinline__ float ldv(const u16* p)   { return bf2f(*p); }
__device__ __forceinline__ void  stv(float* p, float v) { *p = v; }
__device__ __forceinline__ void  stv(u16* p, float v)   { *p = f2bf(v); }

// ======================= problem constants =======================
constexpr int cB = 4, cT = 12, cN = 2048, cF = 26;
constexpr int cHID = 128, cLF = 32, cFF = 256, cHOR = 12;
constexpr int cE = 16384;
constexpr int cR = cB * cT * cN;   // 98304
constexpr int cBT = cB * cT;       // 48
constexpr float cALPHA = 0.9f, cBETA = 0.8f, cEPS = 1e-5f;

#define FLAG_ACC  1
#define FLAG_BIAS 2
#define FLAG_RELU 4

// ======================= MFMA bf16 GEMM (gload_lds + dbuf, hoisted addresses) ==========
// C[m,n] = sum_k A[m,k] * BT[n,k]  (+bias) (+C) (relu)
// A: bf16 [M,K] lda ; BT: bf16 [N,K] ldbt. M%128==0, K%32==0, lda/ldbt%8==0; N guarded
// (OOB B rows clamp to N-1; their output columns are never stored).
// LDS: 2 x linear [128+TN][32] bf16. Staging addresses are precomputed per wave
// (<=5 per-lane pointers) and advanced by 64B per K-step -> K-loop VALU is just
// gload_lds issue + pointer adds. (Round-8 lesson: the 7.08M "conflict" counter is
// intrinsic b128 behavior - exactly 4 extra cyc/b128 - not a fixable conflict.)
template <int NF, typename TC>
__global__ __launch_bounds__(256)
void gemm_mfma(const u16* __restrict__ A, const u16* __restrict__ BT,
               TC* __restrict__ C, const float* __restrict__ bias,
               int M, int N, int K, int lda, int ldbt, int ldc,
               long batchA, long batchB, long batchC, int flags)
{
  constexpr int TN = NF * 32;
  constexpr int ROWS = 128 + TN;        // A rows then BT rows
  constexpr int NINST = ROWS / 16;      // gload_lds wave-instrs per K-step
  constexpr int NPW = (NINST + 3) / 4;  // max instrs per wave
  __shared__ __align__(16) u16 S[2][ROWS * 32];
  A  += (long)blockIdx.z * batchA;
  BT += (long)blockIdx.z * batchB;
  C  += (long)blockIdx.z * batchC;
  const int tid = threadIdx.x;
  const int lane = tid & 63, wid = tid >> 6;
  const int wm = wid & 1, wn = wid >> 1;
  const int m0 = blockIdx.x * 128, n0 = blockIdx.y * TN;
  const int fr = lane & 15, kh = lane >> 4;   // frag row / k-half
  const int nwi = (NINST - wid + 3) / 4;      // this wave's instr count

  // hoisted per-lane staging pointers (advance +32 elts per K-step)
  const u16* gp[NPW];
#pragma unroll
  for (int i = 0; i < NPW; ++i) {
    const int s = wid + i * 4;
    if (s < NINST) {
      const int slot = s * 64 + lane;    // linear 16B LDS slot
      const int row = slot >> 2, q = slot & 3;
      if (row < 128) {
        gp[i] = A + (long)(m0 + row) * lda + q * 8;
      } else {
        const int n = min(n0 + row - 128, N - 1);
        gp[i] = BT + (long)n * ldbt + q * 8;
      }
    } else {
      gp[i] = A;
    }
  }

  f32x4 acc[4][NF];
#pragma unroll
  for (int i = 0; i < 4; ++i)
#pragma unroll
    for (int j = 0; j < NF; ++j) acc[i][j] = f32x4{0.f, 0.f, 0.f, 0.f};

  auto STAGE = [&](int buf) {
#pragma unroll
    for (int i = 0; i < NPW; ++i) {
      if (i < nwi) {
        const int s = wid + i * 4;
        __builtin_amdgcn_global_load_lds(
            (const __attribute__((address_space(1))) unsigned int*)gp[i],
            (__attribute__((address_space(3))) unsigned int*)&S[buf][s * 512],
            16, 0, 0);
        gp[i] += 32;
      }
    }
  };

  STAGE(0);
  int cur = 0;
  for (int k0 = 0; k0 < K; k0 += 32) {
    __syncthreads();                 // drains vmcnt -> S[cur] ready; prior reads of S[cur^1] done
    if (k0 + 32 < K) STAGE(cur ^ 1);
    bf16x8 af[4];
#pragma unroll
    for (int mf = 0; mf < 4; ++mf)
      af[mf] = *(const bf16x8*)&S[cur][(wm * 64 + mf * 16 + fr) * 32 + kh * 8];
#pragma unroll
    for (int nf = 0; nf < NF; ++nf) {
      const bf16x8 bfr =
          *(const bf16x8*)&S[cur][(128 + wn * NF * 16 + nf * 16 + fr) * 32 + kh * 8];
#pragma unroll
      for (int mf = 0; mf < 4; ++mf)
        acc[mf][nf] = __builtin_amdgcn_mfma_f32_16x16x32_bf16(af[mf], bfr, acc[mf][nf], 0, 0, 0);
    }
    cur ^= 1;
  }

#pragma unroll
  for (int mf = 0; mf < 4; ++mf)
#pragma unroll
    for (int nf = 0; nf < NF; ++nf) {
      const int gn = n0 + wn * NF * 16 + nf * 16 + fr;
      if (gn < N) {
#pragma unroll
        for (int r = 0; r < 4; ++r) {
          const long gm = m0 + wm * 64 + mf * 16 + kh * 4 + r;   // C/D: row=(lane>>4)*4+r
          float v = acc[mf][nf][r];
          if (flags & FLAG_BIAS) v += bias[gn];
          if (flags & FLAG_ACC)  v += ldv(&C[gm * ldc + gn]);
          if (flags & FLAG_RELU) v = fmaxf(v, 0.f);
          stv(&C[gm * ldc + gn], v);
        }
      }
    }
}

// ======================= weight convert + transpose (f32 [K,N] -> bf16 [N,K]) ==========
__global__ __launch_bounds__(256)
void wconvT(const float* __restrict__ w, u16* __restrict__ wt, int K, int N)
{
  const long idx = (long)blockIdx.x * 256 + threadIdx.x;
  if (idx >= (long)K * N) return;
  const int n = (int)(idx / K), k = (int)(idx % K);
  wt[idx] = f2bf(w[(long)k * N + n]);
}

// ======================= tiled bf16 transpose: in [R,Cc] -> out [Cc,R], batched ==========
__global__ __launch_bounds__(256)
void transpose_bf16(const u16* __restrict__ in, u16* __restrict__ out,
                    int R, int Cc, long batchIn, long batchOut)
{
  __shared__ u16 t[64][65];
  in  += (long)blockIdx.z * batchIn;
  out += (long)blockIdx.z * batchOut;
  const int tid = threadIdx.x;
  const int r0 = blockIdx.x * 64, c0 = blockIdx.y * 64;
  for (int i = tid; i < 64 * 64; i += 256) {
    const int r = i >> 6, c = i & 63;
    t[r][c] = (r0 + r < R && c0 + c < Cc) ? in[(long)(r0 + r) * Cc + c0 + c] : (u16)0;
  }
  __syncthreads();
  for (int i = tid; i < 64 * 64; i += 256) {
    const int c = i >> 6, r = i & 63;
    if (c0 + c < Cc && r0 + r < R) out[(long)(c0 + c) * R + r0 + r] = t[r][c];
  }
}

__global__ __launch_bounds__(256)
void cvt_f2bf(const float* __restrict__ in, u16* __restrict__ out, long n)
{
  const long idx = (long)blockIdx.x * 256 + threadIdx.x;
  if (idx < n) out[idx] = f2bf(in[idx]);
}

// ======================= graph preprocessing (CSR build) =======================
__global__ __launch_bounds__(256)
void edge_stats(const int* __restrict__ s, const int* __restrict__ d,
                const float* __restrict__ ew, float* degf, float* degb,
                int* cntf, int* cntb)
{
  const int e = blockIdx.x * 256 + threadIdx.x;
  atomicAdd(&degf[d[e]], ew[e]);
  atomicAdd(&degb[s[e]], ew[e]);
  atomicAdd(&cntf[d[e]], 1);
  atomicAdd(&cntb[s[e]], 1);
}

__global__ __launch_bounds__(256)
void scan2(const int* __restrict__ cf, const int* __restrict__ cb,
           int* __restrict__ rf, int* __restrict__ rb)
{
  const int* c = blockIdx.x ? cb : cf;
  int* r       = blockIdx.x ? rb : rf;
  __shared__ int part[256];
  const int t = threadIdx.x, base = t * 8;
  int loc[8]; int s = 0;
#pragma unroll
  for (int i = 0; i < 8; ++i) { loc[i] = c[base + i]; s += loc[i]; }
  part[t] = s; __syncthreads();
  if (t == 0) {
    int run = 0;
    for (int i = 0; i < 256; ++i) { const int v = part[i]; part[i] = run; run += v; }
    r[2048] = run;
  }
  __syncthreads();
  int run = part[t];
#pragma unroll
  for (int i = 0; i < 8; ++i) { r[base + i] = run; run += loc[i]; }
}

__global__ __launch_bounds__(256)
void fill_csr(const int* __restrict__ s, const int* __restrict__ d,
              const float* __restrict__ ew,
              const float* __restrict__ degf, const float* __restrict__ degb,
              const int* __restrict__ rowf, const int* __restrict__ rowb,
              int* curf, int* curb,
              int* __restrict__ colf, int* __restrict__ colb,
              float* __restrict__ wnf, float* __restrict__ wnb)
{
  const int e = blockIdx.x * 256 + threadIdx.x;
  const int si = s[e], di = d[e];
  const float w = ew[e];
  const int p = rowf[di] + atomicAdd(&curf[di], 1);
  colf[p] = si; wnf[p] = w / fmaxf(degf[di], 1e-6f);
  const int q = rowb[si] + atomicAdd(&curb[si], 1);
  colb[q] = di; wnb[q] = w / fmaxf(degb[si], 1e-6f);
}

// ======================= diffusion step, all 48 bt per node ==========
__global__ __launch_bounds__(256)
void prop_gather_all(const u16* __restrict__ x, int ldx, u16* __restrict__ y, int ldy,
                     const int* __restrict__ rowptr, const int* __restrict__ col,
                     const float* __restrict__ w)
{
  const int n = blockIdx.x;
  const int beg = rowptr[n], end = rowptr[n + 1];
  const int tid = threadIdx.x;
  float acc[4][8];
#pragma unroll
  for (int r = 0; r < 4; ++r)
#pragma unroll
    for (int q = 0; q < 8; ++q) acc[r][q] = 0.f;
  int bt_[4], ch_[4];
#pragma unroll
  for (int r = 0; r < 4; ++r) {
    const int item = tid + r * 256;            // < 960 = 48 bt * 20 ch8
    bt_[r] = (item < 960) ? item / 20 : -1;
    ch_[r] = (item % 20) * 8;
  }
  int j = beg;
  for (; j + 1 < end; j += 2) {
    const int c0 = col[j], c1 = col[j + 1];
    const float w0 = w[j], w1 = w[j + 1];
#pragma unroll
    for (int r = 0; r < 4; ++r) {
      if (bt_[r] < 0) continue;
      const bf16x8 v0 = *(const bf16x8*)&x[((long)bt_[r] * cN + c0) * ldx + ch_[r]];
      const bf16x8 v1 = *(const bf16x8*)&x[((long)bt_[r] * cN + c1) * ldx + ch_[r]];
#pragma unroll
      for (int q = 0; q < 8; ++q) {
        acc[r][q] = fmaf(w0, bf2f((u16)v0[q]), acc[r][q]);
        acc[r][q] = fmaf(w1, bf2f((u16)v1[q]), acc[r][q]);
      }
    }
  }
  if (j < end) {
    const int c0 = col[j];
    const float w0 = w[j];
#pragma unroll
    for (int r = 0; r < 4; ++r) {
      if (bt_[r] < 0) continue;
      const bf16x8 v0 = *(const bf16x8*)&x[((long)bt_[r] * cN + c0) * ldx + ch_[r]];
#pragma unroll
      for (int q = 0; q < 8; ++q) acc[r][q] = fmaf(w0, bf2f((u16)v0[q]), acc[r][q]);
    }
  }
#pragma unroll
  for (int r = 0; r < 4; ++r) {
    if (bt_[r] < 0) continue;
    u16 o[8];
#pragma unroll
    for (int q = 0; q < 8; ++q) o[q] = f2bf(acc[r][q]);
    *(bf16x8*)&y[((long)bt_[r] * cN + n) * ldy + ch_[r]] = *(const bf16x8*)o;
  }
}

// ======================= encoder =======================
__global__ __launch_bounds__(160)
void encoder(const float* __restrict__ x, const float* __restrict__ ew_,
             const float* __restrict__ eb, const float* __restrict__ ne,
             const float* __restrict__ lw, u16* __restrict__ h)
{
  __shared__ float xs[cF];
  const int tid = threadIdx.x;
  const long r0 = (long)blockIdx.x * 8;
  for (long row = r0; row < r0 + 8; ++row) {
    if (tid < cF) xs[tid] = x[row * cF + tid];
    __syncthreads();
    const int n = (int)(row % cN);
    float v;
    if (tid < cHID) {
      float acc = eb[tid] + ne[(long)n * cHID + tid];
#pragma unroll
      for (int f = 0; f < cF; ++f) acc = fmaf(xs[f], ew_[f * cHID + tid], acc);
      v = acc;
    } else {
      v = lw[(long)n * cLF + (tid - cHID)];
    }
    h[row * 160 + tid] = f2bf(v);
    __syncthreads();
  }
}

// ======================= adjacency: row softmax of relu(scores) ==========
__global__ __launch_bounds__(256)
void relu_softmax_rows(const float* __restrict__ sc, u16* __restrict__ adj)
{
  const int row = blockIdx.x, tid = threadIdx.x;
  const float* p = sc + (long)row * cN;
  __shared__ float red[256];
  float lv[8];
  float mx = 0.f;   // relu => all >= 0
#pragma unroll
  for (int i = 0; i < 8; ++i) {
    const float v = fmaxf(p[tid + i * 256], 0.f);
    lv[i] = v; mx = fmaxf(mx, v);
  }
  red[tid] = mx; __syncthreads();
  for (int s = 128; s > 0; s >>= 1) { if (tid < s) red[tid] = fmaxf(red[tid], red[tid + s]); __syncthreads(); }
  const float m = red[0]; __syncthreads();
  float sum = 0.f;
#pragma unroll
  for (int i = 0; i < 8; ++i) { lv[i] = __expf(lv[i] - m); sum += lv[i]; }
  red[tid] = sum; __syncthreads();
  for (int s = 128; s > 0; s >>= 1) { if (tid < s) red[tid] += red[tid + s]; __syncthreads(); }
  const float inv = 1.f / red[0]; __syncthreads();
#pragma unroll
  for (int i = 0; i < 8; ++i) adj[(long)row * cN + tid + i * 256] = f2bf(lv[i] * inv);
}

// ======================= temporal 2nd-order LIF scan, bf16x8 ==========
__global__ __launch_bounds__(256)
void scan_syn8(const u16* __restrict__ in, u16* __restrict__ out, int c)
{
  const int c8 = c >> 3;
  const long total = (long)cB * cN * c8;
  const long idx = (long)blockIdx.x * 256 + threadIdx.x;
  if (idx >= total) return;
  const long nc = (long)cN * c;
  const int b = (int)(idx / ((long)cN * c8));
  const long rest = (idx % ((long)cN * c8)) * 8;
  const u16* p = in  + (long)b * cT * nc + rest;
  u16*       q = out + (long)b * cT * nc + rest;
  float syn[8], mem[8];
#pragma unroll
  for (int e = 0; e < 8; ++e) { syn[e] = 0.f; mem[e] = 0.f; }
#pragma unroll
  for (int t = 0; t < cT; ++t) {
    const bf16x8 v = *(const bf16x8*)&p[(long)t * nc];
    u16 o[8];
#pragma unroll
    for (int e = 0; e < 8; ++e) {
      syn[e] = fmaf(cALPHA, syn[e], bf2f((u16)v[e]));
      mem[e] = fmaf(cBETA, mem[e], syn[e]);
      o[e] = f2bf(mem[e]);
    }
    *(bf16x8*)&q[(long)t * nc] = *(const bf16x8*)o;
  }
}

// ======================= batch norm =======================
__global__ __launch_bounds__(256)
void bn_stats(const float* __restrict__ d, const u16* __restrict__ res,
              float* __restrict__ stat, int c)
{
  const int ch = threadIdx.x;
  const long r0 = (long)blockIdx.x * (cR / 512);
  float s = 0.f, s2 = 0.f;
  for (int i = 0; i < cR / 512; ++i) {
    const float v = d[(r0 + i) * c + ch] + bf2f(res[(r0 + i) * c + ch]);
    s += v; s2 = fmaf(v, v, s2);
  }
  atomicAdd(&stat[ch], s);
  atomicAdd(&stat[c + ch], s2);
}

__global__ __launch_bounds__(256)
void bn_finalize(const float* __restrict__ stat, const float* __restrict__ g,
                 const float* __restrict__ b, float* __restrict__ scsh, int c)
{
  const int ch = threadIdx.x;
  const float mu = stat[ch] / cR;
  const float var = stat[c + ch] / cR - mu * mu;
  const float sc = g[ch] * rsqrtf(var + cEPS);
  scsh[ch] = sc;
  scsh[c + ch] = fmaf(-mu, sc, b[ch]);
}

__global__ __launch_bounds__(192)
void bn_apply_concat(const float* __restrict__ d, const u16* __restrict__ res,
                     const float* __restrict__ scsh, const float* __restrict__ lw,
                     u16* __restrict__ out)
{
  const int tid = threadIdx.x;
  const long r0 = (long)blockIdx.x * 8;
  for (long row = r0; row < r0 + 8; ++row) {
    const int n = (int)(row % cN);
    float v;
    if (tid < 160) v = fmaf(d[row * 160 + tid] + bf2f(res[row * 160 + tid]),
                            scsh[tid], scsh[160 + tid]);
    else           v = lw[(long)n * cLF + (tid - 160)];
    out[row * 192 + tid] = f2bf(v);
  }
}

// ======================= output transpose (f32 out) =======================
__global__ __launch_bounds__(256)
void final_transpose(const float* __restrict__ y, float* __restrict__ out)
{
  const long idx = (long)blockIdx.x * 256 + threadIdx.x;
  const int f = (int)(idx % cF);
  long t = idx / cF;
  const int n = (int)(t % cN); t /= cN;
  const int hor = (int)(t % cHOR);
  const int b = (int)(t / cHOR);
  out[idx] = y[((long)b * cN + n) * (cHOR * cF) + hor * cF + f];
}

__global__ __launch_bounds__(256)
void fill_f32(float* __restrict__ out, long n, float val)
{
  const long idx = (long)blockIdx.x * 256 + threadIdx.x;
  if (idx < n) out[idx] = val;
}

// ======================= host orchestration =======================
extern "C" void kernel_launch(void* const* d_in, const int* in_sizes, int n_in,
                              void* d_out, int out_size, void* d_ws, size_t ws_size,
                              hipStream_t stream)
{
  float* outF = (float*)d_out;
  const long outN = out_size;
  if (n_in < 34) { fill_f32<<<(int)((outN + 255) / 256), 256, 0, stream>>>(outF, outN, 500.f); return; }
  if (in_sizes[0] != cB * cT * cN * cF || in_sizes[1] != 2 * cE || in_sizes[9] != 3 * 160 * 160) {
    fill_f32<<<(int)((outN + 255) / 256), 256, 0, stream>>>(outF, outN, 700.f); return;
  }

  const float* x        = (const float*)d_in[0];
  const int*   eidx     = (const int*)d_in[1];
  const float* ew       = (const float*)d_in[2];
  const float* enc_w    = (const float*)d_in[3];
  const float* enc_b    = (const float*)d_in[4];
  const float* node_emb = (const float*)d_in[5];
  const float* src_emb  = (const float*)d_in[6];
  const float* tgt_emb  = (const float*)d_in[7];
  const float* lw0  = (const float*)d_in[8];
  const float* tW0  = (const float*)d_in[9];
  const float* tb0  = (const float*)d_in[10];
  const float* dcw0 = (const float*)d_in[11];
  const float* dcb0 = (const float*)d_in[12];
  const float* dsw0 = (const float*)d_in[13];
  const float* dsb0 = (const float*)d_in[14];
  const float* skw0 = (const float*)d_in[15];
  const float* skb0 = (const float*)d_in[16];
  const float* ng0  = (const float*)d_in[17];
  const float* nb0  = (const float*)d_in[18];
  const float* lw1  = (const float*)d_in[19];
  const float* tW1  = (const float*)d_in[20];
  const float* tb1  = (const float*)d_in[21];
  // d_in[22..25, 28..29] feed only block-1's post-skip h (never read) -> dead.
  const float* skw1 = (const float*)d_in[26];
  const float* skb1 = (const float*)d_in[27];
  const float* rw1  = (const float*)d_in[30];
  const float* rb1  = (const float*)d_in[31];
  const float* rw2  = (const float*)d_in[32];
  const float* rb2  = (const float*)d_in[33];
  const int* srcI = eidx;
  const int* dstI = eidx + cE;

  // ---- workspace layout ----
  char* W = (char*)d_ws;
  size_t off = 0;
  auto A8 = [&](size_t bytes) { size_t r = off; off = (off + bytes + 255) & ~(size_t)255; return r; };
  const size_t oH0 = A8((size_t)cR * 160 * 2);   // res, bf16
  const size_t oHh = A8((size_t)cR * 160 * 2);   // chain h (G1 [cR,192] aliases Hh+T1-head)
  const size_t oT1 = A8((size_t)cR * 160 * 2);   // scratch (Z12 [cR,320] aliases T1+S2)
  const size_t oS2 = A8((size_t)cR * 160 * 2);   // scratch2 / hT
  const size_t oDd = A8((size_t)cR * 160 * 4);   // f32 accumulator (G2, scores alias)
  const size_t oAdj = A8((size_t)cN * cN * 2);
  const size_t oOut = A8((size_t)cB * cN * cFF * 4);       // f32 skip acc (t=11)
  const size_t oR1  = A8((size_t)cB * cN * 512 * 2);       // bf16 r1
  const size_t oY   = A8((size_t)cB * cN * cHOR * cF * 4); // f32
  const size_t oZero = A8(6 * 2048 * 4 + 2 * 192 * 4);
  const size_t oRowf = A8(2049 * 4), oRowb = A8(2049 * 4);
  const size_t oColf = A8((size_t)cE * 4), oColb = A8((size_t)cE * 4);
  const size_t oWnf  = A8((size_t)cE * 4), oWnb  = A8((size_t)cE * 4);
  const size_t oScSh = A8(2 * 192 * 4);
  const size_t oWT   = A8((size_t)721920 * 2);   // bf16 transposed weights
  const size_t oSeb  = A8((size_t)cN * cHID * 2);
  const size_t oTeb  = A8((size_t)cN * cHID * 2);
  if (off > ws_size) {
    fill_f32<<<(int)((outN + 255) / 256), 256, 0, stream>>>(outF, outN, 300.f);
    return;
  }

  u16 *H0 = (u16*)(W + oH0), *Hh = (u16*)(W + oHh), *T1 = (u16*)(W + oT1),
      *S2 = (u16*)(W + oS2), *adjb = (u16*)(W + oAdj);
  float* Dd = (float*)(W + oDd);
  u16 *G1 = (u16*)(W + oHh);   // [cR,192] bf16 over Hh(+T1 head), post-BN only
  u16 *G2 = (u16*)(W + oDd);   // over Dd, post-BN only
  u16 *Z12 = T1;               // [cR,320] bf16 over T1+S2 (diffconv packing)
  float* scores = (float*)(W + oDd);   // phase-0 scratch, dead before Dd use
  float *outacc = (float*)(W + oOut), *yb = (float*)(W + oY);
  u16 *r1b = (u16*)(W + oR1);
  float* zero = (float*)(W + oZero);
  float *degf = zero, *degb = zero + 2048;
  int *cntf = (int*)(zero + 4096), *cntb = cntf + 2048,
      *curf = cntb + 2048, *curb = curf + 2048;
  float* stat = (float*)(curb + 2048);
  int *rowf = (int*)(W + oRowf), *rowb = (int*)(W + oRowb);
  int *colf = (int*)(W + oColf), *colb = (int*)(W + oColb);
  float *wnf = (float*)(W + oWnf), *wnb = (float*)(W + oWnb);
  float* scsh = (float*)(W + oScSh);
  u16* wt   = (u16*)(W + oWT);
  u16 *wt0 = wt,              *wt1 = wt0 + 3 * 25600, *wdc = wt1 + 3 * 36864,
      *wds = wdc + 102400,    *wsk0 = wds + 51200,    *wsk1 = wsk0 + 40960,
      *wr1 = wsk1 + 49152,    *wr2 = wr1 + 131072;
  u16 *seb = (u16*)(W + oSeb), *teb = (u16*)(W + oTeb);

  auto g5u = [&](const u16* Aq, const u16* Bq, u16* Cq, const float* bias,
                 int M, int N, int K, int lda, int ldbt, int ldc,
                 long bA, long bB, long bC, int batch, int flags) {
    dim3 g(M / 128, (N + 159) / 160, batch);
    gemm_mfma<5, u16><<<g, 256, 0, stream>>>(Aq, Bq, Cq, bias, M, N, K, lda, ldbt, ldc, bA, bB, bC, flags);
  };
  auto g5f = [&](const u16* Aq, const u16* Bq, float* Cq, const float* bias,
                 int M, int N, int K, int lda, int ldbt, int ldc, int flags) {
    dim3 g(M / 128, (N + 159) / 160, 1);
    gemm_mfma<5, float><<<g, 256, 0, stream>>>(Aq, Bq, Cq, bias, M, N, K, lda, ldbt, ldc, 0, 0, 0, flags);
  };
  auto g6u = [&](const u16* Aq, const u16* Bq, u16* Cq, const float* bias,
                 int M, int N, int K, int lda, int ldbt, int ldc, int flags) {
    dim3 g(M / 128, (N + 191) / 192, 1);
    gemm_mfma<6, u16><<<g, 256, 0, stream>>>(Aq, Bq, Cq, bias, M, N, K, lda, ldbt, ldc, 0, 0, 0, flags);
  };
  auto g4f = [&](const u16* Aq, const u16* Bq, float* Cq, const float* bias,
                 int M, int N, int K, int lda, int ldbt, int ldc,
                 long bA, long bB, long bC, int batch, int flags) {
    dim3 g(M / 128, (N + 127) / 128, batch);
    gemm_mfma<4, float><<<g, 256, 0, stream>>>(Aq, Bq, Cq, bias, M, N, K, lda, ldbt, ldc, bA, bB, bC, flags);
  };
  auto g4u = [&](const u16* Aq, const u16* Bq, u16* Cq, const float* bias,
                 int M, int N, int K, int lda, int ldbt, int ldc, int flags) {
    dim3 g(M / 128, (N + 127) / 128, 1);
    gemm_mfma<4, u16><<<g, 256, 0, stream>>>(Aq, Bq, Cq, bias, M, N, K, lda, ldbt, ldc, 0, 0, 0, flags);
  };
  auto wcv = [&](const float* src, u16* dst, int K, int N) {
    wconvT<<<(int)(((long)K * N + 255) / 256), 256, 0, stream>>>(src, dst, K, N);
  };

  // ---- phase 0: weight conversion, CSR, encoder, adjacency ----
  for (int l = 0; l < 3; ++l) wcv(tW0 + (long)l * 25600, wt0 + (long)l * 25600, 160, 160);
  for (int l = 0; l < 3; ++l) wcv(tW1 + (long)l * 36864, wt1 + (long)l * 36864, 192, 192);
  wcv(dcw0, wdc, 640, 160);   // [640,160] -> [160][640] (concat-K layout)
  wcv(dsw0, wds, 320, 160);   // [320,160] -> [160][320]
  wcv(skw0, wsk0, 160, 256);
  wcv(skw1, wsk1, 192, 256);
  wcv(rw1, wr1, 256, 512);
  wcv(rw2, wr2, 512, 312);

  hipMemsetAsync(zero, 0, 6 * 2048 * 4 + 2 * 192 * 4, stream);
  edge_stats<<<cE / 256, 256, 0, stream>>>(srcI, dstI, ew, degf, degb, cntf, cntb);
  scan2<<<2, 256, 0, stream>>>(cntf, cntb, rowf, rowb);
  fill_csr<<<cE / 256, 256, 0, stream>>>(srcI, dstI, ew, degf, degb, rowf, rowb,
                                         curf, curb, colf, colb, wnf, wnb);
  encoder<<<cR / 8, 160, 0, stream>>>(x, enc_w, enc_b, node_emb, lw0, H0);

  // learned adjacency: scores = se @ te^T via MFMA, then row relu-softmax
  cvt_f2bf<<<(cN * cHID + 255) / 256, 256, 0, stream>>>(src_emb, seb, (long)cN * cHID);
  cvt_f2bf<<<(cN * cHID + 255) / 256, 256, 0, stream>>>(tgt_emb, teb, (long)cN * cHID);
  g4f(seb, teb, scores, nullptr, cN, cN, cHID, cHID, cHID, cN, 0, 0, 0, 1, 0);
  relu_softmax_rows<<<cN, 256, 0, stream>>>(scores, adjb);

  // ---- block 0 (c = 160) ----
  {
    const int c = 160;
    const long NC = (long)cN * c;
    const int scanGrid = (int)(((long)cB * cN * (c / 8) + 255) / 256);
    // synaptic chain: H0 (res) -> Hh
    g5u(H0, wt0 + 0L * 25600, T1, tb0 + 0 * c, cR, c, c, c, c, c, 0, 0, 0, 1, FLAG_BIAS);
    scan_syn8<<<scanGrid, 256, 0, stream>>>(T1, Hh, c);
    for (int l = 1; l < 3; ++l) {
      g5u(Hh, wt0 + (long)l * 25600, T1, tb0 + l * c, cR, c, c, c, c, c, 0, 0, 0, 1, FLAG_BIAS);
      scan_syn8<<<scanGrid, 256, 0, stream>>>(T1, Hh, c);
    }
    // skip (t=11): outacc[b] = h[b,11]@skw0 + skb0
    g4f(Hh + 11L * NC, wsk0, outacc, skb0, cN, cFF, c, c, c, cFF,
        (long)cT * NC, 0, (long)cN * cFF, cB, FLAG_BIAS);
    // diffconv: pack [z1|z2] then [z3|z4] into Z12 [cR,320]; two K=320 GEMMs
    prop_gather_all<<<cN, 256, 0, stream>>>(Hh, 160, Z12, 320, rowf, colf, wnf);
    prop_gather_all<<<cN, 256, 0, stream>>>(Z12, 320, Z12 + 160, 320, rowf, colf, wnf);
    g5f(Z12, wdc, Dd, dcb0, cR, c, 320, 320, 640, c, FLAG_BIAS);
    prop_gather_all<<<cN, 256, 0, stream>>>(Hh, 160, Z12, 320, rowb, colb, wnb);
    prop_gather_all<<<cN, 256, 0, stream>>>(Z12, 320, Z12 + 160, 320, rowb, colb, wnb);
    g5f(Z12, wdc + 320, Dd, nullptr, cR, c, 320, 320, 640, c, FLAG_ACC);
    // dense conv: hT -> S2 ; x1 = adj@hT -> T1 ; Dd += x1@dsw[:,0:160] ;
    //             x1T -> S2 ; x2 = adj@x1T -> T1 ; Dd += x2@dsw[:,160:320]
    dim3 tg(cN / 64, (c + 63) / 64, cBT);
    transpose_bf16<<<tg, 256, 0, stream>>>(Hh, S2, cN, c, NC, NC);
    g5u(adjb, S2, T1, nullptr, cN, c, cN, cN, cN, c, 0, NC, NC, cBT, 0);
    g5f(T1, wds, Dd, dsb0, cR, c, c, c, 320, c, FLAG_BIAS | FLAG_ACC);
    transpose_bf16<<<tg, 256, 0, stream>>>(T1, S2, cN, c, NC, NC);
    g5u(adjb, S2, T1, nullptr, cN, c, cN, cN, cN, c, 0, NC, NC, cBT, 0);
    g5f(T1, wds + 160, Dd, nullptr, cR, c, c, c, 320, c, FLAG_ACC);
    // BN(Dd + H0) -> G1 (stride 192) + lw1
    bn_stats<<<512, c, 0, stream>>>(Dd, H0, stat, c);
    bn_finalize<<<1, c, 0, stream>>>(stat, ng0, nb0, scsh, c);
    bn_apply_concat<<<cR / 8, 192, 0, stream>>>(Dd, H0, scsh, lw1, G1);
  }

  // ---- block 1 (c = 192): chain + skip only ----
  {
    const int c = 192;
    const long NC = (long)cN * c;
    const int scanGrid = (int)(((long)cB * cN * (c / 8) + 255) / 256);
    for (int l = 0; l < 3; ++l) {
      g6u(G1, wt1 + (long)l * 36864, G2, tb1 + l * c, cR, c, c, c, c, c, FLAG_BIAS);
      scan_syn8<<<scanGrid, 256, 0, stream>>>(G2, G1, c);
    }
    g4f(G1 + 11L * NC, wsk1, outacc, skb1, cN, cFF, c, c, c, cFF,
        (long)cT * NC, 0, (long)cN * cFF, cB, FLAG_BIAS | FLAG_ACC | FLAG_RELU);
  }

  // ---- readout (outacc f32 -> bf16 in S2, then two MFMA GEMMs) ----
  cvt_f2bf<<<(int)(((long)cB * cN * cFF + 255) / 256), 256, 0, stream>>>(outacc, S2, (long)cB * cN * cFF);
  g4u(S2, wr1, r1b, rb1, cB * cN, 2 * cFF, cFF, cFF, cFF, 2 * cFF, FLAG_BIAS | FLAG_RELU);
  g4f(r1b, wr2, yb, rb2, cB * cN, cHOR * cF, 2 * cFF, 2 * cFF, 2 * cFF, cHOR * cF,
      0, 0, 0, 1, FLAG_BIAS);
  final_transpose<<<(cB * cHOR * cN * cF) / 256, 256, 0, stream>>>(yb, outF);
}

// Round 10
// 1341.414 us; speedup vs baseline: 3.0035x; 1.0011x over previous
//
#include <hip/hip_runtime.h>

// ======================= types & helpers =======================
using u16 = unsigned short;
typedef short bf16x8 __attribute__((ext_vector_type(8)));
typedef float f32x4  __attribute__((ext_vector_type(4)));

__device__ __forceinline__ float bf2f(u16 u) { return __uint_as_float(((unsigned)u) << 16); }
__device__ __forceinline__ u16 f2bf(float f) {  // round-to-nearest-even
  unsigned u = __float_as_uint(f);
  return (u16)((u + 0x7FFFu + ((u >> 16) & 1u)) >> 16);
}
__device__ __forceinline__ float ldv(const float* p) { return *p; }
__device__ __forceinline__ float ldv(const u16* p)   { return bf2f(*p); }
__device__ __forceinline__ void  stv(float* p, float v) { *p = v; }
__device__ __forceinline__ void  stv(u16* p, float v)   { *p = f2bf(v); }

// ======================= problem constants =======================
constexpr int cB = 4, cT = 12, cN = 2048, cF = 26;
constexpr int cHID = 128, cLF = 32, cFF = 256, cHOR = 12;
constexpr int cE = 16384;
constexpr int cR = cB * cT * cN;   // 98304
constexpr int cBT = cB * cT;       // 48
constexpr float cALPHA = 0.9f, cBETA = 0.8f, cEPS = 1e-5f;

#define FLAG_ACC  1
#define FLAG_BIAS 2
#define FLAG_RELU 4

// ======================= MFMA bf16 GEMM (gload_lds + dbuf + XCD swizzle) ==========
// C[m,n] = sum_k A[m,k] * BT[n,k]  (+bias) (+C) (relu)
// A: bf16 [M,K] lda ; BT: bf16 [N,K] ldbt. M%128==0, K%32==0, lda/ldbt%8==0; N guarded
// (OOB B rows clamp to N-1; their output columns are never stored).
// biasPerT: bias is [cT][N]; row block m0 uses bias row (m0/2048)%cT (rows = (b,t,n)).
// XCD swizzle (bijective, m204): contiguous work chunks per XCD -> B-panel L2 locality.
template <int NF, typename TC>
__global__ __launch_bounds__(256)
void gemm_mfma(const u16* __restrict__ A, const u16* __restrict__ BT,
               TC* __restrict__ C, const float* __restrict__ bias,
               int M, int N, int K, int lda, int ldbt, int ldc,
               long batchA, long batchB, long batchC, int flags, int biasPerT)
{
  constexpr int TN = NF * 32;
  constexpr int ROWS = 128 + TN;        // A rows then BT rows
  constexpr int NINST = ROWS / 16;      // gload_lds wave-instrs per K-step
  constexpr int NPW = (NINST + 3) / 4;  // max instrs per wave
  __shared__ __align__(16) u16 S[2][ROWS * 32];

  // bijective XCD-aware block remap
  const long gx = gridDim.x, gy = gridDim.y;
  const long total = gx * gy * (long)gridDim.z;
  long lid = blockIdx.x + gx * (blockIdx.y + gy * (long)blockIdx.z);
  { const long q = total >> 3, r = total & 7, xcd = lid & 7, j = lid >> 3;
    lid = (xcd < r ? xcd * (q + 1) : r * (q + 1) + (xcd - r) * q) + j; }
  const int bz = (int)(lid / (gx * gy));
  const long rem = lid % (gx * gy);
  const int by = (int)(rem / gx), bx = (int)(rem % gx);

  A  += (long)bz * batchA;
  BT += (long)bz * batchB;
  C  += (long)bz * batchC;
  const int tid = threadIdx.x;
  const int lane = tid & 63, wid = tid >> 6;
  const int wm = wid & 1, wn = wid >> 1;
  const int m0 = bx * 128, n0 = by * TN;
  const int fr = lane & 15, kh = lane >> 4;   // frag row / k-half
  const int nwi = (NINST - wid + 3) / 4;      // this wave's instr count

  // hoisted per-lane staging pointers (advance +32 elts per K-step)
  const u16* gp[NPW];
#pragma unroll
  for (int i = 0; i < NPW; ++i) {
    const int s = wid + i * 4;
    if (s < NINST) {
      const int slot = s * 64 + lane;    // linear 16B LDS slot
      const int row = slot >> 2, q = slot & 3;
      if (row < 128) {
        gp[i] = A + (long)(m0 + row) * lda + q * 8;
      } else {
        const int n = min(n0 + row - 128, N - 1);
        gp[i] = BT + (long)n * ldbt + q * 8;
      }
    } else {
      gp[i] = A;
    }
  }

  f32x4 acc[4][NF];
#pragma unroll
  for (int i = 0; i < 4; ++i)
#pragma unroll
    for (int j = 0; j < NF; ++j) acc[i][j] = f32x4{0.f, 0.f, 0.f, 0.f};

  auto STAGE = [&](int buf) {
#pragma unroll
    for (int i = 0; i < NPW; ++i) {
      if (i < nwi) {
        const int s = wid + i * 4;
        __builtin_amdgcn_global_load_lds(
            (const __attribute__((address_space(1))) unsigned int*)gp[i],
            (__attribute__((address_space(3))) unsigned int*)&S[buf][s * 512],
            16, 0, 0);
        gp[i] += 32;
      }
    }
  };

  STAGE(0);
  int cur = 0;
  for (int k0 = 0; k0 < K; k0 += 32) {
    __syncthreads();                 // drains vmcnt -> S[cur] ready; prior reads of S[cur^1] done
    if (k0 + 32 < K) STAGE(cur ^ 1);
    bf16x8 af[4];
#pragma unroll
    for (int mf = 0; mf < 4; ++mf)
      af[mf] = *(const bf16x8*)&S[cur][(wm * 64 + mf * 16 + fr) * 32 + kh * 8];
#pragma unroll
    for (int nf = 0; nf < NF; ++nf) {
      const bf16x8 bfr =
          *(const bf16x8*)&S[cur][(128 + wn * NF * 16 + nf * 16 + fr) * 32 + kh * 8];
#pragma unroll
      for (int mf = 0; mf < 4; ++mf)
        acc[mf][nf] = __builtin_amdgcn_mfma_f32_16x16x32_bf16(af[mf], bfr, acc[mf][nf], 0, 0, 0);
    }
    cur ^= 1;
  }

  const float* bp = bias;
  if (biasPerT && bias) bp = bias + (long)((m0 >> 11) % cT) * N;

#pragma unroll
  for (int mf = 0; mf < 4; ++mf)
#pragma unroll
    for (int nf = 0; nf < NF; ++nf) {
      const int gn = n0 + wn * NF * 16 + nf * 16 + fr;
      if (gn < N) {
#pragma unroll
        for (int r = 0; r < 4; ++r) {
          const long gm = m0 + wm * 64 + mf * 16 + kh * 4 + r;   // C/D: row=(lane>>4)*4+r
          float v = acc[mf][nf][r];
          if (flags & FLAG_BIAS) v += bp[gn];
          if (flags & FLAG_ACC)  v += ldv(&C[gm * ldc + gn]);
          if (flags & FLAG_RELU) v = fmaxf(v, 0.f);
          stv(&C[gm * ldc + gn], v);
        }
      }
    }
}

// ======================= small f32 matmul: C[M,N] = A[M,K] @ B[K,N] ==========
__global__ __launch_bounds__(256)
void matmul_small(const float* __restrict__ A, const float* __restrict__ B,
                  float* __restrict__ C, int M, int N, int K)
{
  const int idx = blockIdx.x * 256 + threadIdx.x;
  if (idx >= M * N) return;
  const int m = idx / N, n = idx % N;
  float acc = 0.f;
  for (int k = 0; k < K; ++k) acc = fmaf(A[m * K + k], B[k * N + n], acc);
  C[idx] = acc;
}

// ======================= LIF composed coefficients ==========
// k1 = impulse response of one LIF stage; k2 = k1*k1; k3 = k2*k1 (trunc to T).
__device__ __forceinline__ void lif_coeffs(float* k1, float* k2, float* k3)
{
  float ap = 1.f;
  for (int m = 0; m < cT; ++m) {
    k1[m] = (m ? cBETA * k1[m - 1] : 0.f) + ap;   // k1[m] = sum a^i b^(m-i)
    ap *= cALPHA;
  }
  for (int m = 0; m < cT; ++m) { float s = 0.f; for (int i = 0; i <= m; ++i) s += k1[i] * k1[m - i]; k2[m] = s; }
  for (int m = 0; m < cT; ++m) { float s = 0.f; for (int i = 0; i <= m; ++i) s += k2[i] * k1[m - i]; k3[m] = s; }
}

// Btot[t][ch] = C3[t]*(b1@W23)[ch] + C2[t]*(b2@W3)[ch] + C1[t]*b3[ch]; Ci = cumsum(ki)
__global__ void btot_full(const float* __restrict__ b1, const float* __restrict__ b2,
                          const float* __restrict__ b3, const float* __restrict__ W23,
                          const float* __restrict__ W3, float* __restrict__ Btot, int c)
{
  const int ch = threadIdx.x;
  if (ch >= c) return;
  float k1[cT], k2[cT], k3[cT]; lif_coeffs(k1, k2, k3);
  float v1 = 0.f, v2 = 0.f;
  for (int j = 0; j < c; ++j) { v1 = fmaf(b1[j], W23[j * c + ch], v1); v2 = fmaf(b2[j], W3[j * c + ch], v2); }
  float C1 = 0.f, C2 = 0.f, C3 = 0.f;
  for (int t = 0; t < cT; ++t) {
    C1 += k1[t]; C2 += k2[t]; C3 += k3[t];
    Btot[t * c + ch] = C3 * v1 + C2 * v2 + C1 * b3[ch];
  }
}

// last-t-only variant -> out[c]
__global__ void btot_last(const float* __restrict__ b1, const float* __restrict__ b2,
                          const float* __restrict__ b3, const float* __restrict__ W23,
                          const float* __restrict__ W3, float* __restrict__ out, int c)
{
  const int ch = threadIdx.x;
  if (ch >= c) return;
  float k1[cT], k2[cT], k3[cT]; lif_coeffs(k1, k2, k3);
  float v1 = 0.f, v2 = 0.f;
  for (int j = 0; j < c; ++j) { v1 = fmaf(b1[j], W23[j * c + ch], v1); v2 = fmaf(b2[j], W3[j * c + ch], v2); }
  float C1 = 0.f, C2 = 0.f, C3 = 0.f;
  for (int t = 0; t < cT; ++t) { C1 += k1[t]; C2 += k2[t]; C3 += k3[t]; }
  out[ch] = C3 * v1 + C2 * v2 + C1 * b3[ch];
}

// bias1p[n] = skb1[n] + sum_k Btot11[k] * skw1[k][n]   (n < 256, k < 192)
__global__ void bias_sk(const float* __restrict__ Btot11, const float* __restrict__ skw1,
                        const float* __restrict__ skb1, float* __restrict__ out)
{
  const int n = threadIdx.x;
  float acc = skb1[n];
  for (int k = 0; k < 192; ++k) acc = fmaf(Btot11[k], skw1[k * 256 + n], acc);
  out[n] = acc;
}

// ======================= 3x cascaded LIF (= S^3), full sequence out ==========
__global__ __launch_bounds__(256)
void cascade3_full(const u16* __restrict__ in, u16* __restrict__ out, int c)
{
  const int c8 = c >> 3;
  const long total = (long)cB * cN * c8;
  const long idx = (long)blockIdx.x * 256 + threadIdx.x;
  if (idx >= total) return;
  const long nc = (long)cN * c;
  const int b = (int)(idx / ((long)cN * c8));
  const long rest = (idx % ((long)cN * c8)) * 8;
  const u16* p = in  + (long)b * cT * nc + rest;
  u16*       q = out + (long)b * cT * nc + rest;
  float s1[8] = {}, m1[8] = {}, s2[8] = {}, m2[8] = {}, s3[8] = {}, m3[8] = {};
#pragma unroll
  for (int t = 0; t < cT; ++t) {
    const bf16x8 v = *(const bf16x8*)&p[(long)t * nc];
    u16 o[8];
#pragma unroll
    for (int e = 0; e < 8; ++e) {
      s1[e] = fmaf(cALPHA, s1[e], bf2f((u16)v[e])); m1[e] = fmaf(cBETA, m1[e], s1[e]);
      s2[e] = fmaf(cALPHA, s2[e], m1[e]);           m2[e] = fmaf(cBETA, m2[e], s2[e]);
      s3[e] = fmaf(cALPHA, s3[e], m2[e]);           m3[e] = fmaf(cBETA, m3[e], s3[e]);
      o[e] = f2bf(m3[e]);
    }
    *(bf16x8*)&q[(long)t * nc] = *(const bf16x8*)o;
  }
}

// same, but store only the t=T-1 slice into out [cB*cN, c]
__global__ __launch_bounds__(256)
void cascade3_last(const u16* __restrict__ in, u16* __restrict__ out, int c)
{
  const int c8 = c >> 3;
  const long total = (long)cB * cN * c8;
  const long idx = (long)blockIdx.x * 256 + threadIdx.x;
  if (idx >= total) return;
  const long nc = (long)cN * c;
  const int b = (int)(idx / ((long)cN * c8));
  const long rest = (idx % ((long)cN * c8)) * 8;
  const u16* p = in + (long)b * cT * nc + rest;
  float s1[8] = {}, m1[8] = {}, s2[8] = {}, m2[8] = {}, s3[8] = {}, m3[8] = {};
#pragma unroll
  for (int t = 0; t < cT; ++t) {
    const bf16x8 v = *(const bf16x8*)&p[(long)t * nc];
#pragma unroll
    for (int e = 0; e < 8; ++e) {
      s1[e] = fmaf(cALPHA, s1[e], bf2f((u16)v[e])); m1[e] = fmaf(cBETA, m1[e], s1[e]);
      s2[e] = fmaf(cALPHA, s2[e], m1[e]);           m2[e] = fmaf(cBETA, m2[e], s2[e]);
      s3[e] = fmaf(cALPHA, s3[e], m2[e]);           m3[e] = fmaf(cBETA, m3[e], s3[e]);
    }
  }
  u16 o[8];
#pragma unroll
  for (int e = 0; e < 8; ++e) o[e] = f2bf(m3[e]);
  *(bf16x8*)&out[(long)b * nc + rest] = *(const bf16x8*)o;
}

// ======================= weight convert + transpose (f32 [K,N] -> bf16 [N,K]) ==========
__global__ __launch_bounds__(256)
void wconvT(const float* __restrict__ w, u16* __restrict__ wt, int K, int N)
{
  const long idx = (long)blockIdx.x * 256 + threadIdx.x;
  if (idx >= (long)K * N) return;
  const int n = (int)(idx / K), k = (int)(idx % K);
  wt[idx] = f2bf(w[(long)k * N + n]);
}

// ======================= tiled bf16 transpose: in [R,Cc] -> out [Cc,R], batched ==========
__global__ __launch_bounds__(256)
void transpose_bf16(const u16* __restrict__ in, u16* __restrict__ out,
                    int R, int Cc, long batchIn, long batchOut)
{
  __shared__ u16 t[64][65];
  in  += (long)blockIdx.z * batchIn;
  out += (long)blockIdx.z * batchOut;
  const int tid = threadIdx.x;
  const int r0 = blockIdx.x * 64, c0 = blockIdx.y * 64;
  for (int i = tid; i < 64 * 64; i += 256) {
    const int r = i >> 6, c = i & 63;
    t[r][c] = (r0 + r < R && c0 + c < Cc) ? in[(long)(r0 + r) * Cc + c0 + c] : (u16)0;
  }
  __syncthreads();
  for (int i = tid; i < 64 * 64; i += 256) {
    const int c = i >> 6, r = i & 63;
    if (c0 + c < Cc && r0 + r < R) out[(long)(c0 + c) * R + r0 + r] = t[r][c];
  }
}

__global__ __launch_bounds__(256)
void cvt_f2bf(const float* __restrict__ in, u16* __restrict__ out, long n)
{
  const long idx = (long)blockIdx.x * 256 + threadIdx.x;
  if (idx < n) out[idx] = f2bf(in[idx]);
}

// ======================= graph preprocessing (CSR build) =======================
__global__ __launch_bounds__(256)
void edge_stats(const int* __restrict__ s, const int* __restrict__ d,
                const float* __restrict__ ew, float* degf, float* degb,
                int* cntf, int* cntb)
{
  const int e = blockIdx.x * 256 + threadIdx.x;
  atomicAdd(&degf[d[e]], ew[e]);
  atomicAdd(&degb[s[e]], ew[e]);
  atomicAdd(&cntf[d[e]], 1);
  atomicAdd(&cntb[s[e]], 1);
}

__global__ __launch_bounds__(256)
void scan2(const int* __restrict__ cf, const int* __restrict__ cb,
           int* __restrict__ rf, int* __restrict__ rb)
{
  const int* c = blockIdx.x ? cb : cf;
  int* r       = blockIdx.x ? rb : rf;
  __shared__ int part[256];
  const int t = threadIdx.x, base = t * 8;
  int loc[8]; int s = 0;
#pragma unroll
  for (int i = 0; i < 8; ++i) { loc[i] = c[base + i]; s += loc[i]; }
  part[t] = s; __syncthreads();
  if (t == 0) {
    int run = 0;
    for (int i = 0; i < 256; ++i) { const int v = part[i]; part[i] = run; run += v; }
    r[2048] = run;
  }
  __syncthreads();
  int run = part[t];
#pragma unroll
  for (int i = 0; i < 8; ++i) { r[base + i] = run; run += loc[i]; }
}

__global__ __launch_bounds__(256)
void fill_csr(const int* __restrict__ s, const int* __restrict__ d,
              const float* __restrict__ ew,
              const float* __restrict__ degf, const float* __restrict__ degb,
              const int* __restrict__ rowf, const int* __restrict__ rowb,
              int* curf, int* curb,
              int* __restrict__ colf, int* __restrict__ colb,
              float* __restrict__ wnf, float* __restrict__ wnb)
{
  const int e = blockIdx.x * 256 + threadIdx.x;
  const int si = s[e], di = d[e];
  const float w = ew[e];
  const int p = rowf[di] + atomicAdd(&curf[di], 1);
  colf[p] = si; wnf[p] = w / fmaxf(degf[di], 1e-6f);
  const int q = rowb[si] + atomicAdd(&curb[si], 1);
  colb[q] = di; wnb[q] = w / fmaxf(degb[si], 1e-6f);
}

// ======================= diffusion step, all 48 bt per node ==========
__global__ __launch_bounds__(256)
void prop_gather_all(const u16* __restrict__ x, int ldx, u16* __restrict__ y, int ldy,
                     const int* __restrict__ rowptr, const int* __restrict__ col,
                     const float* __restrict__ w)
{
  const int n = blockIdx.x;
  const int beg = rowptr[n], end = rowptr[n + 1];
  const int tid = threadIdx.x;
  float acc[4][8];
#pragma unroll
  for (int r = 0; r < 4; ++r)
#pragma unroll
    for (int q = 0; q < 8; ++q) acc[r][q] = 0.f;
  int bt_[4], ch_[4];
#pragma unroll
  for (int r = 0; r < 4; ++r) {
    const int item = tid + r * 256;            // < 960 = 48 bt * 20 ch8
    bt_[r] = (item < 960) ? item / 20 : -1;
    ch_[r] = (item % 20) * 8;
  }
  int j = beg;
  for (; j + 1 < end; j += 2) {
    const int c0 = col[j], c1 = col[j + 1];
    const float w0 = w[j], w1 = w[j + 1];
#pragma unroll
    for (int r = 0; r < 4; ++r) {
      if (bt_[r] < 0) continue;
      const bf16x8 v0 = *(const bf16x8*)&x[((long)bt_[r] * cN + c0) * ldx + ch_[r]];
      const bf16x8 v1 = *(const bf16x8*)&x[((long)bt_[r] * cN + c1) * ldx + ch_[r]];
#pragma unroll
      for (int q = 0; q < 8; ++q) {
        acc[r][q] = fmaf(w0, bf2f((u16)v0[q]), acc[r][q]);
        acc[r][q] = fmaf(w1, bf2f((u16)v1[q]), acc[r][q]);
      }
    }
  }
  if (j < end) {
    const int c0 = col[j];
    const float w0 = w[j];
#pragma unroll
    for (int r = 0; r < 4; ++r) {
      if (bt_[r] < 0) continue;
      const bf16x8 v0 = *(const bf16x8*)&x[((long)bt_[r] * cN + c0) * ldx + ch_[r]];
#pragma unroll
      for (int q = 0; q < 8; ++q) acc[r][q] = fmaf(w0, bf2f((u16)v0[q]), acc[r][q]);
    }
  }
#pragma unroll
  for (int r = 0; r < 4; ++r) {
    if (bt_[r] < 0) continue;
    u16 o[8];
#pragma unroll
    for (int q = 0; q < 8; ++q) o[q] = f2bf(acc[r][q]);
    *(bf16x8*)&y[((long)bt_[r] * cN + n) * ldy + ch_[r]] = *(const bf16x8*)o;
  }
}

// ======================= encoder =======================
__global__ __launch_bounds__(160)
void encoder(const float* __restrict__ x, const float* __restrict__ ew_,
             const float* __restrict__ eb, const float* __restrict__ ne,
             const float* __restrict__ lw, u16* __restrict__ h)
{
  __shared__ float xs[cF];
  const int tid = threadIdx.x;
  const long r0 = (long)blockIdx.x * 8;
  for (long row = r0; row < r0 + 8; ++row) {
    if (tid < cF) xs[tid] = x[row * cF + tid];
    __syncthreads();
    const int n = (int)(row % cN);
    float v;
    if (tid < cHID) {
      float acc = eb[tid] + ne[(long)n * cHID + tid];
#pragma unroll
      for (int f = 0; f < cF; ++f) acc = fmaf(xs[f], ew_[f * cHID + tid], acc);
      v = acc;
    } else {
      v = lw[(long)n * cLF + (tid - cHID)];
    }
    h[row * 160 + tid] = f2bf(v);
    __syncthreads();
  }
}

// ======================= adjacency: row softmax of relu(scores) ==========
__global__ __launch_bounds__(256)
void relu_softmax_rows(const float* __restrict__ sc, u16* __restrict__ adj)
{
  const int row = blockIdx.x, tid = threadIdx.x;
  const float* p = sc + (long)row * cN;
  __shared__ float red[256];
  float lv[8];
  float mx = 0.f;   // relu => all >= 0
#pragma unroll
  for (int i = 0; i < 8; ++i) {
    const float v = fmaxf(p[tid + i * 256], 0.f);
    lv[i] = v; mx = fmaxf(mx, v);
  }
  red[tid] = mx; __syncthreads();
  for (int s = 128; s > 0; s >>= 1) { if (tid < s) red[tid] = fmaxf(red[tid], red[tid + s]); __syncthreads(); }
  const float m = red[0]; __syncthreads();
  float sum = 0.f;
#pragma unroll
  for (int i = 0; i < 8; ++i) { lv[i] = __expf(lv[i] - m); sum += lv[i]; }
  red[tid] = sum; __syncthreads();
  for (int s = 128; s > 0; s >>= 1) { if (tid < s) red[tid] += red[tid + s]; __syncthreads(); }
  const float inv = 1.f / red[0]; __syncthreads();
#pragma unroll
  for (int i = 0; i < 8; ++i) adj[(long)row * cN + tid + i * 256] = f2bf(lv[i] * inv);
}

// ======================= batch norm =======================
__global__ __launch_bounds__(256)
void bn_stats(const float* __restrict__ d, const u16* __restrict__ res,
              float* __restrict__ stat, int c)
{
  const int ch = threadIdx.x;
  const long r0 = (long)blockIdx.x * (cR / 512);
  float s = 0.f, s2 = 0.f;
  for (int i = 0; i < cR / 512; ++i) {
    const float v = d[(r0 + i) * c + ch] + bf2f(res[(r0 + i) * c + ch]);
    s += v; s2 = fmaf(v, v, s2);
  }
  atomicAdd(&stat[ch], s);
  atomicAdd(&stat[c + ch], s2);
}

__global__ __launch_bounds__(256)
void bn_finalize(const float* __restrict__ stat, const float* __restrict__ g,
                 const float* __restrict__ b, float* __restrict__ scsh, int c)
{
  const int ch = threadIdx.x;
  const float mu = stat[ch] / cR;
  const float var = stat[c + ch] / cR - mu * mu;
  const float sc = g[ch] * rsqrtf(var + cEPS);
  scsh[ch] = sc;
  scsh[c + ch] = fmaf(-mu, sc, b[ch]);
}

__global__ __launch_bounds__(192)
void bn_apply_concat(const float* __restrict__ d, const u16* __restrict__ res,
                     const float* __restrict__ scsh, const float* __restrict__ lw,
                     u16* __restrict__ out)
{
  const int tid = threadIdx.x;
  const long r0 = (long)blockIdx.x * 8;
  for (long row = r0; row < r0 + 8; ++row) {
    const int n = (int)(row % cN);
    float v;
    if (tid < 160) v = fmaf(d[row * 160 + tid] + bf2f(res[row * 160 + tid]),
                            scsh[tid], scsh[160 + tid]);
    else           v = lw[(long)n * cLF + (tid - 160)];
    out[row * 192 + tid] = f2bf(v);
  }
}

// ======================= output transpose (f32 out) =======================
__global__ __launch_bounds__(256)
void final_transpose(const float* __restrict__ y, float* __restrict__ out)
{
  const long idx = (long)blockIdx.x * 256 + threadIdx.x;
  const int f = (int)(idx % cF);
  long t = idx / cF;
  const int n = (int)(t % cN); t /= cN;
  const int hor = (int)(t % cHOR);
  const int b = (int)(t / cHOR);
  out[idx] = y[((long)b * cN + n) * (cHOR * cF) + hor * cF + f];
}

__global__ __launch_bounds__(256)
void fill_f32(float* __restrict__ out, long n, float val)
{
  const long idx = (long)blockIdx.x * 256 + threadIdx.x;
  if (idx < n) out[idx] = val;
}

// ======================= host orchestration =======================
extern "C" void kernel_launch(void* const* d_in, const int* in_sizes, int n_in,
                              void* d_out, int out_size, void* d_ws, size_t ws_size,
                              hipStream_t stream)
{
  float* outF = (float*)d_out;
  const long outN = out_size;
  if (n_in < 34) { fill_f32<<<(int)((outN + 255) / 256), 256, 0, stream>>>(outF, outN, 500.f); return; }
  if (in_sizes[0] != cB * cT * cN * cF || in_sizes[1] != 2 * cE || in_sizes[9] != 3 * 160 * 160) {
    fill_f32<<<(int)((outN + 255) / 256), 256, 0, stream>>>(outF, outN, 700.f); return;
  }

  const float* x        = (const float*)d_in[0];
  const int*   eidx     = (const int*)d_in[1];
  const float* ew       = (const float*)d_in[2];
  const float* enc_w    = (const float*)d_in[3];
  const float* enc_b    = (const float*)d_in[4];
  const float* node_emb = (const float*)d_in[5];
  const float* src_emb  = (const float*)d_in[6];
  const float* tgt_emb  = (const float*)d_in[7];
  const float* lw0  = (const float*)d_in[8];
  const float* tW0  = (const float*)d_in[9];
  const float* tb0  = (const float*)d_in[10];
  const float* dcw0 = (const float*)d_in[11];
  const float* dcb0 = (const float*)d_in[12];
  const float* dsw0 = (const float*)d_in[13];
  const float* dsb0 = (const float*)d_in[14];
  const float* skw0 = (const float*)d_in[15];
  const float* skb0 = (const float*)d_in[16];
  const float* ng0  = (const float*)d_in[17];
  const float* nb0  = (const float*)d_in[18];
  const float* lw1  = (const float*)d_in[19];
  const float* tW1  = (const float*)d_in[20];
  const float* tb1  = (const float*)d_in[21];
  // d_in[22..25, 28..29] feed only block-1's post-skip h (never read) -> dead.
  const float* skw1 = (const float*)d_in[26];
  const float* skb1 = (const float*)d_in[27];
  const float* rw1  = (const float*)d_in[30];
  const float* rb1  = (const float*)d_in[31];
  const float* rw2  = (const float*)d_in[32];
  const float* rb2  = (const float*)d_in[33];
  const int* srcI = eidx;
  const int* dstI = eidx + cE;

  // ---- workspace layout ----
  char* W = (char*)d_ws;
  size_t off = 0;
  auto A8 = [&](size_t bytes) { size_t r = off; off = (off + bytes + 255) & ~(size_t)255; return r; };
  const size_t oH0 = A8((size_t)cR * 160 * 2);   // res, bf16
  const size_t oHh = A8((size_t)cR * 160 * 2);   // chain h (G1 [cR,192] aliases Hh+T1-head)
  const size_t oT1 = A8((size_t)cR * 160 * 2);   // scratch (Z12 [cR,320] aliases T1+S2)
  const size_t oS2 = A8((size_t)cR * 160 * 2);   // scratch2 / hT / cascade-last out
  const size_t oDd = A8((size_t)cR * 160 * 4);   // f32 accumulator (scores alias)
  const size_t oAdj = A8((size_t)cN * cN * 2);
  const size_t oOut = A8((size_t)cB * cN * cFF * 4);       // f32 skip acc (t=11)
  const size_t oR1  = A8((size_t)cB * cN * 512 * 2);       // bf16 r1
  const size_t oY   = A8((size_t)cB * cN * cHOR * cF * 4); // f32
  const size_t oZero = A8(6 * 2048 * 4 + 2 * 192 * 4);
  const size_t oRowf = A8(2049 * 4), oRowb = A8(2049 * 4);
  const size_t oColf = A8((size_t)cE * 4), oColb = A8((size_t)cE * 4);
  const size_t oWnf  = A8((size_t)cE * 4), oWnb  = A8((size_t)cE * 4);
  const size_t oScSh = A8(2 * 192 * 4);
  const size_t oWT   = A8((size_t)721920 * 2);   // bf16 transposed weights
  const size_t oSeb  = A8((size_t)cN * cHID * 2);
  const size_t oTeb  = A8((size_t)cN * cHID * 2);
  const size_t oW23  = A8(192 * 192 * 4);        // f32 W2@W3
  const size_t oW123 = A8(192 * 192 * 4);        // f32 W1@W2@W3
  const size_t oWskp = A8(192 * 256 * 4);        // f32 W123_1@skw1
  const size_t oBt0  = A8(cT * 160 * 4);         // f32 Btot block0 [12][160]
  const size_t oBt11 = A8(192 * 4);              // f32 Btot1[11]
  const size_t oBsk1 = A8(256 * 4);              // f32 composed skip bias
  if (off > ws_size) {
    fill_f32<<<(int)((outN + 255) / 256), 256, 0, stream>>>(outF, outN, 300.f);
    return;
  }

  u16 *H0 = (u16*)(W + oH0), *Hh = (u16*)(W + oHh), *T1 = (u16*)(W + oT1),
      *S2 = (u16*)(W + oS2), *adjb = (u16*)(W + oAdj);
  float* Dd = (float*)(W + oDd);
  u16 *G1 = (u16*)(W + oHh);   // [cR,192] bf16 over Hh(+T1 head), post-BN only
  u16 *Z12 = T1;               // [cR,320] bf16 over T1+S2 (diffconv packing)
  float* scores = (float*)(W + oDd);   // phase-0 scratch, dead before Dd use
  float *outacc = (float*)(W + oOut), *yb = (float*)(W + oY);
  u16 *r1b = (u16*)(W + oR1);
  float* zero = (float*)(W + oZero);
  float *degf = zero, *degb = zero + 2048;
  int *cntf = (int*)(zero + 4096), *cntb = cntf + 2048,
      *curf = cntb + 2048, *curb = curf + 2048;
  float* stat = (float*)(curb + 2048);
  int *rowf = (int*)(W + oRowf), *rowb = (int*)(W + oRowb);
  int *colf = (int*)(W + oColf), *colb = (int*)(W + oColb);
  float *wnf = (float*)(W + oWnf), *wnb = (float*)(W + oWnb);
  float* scsh = (float*)(W + oScSh);
  u16* wt   = (u16*)(W + oWT);
  // wt region: composed-chain weights reuse the old per-layer slots
  u16 *wt123_0 = wt,            *wsk1pT = wt + 3 * 25600, *wdc = wsk1pT + 3 * 36864,
      *wds = wdc + 102400,      *wsk0 = wds + 51200,
      *wr1 = wsk0 + 40960 + 49152, *wr2 = wr1 + 131072;
  u16 *seb = (u16*)(W + oSeb), *teb = (u16*)(W + oTeb);
  float *W23 = (float*)(W + oW23), *W123 = (float*)(W + oW123), *Wskp = (float*)(W + oWskp);
  float *Bt0 = (float*)(W + oBt0), *Bt11 = (float*)(W + oBt11), *Bsk1 = (float*)(W + oBsk1);

  auto g5u = [&](const u16* Aq, const u16* Bq, u16* Cq, const float* bias,
                 int M, int N, int K, int lda, int ldbt, int ldc,
                 long bA, long bB, long bC, int batch, int flags, int bpt = 0) {
    dim3 g(M / 128, (N + 159) / 160, batch);
    gemm_mfma<5, u16><<<g, 256, 0, stream>>>(Aq, Bq, Cq, bias, M, N, K, lda, ldbt, ldc, bA, bB, bC, flags, bpt);
  };
  auto g5f = [&](const u16* Aq, const u16* Bq, float* Cq, const float* bias,
                 int M, int N, int K, int lda, int ldbt, int ldc, int flags) {
    dim3 g(M / 128, (N + 159) / 160, 1);
    gemm_mfma<5, float><<<g, 256, 0, stream>>>(Aq, Bq, Cq, bias, M, N, K, lda, ldbt, ldc, 0, 0, 0, flags, 0);
  };
  auto g4f = [&](const u16* Aq, const u16* Bq, float* Cq, const float* bias,
                 int M, int N, int K, int lda, int ldbt, int ldc,
                 long bA, long bB, long bC, int batch, int flags) {
    dim3 g(M / 128, (N + 127) / 128, batch);
    gemm_mfma<4, float><<<g, 256, 0, stream>>>(Aq, Bq, Cq, bias, M, N, K, lda, ldbt, ldc, bA, bB, bC, flags, 0);
  };
  auto g4u = [&](const u16* Aq, const u16* Bq, u16* Cq, const float* bias,
                 int M, int N, int K, int lda, int ldbt, int ldc, int flags) {
    dim3 g(M / 128, (N + 127) / 128, 1);
    gemm_mfma<4, u16><<<g, 256, 0, stream>>>(Aq, Bq, Cq, bias, M, N, K, lda, ldbt, ldc, 0, 0, 0, flags, 0);
  };
  auto wcv = [&](const float* src, u16* dst, int K, int N) {
    wconvT<<<(int)(((long)K * N + 255) / 256), 256, 0, stream>>>(src, dst, K, N);
  };
  auto mms = [&](const float* Aq, const float* Bq, float* Cq, int M, int N, int K) {
    matmul_small<<<(M * N + 255) / 256, 256, 0, stream>>>(Aq, Bq, Cq, M, N, K);
  };

  // ---- phase 0a: composed chain weights (S-commutation: chain = S^3 h @ W123 + Btot[t]) ----
  mms(tW0 + 1L * 25600, tW0 + 2L * 25600, W23, 160, 160, 160);   // W23_0 = W2@W3
  mms(tW0,              W23,              W123, 160, 160, 160);  // W123_0
  wcv(W123, wt123_0, 160, 160);
  btot_full<<<1, 160, 0, stream>>>(tb0, tb0 + 160, tb0 + 320, W23, tW0 + 2L * 25600, Bt0, 160);
  mms(tW1 + 1L * 36864, tW1 + 2L * 36864, W23, 192, 192, 192);   // W23_1
  mms(tW1,              W23,              W123, 192, 192, 192);  // W123_1
  mms(W123, skw1, Wskp, 192, 256, 192);                          // W123_1 @ skw1
  wcv(Wskp, wsk1pT, 192, 256);
  btot_last<<<1, 192, 0, stream>>>(tb1, tb1 + 192, tb1 + 384, W23, tW1 + 2L * 36864, Bt11, 192);
  bias_sk<<<1, 256, 0, stream>>>(Bt11, skw1, skb1, Bsk1);

  // ---- phase 0b: other weights, CSR, encoder, adjacency ----
  wcv(dcw0, wdc, 640, 160);   // [640,160] -> [160][640] (concat-K layout)
  wcv(dsw0, wds, 320, 160);   // [320,160] -> [160][320]
  wcv(skw0, wsk0, 160, 256);
  wcv(rw1, wr1, 256, 512);
  wcv(rw2, wr2, 512, 312);

  hipMemsetAsync(zero, 0, 6 * 2048 * 4 + 2 * 192 * 4, stream);
  edge_stats<<<cE / 256, 256, 0, stream>>>(srcI, dstI, ew, degf, degb, cntf, cntb);
  scan2<<<2, 256, 0, stream>>>(cntf, cntb, rowf, rowb);
  fill_csr<<<cE / 256, 256, 0, stream>>>(srcI, dstI, ew, degf, degb, rowf, rowb,
                                         curf, curb, colf, colb, wnf, wnb);
  encoder<<<cR / 8, 160, 0, stream>>>(x, enc_w, enc_b, node_emb, lw0, H0);

  // learned adjacency: scores = se @ te^T via MFMA, then row relu-softmax
  cvt_f2bf<<<(cN * cHID + 255) / 256, 256, 0, stream>>>(src_emb, seb, (long)cN * cHID);
  cvt_f2bf<<<(cN * cHID + 255) / 256, 256, 0, stream>>>(tgt_emb, teb, (long)cN * cHID);
  g4f(seb, teb, scores, nullptr, cN, cN, cHID, cHID, cHID, cN, 0, 0, 0, 1, 0);
  relu_softmax_rows<<<cN, 256, 0, stream>>>(scores, adjb);

  // ---- block 0 (c = 160) ----
  {
    const int c = 160;
    const long NC = (long)cN * c;
    const int casGrid = (int)(((long)cB * cN * (c / 8) + 255) / 256);
    // composed synaptic chain: Hh = (S^3 H0) @ W123_0 + Bt0[t]
    cascade3_full<<<casGrid, 256, 0, stream>>>(H0, T1, c);
    g5u(T1, wt123_0, Hh, Bt0, cR, c, c, c, c, c, 0, 0, 0, 1, FLAG_BIAS, /*bpt=*/1);
    // skip (t=11): outacc[b] = h[b,11]@skw0 + skb0
    g4f(Hh + 11L * NC, wsk0, outacc, skb0, cN, cFF, c, c, c, cFF,
        (long)cT * NC, 0, (long)cN * cFF, cB, FLAG_BIAS);
    // diffconv: pack [z1|z2] then [z3|z4] into Z12 [cR,320]; two K=320 GEMMs
    prop_gather_all<<<cN, 256, 0, stream>>>(Hh, 160, Z12, 320, rowf, colf, wnf);
    prop_gather_all<<<cN, 256, 0, stream>>>(Z12, 320, Z12 + 160, 320, rowf, colf, wnf);
    g5f(Z12, wdc, Dd, dcb0, cR, c, 320, 320, 640, c, FLAG_BIAS);
    prop_gather_all<<<cN, 256, 0, stream>>>(Hh, 160, Z12, 320, rowb, colb, wnb);
    prop_gather_all<<<cN, 256, 0, stream>>>(Z12, 320, Z12 + 160, 320, rowb, colb, wnb);
    g5f(Z12, wdc + 320, Dd, nullptr, cR, c, 320, 320, 640, c, FLAG_ACC);
    // dense conv: hT -> S2 ; x1 = adj@hT -> T1 ; Dd += x1@dsw[:,0:160] ;
    //             x1T -> S2 ; x2 = adj@x1T -> T1 ; Dd += x2@dsw[:,160:320]
    dim3 tg(cN / 64, (c + 63) / 64, cBT);
    transpose_bf16<<<tg, 256, 0, stream>>>(Hh, S2, cN, c, NC, NC);
    g5u(adjb, S2, T1, nullptr, cN, c, cN, cN, cN, c, 0, NC, NC, cBT, 0);
    g5f(T1, wds, Dd, dsb0, cR, c, c, c, 320, c, FLAG_BIAS | FLAG_ACC);
    transpose_bf16<<<tg, 256, 0, stream>>>(T1, S2, cN, c, NC, NC);
    g5u(adjb, S2, T1, nullptr, cN, c, cN, cN, cN, c, 0, NC, NC, cBT, 0);
    g5f(T1, wds + 160, Dd, nullptr, cR, c, c, c, 320, c, FLAG_ACC);
    // BN(Dd + H0) -> G1 (stride 192) + lw1
    bn_stats<<<512, c, 0, stream>>>(Dd, H0, stat, c);
    bn_finalize<<<1, c, 0, stream>>>(stat, ng0, nb0, scsh, c);
    bn_apply_concat<<<cR / 8, 192, 0, stream>>>(Dd, H0, scsh, lw1, G1);
  }

  // ---- block 1 (c = 192): composed chain+skip: only t=11 survives ----
  {
    const int c = 192;
    const int casGrid = (int)(((long)cB * cN * (c / 8) + 255) / 256);
    // S2 <- (S^3 G1)[t=11]  [cB*cN, 192]
    cascade3_last<<<casGrid, 256, 0, stream>>>(G1, S2, c);
    // outacc = relu(outacc + S2 @ (W123_1@skw1) + Bsk1)
    g4f(S2, wsk1pT, outacc, Bsk1, cB * cN, cFF, c, c, c, cFF,
        0, 0, 0, 1, FLAG_BIAS | FLAG_ACC | FLAG_RELU);
  }

  // ---- readout (outacc f32 -> bf16 in S2, then two MFMA GEMMs) ----
  cvt_f2bf<<<(int)(((long)cB * cN * cFF + 255) / 256), 256, 0, stream>>>(outacc, S2, (long)cB * cN * cFF);
  g4u(S2, wr1, r1b, rb1, cB * cN, 2 * cFF, cFF, cFF, cFF, 2 * cFF, FLAG_BIAS | FLAG_RELU);
  g4f(r1b, wr2, yb, rb2, cB * cN, cHOR * cF, 2 * cFF, 2 * cFF, 2 * cFF, cHOR * cF,
      0, 0, 0, 1, FLAG_BIAS);
  final_transpose<<<(cB * cHOR * cN * cF) / 256, 256, 0, stream>>>(yb, outF);
}

// Round 11
// 1268.706 us; speedup vs baseline: 3.1756x; 1.0573x over previous
//
#include <hip/hip_runtime.h>

// ======================= types & helpers =======================
using u16 = unsigned short;
typedef short bf16x8 __attribute__((ext_vector_type(8)));
typedef float f32x4  __attribute__((ext_vector_type(4)));

__device__ __forceinline__ float bf2f(u16 u) { return __uint_as_float(((unsigned)u) << 16); }
__device__ __forceinline__ u16 f2bf(float f) {  // round-to-nearest-even
  unsigned u = __float_as_uint(f);
  return (u16)((u + 0x7FFFu + ((u >> 16) & 1u)) >> 16);
}
__device__ __forceinline__ float ldv(const float* p) { return *p; }
__device__ __forceinline__ float ldv(const u16* p)   { return bf2f(*p); }
__device__ __forceinline__ void  stv(float* p, float v) { *p = v; }
__device__ __forceinline__ void  stv(u16* p, float v)   { *p = f2bf(v); }

// ======================= problem constants =======================
constexpr int cB = 4, cT = 12, cN = 2048, cF = 26;
constexpr int cHID = 128, cLF = 32, cFF = 256, cHOR = 12;
constexpr int cE = 16384;
constexpr int cR = cB * cT * cN;   // 98304
constexpr int cBT = cB * cT;       // 48
constexpr float cALPHA = 0.9f, cBETA = 0.8f, cEPS = 1e-5f;

#define FLAG_ACC  1
#define FLAG_BIAS 2
#define FLAG_RELU 4

// ======================= MFMA bf16 GEMM (gload_lds + dbuf + XCD swizzle) ==========
// C[m,n] = sum_k A[m,k] * BT[n,k]  (+bias) (+C) (relu)
// A: bf16 [M,K] lda ; BT: bf16 [N,K] ldbt. M%128==0, K%32==0, lda/ldbt%8==0; N guarded
// (OOB B rows clamp to N-1; their output columns are never stored).
// biasPerT: bias is [cT][N]; row block m0 uses bias row (m0/2048)%cT (rows = (b,t,n)).
template <int NF, typename TC>
__global__ __launch_bounds__(256)
void gemm_mfma(const u16* __restrict__ A, const u16* __restrict__ BT,
               TC* __restrict__ C, const float* __restrict__ bias,
               int M, int N, int K, int lda, int ldbt, int ldc,
               long batchA, long batchB, long batchC, int flags, int biasPerT)
{
  constexpr int TN = NF * 32;
  constexpr int ROWS = 128 + TN;        // A rows then BT rows
  constexpr int NINST = ROWS / 16;      // gload_lds wave-instrs per K-step
  constexpr int NPW = (NINST + 3) / 4;  // max instrs per wave
  __shared__ __align__(16) u16 S[2][ROWS * 32];

  // bijective XCD-aware block remap
  const long gx = gridDim.x, gy = gridDim.y;
  const long total = gx * gy * (long)gridDim.z;
  long lid = blockIdx.x + gx * (blockIdx.y + gy * (long)blockIdx.z);
  { const long q = total >> 3, r = total & 7, xcd = lid & 7, j = lid >> 3;
    lid = (xcd < r ? xcd * (q + 1) : r * (q + 1) + (xcd - r) * q) + j; }
  const int bz = (int)(lid / (gx * gy));
  const long rem = lid % (gx * gy);
  const int by = (int)(rem / gx), bx = (int)(rem % gx);

  A  += (long)bz * batchA;
  BT += (long)bz * batchB;
  C  += (long)bz * batchC;
  const int tid = threadIdx.x;
  const int lane = tid & 63, wid = tid >> 6;
  const int wm = wid & 1, wn = wid >> 1;
  const int m0 = bx * 128, n0 = by * TN;
  const int fr = lane & 15, kh = lane >> 4;   // frag row / k-half
  const int nwi = (NINST - wid + 3) / 4;      // this wave's instr count

  // hoisted per-lane staging pointers (advance +32 elts per K-step)
  const u16* gp[NPW];
#pragma unroll
  for (int i = 0; i < NPW; ++i) {
    const int s = wid + i * 4;
    if (s < NINST) {
      const int slot = s * 64 + lane;    // linear 16B LDS slot
      const int row = slot >> 2, q = slot & 3;
      if (row < 128) {
        gp[i] = A + (long)(m0 + row) * lda + q * 8;
      } else {
        const int n = min(n0 + row - 128, N - 1);
        gp[i] = BT + (long)n * ldbt + q * 8;
      }
    } else {
      gp[i] = A;
    }
  }

  f32x4 acc[4][NF];
#pragma unroll
  for (int i = 0; i < 4; ++i)
#pragma unroll
    for (int j = 0; j < NF; ++j) acc[i][j] = f32x4{0.f, 0.f, 0.f, 0.f};

  auto STAGE = [&](int buf) {
#pragma unroll
    for (int i = 0; i < NPW; ++i) {
      if (i < nwi) {
        const int s = wid + i * 4;
        __builtin_amdgcn_global_load_lds(
            (const __attribute__((address_space(1))) unsigned int*)gp[i],
            (__attribute__((address_space(3))) unsigned int*)&S[buf][s * 512],
            16, 0, 0);
        gp[i] += 32;
      }
    }
  };

  STAGE(0);
  int cur = 0;
  for (int k0 = 0; k0 < K; k0 += 32) {
    __syncthreads();                 // drains vmcnt -> S[cur] ready; prior reads of S[cur^1] done
    if (k0 + 32 < K) STAGE(cur ^ 1);
    bf16x8 af[4];
#pragma unroll
    for (int mf = 0; mf < 4; ++mf)
      af[mf] = *(const bf16x8*)&S[cur][(wm * 64 + mf * 16 + fr) * 32 + kh * 8];
#pragma unroll
    for (int nf = 0; nf < NF; ++nf) {
      const bf16x8 bfr =
          *(const bf16x8*)&S[cur][(128 + wn * NF * 16 + nf * 16 + fr) * 32 + kh * 8];
#pragma unroll
      for (int mf = 0; mf < 4; ++mf)
        acc[mf][nf] = __builtin_amdgcn_mfma_f32_16x16x32_bf16(af[mf], bfr, acc[mf][nf], 0, 0, 0);
    }
    cur ^= 1;
  }

  const float* bp = bias;
  if (biasPerT && bias) bp = bias + (long)((m0 >> 11) % cT) * N;

#pragma unroll
  for (int mf = 0; mf < 4; ++mf)
#pragma unroll
    for (int nf = 0; nf < NF; ++nf) {
      const int gn = n0 + wn * NF * 16 + nf * 16 + fr;
      if (gn < N) {
#pragma unroll
        for (int r = 0; r < 4; ++r) {
          const long gm = m0 + wm * 64 + mf * 16 + kh * 4 + r;   // C/D: row=(lane>>4)*4+r
          float v = acc[mf][nf][r];
          if (flags & FLAG_BIAS) v += bp[gn];
          if (flags & FLAG_ACC)  v += ldv(&C[gm * ldc + gn]);
          if (flags & FLAG_RELU) v = fmaxf(v, 0.f);
          stv(&C[gm * ldc + gn], v);
        }
      }
    }
}

// ======================= small f32 matmul: C[M,N] = A[M,K] @ B[K,N] ==========
__global__ __launch_bounds__(256)
void matmul_small(const float* __restrict__ A, const float* __restrict__ B,
                  float* __restrict__ C, int M, int N, int K)
{
  const int idx = blockIdx.x * 256 + threadIdx.x;
  if (idx >= M * N) return;
  const int m = idx / N, n = idx % N;
  float acc = 0.f;
  for (int k = 0; k < K; ++k) acc = fmaf(A[m * K + k], B[k * N + n], acc);
  C[idx] = acc;
}

// ======================= LIF composed coefficients ==========
__device__ __forceinline__ void lif_coeffs(float* k1, float* k2, float* k3)
{
  float ap = 1.f;
  for (int m = 0; m < cT; ++m) {
    k1[m] = (m ? cBETA * k1[m - 1] : 0.f) + ap;   // k1[m] = sum a^i b^(m-i)
    ap *= cALPHA;
  }
  for (int m = 0; m < cT; ++m) { float s = 0.f; for (int i = 0; i <= m; ++i) s += k1[i] * k1[m - i]; k2[m] = s; }
  for (int m = 0; m < cT; ++m) { float s = 0.f; for (int i = 0; i <= m; ++i) s += k2[i] * k1[m - i]; k3[m] = s; }
}

// Btot[t][ch] = C3[t]*(b1@W23)[ch] + C2[t]*(b2@W3)[ch] + C1[t]*b3[ch]; Ci = cumsum(ki)
__global__ void btot_full(const float* __restrict__ b1, const float* __restrict__ b2,
                          const float* __restrict__ b3, const float* __restrict__ W23,
                          const float* __restrict__ W3, float* __restrict__ Btot, int c)
{
  const int ch = threadIdx.x;
  if (ch >= c) return;
  float k1[cT], k2[cT], k3[cT]; lif_coeffs(k1, k2, k3);
  float v1 = 0.f, v2 = 0.f;
  for (int j = 0; j < c; ++j) { v1 = fmaf(b1[j], W23[j * c + ch], v1); v2 = fmaf(b2[j], W3[j * c + ch], v2); }
  float C1 = 0.f, C2 = 0.f, C3 = 0.f;
  for (int t = 0; t < cT; ++t) {
    C1 += k1[t]; C2 += k2[t]; C3 += k3[t];
    Btot[t * c + ch] = C3 * v1 + C2 * v2 + C1 * b3[ch];
  }
}

// last-t-only variant -> out[c]
__global__ void btot_last(const float* __restrict__ b1, const float* __restrict__ b2,
                          const float* __restrict__ b3, const float* __restrict__ W23,
                          const float* __restrict__ W3, float* __restrict__ out, int c)
{
  const int ch = threadIdx.x;
  if (ch >= c) return;
  float k1[cT], k2[cT], k3[cT]; lif_coeffs(k1, k2, k3);
  float v1 = 0.f, v2 = 0.f;
  for (int j = 0; j < c; ++j) { v1 = fmaf(b1[j], W23[j * c + ch], v1); v2 = fmaf(b2[j], W3[j * c + ch], v2); }
  float C1 = 0.f, C2 = 0.f, C3 = 0.f;
  for (int t = 0; t < cT; ++t) { C1 += k1[t]; C2 += k2[t]; C3 += k3[t]; }
  out[ch] = C3 * v1 + C2 * v2 + C1 * b3[ch];
}

// bias1p[n] = skb1[n] + sum_k Btot11[k] * skw1[k][n]   (n < 256, k < 192)
__global__ void bias_sk(const float* __restrict__ Btot11, const float* __restrict__ skw1,
                        const float* __restrict__ skb1, float* __restrict__ out)
{
  const int n = threadIdx.x;
  float acc = skb1[n];
  for (int k = 0; k < 192; ++k) acc = fmaf(Btot11[k], skw1[k * 256 + n], acc);
  out[n] = acc;
}

// ======================= 3x cascaded LIF (= S^3), full sequence out ==========
__global__ __launch_bounds__(256)
void cascade3_full(const u16* __restrict__ in, u16* __restrict__ out, int c)
{
  const int c8 = c >> 3;
  const long total = (long)cB * cN * c8;
  const long idx = (long)blockIdx.x * 256 + threadIdx.x;
  if (idx >= total) return;
  const long nc = (long)cN * c;
  const int b = (int)(idx / ((long)cN * c8));
  const long rest = (idx % ((long)cN * c8)) * 8;
  const u16* p = in  + (long)b * cT * nc + rest;
  u16*       q = out + (long)b * cT * nc + rest;
  float s1[8] = {}, m1[8] = {}, s2[8] = {}, m2[8] = {}, s3[8] = {}, m3[8] = {};
#pragma unroll
  for (int t = 0; t < cT; ++t) {
    const bf16x8 v = *(const bf16x8*)&p[(long)t * nc];
    u16 o[8];
#pragma unroll
    for (int e = 0; e < 8; ++e) {
      s1[e] = fmaf(cALPHA, s1[e], bf2f((u16)v[e])); m1[e] = fmaf(cBETA, m1[e], s1[e]);
      s2[e] = fmaf(cALPHA, s2[e], m1[e]);           m2[e] = fmaf(cBETA, m2[e], s2[e]);
      s3[e] = fmaf(cALPHA, s3[e], m2[e]);           m3[e] = fmaf(cBETA, m3[e], s3[e]);
      o[e] = f2bf(m3[e]);
    }
    *(bf16x8*)&q[(long)t * nc] = *(const bf16x8*)o;
  }
}

// same, but store only the t=T-1 slice into out [cB*cN, c]
__global__ __launch_bounds__(256)
void cascade3_last(const u16* __restrict__ in, u16* __restrict__ out, int c)
{
  const int c8 = c >> 3;
  const long total = (long)cB * cN * c8;
  const long idx = (long)blockIdx.x * 256 + threadIdx.x;
  if (idx >= total) return;
  const long nc = (long)cN * c;
  const int b = (int)(idx / ((long)cN * c8));
  const long rest = (idx % ((long)cN * c8)) * 8;
  const u16* p = in + (long)b * cT * nc + rest;
  float s1[8] = {}, m1[8] = {}, s2[8] = {}, m2[8] = {}, s3[8] = {}, m3[8] = {};
#pragma unroll
  for (int t = 0; t < cT; ++t) {
    const bf16x8 v = *(const bf16x8*)&p[(long)t * nc];
#pragma unroll
    for (int e = 0; e < 8; ++e) {
      s1[e] = fmaf(cALPHA, s1[e], bf2f((u16)v[e])); m1[e] = fmaf(cBETA, m1[e], s1[e]);
      s2[e] = fmaf(cALPHA, s2[e], m1[e]);           m2[e] = fmaf(cBETA, m2[e], s2[e]);
      s3[e] = fmaf(cALPHA, s3[e], m2[e]);           m3[e] = fmaf(cBETA, m3[e], s3[e]);
    }
  }
  u16 o[8];
#pragma unroll
  for (int e = 0; e < 8; ++e) o[e] = f2bf(m3[e]);
  *(bf16x8*)&out[(long)b * nc + rest] = *(const bf16x8*)o;
}

// ======================= weight convert + transpose (f32 [K,N] -> bf16 [N,K]) ==========
__global__ __launch_bounds__(256)
void wconvT(const float* __restrict__ w, u16* __restrict__ wt, int K, int N)
{
  const long idx = (long)blockIdx.x * 256 + threadIdx.x;
  if (idx >= (long)K * N) return;
  const int n = (int)(idx / K), k = (int)(idx % K);
  wt[idx] = f2bf(w[(long)k * N + n]);
}

// ======================= tiled bf16 transpose: in [R,Cc] -> out [Cc,R], batched ==========
__global__ __launch_bounds__(256)
void transpose_bf16(const u16* __restrict__ in, u16* __restrict__ out,
                    int R, int Cc, long batchIn, long batchOut)
{
  __shared__ u16 t[64][65];
  in  += (long)blockIdx.z * batchIn;
  out += (long)blockIdx.z * batchOut;
  const int tid = threadIdx.x;
  const int r0 = blockIdx.x * 64, c0 = blockIdx.y * 64;
  for (int i = tid; i < 64 * 64; i += 256) {
    const int r = i >> 6, c = i & 63;
    t[r][c] = (r0 + r < R && c0 + c < Cc) ? in[(long)(r0 + r) * Cc + c0 + c] : (u16)0;
  }
  __syncthreads();
  for (int i = tid; i < 64 * 64; i += 256) {
    const int c = i >> 6, r = i & 63;
    if (c0 + c < Cc && r0 + r < R) out[(long)(c0 + c) * R + r0 + r] = t[r][c];
  }
}

__global__ __launch_bounds__(256)
void cvt_f2bf(const float* __restrict__ in, u16* __restrict__ out, long n)
{
  const long idx = (long)blockIdx.x * 256 + threadIdx.x;
  if (idx < n) out[idx] = f2bf(in[idx]);
}

// ======================= graph preprocessing (CSR build) =======================
__global__ __launch_bounds__(256)
void edge_stats(const int* __restrict__ s, const int* __restrict__ d,
                const float* __restrict__ ew, float* degf, float* degb,
                int* cntf, int* cntb)
{
  const int e = blockIdx.x * 256 + threadIdx.x;
  atomicAdd(&degf[d[e]], ew[e]);
  atomicAdd(&degb[s[e]], ew[e]);
  atomicAdd(&cntf[d[e]], 1);
  atomicAdd(&cntb[s[e]], 1);
}

__global__ __launch_bounds__(256)
void scan2(const int* __restrict__ cf, const int* __restrict__ cb,
           int* __restrict__ rf, int* __restrict__ rb)
{
  const int* c = blockIdx.x ? cb : cf;
  int* r       = blockIdx.x ? rb : rf;
  __shared__ int part[256];
  const int t = threadIdx.x, base = t * 8;
  int loc[8]; int s = 0;
#pragma unroll
  for (int i = 0; i < 8; ++i) { loc[i] = c[base + i]; s += loc[i]; }
  part[t] = s; __syncthreads();
  if (t == 0) {
    int run = 0;
    for (int i = 0; i < 256; ++i) { const int v = part[i]; part[i] = run; run += v; }
    r[2048] = run;
  }
  __syncthreads();
  int run = part[t];
#pragma unroll
  for (int i = 0; i < 8; ++i) { r[base + i] = run; run += loc[i]; }
}

__global__ __launch_bounds__(256)
void fill_csr(const int* __restrict__ s, const int* __restrict__ d,
              const float* __restrict__ ew,
              const float* __restrict__ degf, const float* __restrict__ degb,
              const int* __restrict__ rowf, const int* __restrict__ rowb,
              int* curf, int* curb,
              int* __restrict__ colf, int* __restrict__ colb,
              float* __restrict__ wnf, float* __restrict__ wnb)
{
  const int e = blockIdx.x * 256 + threadIdx.x;
  const int si = s[e], di = d[e];
  const float w = ew[e];
  const int p = rowf[di] + atomicAdd(&curf[di], 1);
  colf[p] = si; wnf[p] = w / fmaxf(degf[di], 1e-6f);
  const int q = rowb[si] + atomicAdd(&curb[si], 1);
  colb[q] = di; wnb[q] = w / fmaxf(degb[si], 1e-6f);
}

// ======================= diffusion step, L2-sliced: one bt per block ==========
// y[bt,n,ch] = sum_j w[j]*x[bt,col[j],ch].
// Block = 12 nodes x 1 bt (240 threads used). lid remap groups 6 consecutive bt
// per XCD (round-robin dispatch) -> per-XCD read slice 6 x 655KB ~ 3.9MB <= 4MB L2.
constexpr int cNPB = 12;                       // nodes per block
constexpr int cNCH = (cN + cNPB - 1) / cNPB;   // 171 chunks (last ragged)
__global__ __launch_bounds__(256)
void prop_gather_bt(const u16* __restrict__ x, int ldx, u16* __restrict__ y, int ldy,
                    const int* __restrict__ rowptr, const int* __restrict__ col,
                    const float* __restrict__ w)
{
  const int lid = blockIdx.x;                  // 0 .. 8*6*cNCH-1
  const int xcd = lid & 7, j = lid >> 3;
  const int bt = xcd * 6 + (j % 6);            // 6 bt per XCD
  const int chunk = j / 6;
  const int item = threadIdx.x;                // (node_i, ch8)
  if (item >= cNPB * 20) return;
  const int n = chunk * cNPB + item / 20;
  if (n >= cN) return;
  const int ch = (item % 20) * 8;
  const int beg = rowptr[n], end = rowptr[n + 1];
  const u16* xb = x + (long)bt * cN * ldx + ch;
  float acc[8] = {};
  int jj = beg;
  for (; jj + 1 < end; jj += 2) {
    const int c0 = col[jj], c1 = col[jj + 1];
    const float w0 = w[jj], w1 = w[jj + 1];
    const bf16x8 v0 = *(const bf16x8*)&xb[(long)c0 * ldx];
    const bf16x8 v1 = *(const bf16x8*)&xb[(long)c1 * ldx];
#pragma unroll
    for (int q = 0; q < 8; ++q) {
      acc[q] = fmaf(w0, bf2f((u16)v0[q]), acc[q]);
      acc[q] = fmaf(w1, bf2f((u16)v1[q]), acc[q]);
    }
  }
  if (jj < end) {
    const float w0 = w[jj];
    const bf16x8 v0 = *(const bf16x8*)&xb[(long)col[jj] * ldx];
#pragma unroll
    for (int q = 0; q < 8; ++q) acc[q] = fmaf(w0, bf2f((u16)v0[q]), acc[q]);
  }
  u16 o[8];
#pragma unroll
  for (int q = 0; q < 8; ++q) o[q] = f2bf(acc[q]);
  *(bf16x8*)&y[((long)bt * cN + n) * ldy + ch] = *(const bf16x8*)o;
}

// ======================= encoder =======================
__global__ __launch_bounds__(160)
void encoder(const float* __restrict__ x, const float* __restrict__ ew_,
             const float* __restrict__ eb, const float* __restrict__ ne,
             const float* __restrict__ lw, u16* __restrict__ h)
{
  __shared__ float xs[cF];
  const int tid = threadIdx.x;
  const long r0 = (long)blockIdx.x * 8;
  for (long row = r0; row < r0 + 8; ++row) {
    if (tid < cF) xs[tid] = x[row * cF + tid];
    __syncthreads();
    const int n = (int)(row % cN);
    float v;
    if (tid < cHID) {
      float acc = eb[tid] + ne[(long)n * cHID + tid];
#pragma unroll
      for (int f = 0; f < cF; ++f) acc = fmaf(xs[f], ew_[f * cHID + tid], acc);
      v = acc;
    } else {
      v = lw[(long)n * cLF + (tid - cHID)];
    }
    h[row * 160 + tid] = f2bf(v);
    __syncthreads();
  }
}

// ======================= adjacency: row softmax of relu(scores) ==========
__global__ __launch_bounds__(256)
void relu_softmax_rows(const float* __restrict__ sc, u16* __restrict__ adj)
{
  const int row = blockIdx.x, tid = threadIdx.x;
  const float* p = sc + (long)row * cN;
  __shared__ float red[256];
  float lv[8];
  float mx = 0.f;   // relu => all >= 0
#pragma unroll
  for (int i = 0; i < 8; ++i) {
    const float v = fmaxf(p[tid + i * 256], 0.f);
    lv[i] = v; mx = fmaxf(mx, v);
  }
  red[tid] = mx; __syncthreads();
  for (int s = 128; s > 0; s >>= 1) { if (tid < s) red[tid] = fmaxf(red[tid], red[tid + s]); __syncthreads(); }
  const float m = red[0]; __syncthreads();
  float sum = 0.f;
#pragma unroll
  for (int i = 0; i < 8; ++i) { lv[i] = __expf(lv[i] - m); sum += lv[i]; }
  red[tid] = sum; __syncthreads();
  for (int s = 128; s > 0; s >>= 1) { if (tid < s) red[tid] += red[tid + s]; __syncthreads(); }
  const float inv = 1.f / red[0]; __syncthreads();
#pragma unroll
  for (int i = 0; i < 8; ++i) adj[(long)row * cN + tid + i * 256] = f2bf(lv[i] * inv);
}

// ======================= batch norm =======================
__global__ __launch_bounds__(256)
void bn_stats(const float* __restrict__ d, const u16* __restrict__ res,
              float* __restrict__ stat, int c)
{
  const int ch = threadIdx.x;
  const long r0 = (long)blockIdx.x * (cR / 512);
  float s = 0.f, s2 = 0.f;
  for (int i = 0; i < cR / 512; ++i) {
    const float v = d[(r0 + i) * c + ch] + bf2f(res[(r0 + i) * c + ch]);
    s += v; s2 = fmaf(v, v, s2);
  }
  atomicAdd(&stat[ch], s);
  atomicAdd(&stat[c + ch], s2);
}

__global__ __launch_bounds__(256)
void bn_finalize(const float* __restrict__ stat, const float* __restrict__ g,
                 const float* __restrict__ b, float* __restrict__ scsh, int c)
{
  const int ch = threadIdx.x;
  const float mu = stat[ch] / cR;
  const float var = stat[c + ch] / cR - mu * mu;
  const float sc = g[ch] * rsqrtf(var + cEPS);
  scsh[ch] = sc;
  scsh[c + ch] = fmaf(-mu, sc, b[ch]);
}

__global__ __launch_bounds__(192)
void bn_apply_concat(const float* __restrict__ d, const u16* __restrict__ res,
                     const float* __restrict__ scsh, const float* __restrict__ lw,
                     u16* __restrict__ out)
{
  const int tid = threadIdx.x;
  const long r0 = (long)blockIdx.x * 8;
  for (long row = r0; row < r0 + 8; ++row) {
    const int n = (int)(row % cN);
    float v;
    if (tid < 160) v = fmaf(d[row * 160 + tid] + bf2f(res[row * 160 + tid]),
                            scsh[tid], scsh[160 + tid]);
    else           v = lw[(long)n * cLF + (tid - 160)];
    out[row * 192 + tid] = f2bf(v);
  }
}

// ======================= output transpose (f32 out) =======================
__global__ __launch_bounds__(256)
void final_transpose(const float* __restrict__ y, float* __restrict__ out)
{
  const long idx = (long)blockIdx.x * 256 + threadIdx.x;
  const int f = (int)(idx % cF);
  long t = idx / cF;
  const int n = (int)(t % cN); t /= cN;
  const int hor = (int)(t % cHOR);
  const int b = (int)(t / cHOR);
  out[idx] = y[((long)b * cN + n) * (cHOR * cF) + hor * cF + f];
}

__global__ __launch_bounds__(256)
void fill_f32(float* __restrict__ out, long n, float val)
{
  const long idx = (long)blockIdx.x * 256 + threadIdx.x;
  if (idx < n) out[idx] = val;
}

// ======================= host orchestration =======================
extern "C" void kernel_launch(void* const* d_in, const int* in_sizes, int n_in,
                              void* d_out, int out_size, void* d_ws, size_t ws_size,
                              hipStream_t stream)
{
  float* outF = (float*)d_out;
  const long outN = out_size;
  if (n_in < 34) { fill_f32<<<(int)((outN + 255) / 256), 256, 0, stream>>>(outF, outN, 500.f); return; }
  if (in_sizes[0] != cB * cT * cN * cF || in_sizes[1] != 2 * cE || in_sizes[9] != 3 * 160 * 160) {
    fill_f32<<<(int)((outN + 255) / 256), 256, 0, stream>>>(outF, outN, 700.f); return;
  }

  const float* x        = (const float*)d_in[0];
  const int*   eidx     = (const int*)d_in[1];
  const float* ew       = (const float*)d_in[2];
  const float* enc_w    = (const float*)d_in[3];
  const float* enc_b    = (const float*)d_in[4];
  const float* node_emb = (const float*)d_in[5];
  const float* src_emb  = (const float*)d_in[6];
  const float* tgt_emb  = (const float*)d_in[7];
  const float* lw0  = (const float*)d_in[8];
  const float* tW0  = (const float*)d_in[9];
  const float* tb0  = (const float*)d_in[10];
  const float* dcw0 = (const float*)d_in[11];
  const float* dcb0 = (const float*)d_in[12];
  const float* dsw0 = (const float*)d_in[13];
  const float* dsb0 = (const float*)d_in[14];
  const float* skw0 = (const float*)d_in[15];
  const float* skb0 = (const float*)d_in[16];
  const float* ng0  = (const float*)d_in[17];
  const float* nb0  = (const float*)d_in[18];
  const float* lw1  = (const float*)d_in[19];
  const float* tW1  = (const float*)d_in[20];
  const float* tb1  = (const float*)d_in[21];
  // d_in[22..25, 28..29] feed only block-1's post-skip h (never read) -> dead.
  const float* skw1 = (const float*)d_in[26];
  const float* skb1 = (const float*)d_in[27];
  const float* rw1  = (const float*)d_in[30];
  const float* rb1  = (const float*)d_in[31];
  const float* rw2  = (const float*)d_in[32];
  const float* rb2  = (const float*)d_in[33];
  const int* srcI = eidx;
  const int* dstI = eidx + cE;

  // ---- workspace layout ----
  char* W = (char*)d_ws;
  size_t off = 0;
  auto A8 = [&](size_t bytes) { size_t r = off; off = (off + bytes + 255) & ~(size_t)255; return r; };
  const size_t oH0 = A8((size_t)cR * 160 * 2);   // res, bf16
  const size_t oHh = A8((size_t)cR * 160 * 2);   // chain h (G1 [cR,192] aliases Hh+T1-head)
  const size_t oT1 = A8((size_t)cR * 160 * 2);   // scratch (Z12 [cR,320] aliases T1+S2)
  const size_t oS2 = A8((size_t)cR * 160 * 2);   // scratch2 / hT / cascade-last out
  const size_t oDd = A8((size_t)cR * 160 * 4);   // f32 accumulator (scores alias)
  const size_t oAdj = A8((size_t)cN * cN * 2);
  const size_t oOut = A8((size_t)cB * cN * cFF * 4);       // f32 skip acc (t=11)
  const size_t oR1  = A8((size_t)cB * cN * 512 * 2);       // bf16 r1
  const size_t oY   = A8((size_t)cB * cN * cHOR * cF * 4); // f32
  const size_t oZero = A8(6 * 2048 * 4 + 2 * 192 * 4);
  const size_t oRowf = A8(2049 * 4), oRowb = A8(2049 * 4);
  const size_t oColf = A8((size_t)cE * 4), oColb = A8((size_t)cE * 4);
  const size_t oWnf  = A8((size_t)cE * 4), oWnb  = A8((size_t)cE * 4);
  const size_t oScSh = A8(2 * 192 * 4);
  const size_t oWT   = A8((size_t)721920 * 2);   // bf16 transposed weights
  const size_t oSeb  = A8((size_t)cN * cHID * 2);
  const size_t oTeb  = A8((size_t)cN * cHID * 2);
  const size_t oW23  = A8(192 * 192 * 4);        // f32 W2@W3
  const size_t oW123 = A8(192 * 192 * 4);        // f32 W1@W2@W3
  const size_t oWskp = A8(192 * 256 * 4);        // f32 W123_1@skw1
  const size_t oBt0  = A8(cT * 160 * 4);         // f32 Btot block0 [12][160]
  const size_t oBt11 = A8(192 * 4);              // f32 Btot1[11]
  const size_t oBsk1 = A8(256 * 4);              // f32 composed skip bias
  if (off > ws_size) {
    fill_f32<<<(int)((outN + 255) / 256), 256, 0, stream>>>(outF, outN, 300.f);
    return;
  }

  u16 *H0 = (u16*)(W + oH0), *Hh = (u16*)(W + oHh), *T1 = (u16*)(W + oT1),
      *S2 = (u16*)(W + oS2), *adjb = (u16*)(W + oAdj);
  float* Dd = (float*)(W + oDd);
  u16 *G1 = (u16*)(W + oHh);   // [cR,192] bf16 over Hh(+T1 head), post-BN only
  u16 *Z12 = T1;               // [cR,320] bf16 over T1+S2 (diffconv packing)
  float* scores = (float*)(W + oDd);   // phase-0 scratch, dead before Dd use
  float *outacc = (float*)(W + oOut), *yb = (float*)(W + oY);
  u16 *r1b = (u16*)(W + oR1);
  float* zero = (float*)(W + oZero);
  float *degf = zero, *degb = zero + 2048;
  int *cntf = (int*)(zero + 4096), *cntb = cntf + 2048,
      *curf = cntb + 2048, *curb = curf + 2048;
  float* stat = (float*)(curb + 2048);
  int *rowf = (int*)(W + oRowf), *rowb = (int*)(W + oRowb);
  int *colf = (int*)(W + oColf), *colb = (int*)(W + oColb);
  float *wnf = (float*)(W + oWnf), *wnb = (float*)(W + oWnb);
  float* scsh = (float*)(W + oScSh);
  u16* wt   = (u16*)(W + oWT);
  u16 *wt123_0 = wt,            *wsk1pT = wt + 3 * 25600, *wdc = wsk1pT + 3 * 36864,
      *wds = wdc + 102400,      *wsk0 = wds + 51200,
      *wr1 = wsk0 + 40960 + 49152, *wr2 = wr1 + 131072;
  u16 *seb = (u16*)(W + oSeb), *teb = (u16*)(W + oTeb);
  float *W23 = (float*)(W + oW23), *W123 = (float*)(W + oW123), *Wskp = (float*)(W + oWskp);
  float *Bt0 = (float*)(W + oBt0), *Bt11 = (float*)(W + oBt11), *Bsk1 = (float*)(W + oBsk1);

  auto g5u = [&](const u16* Aq, const u16* Bq, u16* Cq, const float* bias,
                 int M, int N, int K, int lda, int ldbt, int ldc,
                 long bA, long bB, long bC, int batch, int flags, int bpt = 0) {
    dim3 g(M / 128, (N + 159) / 160, batch);
    gemm_mfma<5, u16><<<g, 256, 0, stream>>>(Aq, Bq, Cq, bias, M, N, K, lda, ldbt, ldc, bA, bB, bC, flags, bpt);
  };
  auto g5f = [&](const u16* Aq, const u16* Bq, float* Cq, const float* bias,
                 int M, int N, int K, int lda, int ldbt, int ldc, int flags) {
    dim3 g(M / 128, (N + 159) / 160, 1);
    gemm_mfma<5, float><<<g, 256, 0, stream>>>(Aq, Bq, Cq, bias, M, N, K, lda, ldbt, ldc, 0, 0, 0, flags, 0);
  };
  auto g4f = [&](const u16* Aq, const u16* Bq, float* Cq, const float* bias,
                 int M, int N, int K, int lda, int ldbt, int ldc,
                 long bA, long bB, long bC, int batch, int flags) {
    dim3 g(M / 128, (N + 127) / 128, batch);
    gemm_mfma<4, float><<<g, 256, 0, stream>>>(Aq, Bq, Cq, bias, M, N, K, lda, ldbt, ldc, bA, bB, bC, flags, 0);
  };
  auto g4u = [&](const u16* Aq, const u16* Bq, u16* Cq, const float* bias,
                 int M, int N, int K, int lda, int ldbt, int ldc, int flags) {
    dim3 g(M / 128, (N + 127) / 128, 1);
    gemm_mfma<4, u16><<<g, 256, 0, stream>>>(Aq, Bq, Cq, bias, M, N, K, lda, ldbt, ldc, 0, 0, 0, flags, 0);
  };
  auto wcv = [&](const float* src, u16* dst, int K, int N) {
    wconvT<<<(int)(((long)K * N + 255) / 256), 256, 0, stream>>>(src, dst, K, N);
  };
  auto mms = [&](const float* Aq, const float* Bq, float* Cq, int M, int N, int K) {
    matmul_small<<<(M * N + 255) / 256, 256, 0, stream>>>(Aq, Bq, Cq, M, N, K);
  };

  // ---- phase 0a: composed chain weights (S-commutation: chain = S^3 h @ W123 + Btot[t]) ----
  mms(tW0 + 1L * 25600, tW0 + 2L * 25600, W23, 160, 160, 160);   // W23_0 = W2@W3
  mms(tW0,              W23,              W123, 160, 160, 160);  // W123_0
  wcv(W123, wt123_0, 160, 160);
  btot_full<<<1, 160, 0, stream>>>(tb0, tb0 + 160, tb0 + 320, W23, tW0 + 2L * 25600, Bt0, 160);
  mms(tW1 + 1L * 36864, tW1 + 2L * 36864, W23, 192, 192, 192);   // W23_1
  mms(tW1,              W23,              W123, 192, 192, 192);  // W123_1
  mms(W123, skw1, Wskp, 192, 256, 192);                          // W123_1 @ skw1
  wcv(Wskp, wsk1pT, 192, 256);
  btot_last<<<1, 192, 0, stream>>>(tb1, tb1 + 192, tb1 + 384, W23, tW1 + 2L * 36864, Bt11, 192);
  bias_sk<<<1, 256, 0, stream>>>(Bt11, skw1, skb1, Bsk1);

  // ---- phase 0b: other weights, CSR, encoder, adjacency ----
  wcv(dcw0, wdc, 640, 160);   // [640,160] -> [160][640] (concat-K layout)
  wcv(dsw0, wds, 320, 160);   // [320,160] -> [160][320]
  wcv(skw0, wsk0, 160, 256);
  wcv(rw1, wr1, 256, 512);
  wcv(rw2, wr2, 512, 312);

  hipMemsetAsync(zero, 0, 6 * 2048 * 4 + 2 * 192 * 4, stream);
  edge_stats<<<cE / 256, 256, 0, stream>>>(srcI, dstI, ew, degf, degb, cntf, cntb);
  scan2<<<2, 256, 0, stream>>>(cntf, cntb, rowf, rowb);
  fill_csr<<<cE / 256, 256, 0, stream>>>(srcI, dstI, ew, degf, degb, rowf, rowb,
                                         curf, curb, colf, colb, wnf, wnb);
  encoder<<<cR / 8, 160, 0, stream>>>(x, enc_w, enc_b, node_emb, lw0, H0);

  // learned adjacency: scores = se @ te^T via MFMA, then row relu-softmax
  cvt_f2bf<<<(cN * cHID + 255) / 256, 256, 0, stream>>>(src_emb, seb, (long)cN * cHID);
  cvt_f2bf<<<(cN * cHID + 255) / 256, 256, 0, stream>>>(tgt_emb, teb, (long)cN * cHID);
  g4f(seb, teb, scores, nullptr, cN, cN, cHID, cHID, cHID, cN, 0, 0, 0, 1, 0);
  relu_softmax_rows<<<cN, 256, 0, stream>>>(scores, adjb);

  const int PROP_GRID = 8 * 6 * cNCH;   // 8 XCD groups x 6 bt x 171 chunks

  // ---- block 0 (c = 160) ----
  {
    const int c = 160;
    const long NC = (long)cN * c;
    const int casGrid = (int)(((long)cB * cN * (c / 8) + 255) / 256);
    // composed synaptic chain: Hh = (S^3 H0) @ W123_0 + Bt0[t]
    cascade3_full<<<casGrid, 256, 0, stream>>>(H0, T1, c);
    g5u(T1, wt123_0, Hh, Bt0, cR, c, c, c, c, c, 0, 0, 0, 1, FLAG_BIAS, /*bpt=*/1);
    // skip (t=11): outacc[b] = h[b,11]@skw0 + skb0
    g4f(Hh + 11L * NC, wsk0, outacc, skb0, cN, cFF, c, c, c, cFF,
        (long)cT * NC, 0, (long)cN * cFF, cB, FLAG_BIAS);
    // diffconv: pack [z1|z2] then [z3|z4] into Z12 [cR,320]; two K=320 GEMMs
    prop_gather_bt<<<PROP_GRID, 256, 0, stream>>>(Hh, 160, Z12, 320, rowf, colf, wnf);
    prop_gather_bt<<<PROP_GRID, 256, 0, stream>>>(Z12, 320, Z12 + 160, 320, rowf, colf, wnf);
    g5f(Z12, wdc, Dd, dcb0, cR, c, 320, 320, 640, c, FLAG_BIAS);
    prop_gather_bt<<<PROP_GRID, 256, 0, stream>>>(Hh, 160, Z12, 320, rowb, colb, wnb);
    prop_gather_bt<<<PROP_GRID, 256, 0, stream>>>(Z12, 320, Z12 + 160, 320, rowb, colb, wnb);
    g5f(Z12, wdc + 320, Dd, nullptr, cR, c, 320, 320, 640, c, FLAG_ACC);
    // dense conv: hT -> S2 ; x1 = adj@hT -> T1 ; Dd += x1@dsw[:,0:160] ;
    //             x1T -> S2 ; x2 = adj@x1T -> T1 ; Dd += x2@dsw[:,160:320]
    dim3 tg(cN / 64, (c + 63) / 64, cBT);
    transpose_bf16<<<tg, 256, 0, stream>>>(Hh, S2, cN, c, NC, NC);
    g5u(adjb, S2, T1, nullptr, cN, c, cN, cN, cN, c, 0, NC, NC, cBT, 0);
    g5f(T1, wds, Dd, dsb0, cR, c, c, c, 320, c, FLAG_BIAS | FLAG_ACC);
    transpose_bf16<<<tg, 256, 0, stream>>>(T1, S2, cN, c, NC, NC);
    g5u(adjb, S2, T1, nullptr, cN, c, cN, cN, cN, c, 0, NC, NC, cBT, 0);
    g5f(T1, wds + 160, Dd, nullptr, cR, c, c, c, 320, c, FLAG_ACC);
    // BN(Dd + H0) -> G1 (stride 192) + lw1
    bn_stats<<<512, c, 0, stream>>>(Dd, H0, stat, c);
    bn_finalize<<<1, c, 0, stream>>>(stat, ng0, nb0, scsh, c);
    bn_apply_concat<<<cR / 8, 192, 0, stream>>>(Dd, H0, scsh, lw1, G1);
  }

  // ---- block 1 (c = 192): composed chain+skip: only t=11 survives ----
  {
    const int c = 192;
    const int casGrid = (int)(((long)cB * cN * (c / 8) + 255) / 256);
    cascade3_last<<<casGrid, 256, 0, stream>>>(G1, S2, c);
    g4f(S2, wsk1pT, outacc, Bsk1, cB * cN, cFF, c, c, c, cFF,
        0, 0, 0, 1, FLAG_BIAS | FLAG_ACC | FLAG_RELU);
  }

  // ---- readout (outacc f32 -> bf16 in S2, then two MFMA GEMMs) ----
  cvt_f2bf<<<(int)(((long)cB * cN * cFF + 255) / 256), 256, 0, stream>>>(outacc, S2, (long)cB * cN * cFF);
  g4u(S2, wr1, r1b, rb1, cB * cN, 2 * cFF, cFF, cFF, cFF, 2 * cFF, FLAG_BIAS | FLAG_RELU);
  g4f(r1b, wr2, yb, rb2, cB * cN, cHOR * cF, 2 * cFF, 2 * cFF, 2 * cFF, cHOR * cF,
      0, 0, 0, 1, FLAG_BIAS);
  final_transpose<<<(cB * cHOR * cN * cF) / 256, 256, 0, stream>>>(yb, outF);
}

// Round 12
// 1173.037 us; speedup vs baseline: 3.4346x; 1.0816x over previous
//
#include <hip/hip_runtime.h>

// ======================= types & helpers =======================
using u16 = unsigned short;
typedef short bf16x8 __attribute__((ext_vector_type(8)));
typedef float f32x4  __attribute__((ext_vector_type(4)));

__device__ __forceinline__ float bf2f(u16 u) { return __uint_as_float(((unsigned)u) << 16); }
__device__ __forceinline__ u16 f2bf(float f) {  // round-to-nearest-even
  unsigned u = __float_as_uint(f);
  return (u16)((u + 0x7FFFu + ((u >> 16) & 1u)) >> 16);
}
__device__ __forceinline__ float ldv(const float* p) { return *p; }
__device__ __forceinline__ float ldv(const u16* p)   { return bf2f(*p); }
__device__ __forceinline__ void  stv(float* p, float v) { *p = v; }
__device__ __forceinline__ void  stv(u16* p, float v)   { *p = f2bf(v); }

// ======================= problem constants =======================
constexpr int cB = 4, cT = 12, cN = 2048, cF = 26;
constexpr int cHID = 128, cLF = 32, cFF = 256, cHOR = 12;
constexpr int cE = 16384;
constexpr int cR = cB * cT * cN;   // 98304
constexpr int cBT = cB * cT;       // 48
constexpr float cALPHA = 0.9f, cBETA = 0.8f, cEPS = 1e-5f;

#define FLAG_ACC  1
#define FLAG_BIAS 2
#define FLAG_RELU 4

// ======================= MFMA bf16 GEMM (gload_lds + dbuf + XCD swizzle) ==========
// C[m,n] = sum_k A[m,k] * BT[n,k]  (+bias) (+C) (relu)
// A: bf16 [M,K] lda ; BT: bf16 [N,K] ldbt. M%128==0, K%32==0, lda/ldbt%8==0; N guarded
// (OOB B rows clamp to N-1; their output columns are never stored).
// biasPerT: bias is [cT][N]; row block m0 uses bias row (m0/2048)%cT (rows = (b,t,n)).
template <int NF, typename TC>
__global__ __launch_bounds__(256)
void gemm_mfma(const u16* __restrict__ A, const u16* __restrict__ BT,
               TC* __restrict__ C, const float* __restrict__ bias,
               int M, int N, int K, int lda, int ldbt, int ldc,
               long batchA, long batchB, long batchC, int flags, int biasPerT)
{
  constexpr int TN = NF * 32;
  constexpr int ROWS = 128 + TN;        // A rows then BT rows
  constexpr int NINST = ROWS / 16;      // gload_lds wave-instrs per K-step
  constexpr int NPW = (NINST + 3) / 4;  // max instrs per wave
  __shared__ __align__(16) u16 S[2][ROWS * 32];

  // bijective XCD-aware block remap
  const long gx = gridDim.x, gy = gridDim.y;
  const long total = gx * gy * (long)gridDim.z;
  long lid = blockIdx.x + gx * (blockIdx.y + gy * (long)blockIdx.z);
  { const long q = total >> 3, r = total & 7, xcd = lid & 7, j = lid >> 3;
    lid = (xcd < r ? xcd * (q + 1) : r * (q + 1) + (xcd - r) * q) + j; }
  const int bz = (int)(lid / (gx * gy));
  const long rem = lid % (gx * gy);
  const int by = (int)(rem / gx), bx = (int)(rem % gx);

  A  += (long)bz * batchA;
  BT += (long)bz * batchB;
  C  += (long)bz * batchC;
  const int tid = threadIdx.x;
  const int lane = tid & 63, wid = tid >> 6;
  const int wm = wid & 1, wn = wid >> 1;
  const int m0 = bx * 128, n0 = by * TN;
  const int fr = lane & 15, kh = lane >> 4;   // frag row / k-half
  const int nwi = (NINST - wid + 3) / 4;      // this wave's instr count

  // hoisted per-lane staging pointers (advance +32 elts per K-step)
  const u16* gp[NPW];
#pragma unroll
  for (int i = 0; i < NPW; ++i) {
    const int s = wid + i * 4;
    if (s < NINST) {
      const int slot = s * 64 + lane;    // linear 16B LDS slot
      const int row = slot >> 2, q = slot & 3;
      if (row < 128) {
        gp[i] = A + (long)(m0 + row) * lda + q * 8;
      } else {
        const int n = min(n0 + row - 128, N - 1);
        gp[i] = BT + (long)n * ldbt + q * 8;
      }
    } else {
      gp[i] = A;
    }
  }

  f32x4 acc[4][NF];
#pragma unroll
  for (int i = 0; i < 4; ++i)
#pragma unroll
    for (int j = 0; j < NF; ++j) acc[i][j] = f32x4{0.f, 0.f, 0.f, 0.f};

  auto STAGE = [&](int buf) {
#pragma unroll
    for (int i = 0; i < NPW; ++i) {
      if (i < nwi) {
        const int s = wid + i * 4;
        __builtin_amdgcn_global_load_lds(
            (const __attribute__((address_space(1))) unsigned int*)gp[i],
            (__attribute__((address_space(3))) unsigned int*)&S[buf][s * 512],
            16, 0, 0);
        gp[i] += 32;
      }
    }
  };

  STAGE(0);
  int cur = 0;
  for (int k0 = 0; k0 < K; k0 += 32) {
    __syncthreads();                 // drains vmcnt -> S[cur] ready; prior reads of S[cur^1] done
    if (k0 + 32 < K) STAGE(cur ^ 1);
    bf16x8 af[4];
#pragma unroll
    for (int mf = 0; mf < 4; ++mf)
      af[mf] = *(const bf16x8*)&S[cur][(wm * 64 + mf * 16 + fr) * 32 + kh * 8];
#pragma unroll
    for (int nf = 0; nf < NF; ++nf) {
      const bf16x8 bfr =
          *(const bf16x8*)&S[cur][(128 + wn * NF * 16 + nf * 16 + fr) * 32 + kh * 8];
#pragma unroll
      for (int mf = 0; mf < 4; ++mf)
        acc[mf][nf] = __builtin_amdgcn_mfma_f32_16x16x32_bf16(af[mf], bfr, acc[mf][nf], 0, 0, 0);
    }
    cur ^= 1;
  }

  const float* bp = bias;
  if (biasPerT && bias) bp = bias + (long)((m0 >> 11) % cT) * N;

#pragma unroll
  for (int mf = 0; mf < 4; ++mf)
#pragma unroll
    for (int nf = 0; nf < NF; ++nf) {
      const int gn = n0 + wn * NF * 16 + nf * 16 + fr;
      if (gn < N) {
#pragma unroll
        for (int r = 0; r < 4; ++r) {
          const long gm = m0 + wm * 64 + mf * 16 + kh * 4 + r;   // C/D: row=(lane>>4)*4+r
          float v = acc[mf][nf][r];
          if (flags & FLAG_BIAS) v += bp[gn];
          if (flags & FLAG_ACC)  v += ldv(&C[gm * ldc + gn]);
          if (flags & FLAG_RELU) v = fmaxf(v, 0.f);
          stv(&C[gm * ldc + gn], v);
        }
      }
    }
}

// ======================= small f32 matmul: C[M,N] = A[M,K] @ B[K,N] ==========
__global__ __launch_bounds__(256)
void matmul_small(const float* __restrict__ A, const float* __restrict__ B,
                  float* __restrict__ C, int M, int N, int K)
{
  const int idx = blockIdx.x * 256 + threadIdx.x;
  if (idx >= M * N) return;
  const int m = idx / N, n = idx % N;
  float acc = 0.f;
  for (int k = 0; k < K; ++k) acc = fmaf(A[m * K + k], B[k * N + n], acc);
  C[idx] = acc;
}

// ======================= LIF composed coefficients ==========
__device__ __forceinline__ void lif_coeffs(float* k1, float* k2, float* k3)
{
  float ap = 1.f;
  for (int m = 0; m < cT; ++m) {
    k1[m] = (m ? cBETA * k1[m - 1] : 0.f) + ap;   // k1[m] = sum a^i b^(m-i)
    ap *= cALPHA;
  }
  for (int m = 0; m < cT; ++m) { float s = 0.f; for (int i = 0; i <= m; ++i) s += k1[i] * k1[m - i]; k2[m] = s; }
  for (int m = 0; m < cT; ++m) { float s = 0.f; for (int i = 0; i <= m; ++i) s += k2[i] * k1[m - i]; k3[m] = s; }
}

// Btot[t][ch] = C3[t]*(b1@W23)[ch] + C2[t]*(b2@W3)[ch] + C1[t]*b3[ch]; Ci = cumsum(ki)
__global__ void btot_full(const float* __restrict__ b1, const float* __restrict__ b2,
                          const float* __restrict__ b3, const float* __restrict__ W23,
                          const float* __restrict__ W3, float* __restrict__ Btot, int c)
{
  const int ch = threadIdx.x;
  if (ch >= c) return;
  float k1[cT], k2[cT], k3[cT]; lif_coeffs(k1, k2, k3);
  float v1 = 0.f, v2 = 0.f;
  for (int j = 0; j < c; ++j) { v1 = fmaf(b1[j], W23[j * c + ch], v1); v2 = fmaf(b2[j], W3[j * c + ch], v2); }
  float C1 = 0.f, C2 = 0.f, C3 = 0.f;
  for (int t = 0; t < cT; ++t) {
    C1 += k1[t]; C2 += k2[t]; C3 += k3[t];
    Btot[t * c + ch] = C3 * v1 + C2 * v2 + C1 * b3[ch];
  }
}

// last-t-only variant -> out[c]
__global__ void btot_last(const float* __restrict__ b1, const float* __restrict__ b2,
                          const float* __restrict__ b3, const float* __restrict__ W23,
                          const float* __restrict__ W3, float* __restrict__ out, int c)
{
  const int ch = threadIdx.x;
  if (ch >= c) return;
  float k1[cT], k2[cT], k3[cT]; lif_coeffs(k1, k2, k3);
  float v1 = 0.f, v2 = 0.f;
  for (int j = 0; j < c; ++j) { v1 = fmaf(b1[j], W23[j * c + ch], v1); v2 = fmaf(b2[j], W3[j * c + ch], v2); }
  float C1 = 0.f, C2 = 0.f, C3 = 0.f;
  for (int t = 0; t < cT; ++t) { C1 += k1[t]; C2 += k2[t]; C3 += k3[t]; }
  out[ch] = C3 * v1 + C2 * v2 + C1 * b3[ch];
}

// bias1p[n] = skb1[n] + sum_k Btot11[k] * skw1[k][n]
__global__ void bias_sk(const float* __restrict__ Btot11, const float* __restrict__ skw1,
                        const float* __restrict__ skb1, float* __restrict__ out)
{
  const int n = threadIdx.x;
  float acc = skb1[n];
  for (int k = 0; k < 192; ++k) acc = fmaf(Btot11[k], skw1[k * 256 + n], acc);
  out[n] = acc;
}

// bsum[ch] = a[ch] + b[ch]
__global__ void vadd2(const float* __restrict__ a, const float* __restrict__ b,
                      float* __restrict__ o, int n)
{
  const int i = threadIdx.x;
  if (i < n) o[i] = a[i] + b[i];
}

// ======================= 3x cascaded LIF (= S^3), full sequence out ==========
__global__ __launch_bounds__(256)
void cascade3_full(const u16* __restrict__ in, u16* __restrict__ out, int c)
{
  const int c8 = c >> 3;
  const long total = (long)cB * cN * c8;
  const long idx = (long)blockIdx.x * 256 + threadIdx.x;
  if (idx >= total) return;
  const long nc = (long)cN * c;
  const int b = (int)(idx / ((long)cN * c8));
  const long rest = (idx % ((long)cN * c8)) * 8;
  const u16* p = in  + (long)b * cT * nc + rest;
  u16*       q = out + (long)b * cT * nc + rest;
  float s1[8] = {}, m1[8] = {}, s2[8] = {}, m2[8] = {}, s3[8] = {}, m3[8] = {};
#pragma unroll
  for (int t = 0; t < cT; ++t) {
    const bf16x8 v = *(const bf16x8*)&p[(long)t * nc];
    u16 o[8];
#pragma unroll
    for (int e = 0; e < 8; ++e) {
      s1[e] = fmaf(cALPHA, s1[e], bf2f((u16)v[e])); m1[e] = fmaf(cBETA, m1[e], s1[e]);
      s2[e] = fmaf(cALPHA, s2[e], m1[e]);           m2[e] = fmaf(cBETA, m2[e], s2[e]);
      s3[e] = fmaf(cALPHA, s3[e], m2[e]);           m3[e] = fmaf(cBETA, m3[e], s3[e]);
      o[e] = f2bf(m3[e]);
    }
    *(bf16x8*)&q[(long)t * nc] = *(const bf16x8*)o;
  }
}

// same, but store only the t=T-1 slice into out [cB*cN, c]
__global__ __launch_bounds__(256)
void cascade3_last(const u16* __restrict__ in, u16* __restrict__ out, int c)
{
  const int c8 = c >> 3;
  const long total = (long)cB * cN * c8;
  const long idx = (long)blockIdx.x * 256 + threadIdx.x;
  if (idx >= total) return;
  const long nc = (long)cN * c;
  const int b = (int)(idx / ((long)cN * c8));
  const long rest = (idx % ((long)cN * c8)) * 8;
  const u16* p = in + (long)b * cT * nc + rest;
  float s1[8] = {}, m1[8] = {}, s2[8] = {}, m2[8] = {}, s3[8] = {}, m3[8] = {};
#pragma unroll
  for (int t = 0; t < cT; ++t) {
    const bf16x8 v = *(const bf16x8*)&p[(long)t * nc];
#pragma unroll
    for (int e = 0; e < 8; ++e) {
      s1[e] = fmaf(cALPHA, s1[e], bf2f((u16)v[e])); m1[e] = fmaf(cBETA, m1[e], s1[e]);
      s2[e] = fmaf(cALPHA, s2[e], m1[e]);           m2[e] = fmaf(cBETA, m2[e], s2[e]);
      s3[e] = fmaf(cALPHA, s3[e], m2[e]);           m3[e] = fmaf(cBETA, m3[e], s3[e]);
    }
  }
  u16 o[8];
#pragma unroll
  for (int e = 0; e < 8; ++e) o[e] = f2bf(m3[e]);
  *(bf16x8*)&out[(long)b * nc + rest] = *(const bf16x8*)o;
}

// ======================= weight convert + transpose (f32 [K,N] -> bf16 [N,K]) ==========
__global__ __launch_bounds__(256)
void wconvT(const float* __restrict__ w, u16* __restrict__ wt, int K, int N)
{
  const long idx = (long)blockIdx.x * 256 + threadIdx.x;
  if (idx >= (long)K * N) return;
  const int n = (int)(idx / K), k = (int)(idx % K);
  wt[idx] = f2bf(w[(long)k * N + n]);
}

// 5 independent transposes fused into one dispatch (segment switch)
__global__ __launch_bounds__(256)
void wconv_multi(const float* __restrict__ w0, u16* __restrict__ d0,   // 640x160
                 const float* __restrict__ w1, u16* __restrict__ d1,   // 320x160
                 const float* __restrict__ w2, u16* __restrict__ d2,   // 160x256
                 const float* __restrict__ w3, u16* __restrict__ d3,   // 256x512
                 const float* __restrict__ w4, u16* __restrict__ d4)   // 512x312
{
  const long s0 = 640L * 160, s1 = s0 + 320L * 160, s2 = s1 + 160L * 256,
             s3 = s2 + 256L * 512, s4 = s3 + 512L * 312;
  long idx = (long)blockIdx.x * 256 + threadIdx.x;
  const float* w; u16* d; int K, N; long base;
  if      (idx < s0) { w = w0; d = d0; K = 640; N = 160; base = 0;  }
  else if (idx < s1) { w = w1; d = d1; K = 320; N = 160; base = s0; }
  else if (idx < s2) { w = w2; d = d2; K = 160; N = 256; base = s1; }
  else if (idx < s3) { w = w3; d = d3; K = 256; N = 512; base = s2; }
  else if (idx < s4) { w = w4; d = d4; K = 512; N = 312; base = s3; }
  else return;
  const long l = idx - base;
  const int n = (int)(l / K), k = (int)(l % K);
  d[l] = f2bf(w[(long)k * N + n]);
}

// ======================= tiled bf16 transpose: in [R,Cc] ld ldi -> out [Cc,R], batched ====
__global__ __launch_bounds__(256)
void transpose_bf16(const u16* __restrict__ in, int ldi, u16* __restrict__ out,
                    int R, int Cc, long batchIn, long batchOut)
{
  __shared__ u16 t[64][65];
  in  += (long)blockIdx.z * batchIn;
  out += (long)blockIdx.z * batchOut;
  const int tid = threadIdx.x;
  const int r0 = blockIdx.x * 64, c0 = blockIdx.y * 64;
  for (int i = tid; i < 64 * 64; i += 256) {
    const int r = i >> 6, c = i & 63;
    t[r][c] = (r0 + r < R && c0 + c < Cc) ? in[(long)(r0 + r) * ldi + c0 + c] : (u16)0;
  }
  __syncthreads();
  for (int i = tid; i < 64 * 64; i += 256) {
    const int c = i >> 6, r = i & 63;
    if (c0 + c < Cc && r0 + r < R) out[(long)(c0 + c) * R + r0 + r] = t[r][c];
  }
}

__global__ __launch_bounds__(256)
void cvt_f2bf(const float* __restrict__ in, u16* __restrict__ out, long n)
{
  const long idx = (long)blockIdx.x * 256 + threadIdx.x;
  if (idx < n) out[idx] = f2bf(in[idx]);
}

// ======================= graph preprocessing (CSR build) =======================
__global__ __launch_bounds__(256)
void edge_stats(const int* __restrict__ s, const int* __restrict__ d,
                const float* __restrict__ ew, float* degf, float* degb,
                int* cntf, int* cntb)
{
  const int e = blockIdx.x * 256 + threadIdx.x;
  atomicAdd(&degf[d[e]], ew[e]);
  atomicAdd(&degb[s[e]], ew[e]);
  atomicAdd(&cntf[d[e]], 1);
  atomicAdd(&cntb[s[e]], 1);
}

__global__ __launch_bounds__(256)
void scan2(const int* __restrict__ cf, const int* __restrict__ cb,
           int* __restrict__ rf, int* __restrict__ rb)
{
  const int* c = blockIdx.x ? cb : cf;
  int* r       = blockIdx.x ? rb : rf;
  __shared__ int part[256];
  const int t = threadIdx.x, base = t * 8;
  int loc[8]; int s = 0;
#pragma unroll
  for (int i = 0; i < 8; ++i) { loc[i] = c[base + i]; s += loc[i]; }
  part[t] = s; __syncthreads();
  if (t == 0) {
    int run = 0;
    for (int i = 0; i < 256; ++i) { const int v = part[i]; part[i] = run; run += v; }
    r[2048] = run;
  }
  __syncthreads();
  int run = part[t];
#pragma unroll
  for (int i = 0; i < 8; ++i) { r[base + i] = run; run += loc[i]; }
}

__global__ __launch_bounds__(256)
void fill_csr(const int* __restrict__ s, const int* __restrict__ d,
              const float* __restrict__ ew,
              const float* __restrict__ degf, const float* __restrict__ degb,
              const int* __restrict__ rowf, const int* __restrict__ rowb,
              int* curf, int* curb,
              int* __restrict__ colf, int* __restrict__ colb,
              float* __restrict__ wnf, float* __restrict__ wnb)
{
  const int e = blockIdx.x * 256 + threadIdx.x;
  const int si = s[e], di = d[e];
  const float w = ew[e];
  const int p = rowf[di] + atomicAdd(&curf[di], 1);
  colf[p] = si; wnf[p] = w / fmaxf(degf[di], 1e-6f);
  const int q = rowb[si] + atomicAdd(&curb[si], 1);
  colb[q] = di; wnb[q] = w / fmaxf(degb[si], 1e-6f);
}

// ======================= diffusion step, L2-sliced: one bt per block ==========
constexpr int cNPB = 12;                       // nodes per block
constexpr int cNCH = (cN + cNPB - 1) / cNPB;   // 171 chunks
__global__ __launch_bounds__(256)
void prop_gather_bt(const u16* __restrict__ x, int ldx, u16* __restrict__ y, int ldy,
                    const int* __restrict__ rowptr, const int* __restrict__ col,
                    const float* __restrict__ w)
{
  const int lid = blockIdx.x;                  // 0 .. 8*6*cNCH-1
  const int xcd = lid & 7, j = lid >> 3;
  const int bt = xcd * 6 + (j % 6);            // 6 bt per XCD
  const int chunk = j / 6;
  const int item = threadIdx.x;                // (node_i, ch8)
  if (item >= cNPB * 20) return;
  const int n = chunk * cNPB + item / 20;
  if (n >= cN) return;
  const int ch = (item % 20) * 8;
  const int beg = rowptr[n], end = rowptr[n + 1];
  const u16* xb = x + (long)bt * cN * ldx + ch;
  float acc[8] = {};
  int jj = beg;
  for (; jj + 1 < end; jj += 2) {
    const int c0 = col[jj], c1 = col[jj + 1];
    const float w0 = w[jj], w1 = w[jj + 1];
    const bf16x8 v0 = *(const bf16x8*)&xb[(long)c0 * ldx];
    const bf16x8 v1 = *(const bf16x8*)&xb[(long)c1 * ldx];
#pragma unroll
    for (int q = 0; q < 8; ++q) {
      acc[q] = fmaf(w0, bf2f((u16)v0[q]), acc[q]);
      acc[q] = fmaf(w1, bf2f((u16)v1[q]), acc[q]);
    }
  }
  if (jj < end) {
    const float w0 = w[jj];
    const bf16x8 v0 = *(const bf16x8*)&xb[(long)col[jj] * ldx];
#pragma unroll
    for (int q = 0; q < 8; ++q) acc[q] = fmaf(w0, bf2f((u16)v0[q]), acc[q]);
  }
  u16 o[8];
#pragma unroll
  for (int q = 0; q < 8; ++q) o[q] = f2bf(acc[q]);
  *(bf16x8*)&y[((long)bt * cN + n) * ldy + ch] = *(const bf16x8*)o;
}

// ======================= encoder =======================
__global__ __launch_bounds__(160)
void encoder(const float* __restrict__ x, const float* __restrict__ ew_,
             const float* __restrict__ eb, const float* __restrict__ ne,
             const float* __restrict__ lw, u16* __restrict__ h)
{
  __shared__ float xs[cF];
  const int tid = threadIdx.x;
  const long r0 = (long)blockIdx.x * 8;
  for (long row = r0; row < r0 + 8; ++row) {
    if (tid < cF) xs[tid] = x[row * cF + tid];
    __syncthreads();
    const int n = (int)(row % cN);
    float v;
    if (tid < cHID) {
      float acc = eb[tid] + ne[(long)n * cHID + tid];
#pragma unroll
      for (int f = 0; f < cF; ++f) acc = fmaf(xs[f], ew_[f * cHID + tid], acc);
      v = acc;
    } else {
      v = lw[(long)n * cLF + (tid - cHID)];
    }
    h[row * 160 + tid] = f2bf(v);
    __syncthreads();
  }
}

// ======================= adjacency: row softmax of relu(scores) ==========
__global__ __launch_bounds__(256)
void relu_softmax_rows(const float* __restrict__ sc, u16* __restrict__ adj)
{
  const int row = blockIdx.x, tid = threadIdx.x;
  const float* p = sc + (long)row * cN;
  __shared__ float red[256];
  float lv[8];
  float mx = 0.f;   // relu => all >= 0
#pragma unroll
  for (int i = 0; i < 8; ++i) {
    const float v = fmaxf(p[tid + i * 256], 0.f);
    lv[i] = v; mx = fmaxf(mx, v);
  }
  red[tid] = mx; __syncthreads();
  for (int s = 128; s > 0; s >>= 1) { if (tid < s) red[tid] = fmaxf(red[tid], red[tid + s]); __syncthreads(); }
  const float m = red[0]; __syncthreads();
  float sum = 0.f;
#pragma unroll
  for (int i = 0; i < 8; ++i) { lv[i] = __expf(lv[i] - m); sum += lv[i]; }
  red[tid] = sum; __syncthreads();
  for (int s = 128; s > 0; s >>= 1) { if (tid < s) red[tid] += red[tid + s]; __syncthreads(); }
  const float inv = 1.f / red[0]; __syncthreads();
#pragma unroll
  for (int i = 0; i < 8; ++i) adj[(long)row * cN + tid + i * 256] = f2bf(lv[i] * inv);
}

// ======================= batch norm (bf16 inputs) =======================
__global__ __launch_bounds__(256)
void bn_stats(const u16* __restrict__ d, const u16* __restrict__ res,
              float* __restrict__ stat, int c)
{
  const int ch = threadIdx.x;
  const long r0 = (long)blockIdx.x * (cR / 512);
  float s = 0.f, s2 = 0.f;
  for (int i = 0; i < cR / 512; ++i) {
    const float v = bf2f(d[(r0 + i) * c + ch]) + bf2f(res[(r0 + i) * c + ch]);
    s += v; s2 = fmaf(v, v, s2);
  }
  atomicAdd(&stat[ch], s);
  atomicAdd(&stat[c + ch], s2);
}

__global__ __launch_bounds__(256)
void bn_finalize(const float* __restrict__ stat, const float* __restrict__ g,
                 const float* __restrict__ b, float* __restrict__ scsh, int c)
{
  const int ch = threadIdx.x;
  const float mu = stat[ch] / cR;
  const float var = stat[c + ch] / cR - mu * mu;
  const float sc = g[ch] * rsqrtf(var + cEPS);
  scsh[ch] = sc;
  scsh[c + ch] = fmaf(-mu, sc, b[ch]);
}

__global__ __launch_bounds__(192)
void bn_apply_concat(const u16* __restrict__ d, const u16* __restrict__ res,
                     const float* __restrict__ scsh, const float* __restrict__ lw,
                     u16* __restrict__ out)
{
  const int tid = threadIdx.x;
  const long r0 = (long)blockIdx.x * 8;
  for (long row = r0; row < r0 + 8; ++row) {
    const int n = (int)(row % cN);
    float v;
    if (tid < 160) v = fmaf(bf2f(d[row * 160 + tid]) + bf2f(res[row * 160 + tid]),
                            scsh[tid], scsh[160 + tid]);
    else           v = lw[(long)n * cLF + (tid - 160)];
    out[row * 192 + tid] = f2bf(v);
  }
}

// ======================= output transpose (f32 out) =======================
__global__ __launch_bounds__(256)
void final_transpose(const float* __restrict__ y, float* __restrict__ out)
{
  const long idx = (long)blockIdx.x * 256 + threadIdx.x;
  const int f = (int)(idx % cF);
  long t = idx / cF;
  const int n = (int)(t % cN); t /= cN;
  const int hor = (int)(t % cHOR);
  const int b = (int)(t / cHOR);
  out[idx] = y[((long)b * cN + n) * (cHOR * cF) + hor * cF + f];
}

__global__ __launch_bounds__(256)
void fill_f32(float* __restrict__ out, long n, float val)
{
  const long idx = (long)blockIdx.x * 256 + threadIdx.x;
  if (idx < n) out[idx] = val;
}

// ======================= host orchestration =======================
extern "C" void kernel_launch(void* const* d_in, const int* in_sizes, int n_in,
                              void* d_out, int out_size, void* d_ws, size_t ws_size,
                              hipStream_t stream)
{
  float* outF = (float*)d_out;
  const long outN = out_size;
  if (n_in < 34) { fill_f32<<<(int)((outN + 255) / 256), 256, 0, stream>>>(outF, outN, 500.f); return; }
  if (in_sizes[0] != cB * cT * cN * cF || in_sizes[1] != 2 * cE || in_sizes[9] != 3 * 160 * 160) {
    fill_f32<<<(int)((outN + 255) / 256), 256, 0, stream>>>(outF, outN, 700.f); return;
  }

  const float* x        = (const float*)d_in[0];
  const int*   eidx     = (const int*)d_in[1];
  const float* ew       = (const float*)d_in[2];
  const float* enc_w    = (const float*)d_in[3];
  const float* enc_b    = (const float*)d_in[4];
  const float* node_emb = (const float*)d_in[5];
  const float* src_emb  = (const float*)d_in[6];
  const float* tgt_emb  = (const float*)d_in[7];
  const float* lw0  = (const float*)d_in[8];
  const float* tW0  = (const float*)d_in[9];
  const float* tb0  = (const float*)d_in[10];
  const float* dcw0 = (const float*)d_in[11];
  const float* dcb0 = (const float*)d_in[12];
  const float* dsw0 = (const float*)d_in[13];
  const float* dsb0 = (const float*)d_in[14];
  const float* skw0 = (const float*)d_in[15];
  const float* skb0 = (const float*)d_in[16];
  const float* ng0  = (const float*)d_in[17];
  const float* nb0  = (const float*)d_in[18];
  const float* lw1  = (const float*)d_in[19];
  const float* tW1  = (const float*)d_in[20];
  const float* tb1  = (const float*)d_in[21];
  // d_in[22..25, 28..29] feed only block-1's post-skip h (never read) -> dead.
  const float* skw1 = (const float*)d_in[26];
  const float* skb1 = (const float*)d_in[27];
  const float* rw1  = (const float*)d_in[30];
  const float* rb1  = (const float*)d_in[31];
  const float* rw2  = (const float*)d_in[32];
  const float* rb2  = (const float*)d_in[33];
  const int* srcI = eidx;
  const int* dstI = eidx + cE;

  // ---- workspace layout ----
  char* W = (char*)d_ws;
  size_t off = 0;
  auto A8 = [&](size_t bytes) { size_t r = off; off = (off + bytes + 255) & ~(size_t)255; return r; };
  const size_t oH0 = A8((size_t)cR * 160 * 2);   // res, bf16
  const size_t oHh = A8((size_t)cR * 160 * 2);   // chain h (G1 [cR,192] aliases Hh+T1-head)
  const size_t oT1 = A8((size_t)cR * 160 * 2);   // scratch (Z12 [cR,320] aliases T1+S2)
  const size_t oS2 = A8((size_t)cR * 160 * 2);   // scratch2 / hT / cascade-last out
  const size_t oDd = A8((size_t)cR * 160 * 2);   // bf16 accumulator (scores alias)
  const size_t oAdj = A8((size_t)cN * cN * 2);
  const size_t oOut = A8((size_t)cB * cN * cFF * 4);       // f32 skip acc (t=11)
  const size_t oR1  = A8((size_t)cB * cN * 512 * 2);       // bf16 r1
  const size_t oY   = A8((size_t)cB * cN * cHOR * cF * 4); // f32
  const size_t oZero = A8(6 * 2048 * 4 + 2 * 192 * 4);
  const size_t oRowf = A8(2049 * 4), oRowb = A8(2049 * 4);
  const size_t oColf = A8((size_t)cE * 4), oColb = A8((size_t)cE * 4);
  const size_t oWnf  = A8((size_t)cE * 4), oWnb  = A8((size_t)cE * 4);
  const size_t oScSh = A8(2 * 192 * 4);
  const size_t oWT   = A8((size_t)721920 * 2);   // bf16 transposed weights
  const size_t oSeb  = A8((size_t)cN * cHID * 2);
  const size_t oTeb  = A8((size_t)cN * cHID * 2);
  const size_t oW23  = A8(192 * 192 * 4);        // f32 W2@W3
  const size_t oW123 = A8(192 * 192 * 4);        // f32 W1@W2@W3
  const size_t oWskp = A8(192 * 256 * 4);        // f32 W123_1@skw1
  const size_t oBt0  = A8(cT * 160 * 4);         // f32 Btot block0 [12][160]
  const size_t oBt11 = A8(192 * 4);              // f32 Btot1[11]
  const size_t oBsk1 = A8(256 * 4);              // f32 composed skip bias
  const size_t oBsum = A8(160 * 4);              // f32 dcb0+dsb0
  // NOTE: scores f32 [cN,cN] = 16.8 MB must fit the Dd region (31.5 MB) ✓
  if (off > ws_size) {
    fill_f32<<<(int)((outN + 255) / 256), 256, 0, stream>>>(outF, outN, 300.f);
    return;
  }

  u16 *H0 = (u16*)(W + oH0), *Hh = (u16*)(W + oHh), *T1 = (u16*)(W + oT1),
      *S2 = (u16*)(W + oS2), *adjb = (u16*)(W + oAdj);
  u16* Dd = (u16*)(W + oDd);           // bf16 accumulator
  u16 *G1 = (u16*)(W + oHh);           // [cR,192] bf16 over Hh(+T1 head), post-BN only
  u16 *Z12 = T1;                       // [cR,320] bf16 over T1+S2 (diffconv packing)
  float* scores = (float*)(W + oDd);   // phase-0 scratch, dead before Dd use
  float *outacc = (float*)(W + oOut), *yb = (float*)(W + oY);
  u16 *r1b = (u16*)(W + oR1);
  float* zero = (float*)(W + oZero);
  float *degf = zero, *degb = zero + 2048;
  int *cntf = (int*)(zero + 4096), *cntb = cntf + 2048,
      *curf = cntb + 2048, *curb = curf + 2048;
  float* stat = (float*)(curb + 2048);
  int *rowf = (int*)(W + oRowf), *rowb = (int*)(W + oRowb);
  int *colf = (int*)(W + oColf), *colb = (int*)(W + oColb);
  float *wnf = (float*)(W + oWnf), *wnb = (float*)(W + oWnb);
  float* scsh = (float*)(W + oScSh);
  u16* wt   = (u16*)(W + oWT);
  u16 *wt123_0 = wt,            *wsk1pT = wt + 3 * 25600, *wdc = wsk1pT + 3 * 36864,
      *wds = wdc + 102400,      *wsk0 = wds + 51200,
      *wr1 = wsk0 + 40960 + 49152, *wr2 = wr1 + 131072;
  u16 *seb = (u16*)(W + oSeb), *teb = (u16*)(W + oTeb);
  float *W23 = (float*)(W + oW23), *W123 = (float*)(W + oW123), *Wskp = (float*)(W + oWskp);
  float *Bt0 = (float*)(W + oBt0), *Bt11 = (float*)(W + oBt11), *Bsk1 = (float*)(W + oBsk1);
  float *Bsum = (float*)(W + oBsum);

  auto g5u = [&](const u16* Aq, const u16* Bq, u16* Cq, const float* bias,
                 int M, int N, int K, int lda, int ldbt, int ldc,
                 long bA, long bB, long bC, int batch, int flags, int bpt = 0) {
    dim3 g(M / 128, (N + 159) / 160, batch);
    gemm_mfma<5, u16><<<g, 256, 0, stream>>>(Aq, Bq, Cq, bias, M, N, K, lda, ldbt, ldc, bA, bB, bC, flags, bpt);
  };
  auto g4f = [&](const u16* Aq, const u16* Bq, float* Cq, const float* bias,
                 int M, int N, int K, int lda, int ldbt, int ldc,
                 long bA, long bB, long bC, int batch, int flags) {
    dim3 g(M / 128, (N + 127) / 128, batch);
    gemm_mfma<4, float><<<g, 256, 0, stream>>>(Aq, Bq, Cq, bias, M, N, K, lda, ldbt, ldc, bA, bB, bC, flags, 0);
  };
  auto g4u = [&](const u16* Aq, const u16* Bq, u16* Cq, const float* bias,
                 int M, int N, int K, int lda, int ldbt, int ldc, int flags) {
    dim3 g(M / 128, (N + 127) / 128, 1);
    gemm_mfma<4, u16><<<g, 256, 0, stream>>>(Aq, Bq, Cq, bias, M, N, K, lda, ldbt, ldc, 0, 0, 0, flags, 0);
  };
  auto wcv = [&](const float* src, u16* dst, int K, int N) {
    wconvT<<<(int)(((long)K * N + 255) / 256), 256, 0, stream>>>(src, dst, K, N);
  };
  auto mms = [&](const float* Aq, const float* Bq, float* Cq, int M, int N, int K) {
    matmul_small<<<(M * N + 255) / 256, 256, 0, stream>>>(Aq, Bq, Cq, M, N, K);
  };

  // ---- phase 0a: composed chain weights ----
  mms(tW0 + 1L * 25600, tW0 + 2L * 25600, W23, 160, 160, 160);   // W23_0
  mms(tW0,              W23,              W123, 160, 160, 160);  // W123_0
  wcv(W123, wt123_0, 160, 160);
  btot_full<<<1, 160, 0, stream>>>(tb0, tb0 + 160, tb0 + 320, W23, tW0 + 2L * 25600, Bt0, 160);
  mms(tW1 + 1L * 36864, tW1 + 2L * 36864, W23, 192, 192, 192);   // W23_1
  mms(tW1,              W23,              W123, 192, 192, 192);  // W123_1
  mms(W123, skw1, Wskp, 192, 256, 192);                          // W123_1 @ skw1
  wcv(Wskp, wsk1pT, 192, 256);
  btot_last<<<1, 192, 0, stream>>>(tb1, tb1 + 192, tb1 + 384, W23, tW1 + 2L * 36864, Bt11, 192);
  bias_sk<<<1, 256, 0, stream>>>(Bt11, skw1, skb1, Bsk1);
  vadd2<<<1, 160, 0, stream>>>(dcb0, dsb0, Bsum, 160);

  // ---- phase 0b: fused weight transposes, CSR, encoder, adjacency ----
  {
    const long tot = 640L * 160 + 320L * 160 + 160L * 256 + 256L * 512 + 512L * 312;
    wconv_multi<<<(int)((tot + 255) / 256), 256, 0, stream>>>(
        dcw0, wdc, dsw0, wds, skw0, wsk0, rw1, wr1, rw2, wr2);
  }
  hipMemsetAsync(zero, 0, 6 * 2048 * 4 + 2 * 192 * 4, stream);
  edge_stats<<<cE / 256, 256, 0, stream>>>(srcI, dstI, ew, degf, degb, cntf, cntb);
  scan2<<<2, 256, 0, stream>>>(cntf, cntb, rowf, rowb);
  fill_csr<<<cE / 256, 256, 0, stream>>>(srcI, dstI, ew, degf, degb, rowf, rowb,
                                         curf, curb, colf, colb, wnf, wnb);
  encoder<<<cR / 8, 160, 0, stream>>>(x, enc_w, enc_b, node_emb, lw0, H0);

  cvt_f2bf<<<(cN * cHID + 255) / 256, 256, 0, stream>>>(src_emb, seb, (long)cN * cHID);
  cvt_f2bf<<<(cN * cHID + 255) / 256, 256, 0, stream>>>(tgt_emb, teb, (long)cN * cHID);
  g4f(seb, teb, scores, nullptr, cN, cN, cHID, cHID, cHID, cN, 0, 0, 0, 1, 0);
  relu_softmax_rows<<<cN, 256, 0, stream>>>(scores, adjb);

  const int PROP_GRID = 8 * 6 * cNCH;

  // ---- block 0 (c = 160): chain -> skip -> DENSE conv (into Dd) -> diffconv (ACC) -> BN ----
  {
    const int c = 160;
    const long NC = (long)cN * c;
    const int casGrid = (int)(((long)cB * cN * (c / 8) + 255) / 256);
    // composed synaptic chain: Hh = (S^3 H0) @ W123_0 + Bt0[t]
    cascade3_full<<<casGrid, 256, 0, stream>>>(H0, T1, c);
    g5u(T1, wt123_0, Hh, Bt0, cR, c, c, c, c, c, 0, 0, 0, 1, FLAG_BIAS, /*bpt=*/1);
    // skip (t=11)
    g4f(Hh + 11L * NC, wsk0, outacc, skb0, cN, cFF, c, c, c, cFF,
        (long)cT * NC, 0, (long)cN * cFF, cB, FLAG_BIAS);
    // dense conv first: Dd = x1@dsw1 + (dcb0+dsb0); Dd += x2@dsw2
    dim3 tg(cN / 64, (c + 63) / 64, cBT);
    transpose_bf16<<<tg, 256, 0, stream>>>(Hh, c, S2, cN, c, NC, NC);           // hT
    g5u(adjb, S2, T1, nullptr, cN, c, cN, cN, cN, c, 0, NC, NC, cBT, 0);        // x1 -> T1
    g5u(T1, wds, Dd, Bsum, cR, c, c, c, 320, c, 0, 0, 0, 1, FLAG_BIAS);         // Dd = x1@dsw1 + bsum
    transpose_bf16<<<tg, 256, 0, stream>>>(T1, c, S2, cN, c, NC, NC);           // x1T (hT dead)
    g5u(adjb, S2, T1, nullptr, cN, c, cN, cN, cN, c, 0, NC, NC, cBT, 0);        // x2 -> T1 (x1 dead)
    g5u(T1, wds + 160, Dd, nullptr, cR, c, c, c, 320, c, 0, 0, 0, 1, FLAG_ACC); // Dd += x2@dsw2
    // diffconv: pack [z1|z2], [z3|z4] into Z12 [cR,320]; two K=320 ACC GEMMs
    prop_gather_bt<<<PROP_GRID, 256, 0, stream>>>(Hh, 160, Z12, 320, rowf, colf, wnf);
    prop_gather_bt<<<PROP_GRID, 256, 0, stream>>>(Z12, 320, Z12 + 160, 320, rowf, colf, wnf);
    g5u(Z12, wdc, Dd, nullptr, cR, c, 320, 320, 640, c, 0, 0, 0, 1, FLAG_ACC);
    prop_gather_bt<<<PROP_GRID, 256, 0, stream>>>(Hh, 160, Z12, 320, rowb, colb, wnb);
    prop_gather_bt<<<PROP_GRID, 256, 0, stream>>>(Z12, 320, Z12 + 160, 320, rowb, colb, wnb);
    g5u(Z12, wdc + 320, Dd, nullptr, cR, c, 320, 320, 640, c, 0, 0, 0, 1, FLAG_ACC);
    // BN(Dd + H0) -> G1 (stride 192) + lw1
    bn_stats<<<512, c, 0, stream>>>(Dd, H0, stat, c);
    bn_finalize<<<1, c, 0, stream>>>(stat, ng0, nb0, scsh, c);
    bn_apply_concat<<<cR / 8, 192, 0, stream>>>(Dd, H0, scsh, lw1, G1);
  }

  // ---- block 1 (c = 192): composed chain+skip, only t=11 survives ----
  {
    const int c = 192;
    const int casGrid = (int)(((long)cB * cN * (c / 8) + 255) / 256);
    cascade3_last<<<casGrid, 256, 0, stream>>>(G1, S2, c);
    g4f(S2, wsk1pT, outacc, Bsk1, cB * cN, cFF, c, c, c, cFF,
        0, 0, 0, 1, FLAG_BIAS | FLAG_ACC | FLAG_RELU);
  }

  // ---- readout ----
  cvt_f2bf<<<(int)(((long)cB * cN * cFF + 255) / 256), 256, 0, stream>>>(outacc, S2, (long)cB * cN * cFF);
  g4u(S2, wr1, r1b, rb1, cB * cN, 2 * cFF, cFF, cFF, cFF, 2 * cFF, FLAG_BIAS | FLAG_RELU);
  g4f(r1b, wr2, yb, rb2, cB * cN, cHOR * cF, 2 * cFF, 2 * cFF, 2 * cFF, cHOR * cF,
      0, 0, 0, 1, FLAG_BIAS);
  final_transpose<<<(cB * cHOR * cN * cF) / 256, 256, 0, stream>>>(yb, outF);
}

// Round 13
// 1099.013 us; speedup vs baseline: 3.6660x; 1.0674x over previous
//
#include <hip/hip_runtime.h>

// ======================= types & helpers =======================
using u16 = unsigned short;
typedef short bf16x8 __attribute__((ext_vector_type(8)));
typedef float f32x4  __attribute__((ext_vector_type(4)));

__device__ __forceinline__ float bf2f(u16 u) { return __uint_as_float(((unsigned)u) << 16); }
__device__ __forceinline__ u16 f2bf(float f) {  // round-to-nearest-even
  unsigned u = __float_as_uint(f);
  return (u16)((u + 0x7FFFu + ((u >> 16) & 1u)) >> 16);
}
__device__ __forceinline__ float ldv(const float* p) { return *p; }
__device__ __forceinline__ float ldv(const u16* p)   { return bf2f(*p); }
__device__ __forceinline__ void  stv(float* p, float v) { *p = v; }
__device__ __forceinline__ void  stv(u16* p, float v)   { *p = f2bf(v); }

// ======================= problem constants =======================
constexpr int cB = 4, cT = 12, cN = 2048, cF = 26;
constexpr int cHID = 128, cLF = 32, cFF = 256, cHOR = 12;
constexpr int cE = 16384;
constexpr int cR = cB * cT * cN;   // 98304
constexpr int cBT = cB * cT;       // 48
constexpr float cALPHA = 0.9f, cBETA = 0.8f, cEPS = 1e-5f;

#define FLAG_ACC  1
#define FLAG_BIAS 2
#define FLAG_RELU 4

// ======================= MFMA bf16 GEMM (gload_lds + dbuf + XCD swizzle) ==========
// C[m,n] = sum_k A[m,k] * BT[n,k]  (+bias) (+C) (relu)
// A: bf16 [M,K] lda ; BT: bf16 [N,K] ldbt. M%128==0, K%32==0, lda/ldbt%8==0; N guarded
// (OOB B rows clamp to N-1; their output columns are never stored).
// biasPerT: bias is [cT][N]; row block m0 uses bias row (m0/2048)%cT (rows = (b,t,n)).
template <int NF, typename TC>
__global__ __launch_bounds__(256)
void gemm_mfma(const u16* __restrict__ A, const u16* __restrict__ BT,
               TC* __restrict__ C, const float* __restrict__ bias,
               int M, int N, int K, int lda, int ldbt, int ldc,
               long batchA, long batchB, long batchC, int flags, int biasPerT)
{
  constexpr int TN = NF * 32;
  constexpr int ROWS = 128 + TN;        // A rows then BT rows
  constexpr int NINST = ROWS / 16;      // gload_lds wave-instrs per K-step
  constexpr int NPW = (NINST + 3) / 4;  // max instrs per wave
  __shared__ __align__(16) u16 S[2][ROWS * 32];

  // bijective XCD-aware block remap
  const long gx = gridDim.x, gy = gridDim.y;
  const long total = gx * gy * (long)gridDim.z;
  long lid = blockIdx.x + gx * (blockIdx.y + gy * (long)blockIdx.z);
  { const long q = total >> 3, r = total & 7, xcd = lid & 7, j = lid >> 3;
    lid = (xcd < r ? xcd * (q + 1) : r * (q + 1) + (xcd - r) * q) + j; }
  const int bz = (int)(lid / (gx * gy));
  const long rem = lid % (gx * gy);
  const int by = (int)(rem / gx), bx = (int)(rem % gx);

  A  += (long)bz * batchA;
  BT += (long)bz * batchB;
  C  += (long)bz * batchC;
  const int tid = threadIdx.x;
  const int lane = tid & 63, wid = tid >> 6;
  const int wm = wid & 1, wn = wid >> 1;
  const int m0 = bx * 128, n0 = by * TN;
  const int fr = lane & 15, kh = lane >> 4;   // frag row / k-half
  const int nwi = (NINST - wid + 3) / 4;      // this wave's instr count

  // hoisted per-lane staging pointers (advance +32 elts per K-step)
  const u16* gp[NPW];
#pragma unroll
  for (int i = 0; i < NPW; ++i) {
    const int s = wid + i * 4;
    if (s < NINST) {
      const int slot = s * 64 + lane;    // linear 16B LDS slot
      const int row = slot >> 2, q = slot & 3;
      if (row < 128) {
        gp[i] = A + (long)(m0 + row) * lda + q * 8;
      } else {
        const int n = min(n0 + row - 128, N - 1);
        gp[i] = BT + (long)n * ldbt + q * 8;
      }
    } else {
      gp[i] = A;
    }
  }

  f32x4 acc[4][NF];
#pragma unroll
  for (int i = 0; i < 4; ++i)
#pragma unroll
    for (int j = 0; j < NF; ++j) acc[i][j] = f32x4{0.f, 0.f, 0.f, 0.f};

  auto STAGE = [&](int buf) {
#pragma unroll
    for (int i = 0; i < NPW; ++i) {
      if (i < nwi) {
        const int s = wid + i * 4;
        __builtin_amdgcn_global_load_lds(
            (const __attribute__((address_space(1))) unsigned int*)gp[i],
            (__attribute__((address_space(3))) unsigned int*)&S[buf][s * 512],
            16, 0, 0);
        gp[i] += 32;
      }
    }
  };

  STAGE(0);
  int cur = 0;
  for (int k0 = 0; k0 < K; k0 += 32) {
    __syncthreads();                 // drains vmcnt -> S[cur] ready; prior reads of S[cur^1] done
    if (k0 + 32 < K) STAGE(cur ^ 1);
    bf16x8 af[4];
#pragma unroll
    for (int mf = 0; mf < 4; ++mf)
      af[mf] = *(const bf16x8*)&S[cur][(wm * 64 + mf * 16 + fr) * 32 + kh * 8];
#pragma unroll
    for (int nf = 0; nf < NF; ++nf) {
      const bf16x8 bfr =
          *(const bf16x8*)&S[cur][(128 + wn * NF * 16 + nf * 16 + fr) * 32 + kh * 8];
#pragma unroll
      for (int mf = 0; mf < 4; ++mf)
        acc[mf][nf] = __builtin_amdgcn_mfma_f32_16x16x32_bf16(af[mf], bfr, acc[mf][nf], 0, 0, 0);
    }
    cur ^= 1;
  }

  const float* bp = bias;
  if (biasPerT && bias) bp = bias + (long)((m0 >> 11) % cT) * N;

#pragma unroll
  for (int mf = 0; mf < 4; ++mf)
#pragma unroll
    for (int nf = 0; nf < NF; ++nf) {
      const int gn = n0 + wn * NF * 16 + nf * 16 + fr;
      if (gn < N) {
#pragma unroll
        for (int r = 0; r < 4; ++r) {
          const long gm = m0 + wm * 64 + mf * 16 + kh * 4 + r;   // C/D: row=(lane>>4)*4+r
          float v = acc[mf][nf][r];
          if (flags & FLAG_BIAS) v += bp[gn];
          if (flags & FLAG_ACC)  v += ldv(&C[gm * ldc + gn]);
          if (flags & FLAG_RELU) v = fmaxf(v, 0.f);
          stv(&C[gm * ldc + gn], v);
        }
      }
    }
}

// ======================= small f32 matmul: C[M,N] = A[M,K] @ B[K,N] ==========
__global__ __launch_bounds__(256)
void matmul_small(const float* __restrict__ A, const float* __restrict__ B,
                  float* __restrict__ C, int M, int N, int K)
{
  const int idx = blockIdx.x * 256 + threadIdx.x;
  if (idx >= M * N) return;
  const int m = idx / N, n = idx % N;
  float acc = 0.f;
  for (int k = 0; k < K; ++k) acc = fmaf(A[m * K + k], B[k * N + n], acc);
  C[idx] = acc;
}

// ======================= LIF composed coefficients ==========
__device__ __forceinline__ void lif_coeffs(float* k1, float* k2, float* k3)
{
  float ap = 1.f;
  for (int m = 0; m < cT; ++m) {
    k1[m] = (m ? cBETA * k1[m - 1] : 0.f) + ap;   // k1[m] = sum a^i b^(m-i)
    ap *= cALPHA;
  }
  for (int m = 0; m < cT; ++m) { float s = 0.f; for (int i = 0; i <= m; ++i) s += k1[i] * k1[m - i]; k2[m] = s; }
  for (int m = 0; m < cT; ++m) { float s = 0.f; for (int i = 0; i <= m; ++i) s += k2[i] * k1[m - i]; k3[m] = s; }
}

// Btot[t][ch] = C3[t]*(b1@W23)[ch] + C2[t]*(b2@W3)[ch] + C1[t]*b3[ch]; Ci = cumsum(ki)
__global__ void btot_full(const float* __restrict__ b1, const float* __restrict__ b2,
                          const float* __restrict__ b3, const float* __restrict__ W23,
                          const float* __restrict__ W3, float* __restrict__ Btot, int c)
{
  const int ch = threadIdx.x;
  if (ch >= c) return;
  float k1[cT], k2[cT], k3[cT]; lif_coeffs(k1, k2, k3);
  float v1 = 0.f, v2 = 0.f;
  for (int j = 0; j < c; ++j) { v1 = fmaf(b1[j], W23[j * c + ch], v1); v2 = fmaf(b2[j], W3[j * c + ch], v2); }
  float C1 = 0.f, C2 = 0.f, C3 = 0.f;
  for (int t = 0; t < cT; ++t) {
    C1 += k1[t]; C2 += k2[t]; C3 += k3[t];
    Btot[t * c + ch] = C3 * v1 + C2 * v2 + C1 * b3[ch];
  }
}

// last-t-only variant -> out[c]
__global__ void btot_last(const float* __restrict__ b1, const float* __restrict__ b2,
                          const float* __restrict__ b3, const float* __restrict__ W23,
                          const float* __restrict__ W3, float* __restrict__ out, int c)
{
  const int ch = threadIdx.x;
  if (ch >= c) return;
  float k1[cT], k2[cT], k3[cT]; lif_coeffs(k1, k2, k3);
  float v1 = 0.f, v2 = 0.f;
  for (int j = 0; j < c; ++j) { v1 = fmaf(b1[j], W23[j * c + ch], v1); v2 = fmaf(b2[j], W3[j * c + ch], v2); }
  float C1 = 0.f, C2 = 0.f, C3 = 0.f;
  for (int t = 0; t < cT; ++t) { C1 += k1[t]; C2 += k2[t]; C3 += k3[t]; }
  out[ch] = C3 * v1 + C2 * v2 + C1 * b3[ch];
}

// bias1p[n] = skb1[n] + sum_k Btot11[k] * skw1[k][n]
__global__ void bias_sk(const float* __restrict__ Btot11, const float* __restrict__ skw1,
                        const float* __restrict__ skb1, float* __restrict__ out)
{
  const int n = threadIdx.x;
  float acc = skb1[n];
  for (int k = 0; k < 192; ++k) acc = fmaf(Btot11[k], skw1[k * 256 + n], acc);
  out[n] = acc;
}

__global__ void vadd2(const float* __restrict__ a, const float* __restrict__ b,
                      float* __restrict__ o, int n)
{
  const int i = threadIdx.x;
  if (i < n) o[i] = a[i] + b[i];
}

// ======================= 3x cascaded LIF (= S^3), full sequence out ==========
__global__ __launch_bounds__(256)
void cascade3_full(const u16* __restrict__ in, u16* __restrict__ out, int c)
{
  const int c8 = c >> 3;
  const long total = (long)cB * cN * c8;
  const long idx = (long)blockIdx.x * 256 + threadIdx.x;
  if (idx >= total) return;
  const long nc = (long)cN * c;
  const int b = (int)(idx / ((long)cN * c8));
  const long rest = (idx % ((long)cN * c8)) * 8;
  const u16* p = in  + (long)b * cT * nc + rest;
  u16*       q = out + (long)b * cT * nc + rest;
  float s1[8] = {}, m1[8] = {}, s2[8] = {}, m2[8] = {}, s3[8] = {}, m3[8] = {};
#pragma unroll
  for (int t = 0; t < cT; ++t) {
    const bf16x8 v = *(const bf16x8*)&p[(long)t * nc];
    u16 o[8];
#pragma unroll
    for (int e = 0; e < 8; ++e) {
      s1[e] = fmaf(cALPHA, s1[e], bf2f((u16)v[e])); m1[e] = fmaf(cBETA, m1[e], s1[e]);
      s2[e] = fmaf(cALPHA, s2[e], m1[e]);           m2[e] = fmaf(cBETA, m2[e], s2[e]);
      s3[e] = fmaf(cALPHA, s3[e], m2[e]);           m3[e] = fmaf(cBETA, m3[e], s3[e]);
      o[e] = f2bf(m3[e]);
    }
    *(bf16x8*)&q[(long)t * nc] = *(const bf16x8*)o;
  }
}

// same, but store only the t=T-1 slice into out [cB*cN, c]
__global__ __launch_bounds__(256)
void cascade3_last(const u16* __restrict__ in, u16* __restrict__ out, int c)
{
  const int c8 = c >> 3;
  const long total = (long)cB * cN * c8;
  const long idx = (long)blockIdx.x * 256 + threadIdx.x;
  if (idx >= total) return;
  const long nc = (long)cN * c;
  const int b = (int)(idx / ((long)cN * c8));
  const long rest = (idx % ((long)cN * c8)) * 8;
  const u16* p = in + (long)b * cT * nc + rest;
  float s1[8] = {}, m1[8] = {}, s2[8] = {}, m2[8] = {}, s3[8] = {}, m3[8] = {};
#pragma unroll
  for (int t = 0; t < cT; ++t) {
    const bf16x8 v = *(const bf16x8*)&p[(long)t * nc];
#pragma unroll
    for (int e = 0; e < 8; ++e) {
      s1[e] = fmaf(cALPHA, s1[e], bf2f((u16)v[e])); m1[e] = fmaf(cBETA, m1[e], s1[e]);
      s2[e] = fmaf(cALPHA, s2[e], m1[e]);           m2[e] = fmaf(cBETA, m2[e], s2[e]);
      s3[e] = fmaf(cALPHA, s3[e], m2[e]);           m3[e] = fmaf(cBETA, m3[e], s3[e]);
    }
  }
  u16 o[8];
#pragma unroll
  for (int e = 0; e < 8; ++e) o[e] = f2bf(m3[e]);
  *(bf16x8*)&out[(long)b * nc + rest] = *(const bf16x8*)o;
}

// ======================= weight convert + transpose (f32 [K,N] -> bf16 [N,K]) ==========
__global__ __launch_bounds__(256)
void wconvT(const float* __restrict__ w, u16* __restrict__ wt, int K, int N)
{
  const long idx = (long)blockIdx.x * 256 + threadIdx.x;
  if (idx >= (long)K * N) return;
  const int n = (int)(idx / K), k = (int)(idx % K);
  wt[idx] = f2bf(w[(long)k * N + n]);
}

// pack diffconv+denseconv weights: W1/W2 [160][480] bf16
// W1[n][k] = k<320 ? dcw[k][n]     : dsw[k-320][n]
// W2[n][k] = k<320 ? dcw[320+k][n] : dsw[160+(k-320)][n]
__global__ __launch_bounds__(256)
void wpack_dcds(const float* __restrict__ dcw, const float* __restrict__ dsw,
                u16* __restrict__ W1, u16* __restrict__ W2)
{
  const int idx = blockIdx.x * 256 + threadIdx.x;
  if (idx >= 2 * 160 * 480) return;
  const int which = idx / (160 * 480);
  const int l = idx % (160 * 480);
  const int n = l / 480, k = l % 480;
  float v;
  if (k < 320) v = dcw[(long)(which * 320 + k) * 160 + n];
  else         v = dsw[(long)(which * 160 + (k - 320)) * 160 + n];
  (which ? W2 : W1)[l] = f2bf(v);
}

// 3 independent transposes fused (skw0 160x256, rw1 256x512, rw2 512x312)
__global__ __launch_bounds__(256)
void wconv_multi(const float* __restrict__ w2, u16* __restrict__ d2,
                 const float* __restrict__ w3, u16* __restrict__ d3,
                 const float* __restrict__ w4, u16* __restrict__ d4)
{
  const long s2 = 160L * 256, s3 = s2 + 256L * 512, s4 = s3 + 512L * 312;
  long idx = (long)blockIdx.x * 256 + threadIdx.x;
  const float* w; u16* d; int K, N; long base;
  if      (idx < s2) { w = w2; d = d2; K = 160; N = 256; base = 0;  }
  else if (idx < s3) { w = w3; d = d3; K = 256; N = 512; base = s2; }
  else if (idx < s4) { w = w4; d = d4; K = 512; N = 312; base = s3; }
  else return;
  const long l = idx - base;
  const int n = (int)(l / K), k = (int)(l % K);
  d[l] = f2bf(w[(long)k * N + n]);
}

// ======================= tiled bf16 transpose: in [R,Cc] ld ldi -> out [Cc,R], batched ====
__global__ __launch_bounds__(256)
void transpose_bf16(const u16* __restrict__ in, int ldi, u16* __restrict__ out,
                    int R, int Cc, long batchIn, long batchOut)
{
  __shared__ u16 t[64][65];
  in  += (long)blockIdx.z * batchIn;
  out += (long)blockIdx.z * batchOut;
  const int tid = threadIdx.x;
  const int r0 = blockIdx.x * 64, c0 = blockIdx.y * 64;
  for (int i = tid; i < 64 * 64; i += 256) {
    const int r = i >> 6, c = i & 63;
    t[r][c] = (r0 + r < R && c0 + c < Cc) ? in[(long)(r0 + r) * ldi + c0 + c] : (u16)0;
  }
  __syncthreads();
  for (int i = tid; i < 64 * 64; i += 256) {
    const int c = i >> 6, r = i & 63;
    if (c0 + c < Cc && r0 + r < R) out[(long)(c0 + c) * R + r0 + r] = t[r][c];
  }
}

// convert src_emb and tgt_emb in one dispatch
__global__ __launch_bounds__(256)
void cvt2_f2bf(const float* __restrict__ a, u16* __restrict__ oa,
               const float* __restrict__ b, u16* __restrict__ ob, long n)
{
  const long idx = (long)blockIdx.x * 256 + threadIdx.x;
  if (idx < n) oa[idx] = f2bf(a[idx]);
  else if (idx < 2 * n) ob[idx - n] = f2bf(b[idx - n]);
}

// ======================= graph preprocessing (CSR build) =======================
__global__ __launch_bounds__(256)
void edge_stats(const int* __restrict__ s, const int* __restrict__ d,
                const float* __restrict__ ew, float* degf, float* degb,
                int* cntf, int* cntb)
{
  const int e = blockIdx.x * 256 + threadIdx.x;
  atomicAdd(&degf[d[e]], ew[e]);
  atomicAdd(&degb[s[e]], ew[e]);
  atomicAdd(&cntf[d[e]], 1);
  atomicAdd(&cntb[s[e]], 1);
}

__global__ __launch_bounds__(256)
void scan2(const int* __restrict__ cf, const int* __restrict__ cb,
           int* __restrict__ rf, int* __restrict__ rb)
{
  const int* c = blockIdx.x ? cb : cf;
  int* r       = blockIdx.x ? rb : rf;
  __shared__ int part[256];
  const int t = threadIdx.x, base = t * 8;
  int loc[8]; int s = 0;
#pragma unroll
  for (int i = 0; i < 8; ++i) { loc[i] = c[base + i]; s += loc[i]; }
  part[t] = s; __syncthreads();
  if (t == 0) {
    int run = 0;
    for (int i = 0; i < 256; ++i) { const int v = part[i]; part[i] = run; run += v; }
    r[2048] = run;
  }
  __syncthreads();
  int run = part[t];
#pragma unroll
  for (int i = 0; i < 8; ++i) { r[base + i] = run; run += loc[i]; }
}

__global__ __launch_bounds__(256)
void fill_csr(const int* __restrict__ s, const int* __restrict__ d,
              const float* __restrict__ ew,
              const float* __restrict__ degf, const float* __restrict__ degb,
              const int* __restrict__ rowf, const int* __restrict__ rowb,
              int* curf, int* curb,
              int* __restrict__ colf, int* __restrict__ colb,
              float* __restrict__ wnf, float* __restrict__ wnb)
{
  const int e = blockIdx.x * 256 + threadIdx.x;
  const int si = s[e], di = d[e];
  const float w = ew[e];
  const int p = rowf[di] + atomicAdd(&curf[di], 1);
  colf[p] = si; wnf[p] = w / fmaxf(degf[di], 1e-6f);
  const int q = rowb[si] + atomicAdd(&curb[si], 1);
  colb[q] = di; wnb[q] = w / fmaxf(degb[si], 1e-6f);
}

// ======================= diffusion step, L2-sliced: one bt per block ==========
constexpr int cNPB = 12;                       // nodes per block
constexpr int cNCH = (cN + cNPB - 1) / cNPB;   // 171 chunks
__global__ __launch_bounds__(256)
void prop_gather_bt(const u16* __restrict__ x, int ldx, u16* __restrict__ y, int ldy,
                    const int* __restrict__ rowptr, const int* __restrict__ col,
                    const float* __restrict__ w)
{
  const int lid = blockIdx.x;                  // 0 .. 8*6*cNCH-1
  const int xcd = lid & 7, j = lid >> 3;
  const int bt = xcd * 6 + (j % 6);            // 6 bt per XCD
  const int chunk = j / 6;
  const int item = threadIdx.x;                // (node_i, ch8)
  if (item >= cNPB * 20) return;
  const int n = chunk * cNPB + item / 20;
  if (n >= cN) return;
  const int ch = (item % 20) * 8;
  const int beg = rowptr[n], end = rowptr[n + 1];
  const u16* xb = x + (long)bt * cN * ldx + ch;
  float acc[8] = {};
  int jj = beg;
  for (; jj + 1 < end; jj += 2) {
    const int c0 = col[jj], c1 = col[jj + 1];
    const float w0 = w[jj], w1 = w[jj + 1];
    const bf16x8 v0 = *(const bf16x8*)&xb[(long)c0 * ldx];
    const bf16x8 v1 = *(const bf16x8*)&xb[(long)c1 * ldx];
#pragma unroll
    for (int q = 0; q < 8; ++q) {
      acc[q] = fmaf(w0, bf2f((u16)v0[q]), acc[q]);
      acc[q] = fmaf(w1, bf2f((u16)v1[q]), acc[q]);
    }
  }
  if (jj < end) {
    const float w0 = w[jj];
    const bf16x8 v0 = *(const bf16x8*)&xb[(long)col[jj] * ldx];
#pragma unroll
    for (int q = 0; q < 8; ++q) acc[q] = fmaf(w0, bf2f((u16)v0[q]), acc[q]);
  }
  u16 o[8];
#pragma unroll
  for (int q = 0; q < 8; ++q) o[q] = f2bf(acc[q]);
  *(bf16x8*)&y[((long)bt * cN + n) * ldy + ch] = *(const bf16x8*)o;
}

// ======================= encoder =======================
__global__ __launch_bounds__(160)
void encoder(const float* __restrict__ x, const float* __restrict__ ew_,
             const float* __restrict__ eb, const float* __restrict__ ne,
             const float* __restrict__ lw, u16* __restrict__ h)
{
  __shared__ float xs[cF];
  const int tid = threadIdx.x;
  const long r0 = (long)blockIdx.x * 8;
  for (long row = r0; row < r0 + 8; ++row) {
    if (tid < cF) xs[tid] = x[row * cF + tid];
    __syncthreads();
    const int n = (int)(row % cN);
    float v;
    if (tid < cHID) {
      float acc = eb[tid] + ne[(long)n * cHID + tid];
#pragma unroll
      for (int f = 0; f < cF; ++f) acc = fmaf(xs[f], ew_[f * cHID + tid], acc);
      v = acc;
    } else {
      v = lw[(long)n * cLF + (tid - cHID)];
    }
    h[row * 160 + tid] = f2bf(v);
    __syncthreads();
  }
}

// ======================= adjacency: row softmax of relu(scores) ==========
__global__ __launch_bounds__(256)
void relu_softmax_rows(const float* __restrict__ sc, u16* __restrict__ adj)
{
  const int row = blockIdx.x, tid = threadIdx.x;
  const float* p = sc + (long)row * cN;
  __shared__ float red[256];
  float lv[8];
  float mx = 0.f;   // relu => all >= 0
#pragma unroll
  for (int i = 0; i < 8; ++i) {
    const float v = fmaxf(p[tid + i * 256], 0.f);
    lv[i] = v; mx = fmaxf(mx, v);
  }
  red[tid] = mx; __syncthreads();
  for (int s = 128; s > 0; s >>= 1) { if (tid < s) red[tid] = fmaxf(red[tid], red[tid + s]); __syncthreads(); }
  const float m = red[0]; __syncthreads();
  float sum = 0.f;
#pragma unroll
  for (int i = 0; i < 8; ++i) { lv[i] = __expf(lv[i] - m); sum += lv[i]; }
  red[tid] = sum; __syncthreads();
  for (int s = 128; s > 0; s >>= 1) { if (tid < s) red[tid] += red[tid + s]; __syncthreads(); }
  const float inv = 1.f / red[0]; __syncthreads();
#pragma unroll
  for (int i = 0; i < 8; ++i) adj[(long)row * cN + tid + i * 256] = f2bf(lv[i] * inv);
}

// ======================= batch norm (bf16 inputs) =======================
__global__ __launch_bounds__(256)
void bn_stats(const u16* __restrict__ d, const u16* __restrict__ res,
              float* __restrict__ stat, int c)
{
  const int ch = threadIdx.x;
  const long r0 = (long)blockIdx.x * (cR / 512);
  float s = 0.f, s2 = 0.f;
  for (int i = 0; i < cR / 512; ++i) {
    const float v = bf2f(d[(r0 + i) * c + ch]) + bf2f(res[(r0 + i) * c + ch]);
    s += v; s2 = fmaf(v, v, s2);
  }
  atomicAdd(&stat[ch], s);
  atomicAdd(&stat[c + ch], s2);
}

__global__ __launch_bounds__(256)
void bn_finalize(const float* __restrict__ stat, const float* __restrict__ g,
                 const float* __restrict__ b, float* __restrict__ scsh, int c)
{
  const int ch = threadIdx.x;
  const float mu = stat[ch] / cR;
  const float var = stat[c + ch] / cR - mu * mu;
  const float sc = g[ch] * rsqrtf(var + cEPS);
  scsh[ch] = sc;
  scsh[c + ch] = fmaf(-mu, sc, b[ch]);
}

__global__ __launch_bounds__(192)
void bn_apply_concat(const u16* __restrict__ d, const u16* __restrict__ res,
                     const float* __restrict__ scsh, const float* __restrict__ lw,
                     u16* __restrict__ out)
{
  const int tid = threadIdx.x;
  const long r0 = (long)blockIdx.x * 8;
  for (long row = r0; row < r0 + 8; ++row) {
    const int n = (int)(row % cN);
    float v;
    if (tid < 160) v = fmaf(bf2f(d[row * 160 + tid]) + bf2f(res[row * 160 + tid]),
                            scsh[tid], scsh[160 + tid]);
    else           v = lw[(long)n * cLF + (tid - 160)];
    out[row * 192 + tid] = f2bf(v);
  }
}

// ======================= output transpose (bf16 in, f32 out) =======================
__global__ __launch_bounds__(256)
void final_transpose(const u16* __restrict__ y, float* __restrict__ out)
{
  const long idx = (long)blockIdx.x * 256 + threadIdx.x;
  const int f = (int)(idx % cF);
  long t = idx / cF;
  const int n = (int)(t % cN); t /= cN;
  const int hor = (int)(t % cHOR);
  const int b = (int)(t / cHOR);
  out[idx] = bf2f(y[((long)b * cN + n) * (cHOR * cF) + hor * cF + f]);
}

__global__ __launch_bounds__(256)
void fill_f32(float* __restrict__ out, long n, float val)
{
  const long idx = (long)blockIdx.x * 256 + threadIdx.x;
  if (idx < n) out[idx] = val;
}

// ======================= host orchestration =======================
extern "C" void kernel_launch(void* const* d_in, const int* in_sizes, int n_in,
                              void* d_out, int out_size, void* d_ws, size_t ws_size,
                              hipStream_t stream)
{
  float* outF = (float*)d_out;
  const long outN = out_size;
  if (n_in < 34) { fill_f32<<<(int)((outN + 255) / 256), 256, 0, stream>>>(outF, outN, 500.f); return; }
  if (in_sizes[0] != cB * cT * cN * cF || in_sizes[1] != 2 * cE || in_sizes[9] != 3 * 160 * 160) {
    fill_f32<<<(int)((outN + 255) / 256), 256, 0, stream>>>(outF, outN, 700.f); return;
  }

  const float* x        = (const float*)d_in[0];
  const int*   eidx     = (const int*)d_in[1];
  const float* ew       = (const float*)d_in[2];
  const float* enc_w    = (const float*)d_in[3];
  const float* enc_b    = (const float*)d_in[4];
  const float* node_emb = (const float*)d_in[5];
  const float* src_emb  = (const float*)d_in[6];
  const float* tgt_emb  = (const float*)d_in[7];
  const float* lw0  = (const float*)d_in[8];
  const float* tW0  = (const float*)d_in[9];
  const float* tb0  = (const float*)d_in[10];
  const float* dcw0 = (const float*)d_in[11];
  const float* dcb0 = (const float*)d_in[12];
  const float* dsw0 = (const float*)d_in[13];
  const float* dsb0 = (const float*)d_in[14];
  const float* skw0 = (const float*)d_in[15];
  const float* skb0 = (const float*)d_in[16];
  const float* ng0  = (const float*)d_in[17];
  const float* nb0  = (const float*)d_in[18];
  const float* lw1  = (const float*)d_in[19];
  const float* tW1  = (const float*)d_in[20];
  const float* tb1  = (const float*)d_in[21];
  // d_in[22..25, 28..29] feed only block-1's post-skip h (never read) -> dead.
  const float* skw1 = (const float*)d_in[26];
  const float* skb1 = (const float*)d_in[27];
  const float* rw1  = (const float*)d_in[30];
  const float* rb1  = (const float*)d_in[31];
  const float* rw2  = (const float*)d_in[32];
  const float* rb2  = (const float*)d_in[33];
  const int* srcI = eidx;
  const int* dstI = eidx + cE;

  // ---- workspace layout ----
  char* W = (char*)d_ws;
  size_t off = 0;
  auto A8 = [&](size_t bytes) { size_t r = off; off = (off + bytes + 255) & ~(size_t)255; return r; };
  const size_t oH0 = A8((size_t)cR * 160 * 2);   // res, bf16
  const size_t oHh = A8((size_t)cR * 160 * 2);   // chain h; G1 [cR,192] = Hh + PK head
  const size_t oPK = A8((size_t)cR * 480 * 2);   // pack [z|z|x], 94.5 MB (scores/r1/yb alias)
  const size_t oSx = A8((size_t)cR * 160 * 2);   // cascade out -> hT -> x1T -> block1 last
  const size_t oDd = A8((size_t)cR * 160 * 2);   // bf16 accumulator
  const size_t oAdj = A8((size_t)cN * cN * 2);
  const size_t oOut = A8((size_t)cB * cN * cFF * 2);       // bf16 skip acc (t=11)
  const size_t oZero = A8(6 * 2048 * 4 + 2 * 192 * 4);
  const size_t oRowf = A8(2049 * 4), oRowb = A8(2049 * 4);
  const size_t oColf = A8((size_t)cE * 4), oColb = A8((size_t)cE * 4);
  const size_t oWnf  = A8((size_t)cE * 4), oWnb  = A8((size_t)cE * 4);
  const size_t oScSh = A8(2 * 192 * 4);
  const size_t oWT   = A8((size_t)600000 * 2);   // bf16 weights
  const size_t oSeb  = A8((size_t)cN * cHID * 2);
  const size_t oTeb  = A8((size_t)cN * cHID * 2);
  const size_t oW23  = A8(192 * 192 * 4);
  const size_t oW123 = A8(192 * 192 * 4);
  const size_t oWskp = A8(192 * 256 * 4);
  const size_t oBt0  = A8(cT * 160 * 4);
  const size_t oBt11 = A8(192 * 4);
  const size_t oBsk1 = A8(256 * 4);
  const size_t oBsum = A8(160 * 4);
  if (off > ws_size) {
    fill_f32<<<(int)((outN + 255) / 256), 256, 0, stream>>>(outF, outN, 300.f);
    return;
  }

  u16 *H0 = (u16*)(W + oH0), *Hh = (u16*)(W + oHh), *PK = (u16*)(W + oPK),
      *Sx = (u16*)(W + oSx), *Dd = (u16*)(W + oDd), *adjb = (u16*)(W + oAdj);
  u16 *G1 = Hh;                          // [cR,192] over Hh + PK head (post-BN only)
  float* scores = (float*)PK;            // phase-0 alias (16.8 MB)
  u16 *r1b = PK + 16L * 1024 * 1024;     // readout alias (PK dead then)
  u16 *ybB = PK + 28L * 1024 * 1024;
  u16 *outB = (u16*)(W + oOut);
  float* zero = (float*)(W + oZero);
  float *degf = zero, *degb = zero + 2048;
  int *cntf = (int*)(zero + 4096), *cntb = cntf + 2048,
      *curf = cntb + 2048, *curb = curf + 2048;
  float* stat = (float*)(curb + 2048);
  int *rowf = (int*)(W + oRowf), *rowb = (int*)(W + oRowb);
  int *colf = (int*)(W + oColf), *colb = (int*)(W + oColb);
  float *wnf = (float*)(W + oWnf), *wnb = (float*)(W + oWnb);
  float* scsh = (float*)(W + oScSh);
  u16* wt = (u16*)(W + oWT);
  u16 *wt123_0 = wt,               *wsk1pT = wt123_0 + 25600,
      *W1pk = wsk1pT + 49152,      *W2pk = W1pk + 76800,
      *wsk0 = W2pk + 76800,        *wr1 = wsk0 + 40960,
      *wr2 = wr1 + 131072;         // + 159744 ends < 600000
  u16 *seb = (u16*)(W + oSeb), *teb = (u16*)(W + oTeb);
  float *W23 = (float*)(W + oW23), *W123 = (float*)(W + oW123), *Wskp = (float*)(W + oWskp);
  float *Bt0 = (float*)(W + oBt0), *Bt11 = (float*)(W + oBt11), *Bsk1 = (float*)(W + oBsk1);
  float *Bsum = (float*)(W + oBsum);

  auto g5u = [&](const u16* Aq, const u16* Bq, u16* Cq, const float* bias,
                 int M, int N, int K, int lda, int ldbt, int ldc,
                 long bA, long bB, long bC, int batch, int flags, int bpt = 0) {
    dim3 g(M / 128, (N + 159) / 160, batch);
    gemm_mfma<5, u16><<<g, 256, 0, stream>>>(Aq, Bq, Cq, bias, M, N, K, lda, ldbt, ldc, bA, bB, bC, flags, bpt);
  };
  auto g4f = [&](const u16* Aq, const u16* Bq, float* Cq, const float* bias,
                 int M, int N, int K, int lda, int ldbt, int ldc,
                 long bA, long bB, long bC, int batch, int flags) {
    dim3 g(M / 128, (N + 127) / 128, batch);
    gemm_mfma<4, float><<<g, 256, 0, stream>>>(Aq, Bq, Cq, bias, M, N, K, lda, ldbt, ldc, bA, bB, bC, flags, 0);
  };
  auto g4u = [&](const u16* Aq, const u16* Bq, u16* Cq, const float* bias,
                 int M, int N, int K, int lda, int ldbt, int ldc,
                 long bA, long bB, long bC, int batch, int flags) {
    dim3 g(M / 128, (N + 127) / 128, batch);
    gemm_mfma<4, u16><<<g, 256, 0, stream>>>(Aq, Bq, Cq, bias, M, N, K, lda, ldbt, ldc, bA, bB, bC, flags, 0);
  };
  auto wcv = [&](const float* src, u16* dst, int K, int N) {
    wconvT<<<(int)(((long)K * N + 255) / 256), 256, 0, stream>>>(src, dst, K, N);
  };
  auto mms = [&](const float* Aq, const float* Bq, float* Cq, int M, int N, int K) {
    matmul_small<<<(M * N + 255) / 256, 256, 0, stream>>>(Aq, Bq, Cq, M, N, K);
  };

  // ---- phase 0a: composed chain weights ----
  mms(tW0 + 1L * 25600, tW0 + 2L * 25600, W23, 160, 160, 160);
  mms(tW0,              W23,              W123, 160, 160, 160);
  wcv(W123, wt123_0, 160, 160);
  btot_full<<<1, 160, 0, stream>>>(tb0, tb0 + 160, tb0 + 320, W23, tW0 + 2L * 25600, Bt0, 160);
  mms(tW1 + 1L * 36864, tW1 + 2L * 36864, W23, 192, 192, 192);
  mms(tW1,              W23,              W123, 192, 192, 192);
  mms(W123, skw1, Wskp, 192, 256, 192);
  wcv(Wskp, wsk1pT, 192, 256);
  btot_last<<<1, 192, 0, stream>>>(tb1, tb1 + 192, tb1 + 384, W23, tW1 + 2L * 36864, Bt11, 192);
  bias_sk<<<1, 256, 0, stream>>>(Bt11, skw1, skb1, Bsk1);
  vadd2<<<1, 160, 0, stream>>>(dcb0, dsb0, Bsum, 160);

  // ---- phase 0b: weight packs, CSR, encoder, adjacency ----
  wpack_dcds<<<(2 * 160 * 480 + 255) / 256, 256, 0, stream>>>(dcw0, dsw0, W1pk, W2pk);
  {
    const long tot = 160L * 256 + 256L * 512 + 512L * 312;
    wconv_multi<<<(int)((tot + 255) / 256), 256, 0, stream>>>(skw0, wsk0, rw1, wr1, rw2, wr2);
  }
  hipMemsetAsync(zero, 0, 6 * 2048 * 4 + 2 * 192 * 4, stream);
  edge_stats<<<cE / 256, 256, 0, stream>>>(srcI, dstI, ew, degf, degb, cntf, cntb);
  scan2<<<2, 256, 0, stream>>>(cntf, cntb, rowf, rowb);
  fill_csr<<<cE / 256, 256, 0, stream>>>(srcI, dstI, ew, degf, degb, rowf, rowb,
                                         curf, curb, colf, colb, wnf, wnb);
  encoder<<<cR / 8, 160, 0, stream>>>(x, enc_w, enc_b, node_emb, lw0, H0);

  cvt2_f2bf<<<(2 * cN * cHID + 255) / 256, 256, 0, stream>>>(src_emb, seb, tgt_emb, teb, (long)cN * cHID);
  g4f(seb, teb, scores, nullptr, cN, cN, cHID, cHID, cHID, cN, 0, 0, 0, 1, 0);
  relu_softmax_rows<<<cN, 256, 0, stream>>>(scores, adjb);

  const int PROP_GRID = 8 * 6 * cNCH;

  // ---- block 0 (c = 160) ----
  {
    const int c = 160;
    const long NC = (long)cN * c;
    const long PB = (long)cN * 480;      // per-bt pack stride
    const int casGrid = (int)(((long)cB * cN * (c / 8) + 255) / 256);
    // chain: Sx = S^3 H0 ; Hh = Sx @ W123_0 + Bt0[t]
    cascade3_full<<<casGrid, 256, 0, stream>>>(H0, Sx, c);
    g5u(Sx, wt123_0, Hh, Bt0, cR, c, c, c, c, c, 0, 0, 0, 1, FLAG_BIAS, /*bpt=*/1);
    // skip (t=11) -> bf16 outB
    g4u(Hh + 11L * NC, wsk0, outB, skb0, cN, cFF, c, c, c, cFF,
        (long)cT * NC, 0, (long)cN * cFF, cB, FLAG_BIAS);
    // hT -> Sx
    dim3 tg(cN / 64, (c + 63) / 64, cBT);
    transpose_bf16<<<tg, 256, 0, stream>>>(Hh, c, Sx, cN, c, NC, NC);
    // pack1 = [z1 | z2 | x1]
    prop_gather_bt<<<PROP_GRID, 256, 0, stream>>>(Hh, 160, PK, 480, rowf, colf, wnf);
    prop_gather_bt<<<PROP_GRID, 256, 0, stream>>>(PK, 480, PK + 160, 480, rowf, colf, wnf);
    g5u(adjb, Sx, PK + 320, nullptr, cN, c, cN, cN, cN, 480, 0, NC, PB, cBT, 0);   // x1
    // GEMM1: Dd = pack1 @ W1 + (dcb0+dsb0)
    g5u(PK, W1pk, Dd, Bsum, cR, c, 480, 480, 480, c, 0, 0, 0, 1, FLAG_BIAS);
    // x1T -> Sx (hT dead)
    transpose_bf16<<<tg, 256, 0, stream>>>(PK + 320, 480, Sx, cN, c, PB, NC);
    // pack2 = [z3 | z4 | x2]
    prop_gather_bt<<<PROP_GRID, 256, 0, stream>>>(Hh, 160, PK, 480, rowb, colb, wnb);
    prop_gather_bt<<<PROP_GRID, 256, 0, stream>>>(PK, 480, PK + 160, 480, rowb, colb, wnb);
    g5u(adjb, Sx, PK + 320, nullptr, cN, c, cN, cN, cN, 480, 0, NC, PB, cBT, 0);   // x2
    // GEMM2: Dd += pack2 @ W2
    g5u(PK, W2pk, Dd, nullptr, cR, c, 480, 480, 480, c, 0, 0, 0, 1, FLAG_ACC);
    // BN(Dd + H0) -> G1 (stride 192) + lw1
    bn_stats<<<512, c, 0, stream>>>(Dd, H0, stat, c);
    bn_finalize<<<1, c, 0, stream>>>(stat, ng0, nb0, scsh, c);
    bn_apply_concat<<<cR / 8, 192, 0, stream>>>(Dd, H0, scsh, lw1, G1);
  }

  // ---- block 1 (c = 192): composed chain+skip, only t=11 survives ----
  {
    const int c = 192;
    const int casGrid = (int)(((long)cB * cN * (c / 8) + 255) / 256);
    cascade3_last<<<casGrid, 256, 0, stream>>>(G1, Sx, c);
    g4u(Sx, wsk1pT, outB, Bsk1, cB * cN, cFF, c, c, c, cFF,
        0, 0, 0, 1, FLAG_BIAS | FLAG_ACC | FLAG_RELU);
  }

  // ---- readout (all bf16) ----
  g4u(outB, wr1, r1b, rb1, cB * cN, 2 * cFF, cFF, cFF, cFF, 2 * cFF,
      0, 0, 0, 1, FLAG_BIAS | FLAG_RELU);
  g4u(r1b, wr2, ybB, rb2, cB * cN, cHOR * cF, 2 * cFF, 2 * cFF, 2 * cFF, cHOR * cF,
      0, 0, 0, 1, FLAG_BIAS);
  final_transpose<<<(cB * cHOR * cN * cF) / 256, 256, 0, stream>>>(ybB, outF);
}

// Round 14
// 1020.099 us; speedup vs baseline: 3.9496x; 1.0774x over previous
//
#include <hip/hip_runtime.h>

// ======================= types & helpers =======================
using u16 = unsigned short;
typedef short bf16x8 __attribute__((ext_vector_type(8)));
typedef float f32x4  __attribute__((ext_vector_type(4)));

__device__ __forceinline__ float bf2f(u16 u) { return __uint_as_float(((unsigned)u) << 16); }
__device__ __forceinline__ u16 f2bf(float f) {  // round-to-nearest-even
  unsigned u = __float_as_uint(f);
  return (u16)((u + 0x7FFFu + ((u >> 16) & 1u)) >> 16);
}
__device__ __forceinline__ float ldv(const float* p) { return *p; }
__device__ __forceinline__ float ldv(const u16* p)   { return bf2f(*p); }
__device__ __forceinline__ void  stv(float* p, float v) { *p = v; }
__device__ __forceinline__ void  stv(u16* p, float v)   { *p = f2bf(v); }

// ======================= problem constants =======================
constexpr int cB = 4, cT = 12, cN = 2048, cF = 26;
constexpr int cHID = 128, cLF = 32, cFF = 256, cHOR = 12;
constexpr int cE = 16384;
constexpr int cR = cB * cT * cN;   // 98304
constexpr int cBT = cB * cT;       // 48
constexpr float cALPHA = 0.9f, cBETA = 0.8f, cEPS = 1e-5f;

#define FLAG_ACC  1
#define FLAG_BIAS 2
#define FLAG_RELU 4

// ======================= MFMA bf16 GEMM (gload_lds + dbuf + XCD swizzle) ==========
// C[m,n] = sum_k A[m,k] * BT[n,k]  (+bias) (+C) (relu)
// A: bf16 [M,K] lda ; BT: bf16 [N,K] ldbt. M%(WM*128)==0, K%32==0, lda/ldbt%8==0;
// N guarded (OOB B rows clamp to N-1; their output columns never stored).
// WM: tile = (WM*128) x (NF*32), WM*4 waves. WM=2 halves barrier-drains per output
// row and improves compute:stage ratio (round-14 lever for the latency floor).
// biasPerT: bias is [cT][N]; row block m0 uses bias row (m0/2048)%cT.
template <int WM, int NF, typename TC>
__global__ __launch_bounds__(WM * 256)
void gemm_mfma(const u16* __restrict__ A, const u16* __restrict__ BT,
               TC* __restrict__ C, const float* __restrict__ bias,
               int M, int N, int K, int lda, int ldbt, int ldc,
               long batchA, long batchB, long batchC, int flags, int biasPerT)
{
  constexpr int TN = NF * 32;
  constexpr int AROWS = WM * 128;
  constexpr int ROWS = AROWS + TN;      // A rows then BT rows
  constexpr int NINST = ROWS / 16;      // gload_lds wave-instrs per K-step
  constexpr int WAVES = WM * 4;
  constexpr int NPW = (NINST + WAVES - 1) / WAVES;
  __shared__ __align__(16) u16 S[2][ROWS * 32];

  // bijective XCD-aware block remap
  const long gx = gridDim.x, gy = gridDim.y;
  const long total = gx * gy * (long)gridDim.z;
  long lid = blockIdx.x + gx * (blockIdx.y + gy * (long)blockIdx.z);
  { const long q = total >> 3, r = total & 7, xcd = lid & 7, j = lid >> 3;
    lid = (xcd < r ? xcd * (q + 1) : r * (q + 1) + (xcd - r) * q) + j; }
  const int bz = (int)(lid / (gx * gy));
  const long rem = lid % (gx * gy);
  const int by = (int)(rem / gx), bx = (int)(rem % gx);

  A  += (long)bz * batchA;
  BT += (long)bz * batchB;
  C  += (long)bz * batchC;
  const int tid = threadIdx.x;
  const int lane = tid & 63, wid = tid >> 6;
  const int wm = wid & (2 * WM - 1);          // WM=1: wid&1 ; WM=2: wid&3
  const int wn = wid >> WM;                   // WM=1: >>1   ; WM=2: >>2
  const int m0 = bx * AROWS, n0 = by * TN;
  const int fr = lane & 15, kh = lane >> 4;   // frag row / k-half
  const int nwi = (NINST - wid + WAVES - 1) / WAVES;

  // hoisted per-lane staging pointers (advance +32 elts per K-step)
  const u16* gp[NPW];
#pragma unroll
  for (int i = 0; i < NPW; ++i) {
    const int s = wid + i * WAVES;
    if (s < NINST) {
      const int slot = s * 64 + lane;    // linear 16B LDS slot
      const int row = slot >> 2, q = slot & 3;
      if (row < AROWS) {
        gp[i] = A + (long)(m0 + row) * lda + q * 8;
      } else {
        const int n = min(n0 + row - AROWS, N - 1);
        gp[i] = BT + (long)n * ldbt + q * 8;
      }
    } else {
      gp[i] = A;
    }
  }

  f32x4 acc[4][NF];
#pragma unroll
  for (int i = 0; i < 4; ++i)
#pragma unroll
    for (int j = 0; j < NF; ++j) acc[i][j] = f32x4{0.f, 0.f, 0.f, 0.f};

  auto STAGE = [&](int buf) {
#pragma unroll
    for (int i = 0; i < NPW; ++i) {
      if (i < nwi) {
        const int s = wid + i * WAVES;
        __builtin_amdgcn_global_load_lds(
            (const __attribute__((address_space(1))) unsigned int*)gp[i],
            (__attribute__((address_space(3))) unsigned int*)&S[buf][s * 512],
            16, 0, 0);
        gp[i] += 32;
      }
    }
  };

  STAGE(0);
  int cur = 0;
  for (int k0 = 0; k0 < K; k0 += 32) {
    __syncthreads();                 // drains vmcnt -> S[cur] ready; prior reads of S[cur^1] done
    if (k0 + 32 < K) STAGE(cur ^ 1);
    bf16x8 af[4];
#pragma unroll
    for (int mf = 0; mf < 4; ++mf)
      af[mf] = *(const bf16x8*)&S[cur][(wm * 64 + mf * 16 + fr) * 32 + kh * 8];
#pragma unroll
    for (int nf = 0; nf < NF; ++nf) {
      const bf16x8 bfr =
          *(const bf16x8*)&S[cur][(AROWS + wn * NF * 16 + nf * 16 + fr) * 32 + kh * 8];
#pragma unroll
      for (int mf = 0; mf < 4; ++mf)
        acc[mf][nf] = __builtin_amdgcn_mfma_f32_16x16x32_bf16(af[mf], bfr, acc[mf][nf], 0, 0, 0);
    }
    cur ^= 1;
  }

  const float* bp = bias;
  if (biasPerT && bias) bp = bias + (long)((m0 >> 11) % cT) * N;

#pragma unroll
  for (int mf = 0; mf < 4; ++mf)
#pragma unroll
    for (int nf = 0; nf < NF; ++nf) {
      const int gn = n0 + wn * NF * 16 + nf * 16 + fr;
      if (gn < N) {
#pragma unroll
        for (int r = 0; r < 4; ++r) {
          const long gm = m0 + wm * 64 + mf * 16 + kh * 4 + r;   // C/D: row=(lane>>4)*4+r
          float v = acc[mf][nf][r];
          if (flags & FLAG_BIAS) v += bp[gn];
          if (flags & FLAG_ACC)  v += ldv(&C[gm * ldc + gn]);
          if (flags & FLAG_RELU) v = fmaxf(v, 0.f);
          stv(&C[gm * ldc + gn], v);
        }
      }
    }
}

// ======================= small f32 matmul: C[M,N] = A[M,K] @ B[K,N] ==========
__global__ __launch_bounds__(256)
void matmul_small(const float* __restrict__ A, const float* __restrict__ B,
                  float* __restrict__ C, int M, int N, int K)
{
  const int idx = blockIdx.x * 256 + threadIdx.x;
  if (idx >= M * N) return;
  const int m = idx / N, n = idx % N;
  float acc = 0.f;
  for (int k = 0; k < K; ++k) acc = fmaf(A[m * K + k], B[k * N + n], acc);
  C[idx] = acc;
}

// ======================= LIF composed coefficients ==========
__device__ __forceinline__ void lif_coeffs(float* k1, float* k2, float* k3)
{
  float ap = 1.f;
  for (int m = 0; m < cT; ++m) {
    k1[m] = (m ? cBETA * k1[m - 1] : 0.f) + ap;   // k1[m] = sum a^i b^(m-i)
    ap *= cALPHA;
  }
  for (int m = 0; m < cT; ++m) { float s = 0.f; for (int i = 0; i <= m; ++i) s += k1[i] * k1[m - i]; k2[m] = s; }
  for (int m = 0; m < cT; ++m) { float s = 0.f; for (int i = 0; i <= m; ++i) s += k2[i] * k1[m - i]; k3[m] = s; }
}

// Btot[t][ch] = C3[t]*(b1@W23)[ch] + C2[t]*(b2@W3)[ch] + C1[t]*b3[ch]; Ci = cumsum(ki)
__global__ void btot_full(const float* __restrict__ b1, const float* __restrict__ b2,
                          const float* __restrict__ b3, const float* __restrict__ W23,
                          const float* __restrict__ W3, float* __restrict__ Btot, int c)
{
  const int ch = threadIdx.x;
  if (ch >= c) return;
  float k1[cT], k2[cT], k3[cT]; lif_coeffs(k1, k2, k3);
  float v1 = 0.f, v2 = 0.f;
  for (int j = 0; j < c; ++j) { v1 = fmaf(b1[j], W23[j * c + ch], v1); v2 = fmaf(b2[j], W3[j * c + ch], v2); }
  float C1 = 0.f, C2 = 0.f, C3 = 0.f;
  for (int t = 0; t < cT; ++t) {
    C1 += k1[t]; C2 += k2[t]; C3 += k3[t];
    Btot[t * c + ch] = C3 * v1 + C2 * v2 + C1 * b3[ch];
  }
}

// last-t-only variant -> out[c]
__global__ void btot_last(const float* __restrict__ b1, const float* __restrict__ b2,
                          const float* __restrict__ b3, const float* __restrict__ W23,
                          const float* __restrict__ W3, float* __restrict__ out, int c)
{
  const int ch = threadIdx.x;
  if (ch >= c) return;
  float k1[cT], k2[cT], k3[cT]; lif_coeffs(k1, k2, k3);
  float v1 = 0.f, v2 = 0.f;
  for (int j = 0; j < c; ++j) { v1 = fmaf(b1[j], W23[j * c + ch], v1); v2 = fmaf(b2[j], W3[j * c + ch], v2); }
  float C1 = 0.f, C2 = 0.f, C3 = 0.f;
  for (int t = 0; t < cT; ++t) { C1 += k1[t]; C2 += k2[t]; C3 += k3[t]; }
  out[ch] = C3 * v1 + C2 * v2 + C1 * b3[ch];
}

// bias1p[n] = skb1[n] + sum_k Btot11[k] * skw1[k][n]
__global__ void bias_sk(const float* __restrict__ Btot11, const float* __restrict__ skw1,
                        const float* __restrict__ skb1, float* __restrict__ out)
{
  const int n = threadIdx.x;
  float acc = skb1[n];
  for (int k = 0; k < 192; ++k) acc = fmaf(Btot11[k], skw1[k * 256 + n], acc);
  out[n] = acc;
}

__global__ void vadd2(const float* __restrict__ a, const float* __restrict__ b,
                      float* __restrict__ o, int n)
{
  const int i = threadIdx.x;
  if (i < n) o[i] = a[i] + b[i];
}

// ======================= 3x cascaded LIF (= S^3), full sequence out ==========
__global__ __launch_bounds__(256)
void cascade3_full(const u16* __restrict__ in, u16* __restrict__ out, int c)
{
  const int c8 = c >> 3;
  const long total = (long)cB * cN * c8;
  const long idx = (long)blockIdx.x * 256 + threadIdx.x;
  if (idx >= total) return;
  const long nc = (long)cN * c;
  const int b = (int)(idx / ((long)cN * c8));
  const long rest = (idx % ((long)cN * c8)) * 8;
  const u16* p = in  + (long)b * cT * nc + rest;
  u16*       q = out + (long)b * cT * nc + rest;
  float s1[8] = {}, m1[8] = {}, s2[8] = {}, m2[8] = {}, s3[8] = {}, m3[8] = {};
#pragma unroll
  for (int t = 0; t < cT; ++t) {
    const bf16x8 v = *(const bf16x8*)&p[(long)t * nc];
    u16 o[8];
#pragma unroll
    for (int e = 0; e < 8; ++e) {
      s1[e] = fmaf(cALPHA, s1[e], bf2f((u16)v[e])); m1[e] = fmaf(cBETA, m1[e], s1[e]);
      s2[e] = fmaf(cALPHA, s2[e], m1[e]);           m2[e] = fmaf(cBETA, m2[e], s2[e]);
      s3[e] = fmaf(cALPHA, s3[e], m2[e]);           m3[e] = fmaf(cBETA, m3[e], s3[e]);
      o[e] = f2bf(m3[e]);
    }
    *(bf16x8*)&q[(long)t * nc] = *(const bf16x8*)o;
  }
}

// same, but store only the t=T-1 slice into out [cB*cN, c]
__global__ __launch_bounds__(256)
void cascade3_last(const u16* __restrict__ in, u16* __restrict__ out, int c)
{
  const int c8 = c >> 3;
  const long total = (long)cB * cN * c8;
  const long idx = (long)blockIdx.x * 256 + threadIdx.x;
  if (idx >= total) return;
  const long nc = (long)cN * c;
  const int b = (int)(idx / ((long)cN * c8));
  const long rest = (idx % ((long)cN * c8)) * 8;
  const u16* p = in + (long)b * cT * nc + rest;
  float s1[8] = {}, m1[8] = {}, s2[8] = {}, m2[8] = {}, s3[8] = {}, m3[8] = {};
#pragma unroll
  for (int t = 0; t < cT; ++t) {
    const bf16x8 v = *(const bf16x8*)&p[(long)t * nc];
#pragma unroll
    for (int e = 0; e < 8; ++e) {
      s1[e] = fmaf(cALPHA, s1[e], bf2f((u16)v[e])); m1[e] = fmaf(cBETA, m1[e], s1[e]);
      s2[e] = fmaf(cALPHA, s2[e], m1[e]);           m2[e] = fmaf(cBETA, m2[e], s2[e]);
      s3[e] = fmaf(cALPHA, s3[e], m2[e]);           m3[e] = fmaf(cBETA, m3[e], s3[e]);
    }
  }
  u16 o[8];
#pragma unroll
  for (int e = 0; e < 8; ++e) o[e] = f2bf(m3[e]);
  *(bf16x8*)&out[(long)b * nc + rest] = *(const bf16x8*)o;
}

// ======================= weight convert + transpose (f32 [K,N] -> bf16 [N,K]) ==========
__global__ __launch_bounds__(256)
void wconvT(const float* __restrict__ w, u16* __restrict__ wt, int K, int N)
{
  const long idx = (long)blockIdx.x * 256 + threadIdx.x;
  if (idx >= (long)K * N) return;
  const int n = (int)(idx / K), k = (int)(idx % K);
  wt[idx] = f2bf(w[(long)k * N + n]);
}

// pack diffconv+denseconv weights: W1/W2 [160][480] bf16
__global__ __launch_bounds__(256)
void wpack_dcds(const float* __restrict__ dcw, const float* __restrict__ dsw,
                u16* __restrict__ W1, u16* __restrict__ W2)
{
  const int idx = blockIdx.x * 256 + threadIdx.x;
  if (idx >= 2 * 160 * 480) return;
  const int which = idx / (160 * 480);
  const int l = idx % (160 * 480);
  const int n = l / 480, k = l % 480;
  float v;
  if (k < 320) v = dcw[(long)(which * 320 + k) * 160 + n];
  else         v = dsw[(long)(which * 160 + (k - 320)) * 160 + n];
  (which ? W2 : W1)[l] = f2bf(v);
}

// 3 independent transposes fused (skw0 160x256, rw1 256x512, rw2 512x312)
__global__ __launch_bounds__(256)
void wconv_multi(const float* __restrict__ w2, u16* __restrict__ d2,
                 const float* __restrict__ w3, u16* __restrict__ d3,
                 const float* __restrict__ w4, u16* __restrict__ d4)
{
  const long s2 = 160L * 256, s3 = s2 + 256L * 512, s4 = s3 + 512L * 312;
  long idx = (long)blockIdx.x * 256 + threadIdx.x;
  const float* w; u16* d; int K, N; long base;
  if      (idx < s2) { w = w2; d = d2; K = 160; N = 256; base = 0;  }
  else if (idx < s3) { w = w3; d = d3; K = 256; N = 512; base = s2; }
  else if (idx < s4) { w = w4; d = d4; K = 512; N = 312; base = s3; }
  else return;
  const long l = idx - base;
  const int n = (int)(l / K), k = (int)(l % K);
  d[l] = f2bf(w[(long)k * N + n]);
}

// ======================= tiled bf16 transpose: in [R,Cc] ld ldi -> out [Cc,R], batched ====
__global__ __launch_bounds__(256)
void transpose_bf16(const u16* __restrict__ in, int ldi, u16* __restrict__ out,
                    int R, int Cc, long batchIn, long batchOut)
{
  __shared__ u16 t[64][65];
  in  += (long)blockIdx.z * batchIn;
  out += (long)blockIdx.z * batchOut;
  const int tid = threadIdx.x;
  const int r0 = blockIdx.x * 64, c0 = blockIdx.y * 64;
  for (int i = tid; i < 64 * 64; i += 256) {
    const int r = i >> 6, c = i & 63;
    t[r][c] = (r0 + r < R && c0 + c < Cc) ? in[(long)(r0 + r) * ldi + c0 + c] : (u16)0;
  }
  __syncthreads();
  for (int i = tid; i < 64 * 64; i += 256) {
    const int c = i >> 6, r = i & 63;
    if (c0 + c < Cc && r0 + r < R) out[(long)(c0 + c) * R + r0 + r] = t[r][c];
  }
}

// convert src_emb and tgt_emb in one dispatch
__global__ __launch_bounds__(256)
void cvt2_f2bf(const float* __restrict__ a, u16* __restrict__ oa,
               const float* __restrict__ b, u16* __restrict__ ob, long n)
{
  const long idx = (long)blockIdx.x * 256 + threadIdx.x;
  if (idx < n) oa[idx] = f2bf(a[idx]);
  else if (idx < 2 * n) ob[idx - n] = f2bf(b[idx - n]);
}

// ======================= graph preprocessing (CSR build) =======================
__global__ __launch_bounds__(256)
void edge_stats(const int* __restrict__ s, const int* __restrict__ d,
                const float* __restrict__ ew, float* degf, float* degb,
                int* cntf, int* cntb)
{
  const int e = blockIdx.x * 256 + threadIdx.x;
  atomicAdd(&degf[d[e]], ew[e]);
  atomicAdd(&degb[s[e]], ew[e]);
  atomicAdd(&cntf[d[e]], 1);
  atomicAdd(&cntb[s[e]], 1);
}

__global__ __launch_bounds__(256)
void scan2(const int* __restrict__ cf, const int* __restrict__ cb,
           int* __restrict__ rf, int* __restrict__ rb)
{
  const int* c = blockIdx.x ? cb : cf;
  int* r       = blockIdx.x ? rb : rf;
  __shared__ int part[256];
  const int t = threadIdx.x, base = t * 8;
  int loc[8]; int s = 0;
#pragma unroll
  for (int i = 0; i < 8; ++i) { loc[i] = c[base + i]; s += loc[i]; }
  part[t] = s; __syncthreads();
  if (t == 0) {
    int run = 0;
    for (int i = 0; i < 256; ++i) { const int v = part[i]; part[i] = run; run += v; }
    r[2048] = run;
  }
  __syncthreads();
  int run = part[t];
#pragma unroll
  for (int i = 0; i < 8; ++i) { r[base + i] = run; run += loc[i]; }
}

__global__ __launch_bounds__(256)
void fill_csr(const int* __restrict__ s, const int* __restrict__ d,
              const float* __restrict__ ew,
              const float* __restrict__ degf, const float* __restrict__ degb,
              const int* __restrict__ rowf, const int* __restrict__ rowb,
              int* curf, int* curb,
              int* __restrict__ colf, int* __restrict__ colb,
              float* __restrict__ wnf, float* __restrict__ wnb)
{
  const int e = blockIdx.x * 256 + threadIdx.x;
  const int si = s[e], di = d[e];
  const float w = ew[e];
  const int p = rowf[di] + atomicAdd(&curf[di], 1);
  colf[p] = si; wnf[p] = w / fmaxf(degf[di], 1e-6f);
  const int q = rowb[si] + atomicAdd(&curb[si], 1);
  colb[q] = di; wnb[q] = w / fmaxf(degb[si], 1e-6f);
}

// ======================= diffusion step, L2-sliced: one bt per block ==========
constexpr int cNPB = 12;                       // nodes per block
constexpr int cNCH = (cN + cNPB - 1) / cNPB;   // 171 chunks
__global__ __launch_bounds__(256)
void prop_gather_bt(const u16* __restrict__ x, int ldx, u16* __restrict__ y, int ldy,
                    const int* __restrict__ rowptr, const int* __restrict__ col,
                    const float* __restrict__ w)
{
  const int lid = blockIdx.x;                  // 0 .. 8*6*cNCH-1
  const int xcd = lid & 7, j = lid >> 3;
  const int bt = xcd * 6 + (j % 6);            // 6 bt per XCD
  const int chunk = j / 6;
  const int item = threadIdx.x;                // (node_i, ch8)
  if (item >= cNPB * 20) return;
  const int n = chunk * cNPB + item / 20;
  if (n >= cN) return;
  const int ch = (item % 20) * 8;
  const int beg = rowptr[n], end = rowptr[n + 1];
  const u16* xb = x + (long)bt * cN * ldx + ch;
  float acc[8] = {};
  int jj = beg;
  for (; jj + 1 < end; jj += 2) {
    const int c0 = col[jj], c1 = col[jj + 1];
    const float w0 = w[jj], w1 = w[jj + 1];
    const bf16x8 v0 = *(const bf16x8*)&xb[(long)c0 * ldx];
    const bf16x8 v1 = *(const bf16x8*)&xb[(long)c1 * ldx];
#pragma unroll
    for (int q = 0; q < 8; ++q) {
      acc[q] = fmaf(w0, bf2f((u16)v0[q]), acc[q]);
      acc[q] = fmaf(w1, bf2f((u16)v1[q]), acc[q]);
    }
  }
  if (jj < end) {
    const float w0 = w[jj];
    const bf16x8 v0 = *(const bf16x8*)&xb[(long)col[jj] * ldx];
#pragma unroll
    for (int q = 0; q < 8; ++q) acc[q] = fmaf(w0, bf2f((u16)v0[q]), acc[q]);
  }
  u16 o[8];
#pragma unroll
  for (int q = 0; q < 8; ++q) o[q] = f2bf(acc[q]);
  *(bf16x8*)&y[((long)bt * cN + n) * ldy + ch] = *(const bf16x8*)o;
}

// ======================= encoder =======================
__global__ __launch_bounds__(160)
void encoder(const float* __restrict__ x, const float* __restrict__ ew_,
             const float* __restrict__ eb, const float* __restrict__ ne,
             const float* __restrict__ lw, u16* __restrict__ h)
{
  __shared__ float xs[cF];
  const int tid = threadIdx.x;
  const long r0 = (long)blockIdx.x * 8;
  for (long row = r0; row < r0 + 8; ++row) {
    if (tid < cF) xs[tid] = x[row * cF + tid];
    __syncthreads();
    const int n = (int)(row % cN);
    float v;
    if (tid < cHID) {
      float acc = eb[tid] + ne[(long)n * cHID + tid];
#pragma unroll
      for (int f = 0; f < cF; ++f) acc = fmaf(xs[f], ew_[f * cHID + tid], acc);
      v = acc;
    } else {
      v = lw[(long)n * cLF + (tid - cHID)];
    }
    h[row * 160 + tid] = f2bf(v);
    __syncthreads();
  }
}

// ======================= adjacency: row softmax of relu(scores) ==========
__global__ __launch_bounds__(256)
void relu_softmax_rows(const float* __restrict__ sc, u16* __restrict__ adj)
{
  const int row = blockIdx.x, tid = threadIdx.x;
  const float* p = sc + (long)row * cN;
  __shared__ float red[256];
  float lv[8];
  float mx = 0.f;   // relu => all >= 0
#pragma unroll
  for (int i = 0; i < 8; ++i) {
    const float v = fmaxf(p[tid + i * 256], 0.f);
    lv[i] = v; mx = fmaxf(mx, v);
  }
  red[tid] = mx; __syncthreads();
  for (int s = 128; s > 0; s >>= 1) { if (tid < s) red[tid] = fmaxf(red[tid], red[tid + s]); __syncthreads(); }
  const float m = red[0]; __syncthreads();
  float sum = 0.f;
#pragma unroll
  for (int i = 0; i < 8; ++i) { lv[i] = __expf(lv[i] - m); sum += lv[i]; }
  red[tid] = sum; __syncthreads();
  for (int s = 128; s > 0; s >>= 1) { if (tid < s) red[tid] += red[tid + s]; __syncthreads(); }
  const float inv = 1.f / red[0]; __syncthreads();
#pragma unroll
  for (int i = 0; i < 8; ++i) adj[(long)row * cN + tid + i * 256] = f2bf(lv[i] * inv);
}

// ======================= batch norm (bf16 inputs) =======================
__global__ __launch_bounds__(256)
void bn_stats(const u16* __restrict__ d, const u16* __restrict__ res,
              float* __restrict__ stat, int c)
{
  const int ch = threadIdx.x;
  const long r0 = (long)blockIdx.x * (cR / 512);
  float s = 0.f, s2 = 0.f;
  for (int i = 0; i < cR / 512; ++i) {
    const float v = bf2f(d[(r0 + i) * c + ch]) + bf2f(res[(r0 + i) * c + ch]);
    s += v; s2 = fmaf(v, v, s2);
  }
  atomicAdd(&stat[ch], s);
  atomicAdd(&stat[c + ch], s2);
}

__global__ __launch_bounds__(256)
void bn_finalize(const float* __restrict__ stat, const float* __restrict__ g,
                 const float* __restrict__ b, float* __restrict__ scsh, int c)
{
  const int ch = threadIdx.x;
  const float mu = stat[ch] / cR;
  const float var = stat[c + ch] / cR - mu * mu;
  const float sc = g[ch] * rsqrtf(var + cEPS);
  scsh[ch] = sc;
  scsh[c + ch] = fmaf(-mu, sc, b[ch]);
}

__global__ __launch_bounds__(192)
void bn_apply_concat(const u16* __restrict__ d, const u16* __restrict__ res,
                     const float* __restrict__ scsh, const float* __restrict__ lw,
                     u16* __restrict__ out)
{
  const int tid = threadIdx.x;
  const long r0 = (long)blockIdx.x * 8;
  for (long row = r0; row < r0 + 8; ++row) {
    const int n = (int)(row % cN);
    float v;
    if (tid < 160) v = fmaf(bf2f(d[row * 160 + tid]) + bf2f(res[row * 160 + tid]),
                            scsh[tid], scsh[160 + tid]);
    else           v = lw[(long)n * cLF + (tid - 160)];
    out[row * 192 + tid] = f2bf(v);
  }
}

// ======================= output transpose (bf16 in, f32 out) =======================
__global__ __launch_bounds__(256)
void final_transpose(const u16* __restrict__ y, float* __restrict__ out)
{
  const long idx = (long)blockIdx.x * 256 + threadIdx.x;
  const int f = (int)(idx % cF);
  long t = idx / cF;
  const int n = (int)(t % cN); t /= cN;
  const int hor = (int)(t % cHOR);
  const int b = (int)(t / cHOR);
  out[idx] = bf2f(y[((long)b * cN + n) * (cHOR * cF) + hor * cF + f]);
}

__global__ __launch_bounds__(256)
void fill_f32(float* __restrict__ out, long n, float val)
{
  const long idx = (long)blockIdx.x * 256 + threadIdx.x;
  if (idx < n) out[idx] = val;
}

// ======================= host orchestration =======================
extern "C" void kernel_launch(void* const* d_in, const int* in_sizes, int n_in,
                              void* d_out, int out_size, void* d_ws, size_t ws_size,
                              hipStream_t stream)
{
  float* outF = (float*)d_out;
  const long outN = out_size;
  if (n_in < 34) { fill_f32<<<(int)((outN + 255) / 256), 256, 0, stream>>>(outF, outN, 500.f); return; }
  if (in_sizes[0] != cB * cT * cN * cF || in_sizes[1] != 2 * cE || in_sizes[9] != 3 * 160 * 160) {
    fill_f32<<<(int)((outN + 255) / 256), 256, 0, stream>>>(outF, outN, 700.f); return;
  }

  const float* x        = (const float*)d_in[0];
  const int*   eidx     = (const int*)d_in[1];
  const float* ew       = (const float*)d_in[2];
  const float* enc_w    = (const float*)d_in[3];
  const float* enc_b    = (const float*)d_in[4];
  const float* node_emb = (const float*)d_in[5];
  const float* src_emb  = (const float*)d_in[6];
  const float* tgt_emb  = (const float*)d_in[7];
  const float* lw0  = (const float*)d_in[8];
  const float* tW0  = (const float*)d_in[9];
  const float* tb0  = (const float*)d_in[10];
  const float* dcw0 = (const float*)d_in[11];
  const float* dcb0 = (const float*)d_in[12];
  const float* dsw0 = (const float*)d_in[13];
  const float* dsb0 = (const float*)d_in[14];
  const float* skw0 = (const float*)d_in[15];
  const float* skb0 = (const float*)d_in[16];
  const float* ng0  = (const float*)d_in[17];
  const float* nb0  = (const float*)d_in[18];
  const float* lw1  = (const float*)d_in[19];
  const float* tW1  = (const float*)d_in[20];
  const float* tb1  = (const float*)d_in[21];
  // d_in[22..25, 28..29] feed only block-1's post-skip h (never read) -> dead.
  const float* skw1 = (const float*)d_in[26];
  const float* skb1 = (const float*)d_in[27];
  const float* rw1  = (const float*)d_in[30];
  const float* rb1  = (const float*)d_in[31];
  const float* rw2  = (const float*)d_in[32];
  const float* rb2  = (const float*)d_in[33];
  const int* srcI = eidx;
  const int* dstI = eidx + cE;

  // ---- workspace layout ----
  char* W = (char*)d_ws;
  size_t off = 0;
  auto A8 = [&](size_t bytes) { size_t r = off; off = (off + bytes + 255) & ~(size_t)255; return r; };
  const size_t oH0 = A8((size_t)cR * 160 * 2);   // res, bf16
  const size_t oHh = A8((size_t)cR * 160 * 2);   // chain h; G1 [cR,192] = Hh + PK head
  const size_t oPK = A8((size_t)cR * 480 * 2);   // pack [z|z|x], 94.5 MB (scores/r1/yb alias)
  const size_t oSx = A8((size_t)cR * 160 * 2);   // cascade out -> hT -> x1T -> block1 last
  const size_t oDd = A8((size_t)cR * 160 * 2);   // bf16 accumulator
  const size_t oAdj = A8((size_t)cN * cN * 2);
  const size_t oOut = A8((size_t)cB * cN * cFF * 2);       // bf16 skip acc (t=11)
  const size_t oZero = A8(6 * 2048 * 4 + 2 * 192 * 4);
  const size_t oRowf = A8(2049 * 4), oRowb = A8(2049 * 4);
  const size_t oColf = A8((size_t)cE * 4), oColb = A8((size_t)cE * 4);
  const size_t oWnf  = A8((size_t)cE * 4), oWnb  = A8((size_t)cE * 4);
  const size_t oScSh = A8(2 * 192 * 4);
  const size_t oWT   = A8((size_t)600000 * 2);   // bf16 weights
  const size_t oSeb  = A8((size_t)cN * cHID * 2);
  const size_t oTeb  = A8((size_t)cN * cHID * 2);
  const size_t oW23  = A8(192 * 192 * 4);
  const size_t oW123 = A8(192 * 192 * 4);
  const size_t oWskp = A8(192 * 256 * 4);
  const size_t oBt0  = A8(cT * 160 * 4);
  const size_t oBt11 = A8(192 * 4);
  const size_t oBsk1 = A8(256 * 4);
  const size_t oBsum = A8(160 * 4);
  if (off > ws_size) {
    fill_f32<<<(int)((outN + 255) / 256), 256, 0, stream>>>(outF, outN, 300.f);
    return;
  }

  u16 *H0 = (u16*)(W + oH0), *Hh = (u16*)(W + oHh), *PK = (u16*)(W + oPK),
      *Sx = (u16*)(W + oSx), *Dd = (u16*)(W + oDd), *adjb = (u16*)(W + oAdj);
  u16 *G1 = Hh;                          // [cR,192] over Hh + PK head (post-BN only)
  float* scores = (float*)PK;            // phase-0 alias (16.8 MB)
  u16 *r1b = PK + 16L * 1024 * 1024;     // readout alias (PK dead then)
  u16 *ybB = PK + 28L * 1024 * 1024;
  u16 *outB = (u16*)(W + oOut);
  float* zero = (float*)(W + oZero);
  float *degf = zero, *degb = zero + 2048;
  int *cntf = (int*)(zero + 4096), *cntb = cntf + 2048,
      *curf = cntb + 2048, *curb = curf + 2048;
  float* stat = (float*)(curb + 2048);
  int *rowf = (int*)(W + oRowf), *rowb = (int*)(W + oRowb);
  int *colf = (int*)(W + oColf), *colb = (int*)(W + oColb);
  float *wnf = (float*)(W + oWnf), *wnb = (float*)(W + oWnb);
  float* scsh = (float*)(W + oScSh);
  u16* wt = (u16*)(W + oWT);
  u16 *wt123_0 = wt,               *wsk1pT = wt123_0 + 25600,
      *W1pk = wsk1pT + 49152,      *W2pk = W1pk + 76800,
      *wsk0 = W2pk + 76800,        *wr1 = wsk0 + 40960,
      *wr2 = wr1 + 131072;
  u16 *seb = (u16*)(W + oSeb), *teb = (u16*)(W + oTeb);
  float *W23 = (float*)(W + oW23), *W123 = (float*)(W + oW123), *Wskp = (float*)(W + oWskp);
  float *Bt0 = (float*)(W + oBt0), *Bt11 = (float*)(W + oBt11), *Bsk1 = (float*)(W + oBsk1);
  float *Bsum = (float*)(W + oBsum);

  // big-M GEMMs: WM=2 (256-row tile, 512 threads)
  auto g5u = [&](const u16* Aq, const u16* Bq, u16* Cq, const float* bias,
                 int M, int N, int K, int lda, int ldbt, int ldc,
                 long bA, long bB, long bC, int batch, int flags, int bpt = 0) {
    dim3 g(M / 256, (N + 159) / 160, batch);
    gemm_mfma<2, 5, u16><<<g, 512, 0, stream>>>(Aq, Bq, Cq, bias, M, N, K, lda, ldbt, ldc, bA, bB, bC, flags, bpt);
  };
  // small-M GEMMs: WM=1 (128-row tile, 256 threads)
  auto g4f = [&](const u16* Aq, const u16* Bq, float* Cq, const float* bias,
                 int M, int N, int K, int lda, int ldbt, int ldc,
                 long bA, long bB, long bC, int batch, int flags) {
    dim3 g(M / 128, (N + 127) / 128, batch);
    gemm_mfma<1, 4, float><<<g, 256, 0, stream>>>(Aq, Bq, Cq, bias, M, N, K, lda, ldbt, ldc, bA, bB, bC, flags, 0);
  };
  auto g4u = [&](const u16* Aq, const u16* Bq, u16* Cq, const float* bias,
                 int M, int N, int K, int lda, int ldbt, int ldc,
                 long bA, long bB, long bC, int batch, int flags) {
    dim3 g(M / 128, (N + 127) / 128, batch);
    gemm_mfma<1, 4, u16><<<g, 256, 0, stream>>>(Aq, Bq, Cq, bias, M, N, K, lda, ldbt, ldc, bA, bB, bC, flags, 0);
  };
  auto wcv = [&](const float* src, u16* dst, int K, int N) {
    wconvT<<<(int)(((long)K * N + 255) / 256), 256, 0, stream>>>(src, dst, K, N);
  };
  auto mms = [&](const float* Aq, const float* Bq, float* Cq, int M, int N, int K) {
    matmul_small<<<(M * N + 255) / 256, 256, 0, stream>>>(Aq, Bq, Cq, M, N, K);
  };

  // ---- phase 0a: composed chain weights ----
  mms(tW0 + 1L * 25600, tW0 + 2L * 25600, W23, 160, 160, 160);
  mms(tW0,              W23,              W123, 160, 160, 160);
  wcv(W123, wt123_0, 160, 160);
  btot_full<<<1, 160, 0, stream>>>(tb0, tb0 + 160, tb0 + 320, W23, tW0 + 2L * 25600, Bt0, 160);
  mms(tW1 + 1L * 36864, tW1 + 2L * 36864, W23, 192, 192, 192);
  mms(tW1,              W23,              W123, 192, 192, 192);
  mms(W123, skw1, Wskp, 192, 256, 192);
  wcv(Wskp, wsk1pT, 192, 256);
  btot_last<<<1, 192, 0, stream>>>(tb1, tb1 + 192, tb1 + 384, W23, tW1 + 2L * 36864, Bt11, 192);
  bias_sk<<<1, 256, 0, stream>>>(Bt11, skw1, skb1, Bsk1);
  vadd2<<<1, 160, 0, stream>>>(dcb0, dsb0, Bsum, 160);

  // ---- phase 0b: weight packs, CSR, encoder, adjacency ----
  wpack_dcds<<<(2 * 160 * 480 + 255) / 256, 256, 0, stream>>>(dcw0, dsw0, W1pk, W2pk);
  {
    const long tot = 160L * 256 + 256L * 512 + 512L * 312;
    wconv_multi<<<(int)((tot + 255) / 256), 256, 0, stream>>>(skw0, wsk0, rw1, wr1, rw2, wr2);
  }
  hipMemsetAsync(zero, 0, 6 * 2048 * 4 + 2 * 192 * 4, stream);
  edge_stats<<<cE / 256, 256, 0, stream>>>(srcI, dstI, ew, degf, degb, cntf, cntb);
  scan2<<<2, 256, 0, stream>>>(cntf, cntb, rowf, rowb);
  fill_csr<<<cE / 256, 256, 0, stream>>>(srcI, dstI, ew, degf, degb, rowf, rowb,
                                         curf, curb, colf, colb, wnf, wnb);
  encoder<<<cR / 8, 160, 0, stream>>>(x, enc_w, enc_b, node_emb, lw0, H0);

  cvt2_f2bf<<<(2 * cN * cHID + 255) / 256, 256, 0, stream>>>(src_emb, seb, tgt_emb, teb, (long)cN * cHID);
  g4f(seb, teb, scores, nullptr, cN, cN, cHID, cHID, cHID, cN, 0, 0, 0, 1, 0);
  relu_softmax_rows<<<cN, 256, 0, stream>>>(scores, adjb);

  const int PROP_GRID = 8 * 6 * cNCH;

  // ---- block 0 (c = 160) ----
  {
    const int c = 160;
    const long NC = (long)cN * c;
    const long PB = (long)cN * 480;      // per-bt pack stride
    const int casGrid = (int)(((long)cB * cN * (c / 8) + 255) / 256);
    // chain: Sx = S^3 H0 ; Hh = Sx @ W123_0 + Bt0[t]
    cascade3_full<<<casGrid, 256, 0, stream>>>(H0, Sx, c);
    g5u(Sx, wt123_0, Hh, Bt0, cR, c, c, c, c, c, 0, 0, 0, 1, FLAG_BIAS, /*bpt=*/1);
    // skip (t=11) -> bf16 outB
    g4u(Hh + 11L * NC, wsk0, outB, skb0, cN, cFF, c, c, c, cFF,
        (long)cT * NC, 0, (long)cN * cFF, cB, FLAG_BIAS);
    // hT -> Sx
    dim3 tg(cN / 64, (c + 63) / 64, cBT);
    transpose_bf16<<<tg, 256, 0, stream>>>(Hh, c, Sx, cN, c, NC, NC);
    // pack1 = [z1 | z2 | x1]
    prop_gather_bt<<<PROP_GRID, 256, 0, stream>>>(Hh, 160, PK, 480, rowf, colf, wnf);
    prop_gather_bt<<<PROP_GRID, 256, 0, stream>>>(PK, 480, PK + 160, 480, rowf, colf, wnf);
    g5u(adjb, Sx, PK + 320, nullptr, cN, c, cN, cN, cN, 480, 0, NC, PB, cBT, 0);   // x1
    // GEMM1: Dd = pack1 @ W1 + (dcb0+dsb0)
    g5u(PK, W1pk, Dd, Bsum, cR, c, 480, 480, 480, c, 0, 0, 0, 1, FLAG_BIAS);
    // x1T -> Sx (hT dead)
    transpose_bf16<<<tg, 256, 0, stream>>>(PK + 320, 480, Sx, cN, c, PB, NC);
    // pack2 = [z3 | z4 | x2]
    prop_gather_bt<<<PROP_GRID, 256, 0, stream>>>(Hh, 160, PK, 480, rowb, colb, wnb);
    prop_gather_bt<<<PROP_GRID, 256, 0, stream>>>(PK, 480, PK + 160, 480, rowb, colb, wnb);
    g5u(adjb, Sx, PK + 320, nullptr, cN, c, cN, cN, cN, 480, 0, NC, PB, cBT, 0);   // x2
    // GEMM2: Dd += pack2 @ W2
    g5u(PK, W2pk, Dd, nullptr, cR, c, 480, 480, 480, c, 0, 0, 0, 1, FLAG_ACC);
    // BN(Dd + H0) -> G1 (stride 192) + lw1
    bn_stats<<<512, c, 0, stream>>>(Dd, H0, stat, c);
    bn_finalize<<<1, c, 0, stream>>>(stat, ng0, nb0, scsh, c);
    bn_apply_concat<<<cR / 8, 192, 0, stream>>>(Dd, H0, scsh, lw1, G1);
  }

  // ---- block 1 (c = 192): composed chain+skip, only t=11 survives ----
  {
    const int c = 192;
    const int casGrid = (int)(((long)cB * cN * (c / 8) + 255) / 256);
    cascade3_last<<<casGrid, 256, 0, stream>>>(G1, Sx, c);
    g4u(Sx, wsk1pT, outB, Bsk1, cB * cN, cFF, c, c, c, cFF,
        0, 0, 0, 1, FLAG_BIAS | FLAG_ACC | FLAG_RELU);
  }

  // ---- readout (all bf16) ----
  g4u(outB, wr1, r1b, rb1, cB * cN, 2 * cFF, cFF, cFF, cFF, 2 * cFF,
      0, 0, 0, 1, FLAG_BIAS | FLAG_RELU);
  g4u(r1b, wr2, ybB, rb2, cB * cN, cHOR * cF, 2 * cFF, 2 * cFF, 2 * cFF, cHOR * cF,
      0, 0, 0, 1, FLAG_BIAS);
  final_transpose<<<(cB * cHOR * cN * cF) / 256, 256, 0, stream>>>(ybB, outF);
}

// Round 15
// 1008.355 us; speedup vs baseline: 3.9956x; 1.0116x over previous
//
#include <hip/hip_runtime.h>

// ======================= types & helpers =======================
using u16 = unsigned short;
typedef short bf16x8 __attribute__((ext_vector_type(8)));
typedef float f32x4  __attribute__((ext_vector_type(4)));

__device__ __forceinline__ float bf2f(u16 u) { return __uint_as_float(((unsigned)u) << 16); }
__device__ __forceinline__ u16 f2bf(float f) {  // round-to-nearest-even
  unsigned u = __float_as_uint(f);
  return (u16)((u + 0x7FFFu + ((u >> 16) & 1u)) >> 16);
}
__device__ __forceinline__ float ldv(const float* p) { return *p; }
__device__ __forceinline__ float ldv(const u16* p)   { return bf2f(*p); }
__device__ __forceinline__ void  stv(float* p, float v) { *p = v; }
__device__ __forceinline__ void  stv(u16* p, float v)   { *p = f2bf(v); }

// ======================= problem constants =======================
constexpr int cB = 4, cT = 12, cN = 2048, cF = 26;
constexpr int cHID = 128, cLF = 32, cFF = 256, cHOR = 12;
constexpr int cE = 16384;
constexpr int cR = cB * cT * cN;   // 98304
constexpr int cBT = cB * cT;       // 48
constexpr float cALPHA = 0.9f, cBETA = 0.8f, cEPS = 1e-5f;

#define FLAG_ACC  1
#define FLAG_BIAS 2
#define FLAG_RELU 4

// ======================= MFMA bf16 GEMM (gload_lds + dbuf + XCD swizzle) ==========
// C[m,n] = sum_k A[m,k] * BT[n,k]  (+bias) (+C) (relu)
// A: bf16 [M,K] lda ; BT: bf16 [N,K] ldbt. M%(WM*128)==0, K%32==0, lda/ldbt%8==0;
// N guarded (OOB B rows clamp to N-1; their output columns never stored).
// WM: tile = (WM*128) x (NF*32), WM*4 waves. biasPerT: bias[cT][N], row (m0/2048)%cT.
template <int WM, int NF, typename TC>
__global__ __launch_bounds__(WM * 256)
void gemm_mfma(const u16* __restrict__ A, const u16* __restrict__ BT,
               TC* __restrict__ C, const float* __restrict__ bias,
               int M, int N, int K, int lda, int ldbt, int ldc,
               long batchA, long batchB, long batchC, int flags, int biasPerT)
{
  constexpr int TN = NF * 32;
  constexpr int AROWS = WM * 128;
  constexpr int ROWS = AROWS + TN;      // A rows then BT rows
  constexpr int NINST = ROWS / 16;      // gload_lds wave-instrs per K-step
  constexpr int WAVES = WM * 4;
  constexpr int NPW = (NINST + WAVES - 1) / WAVES;
  __shared__ __align__(16) u16 S[2][ROWS * 32];

  // bijective XCD-aware block remap
  const long gx = gridDim.x, gy = gridDim.y;
  const long total = gx * gy * (long)gridDim.z;
  long lid = blockIdx.x + gx * (blockIdx.y + gy * (long)blockIdx.z);
  { const long q = total >> 3, r = total & 7, xcd = lid & 7, j = lid >> 3;
    lid = (xcd < r ? xcd * (q + 1) : r * (q + 1) + (xcd - r) * q) + j; }
  const int bz = (int)(lid / (gx * gy));
  const long rem = lid % (gx * gy);
  const int by = (int)(rem / gx), bx = (int)(rem % gx);

  A  += (long)bz * batchA;
  BT += (long)bz * batchB;
  C  += (long)bz * batchC;
  const int tid = threadIdx.x;
  const int lane = tid & 63, wid = tid >> 6;
  const int wm = wid & (2 * WM - 1);
  const int wn = wid >> WM;
  const int m0 = bx * AROWS, n0 = by * TN;
  const int fr = lane & 15, kh = lane >> 4;   // frag row / k-half
  const int nwi = (NINST - wid + WAVES - 1) / WAVES;

  // hoisted per-lane staging pointers (advance +32 elts per K-step)
  const u16* gp[NPW];
#pragma unroll
  for (int i = 0; i < NPW; ++i) {
    const int s = wid + i * WAVES;
    if (s < NINST) {
      const int slot = s * 64 + lane;    // linear 16B LDS slot
      const int row = slot >> 2, q = slot & 3;
      if (row < AROWS) {
        gp[i] = A + (long)(m0 + row) * lda + q * 8;
      } else {
        const int n = min(n0 + row - AROWS, N - 1);
        gp[i] = BT + (long)n * ldbt + q * 8;
      }
    } else {
      gp[i] = A;
    }
  }

  f32x4 acc[4][NF];
#pragma unroll
  for (int i = 0; i < 4; ++i)
#pragma unroll
    for (int j = 0; j < NF; ++j) acc[i][j] = f32x4{0.f, 0.f, 0.f, 0.f};

  auto STAGE = [&](int buf) {
#pragma unroll
    for (int i = 0; i < NPW; ++i) {
      if (i < nwi) {
        const int s = wid + i * WAVES;
        __builtin_amdgcn_global_load_lds(
            (const __attribute__((address_space(1))) unsigned int*)gp[i],
            (__attribute__((address_space(3))) unsigned int*)&S[buf][s * 512],
            16, 0, 0);
        gp[i] += 32;
      }
    }
  };

  STAGE(0);
  int cur = 0;
  for (int k0 = 0; k0 < K; k0 += 32) {
    __syncthreads();                 // drains vmcnt -> S[cur] ready; prior reads of S[cur^1] done
    if (k0 + 32 < K) STAGE(cur ^ 1);
    bf16x8 af[4];
#pragma unroll
    for (int mf = 0; mf < 4; ++mf)
      af[mf] = *(const bf16x8*)&S[cur][(wm * 64 + mf * 16 + fr) * 32 + kh * 8];
#pragma unroll
    for (int nf = 0; nf < NF; ++nf) {
      const bf16x8 bfr =
          *(const bf16x8*)&S[cur][(AROWS + wn * NF * 16 + nf * 16 + fr) * 32 + kh * 8];
#pragma unroll
      for (int mf = 0; mf < 4; ++mf)
        acc[mf][nf] = __builtin_amdgcn_mfma_f32_16x16x32_bf16(af[mf], bfr, acc[mf][nf], 0, 0, 0);
    }
    cur ^= 1;
  }

  const float* bp = bias;
  if (biasPerT && bias) bp = bias + (long)((m0 >> 11) % cT) * N;

#pragma unroll
  for (int mf = 0; mf < 4; ++mf)
#pragma unroll
    for (int nf = 0; nf < NF; ++nf) {
      const int gn = n0 + wn * NF * 16 + nf * 16 + fr;
      if (gn < N) {
#pragma unroll
        for (int r = 0; r < 4; ++r) {
          const long gm = m0 + wm * 64 + mf * 16 + kh * 4 + r;   // C/D: row=(lane>>4)*4+r
          float v = acc[mf][nf][r];
          if (flags & FLAG_BIAS) v += bp[gn];
          if (flags & FLAG_ACC)  v += ldv(&C[gm * ldc + gn]);
          if (flags & FLAG_RELU) v = fmaxf(v, 0.f);
          stv(&C[gm * ldc + gn], v);
        }
      }
    }
}

// ======================= small f32 matmul: C[M,N] = A[M,K] @ B[K,N] ==========
__global__ __launch_bounds__(256)
void matmul_small(const float* __restrict__ A, const float* __restrict__ B,
                  float* __restrict__ C, int M, int N, int K)
{
  const int idx = blockIdx.x * 256 + threadIdx.x;
  if (idx >= M * N) return;
  const int m = idx / N, n = idx % N;
  float acc = 0.f;
  for (int k = 0; k < K; ++k) acc = fmaf(A[m * K + k], B[k * N + n], acc);
  C[idx] = acc;
}

// ======================= LIF composed coefficients ==========
__device__ __forceinline__ void lif_coeffs(float* k1, float* k2, float* k3)
{
  float ap = 1.f;
  for (int m = 0; m < cT; ++m) {
    k1[m] = (m ? cBETA * k1[m - 1] : 0.f) + ap;   // k1[m] = sum a^i b^(m-i)
    ap *= cALPHA;
  }
  for (int m = 0; m < cT; ++m) { float s = 0.f; for (int i = 0; i <= m; ++i) s += k1[i] * k1[m - i]; k2[m] = s; }
  for (int m = 0; m < cT; ++m) { float s = 0.f; for (int i = 0; i <= m; ++i) s += k2[i] * k1[m - i]; k3[m] = s; }
}

// Btot[t][ch] = C3[t]*(b1@W23)[ch] + C2[t]*(b2@W3)[ch] + C1[t]*b3[ch]; Ci = cumsum(ki)
__global__ void btot_full(const float* __restrict__ b1, const float* __restrict__ b2,
                          const float* __restrict__ b3, const float* __restrict__ W23,
                          const float* __restrict__ W3, float* __restrict__ Btot, int c)
{
  const int ch = threadIdx.x;
  if (ch >= c) return;
  float k1[cT], k2[cT], k3[cT]; lif_coeffs(k1, k2, k3);
  float v1 = 0.f, v2 = 0.f;
  for (int j = 0; j < c; ++j) { v1 = fmaf(b1[j], W23[j * c + ch], v1); v2 = fmaf(b2[j], W3[j * c + ch], v2); }
  float C1 = 0.f, C2 = 0.f, C3 = 0.f;
  for (int t = 0; t < cT; ++t) {
    C1 += k1[t]; C2 += k2[t]; C3 += k3[t];
    Btot[t * c + ch] = C3 * v1 + C2 * v2 + C1 * b3[ch];
  }
}

// last-t-only variant -> out[c]
__global__ void btot_last(const float* __restrict__ b1, const float* __restrict__ b2,
                          const float* __restrict__ b3, const float* __restrict__ W23,
                          const float* __restrict__ W3, float* __restrict__ out, int c)
{
  const int ch = threadIdx.x;
  if (ch >= c) return;
  float k1[cT], k2[cT], k3[cT]; lif_coeffs(k1, k2, k3);
  float v1 = 0.f, v2 = 0.f;
  for (int j = 0; j < c; ++j) { v1 = fmaf(b1[j], W23[j * c + ch], v1); v2 = fmaf(b2[j], W3[j * c + ch], v2); }
  float C1 = 0.f, C2 = 0.f, C3 = 0.f;
  for (int t = 0; t < cT; ++t) { C1 += k1[t]; C2 += k2[t]; C3 += k3[t]; }
  out[ch] = C3 * v1 + C2 * v2 + C1 * b3[ch];
}

// bias1p[n] = skb1[n] + sum_k Btot11[k] * skw1[k][n]
__global__ void bias_sk(const float* __restrict__ Btot11, const float* __restrict__ skw1,
                        const float* __restrict__ skb1, float* __restrict__ out)
{
  const int n = threadIdx.x;
  float acc = skb1[n];
  for (int k = 0; k < 192; ++k) acc = fmaf(Btot11[k], skw1[k * 256 + n], acc);
  out[n] = acc;
}

__global__ void vadd2(const float* __restrict__ a, const float* __restrict__ b,
                      float* __restrict__ o, int n)
{
  const int i = threadIdx.x;
  if (i < n) o[i] = a[i] + b[i];
}

// ======================= 3x cascaded LIF (= S^3), full sequence out ==========
__global__ __launch_bounds__(256)
void cascade3_full(const u16* __restrict__ in, u16* __restrict__ out, int c)
{
  const int c8 = c >> 3;
  const long total = (long)cB * cN * c8;
  const long idx = (long)blockIdx.x * 256 + threadIdx.x;
  if (idx >= total) return;
  const long nc = (long)cN * c;
  const int b = (int)(idx / ((long)cN * c8));
  const long rest = (idx % ((long)cN * c8)) * 8;
  const u16* p = in  + (long)b * cT * nc + rest;
  u16*       q = out + (long)b * cT * nc + rest;
  float s1[8] = {}, m1[8] = {}, s2[8] = {}, m2[8] = {}, s3[8] = {}, m3[8] = {};
#pragma unroll
  for (int t = 0; t < cT; ++t) {
    const bf16x8 v = *(const bf16x8*)&p[(long)t * nc];
    u16 o[8];
#pragma unroll
    for (int e = 0; e < 8; ++e) {
      s1[e] = fmaf(cALPHA, s1[e], bf2f((u16)v[e])); m1[e] = fmaf(cBETA, m1[e], s1[e]);
      s2[e] = fmaf(cALPHA, s2[e], m1[e]);           m2[e] = fmaf(cBETA, m2[e], s2[e]);
      s3[e] = fmaf(cALPHA, s3[e], m2[e]);           m3[e] = fmaf(cBETA, m3[e], s3[e]);
      o[e] = f2bf(m3[e]);
    }
    *(bf16x8*)&q[(long)t * nc] = *(const bf16x8*)o;
  }
}

// same, but store only the t=T-1 slice into out [cB*cN, c]
__global__ __launch_bounds__(256)
void cascade3_last(const u16* __restrict__ in, u16* __restrict__ out, int c)
{
  const int c8 = c >> 3;
  const long total = (long)cB * cN * c8;
  const long idx = (long)blockIdx.x * 256 + threadIdx.x;
  if (idx >= total) return;
  const long nc = (long)cN * c;
  const int b = (int)(idx / ((long)cN * c8));
  const long rest = (idx % ((long)cN * c8)) * 8;
  const u16* p = in + (long)b * cT * nc + rest;
  float s1[8] = {}, m1[8] = {}, s2[8] = {}, m2[8] = {}, s3[8] = {}, m3[8] = {};
#pragma unroll
  for (int t = 0; t < cT; ++t) {
    const bf16x8 v = *(const bf16x8*)&p[(long)t * nc];
#pragma unroll
    for (int e = 0; e < 8; ++e) {
      s1[e] = fmaf(cALPHA, s1[e], bf2f((u16)v[e])); m1[e] = fmaf(cBETA, m1[e], s1[e]);
      s2[e] = fmaf(cALPHA, s2[e], m1[e]);           m2[e] = fmaf(cBETA, m2[e], s2[e]);
      s3[e] = fmaf(cALPHA, s3[e], m2[e]);           m3[e] = fmaf(cBETA, m3[e], s3[e]);
    }
  }
  u16 o[8];
#pragma unroll
  for (int e = 0; e < 8; ++e) o[e] = f2bf(m3[e]);
  *(bf16x8*)&out[(long)b * nc + rest] = *(const bf16x8*)o;
}

// ======================= weight convert + transpose (f32 [K,N] -> bf16 [N,K]) ==========
__global__ __launch_bounds__(256)
void wconvT(const float* __restrict__ w, u16* __restrict__ wt, int K, int N)
{
  const long idx = (long)blockIdx.x * 256 + threadIdx.x;
  if (idx >= (long)K * N) return;
  const int n = (int)(idx / K), k = (int)(idx % K);
  wt[idx] = f2bf(w[(long)k * N + n]);
}

// pack diffconv+denseconv weights: W1/W2 [160][480] bf16
__global__ __launch_bounds__(256)
void wpack_dcds(const float* __restrict__ dcw, const float* __restrict__ dsw,
                u16* __restrict__ W1, u16* __restrict__ W2)
{
  const int idx = blockIdx.x * 256 + threadIdx.x;
  if (idx >= 2 * 160 * 480) return;
  const int which = idx / (160 * 480);
  const int l = idx % (160 * 480);
  const int n = l / 480, k = l % 480;
  float v;
  if (k < 320) v = dcw[(long)(which * 320 + k) * 160 + n];
  else         v = dsw[(long)(which * 160 + (k - 320)) * 160 + n];
  (which ? W2 : W1)[l] = f2bf(v);
}

// 3 independent transposes fused (skw0 160x256, rw1 256x512, rw2 512x312)
__global__ __launch_bounds__(256)
void wconv_multi(const float* __restrict__ w2, u16* __restrict__ d2,
                 const float* __restrict__ w3, u16* __restrict__ d3,
                 const float* __restrict__ w4, u16* __restrict__ d4)
{
  const long s2 = 160L * 256, s3 = s2 + 256L * 512, s4 = s3 + 512L * 312;
  long idx = (long)blockIdx.x * 256 + threadIdx.x;
  const float* w; u16* d; int K, N; long base;
  if      (idx < s2) { w = w2; d = d2; K = 160; N = 256; base = 0;  }
  else if (idx < s3) { w = w3; d = d3; K = 256; N = 512; base = s2; }
  else if (idx < s4) { w = w4; d = d4; K = 512; N = 312; base = s3; }
  else return;
  const long l = idx - base;
  const int n = (int)(l / K), k = (int)(l % K);
  d[l] = f2bf(w[(long)k * N + n]);
}

// ======================= tiled bf16 transpose: in [R,Cc] ld ldi -> out [Cc,R], batched ====
__global__ __launch_bounds__(256)
void transpose_bf16(const u16* __restrict__ in, int ldi, u16* __restrict__ out,
                    int R, int Cc, long batchIn, long batchOut)
{
  __shared__ u16 t[64][65];
  in  += (long)blockIdx.z * batchIn;
  out += (long)blockIdx.z * batchOut;
  const int tid = threadIdx.x;
  const int r0 = blockIdx.x * 64, c0 = blockIdx.y * 64;
  for (int i = tid; i < 64 * 64; i += 256) {
    const int r = i >> 6, c = i & 63;
    t[r][c] = (r0 + r < R && c0 + c < Cc) ? in[(long)(r0 + r) * ldi + c0 + c] : (u16)0;
  }
  __syncthreads();
  for (int i = tid; i < 64 * 64; i += 256) {
    const int c = i >> 6, r = i & 63;
    if (c0 + c < Cc && r0 + r < R) out[(long)(c0 + c) * R + r0 + r] = t[r][c];
  }
}

// convert src_emb and tgt_emb in one dispatch
__global__ __launch_bounds__(256)
void cvt2_f2bf(const float* __restrict__ a, u16* __restrict__ oa,
               const float* __restrict__ b, u16* __restrict__ ob, long n)
{
  const long idx = (long)blockIdx.x * 256 + threadIdx.x;
  if (idx < n) oa[idx] = f2bf(a[idx]);
  else if (idx < 2 * n) ob[idx - n] = f2bf(b[idx - n]);
}

// ======================= graph preprocessing (CSR build) =======================
__global__ __launch_bounds__(256)
void edge_stats(const int* __restrict__ s, const int* __restrict__ d,
                const float* __restrict__ ew, float* degf, float* degb,
                int* cntf, int* cntb)
{
  const int e = blockIdx.x * 256 + threadIdx.x;
  atomicAdd(&degf[d[e]], ew[e]);
  atomicAdd(&degb[s[e]], ew[e]);
  atomicAdd(&cntf[d[e]], 1);
  atomicAdd(&cntb[s[e]], 1);
}

__global__ __launch_bounds__(256)
void scan2(const int* __restrict__ cf, const int* __restrict__ cb,
           int* __restrict__ rf, int* __restrict__ rb)
{
  const int* c = blockIdx.x ? cb : cf;
  int* r       = blockIdx.x ? rb : rf;
  __shared__ int part[256];
  const int t = threadIdx.x, base = t * 8;
  int loc[8]; int s = 0;
#pragma unroll
  for (int i = 0; i < 8; ++i) { loc[i] = c[base + i]; s += loc[i]; }
  part[t] = s; __syncthreads();
  if (t == 0) {
    int run = 0;
    for (int i = 0; i < 256; ++i) { const int v = part[i]; part[i] = run; run += v; }
    r[2048] = run;
  }
  __syncthreads();
  int run = part[t];
#pragma unroll
  for (int i = 0; i < 8; ++i) { r[base + i] = run; run += loc[i]; }
}

__global__ __launch_bounds__(256)
void fill_csr(const int* __restrict__ s, const int* __restrict__ d,
              const float* __restrict__ ew,
              const float* __restrict__ degf, const float* __restrict__ degb,
              const int* __restrict__ rowf, const int* __restrict__ rowb,
              int* curf, int* curb,
              int* __restrict__ colf, int* __restrict__ colb,
              float* __restrict__ wnf, float* __restrict__ wnb)
{
  const int e = blockIdx.x * 256 + threadIdx.x;
  const int si = s[e], di = d[e];
  const float w = ew[e];
  const int p = rowf[di] + atomicAdd(&curf[di], 1);
  colf[p] = si; wnf[p] = w / fmaxf(degf[di], 1e-6f);
  const int q = rowb[si] + atomicAdd(&curb[si], 1);
  colb[q] = di; wnb[q] = w / fmaxf(degb[si], 1e-6f);
}

// ======================= diffusion step, L2-sliced: one bt per block ==========
constexpr int cNPB = 12;                       // nodes per block
constexpr int cNCH = (cN + cNPB - 1) / cNPB;   // 171 chunks
__global__ __launch_bounds__(256)
void prop_gather_bt(const u16* __restrict__ x, int ldx, u16* __restrict__ y, int ldy,
                    const int* __restrict__ rowptr, const int* __restrict__ col,
                    const float* __restrict__ w)
{
  const int lid = blockIdx.x;                  // 0 .. 8*6*cNCH-1
  const int xcd = lid & 7, j = lid >> 3;
  const int bt = xcd * 6 + (j % 6);            // 6 bt per XCD
  const int chunk = j / 6;
  const int item = threadIdx.x;                // (node_i, ch8)
  if (item >= cNPB * 20) return;
  const int n = chunk * cNPB + item / 20;
  if (n >= cN) return;
  const int ch = (item % 20) * 8;
  const int beg = rowptr[n], end = rowptr[n + 1];
  const u16* xb = x + (long)bt * cN * ldx + ch;
  float acc[8] = {};
  int jj = beg;
  for (; jj + 1 < end; jj += 2) {
    const int c0 = col[jj], c1 = col[jj + 1];
    const float w0 = w[jj], w1 = w[jj + 1];
    const bf16x8 v0 = *(const bf16x8*)&xb[(long)c0 * ldx];
    const bf16x8 v1 = *(const bf16x8*)&xb[(long)c1 * ldx];
#pragma unroll
    for (int q = 0; q < 8; ++q) {
      acc[q] = fmaf(w0, bf2f((u16)v0[q]), acc[q]);
      acc[q] = fmaf(w1, bf2f((u16)v1[q]), acc[q]);
    }
  }
  if (jj < end) {
    const float w0 = w[jj];
    const bf16x8 v0 = *(const bf16x8*)&xb[(long)col[jj] * ldx];
#pragma unroll
    for (int q = 0; q < 8; ++q) acc[q] = fmaf(w0, bf2f((u16)v0[q]), acc[q]);
  }
  u16 o[8];
#pragma unroll
  for (int q = 0; q < 8; ++q) o[q] = f2bf(acc[q]);
  *(bf16x8*)&y[((long)bt * cN + n) * ldy + ch] = *(const bf16x8*)o;
}

// ======================= encoder v2: LDS-cached weights, bf16x8 stores ==========
// 256 threads x 16 rows/block. swT[ch][f] layout: per-lane serial 26-float reads,
// lane stride 26 f32 -> 2-way bank alias (free). FMA order over f matches v1.
constexpr int cRPB = 16;
__global__ __launch_bounds__(256)
void encoder2(const float* __restrict__ x, const float* __restrict__ ew_,
              const float* __restrict__ eb, const float* __restrict__ ne,
              const float* __restrict__ lw, u16* __restrict__ h)
{
  __shared__ float swT[cHID * cF];   // swT[ch*26+f] = ew_[f*128+ch]
  __shared__ float sb[cHID];
  __shared__ float sx[cRPB][cF + 2];
  const int tid = threadIdx.x;
  for (int i = tid; i < cHID * cF; i += 256) {
    const int ch = i / cF, f = i % cF;
    swT[i] = ew_[f * cHID + ch];
  }
  if (tid < cHID) sb[tid] = eb[tid];
  const long r0 = (long)blockIdx.x * cRPB;
  for (int i = tid; i < cRPB * cF; i += 256) {
    const int r = i / cF, f = i % cF;
    sx[r][f] = x[(r0 + r) * cF + f];
  }
  __syncthreads();
  for (int item = tid; item < cRPB * 20; item += 256) {
    const int rl = item / 20, cg = item % 20;
    const long row = r0 + rl;
    const int n = (int)(row % cN);
    const int ch = cg * 8;
    u16 o[8];
    if (cg < 16) {
      const f32x4 ne0 = *(const f32x4*)&ne[(long)n * cHID + ch];
      const f32x4 ne1 = *(const f32x4*)&ne[(long)n * cHID + ch + 4];
#pragma unroll
      for (int q = 0; q < 8; ++q) {
        float a = sb[ch + q] + (q < 4 ? ne0[q] : ne1[q - 4]);
        const float* wp = &swT[(ch + q) * cF];
        for (int f = 0; f < cF; ++f) a = fmaf(sx[rl][f], wp[f], a);
        o[q] = f2bf(a);
      }
    } else {
      const f32x4 l0 = *(const f32x4*)&lw[(long)n * cLF + (ch - cHID)];
      const f32x4 l1 = *(const f32x4*)&lw[(long)n * cLF + (ch - cHID) + 4];
#pragma unroll
      for (int q = 0; q < 8; ++q) o[q] = f2bf(q < 4 ? l0[q] : l1[q - 4]);
    }
    *(bf16x8*)&h[row * 160 + ch] = *(const bf16x8*)o;
  }
}

// ======================= adjacency: row softmax of relu(scores) ==========
__global__ __launch_bounds__(256)
void relu_softmax_rows(const float* __restrict__ sc, u16* __restrict__ adj)
{
  const int row = blockIdx.x, tid = threadIdx.x;
  const float* p = sc + (long)row * cN;
  __shared__ float red[256];
  float lv[8];
  float mx = 0.f;   // relu => all >= 0
#pragma unroll
  for (int i = 0; i < 8; ++i) {
    const float v = fmaxf(p[tid + i * 256], 0.f);
    lv[i] = v; mx = fmaxf(mx, v);
  }
  red[tid] = mx; __syncthreads();
  for (int s = 128; s > 0; s >>= 1) { if (tid < s) red[tid] = fmaxf(red[tid], red[tid + s]); __syncthreads(); }
  const float m = red[0]; __syncthreads();
  float sum = 0.f;
#pragma unroll
  for (int i = 0; i < 8; ++i) { lv[i] = __expf(lv[i] - m); sum += lv[i]; }
  red[tid] = sum; __syncthreads();
  for (int s = 128; s > 0; s >>= 1) { if (tid < s) red[tid] += red[tid + s]; __syncthreads(); }
  const float inv = 1.f / red[0]; __syncthreads();
#pragma unroll
  for (int i = 0; i < 8; ++i) adj[(long)row * cN + tid + i * 256] = f2bf(lv[i] * inv);
}

// ======================= batch norm (bf16 inputs) =======================
__global__ __launch_bounds__(256)
void bn_stats(const u16* __restrict__ d, const u16* __restrict__ res,
              float* __restrict__ stat, int c)
{
  const int ch = threadIdx.x;
  const long r0 = (long)blockIdx.x * (cR / 512);
  float s = 0.f, s2 = 0.f;
  for (int i = 0; i < cR / 512; ++i) {
    const float v = bf2f(d[(r0 + i) * c + ch]) + bf2f(res[(r0 + i) * c + ch]);
    s += v; s2 = fmaf(v, v, s2);
  }
  atomicAdd(&stat[ch], s);
  atomicAdd(&stat[c + ch], s2);
}

__global__ __launch_bounds__(256)
void bn_finalize(const float* __restrict__ stat, const float* __restrict__ g,
                 const float* __restrict__ b, float* __restrict__ scsh, int c)
{
  const int ch = threadIdx.x;
  const float mu = stat[ch] / cR;
  const float var = stat[c + ch] / cR - mu * mu;
  const float sc = g[ch] * rsqrtf(var + cEPS);
  scsh[ch] = sc;
  scsh[c + ch] = fmaf(-mu, sc, b[ch]);
}

__global__ __launch_bounds__(192)
void bn_apply_concat(const u16* __restrict__ d, const u16* __restrict__ res,
                     const float* __restrict__ scsh, const float* __restrict__ lw,
                     u16* __restrict__ out)
{
  const int tid = threadIdx.x;
  const long r0 = (long)blockIdx.x * 8;
  for (long row = r0; row < r0 + 8; ++row) {
    const int n = (int)(row % cN);
    float v;
    if (tid < 160) v = fmaf(bf2f(d[row * 160 + tid]) + bf2f(res[row * 160 + tid]),
                            scsh[tid], scsh[160 + tid]);
    else           v = lw[(long)n * cLF + (tid - 160)];
    out[row * 192 + tid] = f2bf(v);
  }
}

// ======================= output transpose (bf16 in, f32 out) =======================
__global__ __launch_bounds__(256)
void final_transpose(const u16* __restrict__ y, float* __restrict__ out)
{
  const long idx = (long)blockIdx.x * 256 + threadIdx.x;
  const int f = (int)(idx % cF);
  long t = idx / cF;
  const int n = (int)(t % cN); t /= cN;
  const int hor = (int)(t % cHOR);
  const int b = (int)(t / cHOR);
  out[idx] = bf2f(y[((long)b * cN + n) * (cHOR * cF) + hor * cF + f]);
}

__global__ __launch_bounds__(256)
void fill_f32(float* __restrict__ out, long n, float val)
{
  const long idx = (long)blockIdx.x * 256 + threadIdx.x;
  if (idx < n) out[idx] = val;
}

// ======================= host orchestration =======================
extern "C" void kernel_launch(void* const* d_in, const int* in_sizes, int n_in,
                              void* d_out, int out_size, void* d_ws, size_t ws_size,
                              hipStream_t stream)
{
  float* outF = (float*)d_out;
  const long outN = out_size;
  if (n_in < 34) { fill_f32<<<(int)((outN + 255) / 256), 256, 0, stream>>>(outF, outN, 500.f); return; }
  if (in_sizes[0] != cB * cT * cN * cF || in_sizes[1] != 2 * cE || in_sizes[9] != 3 * 160 * 160) {
    fill_f32<<<(int)((outN + 255) / 256), 256, 0, stream>>>(outF, outN, 700.f); return;
  }

  const float* x        = (const float*)d_in[0];
  const int*   eidx     = (const int*)d_in[1];
  const float* ew       = (const float*)d_in[2];
  const float* enc_w    = (const float*)d_in[3];
  const float* enc_b    = (const float*)d_in[4];
  const float* node_emb = (const float*)d_in[5];
  const float* src_emb  = (const float*)d_in[6];
  const float* tgt_emb  = (const float*)d_in[7];
  const float* lw0  = (const float*)d_in[8];
  const float* tW0  = (const float*)d_in[9];
  const float* tb0  = (const float*)d_in[10];
  const float* dcw0 = (const float*)d_in[11];
  const float* dcb0 = (const float*)d_in[12];
  const float* dsw0 = (const float*)d_in[13];
  const float* dsb0 = (const float*)d_in[14];
  const float* skw0 = (const float*)d_in[15];
  const float* skb0 = (const float*)d_in[16];
  const float* ng0  = (const float*)d_in[17];
  const float* nb0  = (const float*)d_in[18];
  const float* lw1  = (const float*)d_in[19];
  const float* tW1  = (const float*)d_in[20];
  const float* tb1  = (const float*)d_in[21];
  // d_in[22..25, 28..29] feed only block-1's post-skip h (never read) -> dead.
  const float* skw1 = (const float*)d_in[26];
  const float* skb1 = (const float*)d_in[27];
  const float* rw1  = (const float*)d_in[30];
  const float* rb1  = (const float*)d_in[31];
  const float* rw2  = (const float*)d_in[32];
  const float* rb2  = (const float*)d_in[33];
  const int* srcI = eidx;
  const int* dstI = eidx + cE;

  // ---- workspace layout ----
  char* W = (char*)d_ws;
  size_t off = 0;
  auto A8 = [&](size_t bytes) { size_t r = off; off = (off + bytes + 255) & ~(size_t)255; return r; };
  const size_t oH0 = A8((size_t)cR * 160 * 2);   // res, bf16
  const size_t oHh = A8((size_t)cR * 160 * 2);   // chain h; G1 [cR,192] = Hh + PK head
  const size_t oPK = A8((size_t)cR * 480 * 2);   // pack [z|z|x], 94.5 MB (scores/r1/yb alias)
  const size_t oSx = A8((size_t)cR * 160 * 2);   // cascade out -> hT -> x1T -> block1 last
  const size_t oDd = A8((size_t)cR * 160 * 2);   // bf16 accumulator
  const size_t oAdj = A8((size_t)cN * cN * 2);
  const size_t oOut = A8((size_t)cB * cN * cFF * 2);       // bf16 skip acc (t=11)
  const size_t oZero = A8(6 * 2048 * 4 + 2 * 192 * 4);
  const size_t oRowf = A8(2049 * 4), oRowb = A8(2049 * 4);
  const size_t oColf = A8((size_t)cE * 4), oColb = A8((size_t)cE * 4);
  const size_t oWnf  = A8((size_t)cE * 4), oWnb  = A8((size_t)cE * 4);
  const size_t oScSh = A8(2 * 192 * 4);
  const size_t oWT   = A8((size_t)600000 * 2);   // bf16 weights
  const size_t oSeb  = A8((size_t)cN * cHID * 2);
  const size_t oTeb  = A8((size_t)cN * cHID * 2);
  const size_t oW23  = A8(192 * 192 * 4);
  const size_t oW123 = A8(192 * 192 * 4);
  const size_t oWskp = A8(192 * 256 * 4);
  const size_t oBt0  = A8(cT * 160 * 4);
  const size_t oBt11 = A8(192 * 4);
  const size_t oBsk1 = A8(256 * 4);
  const size_t oBsum = A8(160 * 4);
  if (off > ws_size) {
    fill_f32<<<(int)((outN + 255) / 256), 256, 0, stream>>>(outF, outN, 300.f);
    return;
  }

  u16 *H0 = (u16*)(W + oH0), *Hh = (u16*)(W + oHh), *PK = (u16*)(W + oPK),
      *Sx = (u16*)(W + oSx), *Dd = (u16*)(W + oDd), *adjb = (u16*)(W + oAdj);
  u16 *G1 = Hh;                          // [cR,192] over Hh + PK head (post-BN only)
  float* scores = (float*)PK;            // phase-0 alias (16.8 MB)
  u16 *r1b = PK + 16L * 1024 * 1024;     // readout alias (PK dead then)
  u16 *ybB = PK + 28L * 1024 * 1024;
  u16 *outB = (u16*)(W + oOut);
  float* zero = (float*)(W + oZero);
  float *degf = zero, *degb = zero + 2048;
  int *cntf = (int*)(zero + 4096), *cntb = cntf + 2048,
      *curf = cntb + 2048, *curb = curf + 2048;
  float* stat = (float*)(curb + 2048);
  int *rowf = (int*)(W + oRowf), *rowb = (int*)(W + oRowb);
  int *colf = (int*)(W + oColf), *colb = (int*)(W + oColb);
  float *wnf = (float*)(W + oWnf), *wnb = (float*)(W + oWnb);
  float* scsh = (float*)(W + oScSh);
  u16* wt = (u16*)(W + oWT);
  u16 *wt123_0 = wt,               *wsk1pT = wt123_0 + 25600,
      *W1pk = wsk1pT + 49152,      *W2pk = W1pk + 76800,
      *wsk0 = W2pk + 76800,        *wr1 = wsk0 + 40960,
      *wr2 = wr1 + 131072;
  u16 *seb = (u16*)(W + oSeb), *teb = (u16*)(W + oTeb);
  float *W23 = (float*)(W + oW23), *W123 = (float*)(W + oW123), *Wskp = (float*)(W + oWskp);
  float *Bt0 = (float*)(W + oBt0), *Bt11 = (float*)(W + oBt11), *Bsk1 = (float*)(W + oBsk1);
  float *Bsum = (float*)(W + oBsum);

  // big-M GEMMs: WM=2 (256-row tile, 512 threads)
  auto g5u = [&](const u16* Aq, const u16* Bq, u16* Cq, const float* bias,
                 int M, int N, int K, int lda, int ldbt, int ldc,
                 long bA, long bB, long bC, int batch, int flags, int bpt = 0) {
    dim3 g(M / 256, (N + 159) / 160, batch);
    gemm_mfma<2, 5, u16><<<g, 512, 0, stream>>>(Aq, Bq, Cq, bias, M, N, K, lda, ldbt, ldc, bA, bB, bC, flags, bpt);
  };
  // small-M GEMMs: WM=1 (128-row tile, 256 threads)
  auto g4f = [&](const u16* Aq, const u16* Bq, float* Cq, const float* bias,
                 int M, int N, int K, int lda, int ldbt, int ldc,
                 long bA, long bB, long bC, int batch, int flags) {
    dim3 g(M / 128, (N + 127) / 128, batch);
    gemm_mfma<1, 4, float><<<g, 256, 0, stream>>>(Aq, Bq, Cq, bias, M, N, K, lda, ldbt, ldc, bA, bB, bC, flags, 0);
  };
  auto g4u = [&](const u16* Aq, const u16* Bq, u16* Cq, const float* bias,
                 int M, int N, int K, int lda, int ldbt, int ldc,
                 long bA, long bB, long bC, int batch, int flags) {
    dim3 g(M / 128, (N + 127) / 128, batch);
    gemm_mfma<1, 4, u16><<<g, 256, 0, stream>>>(Aq, Bq, Cq, bias, M, N, K, lda, ldbt, ldc, bA, bB, bC, flags, 0);
  };
  auto wcv = [&](const float* src, u16* dst, int K, int N) {
    wconvT<<<(int)(((long)K * N + 255) / 256), 256, 0, stream>>>(src, dst, K, N);
  };
  auto mms = [&](const float* Aq, const float* Bq, float* Cq, int M, int N, int K) {
    matmul_small<<<(M * N + 255) / 256, 256, 0, stream>>>(Aq, Bq, Cq, M, N, K);
  };

  // ---- phase 0a: composed chain weights ----
  mms(tW0 + 1L * 25600, tW0 + 2L * 25600, W23, 160, 160, 160);
  mms(tW0,              W23,              W123, 160, 160, 160);
  wcv(W123, wt123_0, 160, 160);
  btot_full<<<1, 160, 0, stream>>>(tb0, tb0 + 160, tb0 + 320, W23, tW0 + 2L * 25600, Bt0, 160);
  mms(tW1 + 1L * 36864, tW1 + 2L * 36864, W23, 192, 192, 192);
  mms(tW1,              W23,              W123, 192, 192, 192);
  mms(W123, skw1, Wskp, 192, 256, 192);
  wcv(Wskp, wsk1pT, 192, 256);
  btot_last<<<1, 192, 0, stream>>>(tb1, tb1 + 192, tb1 + 384, W23, tW1 + 2L * 36864, Bt11, 192);
  bias_sk<<<1, 256, 0, stream>>>(Bt11, skw1, skb1, Bsk1);
  vadd2<<<1, 160, 0, stream>>>(dcb0, dsb0, Bsum, 160);

  // ---- phase 0b: weight packs, CSR, encoder, adjacency ----
  wpack_dcds<<<(2 * 160 * 480 + 255) / 256, 256, 0, stream>>>(dcw0, dsw0, W1pk, W2pk);
  {
    const long tot = 160L * 256 + 256L * 512 + 512L * 312;
    wconv_multi<<<(int)((tot + 255) / 256), 256, 0, stream>>>(skw0, wsk0, rw1, wr1, rw2, wr2);
  }
  hipMemsetAsync(zero, 0, 6 * 2048 * 4 + 2 * 192 * 4, stream);
  edge_stats<<<cE / 256, 256, 0, stream>>>(srcI, dstI, ew, degf, degb, cntf, cntb);
  scan2<<<2, 256, 0, stream>>>(cntf, cntb, rowf, rowb);
  fill_csr<<<cE / 256, 256, 0, stream>>>(srcI, dstI, ew, degf, degb, rowf, rowb,
                                         curf, curb, colf, colb, wnf, wnb);
  encoder2<<<cR / cRPB, 256, 0, stream>>>(x, enc_w, enc_b, node_emb, lw0, H0);

  cvt2_f2bf<<<(2 * cN * cHID + 255) / 256, 256, 0, stream>>>(src_emb, seb, tgt_emb, teb, (long)cN * cHID);
  g4f(seb, teb, scores, nullptr, cN, cN, cHID, cHID, cHID, cN, 0, 0, 0, 1, 0);
  relu_softmax_rows<<<cN, 256, 0, stream>>>(scores, adjb);

  const int PROP_GRID = 8 * 6 * cNCH;

  // ---- block 0 (c = 160) ----
  {
    const int c = 160;
    const long NC = (long)cN * c;
    const long PB = (long)cN * 480;      // per-bt pack stride
    const int casGrid = (int)(((long)cB * cN * (c / 8) + 255) / 256);
    // chain: Sx = S^3 H0 ; Hh = Sx @ W123_0 + Bt0[t]
    cascade3_full<<<casGrid, 256, 0, stream>>>(H0, Sx, c);
    g5u(Sx, wt123_0, Hh, Bt0, cR, c, c, c, c, c, 0, 0, 0, 1, FLAG_BIAS, /*bpt=*/1);
    // skip (t=11) -> bf16 outB
    g4u(Hh + 11L * NC, wsk0, outB, skb0, cN, cFF, c, c, c, cFF,
        (long)cT * NC, 0, (long)cN * cFF, cB, FLAG_BIAS);
    // hT -> Sx
    dim3 tg(cN / 64, (c + 63) / 64, cBT);
    transpose_bf16<<<tg, 256, 0, stream>>>(Hh, c, Sx, cN, c, NC, NC);
    // pack1 = [z1 | z2 | x1]
    prop_gather_bt<<<PROP_GRID, 256, 0, stream>>>(Hh, 160, PK, 480, rowf, colf, wnf);
    prop_gather_bt<<<PROP_GRID, 256, 0, stream>>>(PK, 480, PK + 160, 480, rowf, colf, wnf);
    g5u(adjb, Sx, PK + 320, nullptr, cN, c, cN, cN, cN, 480, 0, NC, PB, cBT, 0);   // x1
    // GEMM1: Dd = pack1 @ W1 + (dcb0+dsb0)
    g5u(PK, W1pk, Dd, Bsum, cR, c, 480, 480, 480, c, 0, 0, 0, 1, FLAG_BIAS);
    // x1T -> Sx (hT dead)
    transpose_bf16<<<tg, 256, 0, stream>>>(PK + 320, 480, Sx, cN, c, PB, NC);
    // pack2 = [z3 | z4 | x2]
    prop_gather_bt<<<PROP_GRID, 256, 0, stream>>>(Hh, 160, PK, 480, rowb, colb, wnb);
    prop_gather_bt<<<PROP_GRID, 256, 0, stream>>>(PK, 480, PK + 160, 480, rowb, colb, wnb);
    g5u(adjb, Sx, PK + 320, nullptr, cN, c, cN, cN, cN, 480, 0, NC, PB, cBT, 0);   // x2
    // GEMM2: Dd += pack2 @ W2
    g5u(PK, W2pk, Dd, nullptr, cR, c, 480, 480, 480, c, 0, 0, 0, 1, FLAG_ACC);
    // BN(Dd + H0) -> G1 (stride 192) + lw1
    bn_stats<<<512, c, 0, stream>>>(Dd, H0, stat, c);
    bn_finalize<<<1, c, 0, stream>>>(stat, ng0, nb0, scsh, c);
    bn_apply_concat<<<cR / 8, 192, 0, stream>>>(Dd, H0, scsh, lw1, G1);
  }

  // ---- block 1 (c = 192): composed chain+skip, only t=11 survives ----
  {
    const int c = 192;
    const int casGrid = (int)(((long)cB * cN * (c / 8) + 255) / 256);
    cascade3_last<<<casGrid, 256, 0, stream>>>(G1, Sx, c);
    g4u(Sx, wsk1pT, outB, Bsk1, cB * cN, cFF, c, c, c, cFF,
        0, 0, 0, 1, FLAG_BIAS | FLAG_ACC | FLAG_RELU);
  }

  // ---- readout (all bf16) ----
  g4u(outB, wr1, r1b, rb1, cB * cN, 2 * cFF, cFF, cFF, cFF, 2 * cFF,
      0, 0, 0, 1, FLAG_BIAS | FLAG_RELU);
  g4u(r1b, wr2, ybB, rb2, cB * cN, cHOR * cF, 2 * cFF, 2 * cFF, 2 * cFF, cHOR * cF,
      0, 0, 0, 1, FLAG_BIAS);
  final_transpose<<<(cB * cHOR * cN * cF) / 256, 256, 0, stream>>>(ybB, outF);
}